// Round 8
// baseline (760.182 us; speedup 1.0000x reference)
//
#include <hip/hip_runtime.h>
#include <hip/hip_fp16.h>
#include <math.h>
#include <stdint.h>

#define H 64
#define ED 16
#define CO 16
#define WGRID 2048
#define NWAVES (WGRID * 4)
static constexpr float EPSV = 1e-5f;
static constexpr float LOG2E = 1.44269504f;

typedef _Float16 h2v __attribute__((ext_vector_type(2)));

// sigmoid with pre-scaled (log2e-folded) argument: 1/(1+2^-z)
__device__ __forceinline__ float sigm2(float z) {
    return __builtin_amdgcn_rcpf(1.0f + __builtin_amdgcn_exp2f(-z));
}

__device__ __forceinline__ h2v as_h2(int x) { union { int i; h2v h; } u; u.i = x; return u.h; }

__device__ __forceinline__ int pack2(float a, float b) {
    __half2 h = __floats2half2_rn(a, b);
    return *reinterpret_cast<int*>(&h);
}

// ---------------- prep: packed-f16 gate weights (log2e-folded gate path), self-loop consts, zero stats --
__global__ void k_prep(const float* __restrict__ We1, const float* __restrict__ be1, const float* __restrict__ Wg1,
                       const float* __restrict__ We2, const float* __restrict__ be2, const float* __restrict__ Wg2,
                       float* __restrict__ ws) {
    int j = threadIdx.x;  // 0..63
    for (int l = 0; l < 2; ++l) {
        const float* We = l ? We2 : We1;
        const float* be = l ? be2 : be1;
        const float* Wg = l ? Wg2 : Wg1;
        int* wth = (int*)(ws + (l ? 1024 : 0));
        int* wgh = (int*)(ws + (l ? 1536 : 512));
        float* ets = ws + 2048 + l * 192;
        float* vs  = ws + 2112 + l * 192;
        float* dv  = ws + 2176 + l * 192;
        float wt[ED], wg[ED];
        float et = be[j];
        for (int k = 0; k < ED; ++k) { wt[k] = We[k * H + j]; et += wt[k]; }
        ets[j] = et;                                   // ea_t for self-loop (ea = ones)
        float d = 0.f;
        for (int m = 0; m < H; ++m) d += be[m] * Wg[(H + m) * H + j];
        float vsum = d;
        for (int k = 0; k < ED; ++k) {
            float acc = 0.f;
            for (int m = 0; m < H; ++m) acc += We[k * H + m] * Wg[(H + m) * H + j];
            wg[k] = acc;                               // (We @ Wg_bot)^T
            vsum += acc;
        }
        dv[j] = d * LOG2E;
        vs[j] = vsum * LOG2E;
        for (int q = 0; q < 8; ++q) {
            wth[j * 8 + q] = pack2(wt[2 * q], wt[2 * q + 1]);
            wgh[j * 8 + q] = pack2(wg[2 * q] * LOG2E, wg[2 * q + 1] * LOG2E);
        }
    }
    for (int s = 0; s < 8; ++s) ws[2432 + s * 64 + j] = 0.f;  // zero all stats
}

// ---------------- x -> f16 ----------------
__global__ void k_xh(const float* __restrict__ x, __half* __restrict__ xh, int total4) {
    int i = blockIdx.x * blockDim.x + threadIdx.x;
    if (i >= total4) return;
    float4 v = *reinterpret_cast<const float4*>(x + (size_t)i * 4);
    __half2 h0 = __floats2half2_rn(v.x, v.y), h1 = __floats2half2_rn(v.z, v.w);
    uint2 o;
    o.x = *reinterpret_cast<unsigned*>(&h0);
    o.y = *reinterpret_cast<unsigned*>(&h1);
    *reinterpret_cast<uint2*>(xh + (size_t)i * 4) = o;
}

// ---------------- CSR build ----------------
__global__ void k_count(const int* __restrict__ cols, int* __restrict__ cnt, int E) {
    int e = blockIdx.x * blockDim.x + threadIdx.x;
    if (e < E) atomicAdd(&cnt[cols[e]], 1);
}

__global__ __launch_bounds__(1024) void k_scan1(const int* __restrict__ cnt, int* __restrict__ bs, int N) {
    __shared__ int ls[1024];
    int t = threadIdx.x;
    int i = blockIdx.x * 1024 + t;
    ls[t] = (i < N) ? cnt[i] : 0;
    __syncthreads();
    for (int off = 512; off > 0; off >>= 1) {
        if (t < off) ls[t] += ls[t + off];
        __syncthreads();
    }
    if (t == 0) bs[blockIdx.x] = ls[0];
}

__global__ __launch_bounds__(1024) void k_scan2(int* __restrict__ bs, int SB) {
    __shared__ int ls[1024];
    int t = threadIdx.x;
    int v = (t < SB) ? bs[t] : 0;
    ls[t] = v;
    __syncthreads();
    for (int off = 1; off < 1024; off <<= 1) {
        int x = (t >= off) ? ls[t - off] : 0;
        __syncthreads();
        ls[t] += x;
        __syncthreads();
    }
    if (t < SB) bs[t] = ls[t] - v;  // exclusive
}

__global__ __launch_bounds__(1024) void k_scan3(const int* __restrict__ cnt, const int* __restrict__ bs,
                                                int* __restrict__ rowptr, int N, int E) {
    __shared__ int ls[1024];
    int t = threadIdx.x;
    int i = blockIdx.x * 1024 + t;
    int v = (i < N) ? cnt[i] : 0;
    ls[t] = v;
    __syncthreads();
    for (int off = 1; off < 1024; off <<= 1) {
        int x = (t >= off) ? ls[t - off] : 0;
        __syncthreads();
        ls[t] += x;
        __syncthreads();
    }
    if (i < N) rowptr[i] = bs[blockIdx.x] + ls[t] - v;  // exclusive prefix
    if (i == 0) rowptr[N] = E;
}

// ---------------- wave ranges ----------------
__global__ void k_ranges(const int* __restrict__ rowptr, int* __restrict__ ranges, int N, int E, int nw) {
    int w = blockIdx.x * blockDim.x + threadIdx.x;
    if (w > nw) return;
    if (w == nw) { ranges[nw] = N; return; }
    int t0 = (int)((long)E * w / nw);
    int lo = 0, hi = N;
    while (lo < hi) { int mid = (lo + hi) >> 1; if (rowptr[mid] < t0) lo = mid + 1; else hi = mid; }
    ranges[w] = lo;
}

// ---------------- scatter (light): eid/erow only, random 4B writes (L2-absorbed) ----------------
__global__ void k_scatter(const int* __restrict__ rows, const int* __restrict__ cols,
                          const int* __restrict__ rowptr, int* __restrict__ cur,
                          int* __restrict__ erow, int* __restrict__ eid, int E) {
    int e = blockIdx.x * blockDim.x + threadIdx.x;
    if (e >= E) return;
    int c = cols[e];
    int p = rowptr[c] + atomicAdd(&cur[c], 1);
    erow[p] = rows[e];
    eid[p] = e;
}

// ---------------- permute: sequential p, random full-line ea read, sequential f16 eap write ----------
__global__ void k_permute(const int* __restrict__ eid, const float* __restrict__ ea,
                          __half* __restrict__ eap, int E) {
    int p = blockIdx.x * blockDim.x + threadIdx.x;
    if (p >= E) return;
    int e = eid[p];
    const float4* src = reinterpret_cast<const float4*>(ea + (size_t)e * ED);
    float4 v0 = src[0], v1 = src[1], v2 = src[2], v3 = src[3];
    int hh[8];
    hh[0] = pack2(v0.x, v0.y); hh[1] = pack2(v0.z, v0.w);
    hh[2] = pack2(v1.x, v1.y); hh[3] = pack2(v1.z, v1.w);
    hh[4] = pack2(v2.x, v2.y); hh[5] = pack2(v2.z, v2.w);
    hh[6] = pack2(v3.x, v3.y); hh[7] = pack2(v3.z, v3.w);
    const int4* o = reinterpret_cast<const int4*>(hh);
    int4* dst = reinterpret_cast<int4*>(eap + (size_t)p * ED);
    dst[0] = o[0]; dst[1] = o[1];
}

// ---------------- gather (f16 input): agg[n] = T(x[n]) + sum_in T(x[row]) ----
template <int CIN, bool GN>
__global__ __launch_bounds__(256) void k_gather(const __half* __restrict__ x, const int* __restrict__ rowptr,
                         const int* __restrict__ ranges,
                         const int* __restrict__ erow, float* __restrict__ agg,
                         const float* __restrict__ s1, const float* __restrict__ s2,
                         const float* __restrict__ gng, const float* __restrict__ gnb,
                         const float* __restrict__ gna, float Ninv, int N) {
    int lane = threadIdx.x & 63;
    int w = (blockIdx.x * blockDim.x + threadIdx.x) >> 6;
    float A = 1.f, B = 0.f;
    if (GN) {
        float mu = s1[lane] * Ninv, m2 = s2[lane] * Ninv, a = gna[lane];
        float var = m2 - 2.f * a * mu * mu + a * a * mu * mu;
        A = gng[lane] * rsqrtf(var + EPSV);
        B = gnb[lane] - A * a * mu;
    }
    int n0 = ranges[w], n1 = ranges[w + 1];
    for (int n = n0; n < n1; ++n) {
        int s = rowptr[n], te = rowptr[n + 1];
        if (CIN == 64) {
            float raw = __half2float(x[(size_t)n * 64 + lane]);
            float acc = GN ? fmaxf(fmaf(A, raw, B), 0.f) : raw;
            int i = s;
            for (; i + 7 < te; i += 8) {
                int r0 = erow[i],     r1 = erow[i + 1], r2 = erow[i + 2], r3 = erow[i + 3];
                int r4 = erow[i + 4], r5 = erow[i + 5], r6 = erow[i + 6], r7 = erow[i + 7];
                float x0 = __half2float(x[(size_t)r0 * 64 + lane]);
                float x1 = __half2float(x[(size_t)r1 * 64 + lane]);
                float x2 = __half2float(x[(size_t)r2 * 64 + lane]);
                float x3 = __half2float(x[(size_t)r3 * 64 + lane]);
                float x4 = __half2float(x[(size_t)r4 * 64 + lane]);
                float x5 = __half2float(x[(size_t)r5 * 64 + lane]);
                float x6 = __half2float(x[(size_t)r6 * 64 + lane]);
                float x7 = __half2float(x[(size_t)r7 * 64 + lane]);
                if (GN) {
                    x0 = fmaxf(fmaf(A, x0, B), 0.f); x1 = fmaxf(fmaf(A, x1, B), 0.f);
                    x2 = fmaxf(fmaf(A, x2, B), 0.f); x3 = fmaxf(fmaf(A, x3, B), 0.f);
                    x4 = fmaxf(fmaf(A, x4, B), 0.f); x5 = fmaxf(fmaf(A, x5, B), 0.f);
                    x6 = fmaxf(fmaf(A, x6, B), 0.f); x7 = fmaxf(fmaf(A, x7, B), 0.f);
                }
                acc += ((x0 + x1) + (x2 + x3)) + ((x4 + x5) + (x6 + x7));
            }
            for (; i < te; ++i) {
                float xv = __half2float(x[(size_t)erow[i] * 64 + lane]);
                if (GN) xv = fmaxf(fmaf(A, xv, B), 0.f);
                acc += xv;
            }
            agg[(size_t)n * H + lane] = acc;
        } else {
            int c = lane & 31, half = lane >> 5;
            float acc = half ? 0.f : __half2float(x[(size_t)n * 32 + c]);
            int i = s + half;
            for (; i + 6 < te; i += 8) {
                int r0 = erow[i], r1 = erow[i + 2], r2 = erow[i + 4], r3 = erow[i + 6];
                float x0 = __half2float(x[(size_t)r0 * 32 + c]);
                float x1 = __half2float(x[(size_t)r1 * 32 + c]);
                float x2 = __half2float(x[(size_t)r2 * 32 + c]);
                float x3 = __half2float(x[(size_t)r3 * 32 + c]);
                acc += (x0 + x1) + (x2 + x3);
            }
            for (; i < te; i += 2) acc += __half2float(x[(size_t)erow[i] * 32 + c]);
            acc += __shfl_xor(acc, 32);
            if (half == 0) agg[(size_t)n * H + c] = acc;
        }
    }
}

// ---------------- fused GEMM: pre = (agg/deg)@Wl + T(x)@Wr + bl ; u = (pre@Wg_top + bg)*log2e ----------
// pre/u written as f16.
#define MT4A(mq, aval) \
    acc[mq][0] = fmaf(aval, w1.x, acc[mq][0]); acc[mq][1] = fmaf(aval, w1.y, acc[mq][1]); \
    acc[mq][2] = fmaf(aval, w1.z, acc[mq][2]); acc[mq][3] = fmaf(aval, w1.w, acc[mq][3]);
#define MT4X(mq, aval) \
    acc[mq][0] = fmaf(aval, w2.x, acc[mq][0]); acc[mq][1] = fmaf(aval, w2.y, acc[mq][1]); \
    acc[mq][2] = fmaf(aval, w2.z, acc[mq][2]); acc[mq][3] = fmaf(aval, w2.w, acc[mq][3]);

template <int K, bool GN>
__global__ __launch_bounds__(256) void k_gemmfu(
        const float* __restrict__ A,               // agg, stride 64
        const __half* __restrict__ A2, int lda2,   // x-side (f16)
        const float* __restrict__ W1, const float* __restrict__ W2,
        const float* __restrict__ bias,
        const float* __restrict__ Wg, const float* __restrict__ bg,
        const float* __restrict__ s1, const float* __restrict__ s2,
        const float* __restrict__ gng, const float* __restrict__ gnb,
        const float* __restrict__ gna, float Ninv,
        const int* __restrict__ rowptr,
        __half* __restrict__ pre, __half* __restrict__ uout, int N) {
    __shared__ float WA[64 * 64];
    __shared__ float WB[K * 64];
    __shared__ float big[64][68];
    __shared__ float As[64], Bs[64], invd[64];
    int tid = threadIdx.x;
    for (int idx = tid; idx < K * 64; idx += 256) { WA[idx] = W1[idx]; WB[idx] = W2[idx]; }
    int nb = blockIdx.x * 64;
    if (tid < 64) {
        if (GN) {
            float mu = s1[tid] * Ninv, m2 = s2[tid] * Ninv, a = gna[tid];
            float var = m2 - 2.f * a * mu * mu + a * a * mu * mu;
            float Av = gng[tid] * rsqrtf(var + EPSV);
            As[tid] = Av; Bs[tid] = gnb[tid] - Av * a * mu;
        }
        int n = nb + tid;
        invd[tid] = (n < N) ? 1.f / (float)(rowptr[n + 1] - rowptr[n] + 1) : 0.f;
    }
    __syncthreads();
    int tm = tid >> 4, tn = tid & 15;
    int m0 = tm * 4, j0 = tn * 4;
    float acc[4][4];
#pragma unroll
    for (int jq = 0; jq < 4; ++jq) {
        float b = bias[j0 + jq];
#pragma unroll
        for (int mq = 0; mq < 4; ++mq) acc[mq][jq] = b;
    }
    int sn = tid >> 2, kq4 = (tid & 3) * 4;
    int sg = nb + sn;
    for (int k0 = 0; k0 < K; k0 += 16) {
        if (k0) __syncthreads();
        if (sg < N) {
            float4 av = *reinterpret_cast<const float4*>(A + (size_t)sg * 64 + k0 + kq4);
            float sc = invd[sn];
            av.x *= sc; av.y *= sc; av.z *= sc; av.w *= sc;
            big[kq4 + 0][sn] = av.x; big[kq4 + 1][sn] = av.y;
            big[kq4 + 2][sn] = av.z; big[kq4 + 3][sn] = av.w;
            uint2 hv = *reinterpret_cast<const uint2*>(A2 + (size_t)sg * lda2 + k0 + kq4);
            __half2 h01 = *reinterpret_cast<__half2*>(&hv.x);
            __half2 h23 = *reinterpret_cast<__half2*>(&hv.y);
            float2 f01 = __half22float2(h01), f23 = __half22float2(h23);
            float xv0 = f01.x, xv1 = f01.y, xv2 = f23.x, xv3 = f23.y;
            if (GN) {
                xv0 = fmaxf(fmaf(As[k0 + kq4 + 0], xv0, Bs[k0 + kq4 + 0]), 0.f);
                xv1 = fmaxf(fmaf(As[k0 + kq4 + 1], xv1, Bs[k0 + kq4 + 1]), 0.f);
                xv2 = fmaxf(fmaf(As[k0 + kq4 + 2], xv2, Bs[k0 + kq4 + 2]), 0.f);
                xv3 = fmaxf(fmaf(As[k0 + kq4 + 3], xv3, Bs[k0 + kq4 + 3]), 0.f);
            }
            big[16 + kq4 + 0][sn] = xv0; big[16 + kq4 + 1][sn] = xv1;
            big[16 + kq4 + 2][sn] = xv2; big[16 + kq4 + 3][sn] = xv3;
        } else {
#pragma unroll
            for (int q = 0; q < 4; ++q) { big[kq4 + q][sn] = 0.f; big[16 + kq4 + q][sn] = 0.f; }
        }
        __syncthreads();
#pragma unroll
        for (int k = 0; k < 16; ++k) {
            float4 am = *reinterpret_cast<const float4*>(&big[k][m0]);
            float4 w1 = *reinterpret_cast<const float4*>(&WA[(k0 + k) * 64 + j0]);
            MT4A(0, am.x) MT4A(1, am.y) MT4A(2, am.z) MT4A(3, am.w)
            float4 xm = *reinterpret_cast<const float4*>(&big[16 + k][m0]);
            float4 w2 = *reinterpret_cast<const float4*>(&WB[(k0 + k) * 64 + j0]);
            MT4X(0, xm.x) MT4X(1, xm.y) MT4X(2, xm.z) MT4X(3, xm.w)
        }
    }
    __syncthreads();
    // write pre (f16) + stash transposed (big[k][m] = pre[m][k])
#pragma unroll
    for (int mq = 0; mq < 4; ++mq) {
        int n = nb + m0 + mq;
        if (n < N) {
            uint2 o;
            o.x = pack2(acc[mq][0], acc[mq][1]);
            o.y = pack2(acc[mq][2], acc[mq][3]);
            *reinterpret_cast<uint2*>(pre + (size_t)n * 64 + j0) = o;
        }
#pragma unroll
        for (int jq = 0; jq < 4; ++jq) big[j0 + jq][m0 + mq] = acc[mq][jq];
    }
    for (int idx = tid; idx < 4096; idx += 256) WA[idx] = Wg[idx] * LOG2E;
    __syncthreads();
    float acc2[4][4];
#pragma unroll
    for (int jq = 0; jq < 4; ++jq) {
        float b = bg[j0 + jq] * LOG2E;
#pragma unroll
        for (int mq = 0; mq < 4; ++mq) acc2[mq][jq] = b;
    }
#pragma unroll 8
    for (int k = 0; k < 64; ++k) {
        float4 pm = *reinterpret_cast<const float4*>(&big[k][m0]);
        float4 w1 = *reinterpret_cast<const float4*>(&WA[k * 64 + j0]);
        acc2[0][0] = fmaf(pm.x, w1.x, acc2[0][0]); acc2[0][1] = fmaf(pm.x, w1.y, acc2[0][1]);
        acc2[0][2] = fmaf(pm.x, w1.z, acc2[0][2]); acc2[0][3] = fmaf(pm.x, w1.w, acc2[0][3]);
        acc2[1][0] = fmaf(pm.y, w1.x, acc2[1][0]); acc2[1][1] = fmaf(pm.y, w1.y, acc2[1][1]);
        acc2[1][2] = fmaf(pm.y, w1.z, acc2[1][2]); acc2[1][3] = fmaf(pm.y, w1.w, acc2[1][3]);
        acc2[2][0] = fmaf(pm.z, w1.x, acc2[2][0]); acc2[2][1] = fmaf(pm.z, w1.y, acc2[2][1]);
        acc2[2][2] = fmaf(pm.z, w1.z, acc2[2][2]); acc2[2][3] = fmaf(pm.z, w1.w, acc2[2][3]);
        acc2[3][0] = fmaf(pm.w, w1.x, acc2[3][0]); acc2[3][1] = fmaf(pm.w, w1.y, acc2[3][1]);
        acc2[3][2] = fmaf(pm.w, w1.z, acc2[3][2]); acc2[3][3] = fmaf(pm.w, w1.w, acc2[3][3]);
    }
#pragma unroll
    for (int mq = 0; mq < 4; ++mq) {
        int n = nb + m0 + mq;
        if (n < N) {
            uint2 o;
            o.x = pack2(acc2[mq][0], acc2[mq][1]);
            o.y = pack2(acc2[mq][2], acc2[mq][3]);
            *reinterpret_cast<uint2*>(uout + (size_t)n * 64 + j0) = o;
        }
    }
}

// ---------------- gate edge term: 2 dots via v_dot2_f32_f16 ----------
__device__ __forceinline__ float edge_term(const int4& a, const int4& b,
                                           const h2v* wt, const h2v* wg,
                                           float be_l, float dv_l, float u_l) {
    int ua[8] = {a.x, a.y, a.z, a.w, b.x, b.y, b.z, b.w};
    float et = be_l, v = dv_l;
#pragma unroll
    for (int q = 0; q < 8; ++q) {
        h2v e = as_h2(ua[q]);
        et = __builtin_amdgcn_fdot2(e, wt[q], et, false);
        v  = __builtin_amdgcn_fdot2(e, wg[q], v, false);
    }
    return sigm2(u_l + v) * et;
}

// ---------------- gate: LDS-staged edge stream, wave per node-range (f16 u/pre) ----------------
__global__ __launch_bounds__(256) void k_gate(
        const int* __restrict__ rowptr, const int* __restrict__ ranges,
        const __half* __restrict__ eap,
        const int* __restrict__ wth, const int* __restrict__ wgh,
        const float* __restrict__ be, const float* __restrict__ dv,
        const float* __restrict__ ets, const float* __restrict__ vs,
        const __half* __restrict__ u, __half* __restrict__ pre,
        float* __restrict__ s1, float* __restrict__ s2, int N) {
    __shared__ __align__(16) int4 estage[4][128];   // 2KB per wave (64 edges x 32B)
    __shared__ float ls[2][4][H];
    int lane = threadIdx.x & 63;
    int wv = threadIdx.x >> 6;
    int w = (blockIdx.x << 2) | wv;
    h2v wt[8], wg[8];
#pragma unroll
    for (int q = 0; q < 8; ++q) { wt[q] = as_h2(wth[lane * 8 + q]); wg[q] = as_h2(wgh[lane * 8 + q]); }
    float be_l = be[lane], dv_l = dv[lane], ets_l = ets[lane], vs_l = vs[lane];
    int n0 = ranges[w], n1 = ranges[w + 1];
    float s = 0.f, ss = 0.f;
    if (n0 < n1) {
        int4* dst = &estage[wv][0];
        const int4* gsrc = reinterpret_cast<const int4*>(eap);
        int e0 = rowptr[n0], e1 = rowptr[n1];
        int n = n0;
        int nend = rowptr[n0 + 1];
        size_t idx = (size_t)n * H + lane;
        float u_l = __half2float(u[idx]);
        float pv = __half2float(pre[idx]);
        float acc = sigm2(u_l + vs_l) * ets_l;   // folded self-loop contribution
        {   // stage first chunk
            int bytes = min(64, e1 - e0) * 32;
            int4 p0, p1;
            if (lane * 16 < bytes) p0 = gsrc[(size_t)e0 * 2 + lane];
            if (1024 + lane * 16 < bytes) p1 = gsrc[(size_t)e0 * 2 + 64 + lane];
            if (lane * 16 < bytes) dst[lane] = p0;
            if (1024 + lane * 16 < bytes) dst[64 + lane] = p1;
        }
        for (int c = e0; c < e1; c += 64) {
            int cnt = min(64, e1 - c);
            int nbytes = (c + 64 < e1) ? min(64, e1 - c - 64) * 32 : 0;
            int4 p0, p1;
            if (lane * 16 < nbytes) p0 = gsrc[(size_t)(c + 64) * 2 + lane];
            if (1024 + lane * 16 < nbytes) p1 = gsrc[(size_t)(c + 64) * 2 + 64 + lane];
            for (int k = 0; k < cnt; ++k) {
                while (c + k == nend) {       // node boundary: finish n, start next
                    float tval = pv + acc;
                    pre[idx] = __float2half(tval);
                    s += tval; ss += tval * tval;
                    ++n;
                    idx = (size_t)n * H + lane;
                    u_l = __half2float(u[idx]);
                    pv = __half2float(pre[idx]);
                    acc = sigm2(u_l + vs_l) * ets_l;
                    nend = rowptr[n + 1];
                }
                acc += edge_term(dst[k * 2], dst[k * 2 + 1], wt, wg, be_l, dv_l, u_l);
            }
            if (lane * 16 < nbytes) dst[lane] = p0;
            if (1024 + lane * 16 < nbytes) dst[64 + lane] = p1;
        }
        for (;;) {   // finish current + trailing zero-edge nodes
            float tval = pv + acc;
            pre[idx] = __float2half(tval);
            s += tval; ss += tval * tval;
            ++n;
            if (n >= n1) break;
            idx = (size_t)n * H + lane;
            u_l = __half2float(u[idx]);
            pv = __half2float(pre[idx]);
            acc = sigm2(u_l + vs_l) * ets_l;
        }
    }
    ls[0][wv][lane] = s; ls[1][wv][lane] = ss;
    __syncthreads();
    if (threadIdx.x < H) {
        float a = ls[0][0][lane] + ls[0][1][lane] + ls[0][2][lane] + ls[0][3][lane];
        float b = ls[1][0][lane] + ls[1][1][lane] + ls[1][2][lane] + ls[1][3][lane];
        atomicAdd(&s1[lane], a);
        atomicAdd(&s2[lane], b);
    }
}

// ---------------- apply: h = relu(2*bn(t)) -> f16 + GraphNorm stats ----------------
__global__ void k_apply(const __half* __restrict__ in, __half* __restrict__ outb,
                        const float* __restrict__ bng, const float* __restrict__ bnb,
                        const float* __restrict__ s1b, const float* __restrict__ s2b,
                        float* __restrict__ s1g, float* __restrict__ s2g, float Ninv, int N) {
    int j = threadIdx.x, ty = threadIdx.y;
    __shared__ float As[H], Bs[H];
    if (ty == 0) {
        float mu = s1b[j] * Ninv, var = s2b[j] * Ninv - mu * mu;
        float r = rsqrtf(var + EPSV);
        float A = 2.f * bng[j] * r;
        As[j] = A; Bs[j] = 2.f * (bnb[j] - bng[j] * r * mu);
    }
    __syncthreads();
    float A = As[j], B = Bs[j];
    float s = 0.f, ss = 0.f;
    for (int n = blockIdx.x * 4 + ty; n < N; n += gridDim.x * 4) {
        size_t idx = (size_t)n * H + j;
        float v = fmaxf(fmaf(A, __half2float(in[idx]), B), 0.f);
        outb[idx] = __float2half(v);
        s += v; ss += v * v;
    }
    __shared__ float ls[2][4][H];
    ls[0][ty][j] = s; ls[1][ty][j] = ss;
    __syncthreads();
    if (ty == 0) {
        float a = ls[0][0][j] + ls[0][1][j] + ls[0][2][j] + ls[0][3][j];
        float b = ls[1][0][j] + ls[1][1][j] + ls[1][2][j] + ls[1][3][j];
        atomicAdd(&s1g[j], a);
        atomicAdd(&s2g[j], b);
    }
}

// ---------------- final: out = relu(gn2(h)) @ lin_W + lin_b ----------------
__global__ __launch_bounds__(256) void k_final(const __half* __restrict__ hraw, const float* __restrict__ W,
                        const float* __restrict__ bias,
                        const float* __restrict__ s1, const float* __restrict__ s2,
                        const float* __restrict__ gng, const float* __restrict__ gnb,
                        const float* __restrict__ gna, float Ninv,
                        float* __restrict__ outp, int N) {
    __shared__ float As[H], Bs[H];
    if (threadIdx.x < H) {
        int j = threadIdx.x;
        float mu = s1[j] * Ninv, m2 = s2[j] * Ninv, a = gna[j];
        float var = m2 - 2.f * a * mu * mu + a * a * mu * mu;
        float A = gng[j] * rsqrtf(var + EPSV);
        As[j] = A; Bs[j] = gnb[j] - A * a * mu;
    }
    __syncthreads();
    int n = blockIdx.x * blockDim.x + threadIdx.x;
    if (n >= N) return;
    float o[CO];
#pragma unroll
    for (int t = 0; t < CO; ++t) o[t] = bias[t];
    const __half* hr = hraw + (size_t)n * H;
    for (int m4 = 0; m4 < H / 4; ++m4) {
        uint2 hv = *reinterpret_cast<const uint2*>(hr + m4 * 4);
        __half2 h01 = *reinterpret_cast<__half2*>(&hv.x);
        __half2 h23 = *reinterpret_cast<__half2*>(&hv.y);
        float2 f01 = __half22float2(h01), f23 = __half22float2(h23);
        float hx = fmaxf(fmaf(As[m4*4+0], f01.x, Bs[m4*4+0]), 0.f);
        float hy = fmaxf(fmaf(As[m4*4+1], f01.y, Bs[m4*4+1]), 0.f);
        float hz = fmaxf(fmaf(As[m4*4+2], f23.x, Bs[m4*4+2]), 0.f);
        float hw = fmaxf(fmaf(As[m4*4+3], f23.y, Bs[m4*4+3]), 0.f);
#pragma unroll
        for (int t = 0; t < CO; ++t) {
            o[t] += hx * W[(m4*4+0) * CO + t];
            o[t] += hy * W[(m4*4+1) * CO + t];
            o[t] += hz * W[(m4*4+2) * CO + t];
            o[t] += hw * W[(m4*4+3) * CO + t];
        }
    }
    float* orow = outp + (size_t)n * CO;
#pragma unroll
    for (int t4 = 0; t4 < CO / 4; ++t4)
        reinterpret_cast<float4*>(orow)[t4] = make_float4(o[t4*4+0], o[t4*4+1], o[t4*4+2], o[t4*4+3]);
}

extern "C" void kernel_launch(void* const* d_in, const int* in_sizes, int n_in,
                              void* d_out, int out_size, void* d_ws, size_t ws_size,
                              hipStream_t stream) {
    const float* x     = (const float*)d_in[0];
    const int*   ei    = (const int*)d_in[1];
    const float* ea    = (const float*)d_in[2];
    const float* l1_Wl = (const float*)d_in[3];  const float* l1_bl = (const float*)d_in[4];
    const float* l1_Wr = (const float*)d_in[5];  const float* l1_We = (const float*)d_in[6];
    const float* l1_be = (const float*)d_in[7];  const float* l1_Wg = (const float*)d_in[8];
    const float* l1_bg = (const float*)d_in[9];  const float* l1_bng= (const float*)d_in[10];
    const float* l1_bnb= (const float*)d_in[11];
    const float* l2_Wl = (const float*)d_in[12]; const float* l2_bl = (const float*)d_in[13];
    const float* l2_Wr = (const float*)d_in[14]; const float* l2_We = (const float*)d_in[15];
    const float* l2_be = (const float*)d_in[16]; const float* l2_Wg = (const float*)d_in[17];
    const float* l2_bg = (const float*)d_in[18]; const float* l2_bng= (const float*)d_in[19];
    const float* l2_bnb= (const float*)d_in[20];
    const float* gn1_g = (const float*)d_in[21]; const float* gn1_b = (const float*)d_in[22];
    const float* gn1_a = (const float*)d_in[23];
    const float* gn2_g = (const float*)d_in[24]; const float* gn2_b = (const float*)d_in[25];
    const float* gn2_a = (const float*)d_in[26];
    const float* lin_W = (const float*)d_in[27]; const float* lin_b = (const float*)d_in[28];

    const int N = in_sizes[0] / 32;
    const int E = in_sizes[1] / 2;
    const int* rows = ei;
    const int* cols = ei + E;

    float* w    = (float*)d_ws;
    int* wth1   = (int*)w;
    int* wgh1   = (int*)(w + 512);
    int* wth2   = (int*)(w + 1024);
    int* wgh2   = (int*)(w + 1536);
    float* ets1 = w + 2048; float* vs1 = w + 2112; float* dv1 = w + 2176;
    float* ets2 = w + 2240; float* vs2 = w + 2304; float* dv2 = w + 2368;
    float* stats= w + 2432;

    int* ip     = (int*)(w + 8192);
    int* rowptr = ip;                 // N+1
    int* cnt    = ip + (N + 1);       // N
    int* cur    = cnt + N;            // N (contiguous with cnt for one memset)
    int* bs     = cur + N;            // scan block sums
    int* ranges = bs + 1024;          // NWAVES+1
    int* erow   = ranges + (NWAVES + 2);  // E
    int* eid    = erow + E;           // E

    uintptr_t pa = (uintptr_t)(eid + E);
    pa = (pa + 255) & ~(uintptr_t)255;
    __half* eap = (__half*)pa;        // E*16 halves
    uintptr_t pb = (uintptr_t)(eap + (size_t)E * ED);
    pb = (pb + 255) & ~(uintptr_t)255;
    float* B0 = (float*)pb;           // agg (fp32, N*64)
    size_t NB = (size_t)N * H;
    __half* Bpre = (__half*)(B0 + NB);       // pre/t (f16, N*64)
    __half* Bu   = Bpre + NB;                // u (f16, N*64)
    __half* xh   = Bu + NB;                  // x f16 (N*32)
    __half* B3h  = xh + (size_t)N * 32;      // h layer1 (f16, N*64)
    __half* B0h  = (__half*)B0;              // h layer2 reuses B0 space

    const float Ninv = 1.0f / (float)N;
    dim3 rb(64, 4);
    int egrid = (E + 255) / 256;
    int ngrid = (N + 255) / 256;
    int g64 = (N + 63) / 64;
    const int SB = (N + 1023) >> 10;

    k_prep<<<1, 64, 0, stream>>>(l1_We, l1_be, l1_Wg, l2_We, l2_be, l2_Wg, w);
    k_xh<<<(N * 8 + 255) / 256, 256, 0, stream>>>(x, xh, N * 8);

    // ---- CSR build: count -> scan -> light scatter -> sequential permute ----
    hipMemsetAsync(cnt, 0, sizeof(int) * 2 * (size_t)N, stream);
    k_count<<<egrid, 256, 0, stream>>>(cols, cnt, E);
    k_scan1<<<SB, 1024, 0, stream>>>(cnt, bs, N);
    k_scan2<<<1, 1024, 0, stream>>>(bs, SB);
    k_scan3<<<SB, 1024, 0, stream>>>(cnt, bs, rowptr, N, E);
    k_ranges<<<(NWAVES + 256) / 256, 256, 0, stream>>>(rowptr, ranges, N, E, NWAVES);
    k_scatter<<<egrid, 256, 0, stream>>>(rows, cols, rowptr, cur, erow, eid, E);
    k_permute<<<egrid, 256, 0, stream>>>(eid, ea, eap, E);

    // ---- layer 1 ----
    k_gather<32, false><<<WGRID, 256, 0, stream>>>(xh, rowptr, ranges, erow, B0,
                                                   nullptr, nullptr, nullptr, nullptr, nullptr, 0.f, N);
    k_gemmfu<32, false><<<g64, 256, 0, stream>>>(B0, xh, 32, l1_Wl, l1_Wr, l1_bl, l1_Wg, l1_bg,
                                                 nullptr, nullptr, nullptr, nullptr, nullptr, 0.f,
                                                 rowptr, Bpre, Bu, N);
    k_gate<<<WGRID, 256, 0, stream>>>(rowptr, ranges, eap, wth1, wgh1, l1_be, dv1, ets1, vs1,
                                      Bu, Bpre, stats + 0, stats + 64, N);
    k_apply<<<256, rb, 0, stream>>>(Bpre, B3h, l1_bng, l1_bnb, stats + 0, stats + 64,
                                    stats + 128, stats + 192, Ninv, N);

    // ---- layer 2 (gn1 folded into readers of B3h) ----
    k_gather<64, true><<<WGRID, 256, 0, stream>>>(B3h, rowptr, ranges, erow, B0,
                                                  stats + 128, stats + 192, gn1_g, gn1_b, gn1_a, Ninv, N);
    k_gemmfu<64, true><<<g64, 256, 0, stream>>>(B0, B3h, 64, l2_Wl, l2_Wr, l2_bl, l2_Wg, l2_bg,
                                                stats + 128, stats + 192, gn1_g, gn1_b, gn1_a, Ninv,
                                                rowptr, Bpre, Bu, N);
    k_gate<<<WGRID, 256, 0, stream>>>(rowptr, ranges, eap, wth2, wgh2, l2_be, dv2, ets2, vs2,
                                      Bu, Bpre, stats + 256, stats + 320, N);
    k_apply<<<256, rb, 0, stream>>>(Bpre, B0h, l2_bng, l2_bnb, stats + 256, stats + 320,
                                    stats + 384, stats + 448, Ninv, N);

    // ---- final ----
    k_final<<<ngrid, 256, 0, stream>>>(B0h, lin_W, lin_b, stats + 384, stats + 448,
                                       gn2_g, gn2_b, gn2_a, Ninv, (float*)d_out, N);
}

// Round 9
// 719.143 us; speedup vs baseline: 1.0571x; 1.0571x over previous
//
#include <hip/hip_runtime.h>
#include <hip/hip_fp16.h>
#include <math.h>
#include <stdint.h>

#define H 64
#define ED 16
#define CO 16
#define WGRID 2048
#define NWAVES (WGRID * 4)
#define CPART 2048
static constexpr float EPSV = 1e-5f;
static constexpr float LOG2E = 1.44269504f;

typedef _Float16 h2v __attribute__((ext_vector_type(2)));

__device__ __forceinline__ float sigm2(float z) {
    return __builtin_amdgcn_rcpf(1.0f + __builtin_amdgcn_exp2f(-z));
}

__device__ __forceinline__ h2v as_h2(int x) { union { int i; h2v h; } u; u.i = x; return u.h; }

__device__ __forceinline__ int pack2(float a, float b) {
    __half2 h = __floats2half2_rn(a, b);
    return *reinterpret_cast<int*>(&h);
}

// ---------------- prep: packed-f16 gate weights (log2e-folded gate path), self-loop consts, zero stats --
__global__ void k_prep(const float* __restrict__ We1, const float* __restrict__ be1, const float* __restrict__ Wg1,
                       const float* __restrict__ We2, const float* __restrict__ be2, const float* __restrict__ Wg2,
                       float* __restrict__ ws) {
    int j = threadIdx.x;  // 0..63
    for (int l = 0; l < 2; ++l) {
        const float* We = l ? We2 : We1;
        const float* be = l ? be2 : be1;
        const float* Wg = l ? Wg2 : Wg1;
        int* wth = (int*)(ws + (l ? 1024 : 0));
        int* wgh = (int*)(ws + (l ? 1536 : 512));
        float* ets = ws + 2048 + l * 192;
        float* vs  = ws + 2112 + l * 192;
        float* dv  = ws + 2176 + l * 192;
        float wt[ED], wg[ED];
        float et = be[j];
        for (int k = 0; k < ED; ++k) { wt[k] = We[k * H + j]; et += wt[k]; }
        ets[j] = et;                                   // ea_t for self-loop (ea = ones)
        float d = 0.f;
        for (int m = 0; m < H; ++m) d += be[m] * Wg[(H + m) * H + j];
        float vsum = d;
        for (int k = 0; k < ED; ++k) {
            float acc = 0.f;
            for (int m = 0; m < H; ++m) acc += We[k * H + m] * Wg[(H + m) * H + j];
            wg[k] = acc;                               // (We @ Wg_bot)^T
            vsum += acc;
        }
        dv[j] = d * LOG2E;
        vs[j] = vsum * LOG2E;
        for (int q = 0; q < 8; ++q) {
            wth[j * 8 + q] = pack2(wt[2 * q], wt[2 * q + 1]);
            wgh[j * 8 + q] = pack2(wg[2 * q] * LOG2E, wg[2 * q + 1] * LOG2E);
        }
    }
    for (int s = 0; s < 8; ++s) ws[2432 + s * 64 + j] = 0.f;  // zero all stats
}

// ---------------- x -> f16 ----------------
__global__ void k_xh(const float* __restrict__ x, __half* __restrict__ xh, int total4) {
    int i = blockIdx.x * blockDim.x + threadIdx.x;
    if (i >= total4) return;
    float4 v = *reinterpret_cast<const float4*>(x + (size_t)i * 4);
    __half2 h0 = __floats2half2_rn(v.x, v.y), h1 = __floats2half2_rn(v.z, v.w);
    uint2 o;
    o.x = *reinterpret_cast<unsigned*>(&h0);
    o.y = *reinterpret_cast<unsigned*>(&h1);
    *reinterpret_cast<uint2*>(xh + (size_t)i * 4) = o;
}

// ---------------- CSR build: count + scan ----------------
__global__ void k_count(const int* __restrict__ cols, int* __restrict__ cnt, int E) {
    int e = blockIdx.x * blockDim.x + threadIdx.x;
    if (e < E) atomicAdd(&cnt[cols[e]], 1);
}

__global__ __launch_bounds__(1024) void k_scan1(const int* __restrict__ cnt, int* __restrict__ bs, int N) {
    __shared__ int ls[1024];
    int t = threadIdx.x;
    int i = blockIdx.x * 1024 + t;
    ls[t] = (i < N) ? cnt[i] : 0;
    __syncthreads();
    for (int off = 512; off > 0; off >>= 1) {
        if (t < off) ls[t] += ls[t + off];
        __syncthreads();
    }
    if (t == 0) bs[blockIdx.x] = ls[0];
}

__global__ __launch_bounds__(1024) void k_scan2(int* __restrict__ bs, int SB) {
    __shared__ int ls[1024];
    int t = threadIdx.x;
    int v = (t < SB) ? bs[t] : 0;
    ls[t] = v;
    __syncthreads();
    for (int off = 1; off < 1024; off <<= 1) {
        int x = (t >= off) ? ls[t - off] : 0;
        __syncthreads();
        ls[t] += x;
        __syncthreads();
    }
    if (t < SB) bs[t] = ls[t] - v;  // exclusive
}

__global__ __launch_bounds__(1024) void k_scan3(const int* __restrict__ cnt, const int* __restrict__ bs,
                                                int* __restrict__ rowptr, int N, int E) {
    __shared__ int ls[1024];
    int t = threadIdx.x;
    int i = blockIdx.x * 1024 + t;
    int v = (i < N) ? cnt[i] : 0;
    ls[t] = v;
    __syncthreads();
    for (int off = 1; off < 1024; off <<= 1) {
        int x = (t >= off) ? ls[t - off] : 0;
        __syncthreads();
        ls[t] += x;
        __syncthreads();
    }
    if (i < N) rowptr[i] = bs[blockIdx.x] + ls[t] - v;  // exclusive prefix
    if (i == 0) rowptr[N] = E;
}

// ---------------- wave ranges ----------------
__global__ void k_ranges(const int* __restrict__ rowptr, int* __restrict__ ranges, int N, int E, int nw) {
    int w = blockIdx.x * blockDim.x + threadIdx.x;
    if (w > nw) return;
    if (w == nw) { ranges[nw] = N; return; }
    int t0 = (int)((long)E * w / nw);
    int lo = 0, hi = N;
    while (lo < hi) { int mid = (lo + hi) >> 1; if (rowptr[mid] < t0) lo = mid + 1; else hi = mid; }
    ranges[w] = lo;
}

// ---------------- partition pass 1: block-local bucket sort, fully coalesced writes ----------------
// bucket = col >> SH. Each block: histogram -> scan -> LDS-sort -> sequential write of its tmp region.
__global__ __launch_bounds__(256) void k_part(const int* __restrict__ rows, const int* __restrict__ cols,
                                              int2* __restrict__ tmp, int* __restrict__ offtab,
                                              int E, int NB, int SH) {
    __shared__ int hist[1025];
    __shared__ int pscan[256];
    __shared__ int2 stage[CPART];
    int tid = threadIdx.x;
    int base = blockIdx.x * CPART;
    int cnt = min(CPART, E - base);
    for (int i = tid; i <= NB; i += 256) hist[i] = 0;
    __syncthreads();
    int myc[8], myr[8];
#pragma unroll
    for (int q = 0; q < 8; ++q) {
        int li = q * 256 + tid;
        if (li < cnt) {
            int e = base + li;
            myc[q] = cols[e];
            myr[q] = rows[e];
            atomicAdd(&hist[myc[q] >> SH], 1);
        } else myc[q] = -1;
    }
    __syncthreads();
    // exclusive scan of hist[0..NB)
    int h[4], s = 0;
    int b0 = tid * 4;
#pragma unroll
    for (int k = 0; k < 4; ++k) { h[k] = (b0 + k < NB) ? hist[b0 + k] : 0; s += h[k]; }
    pscan[tid] = s;
    __syncthreads();
    for (int off = 1; off < 256; off <<= 1) {
        int v = (tid >= off) ? pscan[tid - off] : 0;
        __syncthreads();
        pscan[tid] += v;
        __syncthreads();
    }
    int excl = pscan[tid] - s;
    __syncthreads();
    int run = excl;
#pragma unroll
    for (int k = 0; k < 4; ++k) {
        if (b0 + k < NB) hist[b0 + k] = run;
        run += h[k];
    }
    __syncthreads();
    // write per-block bucket offsets (coalesced)
    int* ot = offtab + (size_t)blockIdx.x * (NB + 1);
    for (int i = tid; i < NB; i += 256) ot[i] = hist[i];
    if (tid == 0) ot[NB] = cnt;
    __syncthreads();
    // slot allocation + LDS staging
    int mask = (1 << SH) - 1;
#pragma unroll
    for (int q = 0; q < 8; ++q) {
        if (myc[q] >= 0) {
            int b = myc[q] >> SH;
            int p = atomicAdd(&hist[b], 1);
            int e = base + q * 256 + tid;
            stage[p] = make_int2(myr[q], (e << SH) | (myc[q] & mask));
        }
    }
    __syncthreads();
    int2* dst = tmp + base;
    for (int i = tid; i < cnt; i += 256) dst[i] = stage[i];
}

// ---------------- build pass 2: per-bucket exact CSR scatter (LDS cursors, L2-local writes) ----------
__global__ __launch_bounds__(256) void k_build(const int* __restrict__ rowptr, const int2* __restrict__ tmp,
                                               const int* __restrict__ offtab, const float* __restrict__ ea,
                                               int* __restrict__ erow, __half* __restrict__ eap,
                                               int N, int NB, int SH, int PB) {
    __shared__ int lcur[1024];
    int tid = threadIdx.x;
    int b = blockIdx.x;
    int NPB = 1 << SH;
    int nodelo = b << SH;
    for (int j = tid; j < NPB; j += 256) {
        int n = nodelo + j;
        lcur[j] = (n < N) ? rowptr[n] : 0;
    }
    __syncthreads();
    int mask = NPB - 1;
    for (int i = tid; i < PB; i += 256) {
        const int* ot = offtab + (size_t)i * (NB + 1);
        int j0 = ot[b], j1 = ot[b + 1];
        for (int j = j0; j < j1; ++j) {
            int2 v = tmp[(size_t)i * CPART + j];
            int e = (int)(((unsigned)v.y) >> SH);
            int cl = v.y & mask;
            int p = atomicAdd(&lcur[cl], 1);
            erow[p] = v.x;
            const float4* src = reinterpret_cast<const float4*>(ea + (size_t)e * ED);
            float4 v0 = src[0], v1 = src[1], v2 = src[2], v3 = src[3];
            int hh[8];
            hh[0] = pack2(v0.x, v0.y); hh[1] = pack2(v0.z, v0.w);
            hh[2] = pack2(v1.x, v1.y); hh[3] = pack2(v1.z, v1.w);
            hh[4] = pack2(v2.x, v2.y); hh[5] = pack2(v2.z, v2.w);
            hh[6] = pack2(v3.x, v3.y); hh[7] = pack2(v3.z, v3.w);
            const int4* o = reinterpret_cast<const int4*>(hh);
            int4* d = reinterpret_cast<int4*>(eap + (size_t)p * ED);
            d[0] = o[0]; d[1] = o[1];
        }
    }
}

// ---------------- gather (f16 input): agg[n] = T(x[n]) + sum_in T(x[row]) ----
template <int CIN, bool GN>
__global__ __launch_bounds__(256) void k_gather(const __half* __restrict__ x, const int* __restrict__ rowptr,
                         const int* __restrict__ ranges,
                         const int* __restrict__ erow, float* __restrict__ agg,
                         const float* __restrict__ s1, const float* __restrict__ s2,
                         const float* __restrict__ gng, const float* __restrict__ gnb,
                         const float* __restrict__ gna, float Ninv, int N) {
    int lane = threadIdx.x & 63;
    int w = (blockIdx.x * blockDim.x + threadIdx.x) >> 6;
    float A = 1.f, B = 0.f;
    if (GN) {
        float mu = s1[lane] * Ninv, m2 = s2[lane] * Ninv, a = gna[lane];
        float var = m2 - 2.f * a * mu * mu + a * a * mu * mu;
        A = gng[lane] * rsqrtf(var + EPSV);
        B = gnb[lane] - A * a * mu;
    }
    int n0 = ranges[w], n1 = ranges[w + 1];
    for (int n = n0; n < n1; ++n) {
        int s = rowptr[n], te = rowptr[n + 1];
        if (CIN == 64) {
            float raw = __half2float(x[(size_t)n * 64 + lane]);
            float acc = GN ? fmaxf(fmaf(A, raw, B), 0.f) : raw;
            int i = s;
            for (; i + 7 < te; i += 8) {
                int r0 = erow[i],     r1 = erow[i + 1], r2 = erow[i + 2], r3 = erow[i + 3];
                int r4 = erow[i + 4], r5 = erow[i + 5], r6 = erow[i + 6], r7 = erow[i + 7];
                float x0 = __half2float(x[(size_t)r0 * 64 + lane]);
                float x1 = __half2float(x[(size_t)r1 * 64 + lane]);
                float x2 = __half2float(x[(size_t)r2 * 64 + lane]);
                float x3 = __half2float(x[(size_t)r3 * 64 + lane]);
                float x4 = __half2float(x[(size_t)r4 * 64 + lane]);
                float x5 = __half2float(x[(size_t)r5 * 64 + lane]);
                float x6 = __half2float(x[(size_t)r6 * 64 + lane]);
                float x7 = __half2float(x[(size_t)r7 * 64 + lane]);
                if (GN) {
                    x0 = fmaxf(fmaf(A, x0, B), 0.f); x1 = fmaxf(fmaf(A, x1, B), 0.f);
                    x2 = fmaxf(fmaf(A, x2, B), 0.f); x3 = fmaxf(fmaf(A, x3, B), 0.f);
                    x4 = fmaxf(fmaf(A, x4, B), 0.f); x5 = fmaxf(fmaf(A, x5, B), 0.f);
                    x6 = fmaxf(fmaf(A, x6, B), 0.f); x7 = fmaxf(fmaf(A, x7, B), 0.f);
                }
                acc += ((x0 + x1) + (x2 + x3)) + ((x4 + x5) + (x6 + x7));
            }
            for (; i < te; ++i) {
                float xv = __half2float(x[(size_t)erow[i] * 64 + lane]);
                if (GN) xv = fmaxf(fmaf(A, xv, B), 0.f);
                acc += xv;
            }
            agg[(size_t)n * H + lane] = acc;
        } else {
            int c = lane & 31, half = lane >> 5;
            float acc = half ? 0.f : __half2float(x[(size_t)n * 32 + c]);
            int i = s + half;
            for (; i + 6 < te; i += 8) {
                int r0 = erow[i], r1 = erow[i + 2], r2 = erow[i + 4], r3 = erow[i + 6];
                float x0 = __half2float(x[(size_t)r0 * 32 + c]);
                float x1 = __half2float(x[(size_t)r1 * 32 + c]);
                float x2 = __half2float(x[(size_t)r2 * 32 + c]);
                float x3 = __half2float(x[(size_t)r3 * 32 + c]);
                acc += (x0 + x1) + (x2 + x3);
            }
            for (; i < te; i += 2) acc += __half2float(x[(size_t)erow[i] * 32 + c]);
            acc += __shfl_xor(acc, 32);
            if (half == 0) agg[(size_t)n * H + c] = acc;
        }
    }
}

// ---------------- fused GEMM: pre = (agg/deg)@Wl + T(x)@Wr + bl ; u = (pre@Wg_top + bg)*log2e ----------
#define MT4A(mq, aval) \
    acc[mq][0] = fmaf(aval, w1.x, acc[mq][0]); acc[mq][1] = fmaf(aval, w1.y, acc[mq][1]); \
    acc[mq][2] = fmaf(aval, w1.z, acc[mq][2]); acc[mq][3] = fmaf(aval, w1.w, acc[mq][3]);
#define MT4X(mq, aval) \
    acc[mq][0] = fmaf(aval, w2.x, acc[mq][0]); acc[mq][1] = fmaf(aval, w2.y, acc[mq][1]); \
    acc[mq][2] = fmaf(aval, w2.z, acc[mq][2]); acc[mq][3] = fmaf(aval, w2.w, acc[mq][3]);

template <int K, bool GN>
__global__ __launch_bounds__(256) void k_gemmfu(
        const float* __restrict__ A,               // agg, stride 64
        const __half* __restrict__ A2, int lda2,   // x-side (f16)
        const float* __restrict__ W1, const float* __restrict__ W2,
        const float* __restrict__ bias,
        const float* __restrict__ Wg, const float* __restrict__ bg,
        const float* __restrict__ s1, const float* __restrict__ s2,
        const float* __restrict__ gng, const float* __restrict__ gnb,
        const float* __restrict__ gna, float Ninv,
        const int* __restrict__ rowptr,
        __half* __restrict__ pre, __half* __restrict__ uout, int N) {
    __shared__ float WA[64 * 64];
    __shared__ float WB[K * 64];
    __shared__ float big[64][68];
    __shared__ float As[64], Bs[64], invd[64];
    int tid = threadIdx.x;
    for (int idx = tid; idx < K * 64; idx += 256) { WA[idx] = W1[idx]; WB[idx] = W2[idx]; }
    int nb = blockIdx.x * 64;
    if (tid < 64) {
        if (GN) {
            float mu = s1[tid] * Ninv, m2 = s2[tid] * Ninv, a = gna[tid];
            float var = m2 - 2.f * a * mu * mu + a * a * mu * mu;
            float Av = gng[tid] * rsqrtf(var + EPSV);
            As[tid] = Av; Bs[tid] = gnb[tid] - Av * a * mu;
        }
        int n = nb + tid;
        invd[tid] = (n < N) ? 1.f / (float)(rowptr[n + 1] - rowptr[n] + 1) : 0.f;
    }
    __syncthreads();
    int tm = tid >> 4, tn = tid & 15;
    int m0 = tm * 4, j0 = tn * 4;
    float acc[4][4];
#pragma unroll
    for (int jq = 0; jq < 4; ++jq) {
        float b = bias[j0 + jq];
#pragma unroll
        for (int mq = 0; mq < 4; ++mq) acc[mq][jq] = b;
    }
    int sn = tid >> 2, kq4 = (tid & 3) * 4;
    int sg = nb + sn;
    for (int k0 = 0; k0 < K; k0 += 16) {
        if (k0) __syncthreads();
        if (sg < N) {
            float4 av = *reinterpret_cast<const float4*>(A + (size_t)sg * 64 + k0 + kq4);
            float sc = invd[sn];
            av.x *= sc; av.y *= sc; av.z *= sc; av.w *= sc;
            big[kq4 + 0][sn] = av.x; big[kq4 + 1][sn] = av.y;
            big[kq4 + 2][sn] = av.z; big[kq4 + 3][sn] = av.w;
            uint2 hv = *reinterpret_cast<const uint2*>(A2 + (size_t)sg * lda2 + k0 + kq4);
            __half2 h01 = *reinterpret_cast<__half2*>(&hv.x);
            __half2 h23 = *reinterpret_cast<__half2*>(&hv.y);
            float2 f01 = __half22float2(h01), f23 = __half22float2(h23);
            float xv0 = f01.x, xv1 = f01.y, xv2 = f23.x, xv3 = f23.y;
            if (GN) {
                xv0 = fmaxf(fmaf(As[k0 + kq4 + 0], xv0, Bs[k0 + kq4 + 0]), 0.f);
                xv1 = fmaxf(fmaf(As[k0 + kq4 + 1], xv1, Bs[k0 + kq4 + 1]), 0.f);
                xv2 = fmaxf(fmaf(As[k0 + kq4 + 2], xv2, Bs[k0 + kq4 + 2]), 0.f);
                xv3 = fmaxf(fmaf(As[k0 + kq4 + 3], xv3, Bs[k0 + kq4 + 3]), 0.f);
            }
            big[16 + kq4 + 0][sn] = xv0; big[16 + kq4 + 1][sn] = xv1;
            big[16 + kq4 + 2][sn] = xv2; big[16 + kq4 + 3][sn] = xv3;
        } else {
#pragma unroll
            for (int q = 0; q < 4; ++q) { big[kq4 + q][sn] = 0.f; big[16 + kq4 + q][sn] = 0.f; }
        }
        __syncthreads();
#pragma unroll
        for (int k = 0; k < 16; ++k) {
            float4 am = *reinterpret_cast<const float4*>(&big[k][m0]);
            float4 w1 = *reinterpret_cast<const float4*>(&WA[(k0 + k) * 64 + j0]);
            MT4A(0, am.x) MT4A(1, am.y) MT4A(2, am.z) MT4A(3, am.w)
            float4 xm = *reinterpret_cast<const float4*>(&big[16 + k][m0]);
            float4 w2 = *reinterpret_cast<const float4*>(&WB[(k0 + k) * 64 + j0]);
            MT4X(0, xm.x) MT4X(1, xm.y) MT4X(2, xm.z) MT4X(3, xm.w)
        }
    }
    __syncthreads();
#pragma unroll
    for (int mq = 0; mq < 4; ++mq) {
        int n = nb + m0 + mq;
        if (n < N) {
            uint2 o;
            o.x = pack2(acc[mq][0], acc[mq][1]);
            o.y = pack2(acc[mq][2], acc[mq][3]);
            *reinterpret_cast<uint2*>(pre + (size_t)n * 64 + j0) = o;
        }
#pragma unroll
        for (int jq = 0; jq < 4; ++jq) big[j0 + jq][m0 + mq] = acc[mq][jq];
    }
    for (int idx = tid; idx < 4096; idx += 256) WA[idx] = Wg[idx] * LOG2E;
    __syncthreads();
    float acc2[4][4];
#pragma unroll
    for (int jq = 0; jq < 4; ++jq) {
        float b = bg[j0 + jq] * LOG2E;
#pragma unroll
        for (int mq = 0; mq < 4; ++mq) acc2[mq][jq] = b;
    }
#pragma unroll 8
    for (int k = 0; k < 64; ++k) {
        float4 pm = *reinterpret_cast<const float4*>(&big[k][m0]);
        float4 w1 = *reinterpret_cast<const float4*>(&WA[k * 64 + j0]);
        acc2[0][0] = fmaf(pm.x, w1.x, acc2[0][0]); acc2[0][1] = fmaf(pm.x, w1.y, acc2[0][1]);
        acc2[0][2] = fmaf(pm.x, w1.z, acc2[0][2]); acc2[0][3] = fmaf(pm.x, w1.w, acc2[0][3]);
        acc2[1][0] = fmaf(pm.y, w1.x, acc2[1][0]); acc2[1][1] = fmaf(pm.y, w1.y, acc2[1][1]);
        acc2[1][2] = fmaf(pm.y, w1.z, acc2[1][2]); acc2[1][3] = fmaf(pm.y, w1.w, acc2[1][3]);
        acc2[2][0] = fmaf(pm.z, w1.x, acc2[2][0]); acc2[2][1] = fmaf(pm.z, w1.y, acc2[2][1]);
        acc2[2][2] = fmaf(pm.z, w1.z, acc2[2][2]); acc2[2][3] = fmaf(pm.z, w1.w, acc2[2][3]);
        acc2[3][0] = fmaf(pm.w, w1.x, acc2[3][0]); acc2[3][1] = fmaf(pm.w, w1.y, acc2[3][1]);
        acc2[3][2] = fmaf(pm.w, w1.z, acc2[3][2]); acc2[3][3] = fmaf(pm.w, w1.w, acc2[3][3]);
    }
#pragma unroll
    for (int mq = 0; mq < 4; ++mq) {
        int n = nb + m0 + mq;
        if (n < N) {
            uint2 o;
            o.x = pack2(acc2[mq][0], acc2[mq][1]);
            o.y = pack2(acc2[mq][2], acc2[mq][3]);
            *reinterpret_cast<uint2*>(uout + (size_t)n * 64 + j0) = o;
        }
    }
}

// ---------------- gate edge term: 2 dots via v_dot2_f32_f16 ----------
__device__ __forceinline__ float edge_term(const int4& a, const int4& b,
                                           const h2v* wt, const h2v* wg,
                                           float be_l, float dv_l, float u_l) {
    int ua[8] = {a.x, a.y, a.z, a.w, b.x, b.y, b.z, b.w};
    float et = be_l, v = dv_l;
#pragma unroll
    for (int q = 0; q < 8; ++q) {
        h2v e = as_h2(ua[q]);
        et = __builtin_amdgcn_fdot2(e, wt[q], et, false);
        v  = __builtin_amdgcn_fdot2(e, wg[q], v, false);
    }
    return sigm2(u_l + v) * et;
}

// ---------------- gate: LDS-staged edge stream, wave per node-range (f16 u/pre) ----------------
__global__ __launch_bounds__(256) void k_gate(
        const int* __restrict__ rowptr, const int* __restrict__ ranges,
        const __half* __restrict__ eap,
        const int* __restrict__ wth, const int* __restrict__ wgh,
        const float* __restrict__ be, const float* __restrict__ dv,
        const float* __restrict__ ets, const float* __restrict__ vs,
        const __half* __restrict__ u, __half* __restrict__ pre,
        float* __restrict__ s1, float* __restrict__ s2, int N) {
    __shared__ __align__(16) int4 estage[4][128];   // 2KB per wave (64 edges x 32B)
    __shared__ float ls[2][4][H];
    int lane = threadIdx.x & 63;
    int wv = threadIdx.x >> 6;
    int w = (blockIdx.x << 2) | wv;
    h2v wt[8], wg[8];
#pragma unroll
    for (int q = 0; q < 8; ++q) { wt[q] = as_h2(wth[lane * 8 + q]); wg[q] = as_h2(wgh[lane * 8 + q]); }
    float be_l = be[lane], dv_l = dv[lane], ets_l = ets[lane], vs_l = vs[lane];
    int n0 = ranges[w], n1 = ranges[w + 1];
    float s = 0.f, ss = 0.f;
    if (n0 < n1) {
        int4* dst = &estage[wv][0];
        const int4* gsrc = reinterpret_cast<const int4*>(eap);
        int e0 = rowptr[n0], e1 = rowptr[n1];
        int n = n0;
        int nend = rowptr[n0 + 1];
        size_t idx = (size_t)n * H + lane;
        float u_l = __half2float(u[idx]);
        float pv = __half2float(pre[idx]);
        float acc = sigm2(u_l + vs_l) * ets_l;   // folded self-loop contribution
        {   // stage first chunk
            int bytes = min(64, e1 - e0) * 32;
            int4 p0, p1;
            if (lane * 16 < bytes) p0 = gsrc[(size_t)e0 * 2 + lane];
            if (1024 + lane * 16 < bytes) p1 = gsrc[(size_t)e0 * 2 + 64 + lane];
            if (lane * 16 < bytes) dst[lane] = p0;
            if (1024 + lane * 16 < bytes) dst[64 + lane] = p1;
        }
        for (int c = e0; c < e1; c += 64) {
            int cnt = min(64, e1 - c);
            int nbytes = (c + 64 < e1) ? min(64, e1 - c - 64) * 32 : 0;
            int4 p0, p1;
            if (lane * 16 < nbytes) p0 = gsrc[(size_t)(c + 64) * 2 + lane];
            if (1024 + lane * 16 < nbytes) p1 = gsrc[(size_t)(c + 64) * 2 + 64 + lane];
            for (int k = 0; k < cnt; ++k) {
                while (c + k == nend) {       // node boundary: finish n, start next
                    float tval = pv + acc;
                    pre[idx] = __float2half(tval);
                    s += tval; ss += tval * tval;
                    ++n;
                    idx = (size_t)n * H + lane;
                    u_l = __half2float(u[idx]);
                    pv = __half2float(pre[idx]);
                    acc = sigm2(u_l + vs_l) * ets_l;
                    nend = rowptr[n + 1];
                }
                acc += edge_term(dst[k * 2], dst[k * 2 + 1], wt, wg, be_l, dv_l, u_l);
            }
            if (lane * 16 < nbytes) dst[lane] = p0;
            if (1024 + lane * 16 < nbytes) dst[64 + lane] = p1;
        }
        for (;;) {   // finish current + trailing zero-edge nodes
            float tval = pv + acc;
            pre[idx] = __float2half(tval);
            s += tval; ss += tval * tval;
            ++n;
            if (n >= n1) break;
            idx = (size_t)n * H + lane;
            u_l = __half2float(u[idx]);
            pv = __half2float(pre[idx]);
            acc = sigm2(u_l + vs_l) * ets_l;
        }
    }
    ls[0][wv][lane] = s; ls[1][wv][lane] = ss;
    __syncthreads();
    if (threadIdx.x < H) {
        float a = ls[0][0][lane] + ls[0][1][lane] + ls[0][2][lane] + ls[0][3][lane];
        float b = ls[1][0][lane] + ls[1][1][lane] + ls[1][2][lane] + ls[1][3][lane];
        atomicAdd(&s1[lane], a);
        atomicAdd(&s2[lane], b);
    }
}

// ---------------- apply: h = relu(2*bn(t)) -> f16 + GraphNorm stats ----------------
__global__ void k_apply(const __half* __restrict__ in, __half* __restrict__ outb,
                        const float* __restrict__ bng, const float* __restrict__ bnb,
                        const float* __restrict__ s1b, const float* __restrict__ s2b,
                        float* __restrict__ s1g, float* __restrict__ s2g, float Ninv, int N) {
    int j = threadIdx.x, ty = threadIdx.y;
    __shared__ float As[H], Bs[H];
    if (ty == 0) {
        float mu = s1b[j] * Ninv, var = s2b[j] * Ninv - mu * mu;
        float r = rsqrtf(var + EPSV);
        float A = 2.f * bng[j] * r;
        As[j] = A; Bs[j] = 2.f * (bnb[j] - bng[j] * r * mu);
    }
    __syncthreads();
    float A = As[j], B = Bs[j];
    float s = 0.f, ss = 0.f;
    for (int n = blockIdx.x * 4 + ty; n < N; n += gridDim.x * 4) {
        size_t idx = (size_t)n * H + j;
        float v = fmaxf(fmaf(A, __half2float(in[idx]), B), 0.f);
        outb[idx] = __float2half(v);
        s += v; ss += v * v;
    }
    __shared__ float ls[2][4][H];
    ls[0][ty][j] = s; ls[1][ty][j] = ss;
    __syncthreads();
    if (ty == 0) {
        float a = ls[0][0][j] + ls[0][1][j] + ls[0][2][j] + ls[0][3][j];
        float b = ls[1][0][j] + ls[1][1][j] + ls[1][2][j] + ls[1][3][j];
        atomicAdd(&s1g[j], a);
        atomicAdd(&s2g[j], b);
    }
}

// ---------------- final: out = relu(gn2(h)) @ lin_W + lin_b ----------------
__global__ __launch_bounds__(256) void k_final(const __half* __restrict__ hraw, const float* __restrict__ W,
                        const float* __restrict__ bias,
                        const float* __restrict__ s1, const float* __restrict__ s2,
                        const float* __restrict__ gng, const float* __restrict__ gnb,
                        const float* __restrict__ gna, float Ninv,
                        float* __restrict__ outp, int N) {
    __shared__ float As[H], Bs[H];
    if (threadIdx.x < H) {
        int j = threadIdx.x;
        float mu = s1[j] * Ninv, m2 = s2[j] * Ninv, a = gna[j];
        float var = m2 - 2.f * a * mu * mu + a * a * mu * mu;
        float A = gng[j] * rsqrtf(var + EPSV);
        As[j] = A; Bs[j] = gnb[j] - A * a * mu;
    }
    __syncthreads();
    int n = blockIdx.x * blockDim.x + threadIdx.x;
    if (n >= N) return;
    float o[CO];
#pragma unroll
    for (int t = 0; t < CO; ++t) o[t] = bias[t];
    const __half* hr = hraw + (size_t)n * H;
    for (int m4 = 0; m4 < H / 4; ++m4) {
        uint2 hv = *reinterpret_cast<const uint2*>(hr + m4 * 4);
        __half2 h01 = *reinterpret_cast<__half2*>(&hv.x);
        __half2 h23 = *reinterpret_cast<__half2*>(&hv.y);
        float2 f01 = __half22float2(h01), f23 = __half22float2(h23);
        float hx = fmaxf(fmaf(As[m4*4+0], f01.x, Bs[m4*4+0]), 0.f);
        float hy = fmaxf(fmaf(As[m4*4+1], f01.y, Bs[m4*4+1]), 0.f);
        float hz = fmaxf(fmaf(As[m4*4+2], f23.x, Bs[m4*4+2]), 0.f);
        float hw = fmaxf(fmaf(As[m4*4+3], f23.y, Bs[m4*4+3]), 0.f);
#pragma unroll
        for (int t = 0; t < CO; ++t) {
            o[t] += hx * W[(m4*4+0) * CO + t];
            o[t] += hy * W[(m4*4+1) * CO + t];
            o[t] += hz * W[(m4*4+2) * CO + t];
            o[t] += hw * W[(m4*4+3) * CO + t];
        }
    }
    float* orow = outp + (size_t)n * CO;
#pragma unroll
    for (int t4 = 0; t4 < CO / 4; ++t4)
        reinterpret_cast<float4*>(orow)[t4] = make_float4(o[t4*4+0], o[t4*4+1], o[t4*4+2], o[t4*4+3]);
}

extern "C" void kernel_launch(void* const* d_in, const int* in_sizes, int n_in,
                              void* d_out, int out_size, void* d_ws, size_t ws_size,
                              hipStream_t stream) {
    const float* x     = (const float*)d_in[0];
    const int*   ei    = (const int*)d_in[1];
    const float* ea    = (const float*)d_in[2];
    const float* l1_Wl = (const float*)d_in[3];  const float* l1_bl = (const float*)d_in[4];
    const float* l1_Wr = (const float*)d_in[5];  const float* l1_We = (const float*)d_in[6];
    const float* l1_be = (const float*)d_in[7];  const float* l1_Wg = (const float*)d_in[8];
    const float* l1_bg = (const float*)d_in[9];  const float* l1_bng= (const float*)d_in[10];
    const float* l1_bnb= (const float*)d_in[11];
    const float* l2_Wl = (const float*)d_in[12]; const float* l2_bl = (const float*)d_in[13];
    const float* l2_Wr = (const float*)d_in[14]; const float* l2_We = (const float*)d_in[15];
    const float* l2_be = (const float*)d_in[16]; const float* l2_Wg = (const float*)d_in[17];
    const float* l2_bg = (const float*)d_in[18]; const float* l2_bng= (const float*)d_in[19];
    const float* l2_bnb= (const float*)d_in[20];
    const float* gn1_g = (const float*)d_in[21]; const float* gn1_b = (const float*)d_in[22];
    const float* gn1_a = (const float*)d_in[23];
    const float* gn2_g = (const float*)d_in[24]; const float* gn2_b = (const float*)d_in[25];
    const float* gn2_a = (const float*)d_in[26];
    const float* lin_W = (const float*)d_in[27]; const float* lin_b = (const float*)d_in[28];

    const int N = in_sizes[0] / 32;
    const int E = in_sizes[1] / 2;
    const int* rows = ei;
    const int* cols = ei + E;

    // bucket geometry
    int SH = 7, NPB = 128;
    while (((N + NPB - 1) >> SH) > 1024) { SH++; NPB <<= 1; }
    const int NB = (N + NPB - 1) >> SH;
    const int PB = (E + CPART - 1) / CPART;

    float* w    = (float*)d_ws;
    int* wth1   = (int*)w;
    int* wgh1   = (int*)(w + 512);
    int* wth2   = (int*)(w + 1024);
    int* wgh2   = (int*)(w + 1536);
    float* ets1 = w + 2048; float* vs1 = w + 2112; float* dv1 = w + 2176;
    float* ets2 = w + 2240; float* vs2 = w + 2304; float* dv2 = w + 2368;
    float* stats= w + 2432;

    int* ip     = (int*)(w + 8192);
    int* rowptr = ip;                 // N+1
    int* cnt    = ip + (N + 1);       // N
    int* bs     = cnt + N;            // scan block sums
    int* ranges = bs + 1024;          // NWAVES+1
    int* erow   = ranges + (NWAVES + 2);  // E

    uintptr_t pt = (uintptr_t)(erow + E);
    pt = (pt + 255) & ~(uintptr_t)255;
    int2* tmp = (int2*)pt;            // E (partitioned edges)
    int* offtab = (int*)(tmp + E);    // PB * (NB+1)
    uintptr_t pa = (uintptr_t)(offtab + (size_t)PB * (NB + 1));
    pa = (pa + 255) & ~(uintptr_t)255;
    __half* eap = (__half*)pa;        // E*16 halves (CSR-ordered f16 edge attrs)
    uintptr_t pb = (uintptr_t)(eap + (size_t)E * ED);
    pb = (pb + 255) & ~(uintptr_t)255;
    float* B0 = (float*)pb;           // agg (fp32, N*64)
    size_t NB64 = (size_t)N * H;
    __half* Bpre = (__half*)(B0 + NB64);     // pre/t (f16, N*64)
    __half* Bu   = Bpre + NB64;              // u (f16, N*64)
    __half* xh   = Bu + NB64;                // x f16 (N*32)
    __half* B3h  = xh + (size_t)N * 32;      // h layer1 (f16, N*64)
    __half* B0h  = (__half*)B0;              // h layer2 reuses B0 space

    const float Ninv = 1.0f / (float)N;
    dim3 rb(64, 4);
    int egrid = (E + 255) / 256;
    int ngrid = (N + 255) / 256;
    int g64 = (N + 63) / 64;
    const int SB = (N + 1023) >> 10;

    k_prep<<<1, 64, 0, stream>>>(l1_We, l1_be, l1_Wg, l2_We, l2_be, l2_Wg, w);
    k_xh<<<(N * 8 + 255) / 256, 256, 0, stream>>>(x, xh, N * 8);

    // ---- CSR build: count -> scan -> partition -> per-bucket exact build ----
    hipMemsetAsync(cnt, 0, sizeof(int) * (size_t)N, stream);
    k_count<<<egrid, 256, 0, stream>>>(cols, cnt, E);
    k_scan1<<<SB, 1024, 0, stream>>>(cnt, bs, N);
    k_scan2<<<1, 1024, 0, stream>>>(bs, SB);
    k_scan3<<<SB, 1024, 0, stream>>>(cnt, bs, rowptr, N, E);
    k_ranges<<<(NWAVES + 256) / 256, 256, 0, stream>>>(rowptr, ranges, N, E, NWAVES);
    k_part<<<PB, 256, 0, stream>>>(rows, cols, tmp, offtab, E, NB, SH);
    k_build<<<NB, 256, 0, stream>>>(rowptr, tmp, offtab, ea, erow, eap, N, NB, SH, PB);

    // ---- layer 1 ----
    k_gather<32, false><<<WGRID, 256, 0, stream>>>(xh, rowptr, ranges, erow, B0,
                                                   nullptr, nullptr, nullptr, nullptr, nullptr, 0.f, N);
    k_gemmfu<32, false><<<g64, 256, 0, stream>>>(B0, xh, 32, l1_Wl, l1_Wr, l1_bl, l1_Wg, l1_bg,
                                                 nullptr, nullptr, nullptr, nullptr, nullptr, 0.f,
                                                 rowptr, Bpre, Bu, N);
    k_gate<<<WGRID, 256, 0, stream>>>(rowptr, ranges, eap, wth1, wgh1, l1_be, dv1, ets1, vs1,
                                      Bu, Bpre, stats + 0, stats + 64, N);
    k_apply<<<256, rb, 0, stream>>>(Bpre, B3h, l1_bng, l1_bnb, stats + 0, stats + 64,
                                    stats + 128, stats + 192, Ninv, N);

    // ---- layer 2 (gn1 folded into readers of B3h) ----
    k_gather<64, true><<<WGRID, 256, 0, stream>>>(B3h, rowptr, ranges, erow, B0,
                                                  stats + 128, stats + 192, gn1_g, gn1_b, gn1_a, Ninv, N);
    k_gemmfu<64, true><<<g64, 256, 0, stream>>>(B0, B3h, 64, l2_Wl, l2_Wr, l2_bl, l2_Wg, l2_bg,
                                                stats + 128, stats + 192, gn1_g, gn1_b, gn1_a, Ninv,
                                                rowptr, Bpre, Bu, N);
    k_gate<<<WGRID, 256, 0, stream>>>(rowptr, ranges, eap, wth2, wgh2, l2_be, dv2, ets2, vs2,
                                      Bu, Bpre, stats + 256, stats + 320, N);
    k_apply<<<256, rb, 0, stream>>>(Bpre, B0h, l2_bng, l2_bnb, stats + 256, stats + 320,
                                    stats + 384, stats + 448, Ninv, N);

    // ---- final ----
    k_final<<<ngrid, 256, 0, stream>>>(B0h, lin_W, lin_b, stats + 384, stats + 448,
                                       gn2_g, gn2_b, gn2_a, Ninv, (float*)d_out, N);
}

// Round 10
// 713.000 us; speedup vs baseline: 1.0662x; 1.0086x over previous
//
#include <hip/hip_runtime.h>
#include <hip/hip_fp16.h>
#include <math.h>
#include <stdint.h>

#define H 64
#define ED 16
#define CO 16
#define WGRID 2048
#define NWAVES (WGRID * 4)
#define CPART 2048
static constexpr float EPSV = 1e-5f;
static constexpr float LOG2E = 1.44269504f;

typedef _Float16 h2v __attribute__((ext_vector_type(2)));

__device__ __forceinline__ float sigm2(float z) {
    return __builtin_amdgcn_rcpf(1.0f + __builtin_amdgcn_exp2f(-z));
}

__device__ __forceinline__ h2v as_h2(int x) { union { int i; h2v h; } u; u.i = x; return u.h; }

__device__ __forceinline__ int pack2(float a, float b) {
    __half2 h = __floats2half2_rn(a, b);
    return *reinterpret_cast<int*>(&h);
}

// ---------------- prep: packed-f16 gate weights (log2e-folded gate path), self-loop consts, zero stats --
__global__ void k_prep(const float* __restrict__ We1, const float* __restrict__ be1, const float* __restrict__ Wg1,
                       const float* __restrict__ We2, const float* __restrict__ be2, const float* __restrict__ Wg2,
                       float* __restrict__ ws) {
    int j = threadIdx.x;  // 0..63
    for (int l = 0; l < 2; ++l) {
        const float* We = l ? We2 : We1;
        const float* be = l ? be2 : be1;
        const float* Wg = l ? Wg2 : Wg1;
        int* wth = (int*)(ws + (l ? 1024 : 0));
        int* wgh = (int*)(ws + (l ? 1536 : 512));
        float* ets = ws + 2048 + l * 192;
        float* vs  = ws + 2112 + l * 192;
        float* dv  = ws + 2176 + l * 192;
        float wt[ED], wg[ED];
        float et = be[j];
        for (int k = 0; k < ED; ++k) { wt[k] = We[k * H + j]; et += wt[k]; }
        ets[j] = et;                                   // ea_t for self-loop (ea = ones)
        float d = 0.f;
        for (int m = 0; m < H; ++m) d += be[m] * Wg[(H + m) * H + j];
        float vsum = d;
        for (int k = 0; k < ED; ++k) {
            float acc = 0.f;
            for (int m = 0; m < H; ++m) acc += We[k * H + m] * Wg[(H + m) * H + j];
            wg[k] = acc;                               // (We @ Wg_bot)^T
            vsum += acc;
        }
        dv[j] = d * LOG2E;
        vs[j] = vsum * LOG2E;
        for (int q = 0; q < 8; ++q) {
            wth[j * 8 + q] = pack2(wt[2 * q], wt[2 * q + 1]);
            wgh[j * 8 + q] = pack2(wg[2 * q] * LOG2E, wg[2 * q + 1] * LOG2E);
        }
    }
    for (int s = 0; s < 8; ++s) ws[2432 + s * 64 + j] = 0.f;  // zero all stats
}

// ---------------- x -> f16 ----------------
__global__ void k_xh(const float* __restrict__ x, __half* __restrict__ xh, int total4) {
    int i = blockIdx.x * blockDim.x + threadIdx.x;
    if (i >= total4) return;
    float4 v = *reinterpret_cast<const float4*>(x + (size_t)i * 4);
    __half2 h0 = __floats2half2_rn(v.x, v.y), h1 = __floats2half2_rn(v.z, v.w);
    uint2 o;
    o.x = *reinterpret_cast<unsigned*>(&h0);
    o.y = *reinterpret_cast<unsigned*>(&h1);
    *reinterpret_cast<uint2*>(xh + (size_t)i * 4) = o;
}

// ---------------- ea -> f16 (input order, coalesced) ----------------
__global__ void k_eah(const float* __restrict__ ea, int4* __restrict__ eah, int E) {
    int e = blockIdx.x * blockDim.x + threadIdx.x;
    if (e >= E) return;
    const float4* src = reinterpret_cast<const float4*>(ea + (size_t)e * ED);
    float4 v0 = src[0], v1 = src[1], v2 = src[2], v3 = src[3];
    int hh[8];
    hh[0] = pack2(v0.x, v0.y); hh[1] = pack2(v0.z, v0.w);
    hh[2] = pack2(v1.x, v1.y); hh[3] = pack2(v1.z, v1.w);
    hh[4] = pack2(v2.x, v2.y); hh[5] = pack2(v2.z, v2.w);
    hh[6] = pack2(v3.x, v3.y); hh[7] = pack2(v3.z, v3.w);
    const int4* o = reinterpret_cast<const int4*>(hh);
    eah[(size_t)e * 2 + 0] = o[0];
    eah[(size_t)e * 2 + 1] = o[1];
}

// ---------------- CSR build: count + scan ----------------
__global__ void k_count(const int* __restrict__ cols, int* __restrict__ cnt, int E) {
    int e = blockIdx.x * blockDim.x + threadIdx.x;
    if (e < E) atomicAdd(&cnt[cols[e]], 1);
}

__global__ __launch_bounds__(1024) void k_scan1(const int* __restrict__ cnt, int* __restrict__ bs, int N) {
    __shared__ int ls[1024];
    int t = threadIdx.x;
    int i = blockIdx.x * 1024 + t;
    ls[t] = (i < N) ? cnt[i] : 0;
    __syncthreads();
    for (int off = 512; off > 0; off >>= 1) {
        if (t < off) ls[t] += ls[t + off];
        __syncthreads();
    }
    if (t == 0) bs[blockIdx.x] = ls[0];
}

__global__ __launch_bounds__(1024) void k_scan2(int* __restrict__ bs, int SB) {
    __shared__ int ls[1024];
    int t = threadIdx.x;
    int v = (t < SB) ? bs[t] : 0;
    ls[t] = v;
    __syncthreads();
    for (int off = 1; off < 1024; off <<= 1) {
        int x = (t >= off) ? ls[t - off] : 0;
        __syncthreads();
        ls[t] += x;
        __syncthreads();
    }
    if (t < SB) bs[t] = ls[t] - v;  // exclusive
}

__global__ __launch_bounds__(1024) void k_scan3(const int* __restrict__ cnt, const int* __restrict__ bs,
                                                int* __restrict__ rowptr, int N, int E) {
    __shared__ int ls[1024];
    int t = threadIdx.x;
    int i = blockIdx.x * 1024 + t;
    int v = (i < N) ? cnt[i] : 0;
    ls[t] = v;
    __syncthreads();
    for (int off = 1; off < 1024; off <<= 1) {
        int x = (t >= off) ? ls[t - off] : 0;
        __syncthreads();
        ls[t] += x;
        __syncthreads();
    }
    if (i < N) rowptr[i] = bs[blockIdx.x] + ls[t] - v;  // exclusive prefix
    if (i == 0) rowptr[N] = E;
}

// ---------------- wave ranges ----------------
__global__ void k_ranges(const int* __restrict__ rowptr, int* __restrict__ ranges, int N, int E, int nw) {
    int w = blockIdx.x * blockDim.x + threadIdx.x;
    if (w > nw) return;
    if (w == nw) { ranges[nw] = N; return; }
    int t0 = (int)((long)E * w / nw);
    int lo = 0, hi = N;
    while (lo < hi) { int mid = (lo + hi) >> 1; if (rowptr[mid] < t0) lo = mid + 1; else hi = mid; }
    ranges[w] = lo;
}

// ---------------- partition pass 1: block-local bucket sort, fully coalesced writes ----------------
__global__ __launch_bounds__(256) void k_part(const int* __restrict__ rows, const int* __restrict__ cols,
                                              int2* __restrict__ tmp, int* __restrict__ offtab,
                                              int E, int NB, int SH) {
    __shared__ int hist[1025];
    __shared__ int pscan[256];
    __shared__ int2 stage[CPART];
    int tid = threadIdx.x;
    int base = blockIdx.x * CPART;
    int cnt = min(CPART, E - base);
    for (int i = tid; i <= NB; i += 256) hist[i] = 0;
    __syncthreads();
    int myc[8], myr[8];
#pragma unroll
    for (int q = 0; q < 8; ++q) {
        int li = q * 256 + tid;
        if (li < cnt) {
            int e = base + li;
            myc[q] = cols[e];
            myr[q] = rows[e];
            atomicAdd(&hist[myc[q] >> SH], 1);
        } else myc[q] = -1;
    }
    __syncthreads();
    int h[4], s = 0;
    int b0 = tid * 4;
#pragma unroll
    for (int k = 0; k < 4; ++k) { h[k] = (b0 + k < NB) ? hist[b0 + k] : 0; s += h[k]; }
    pscan[tid] = s;
    __syncthreads();
    for (int off = 1; off < 256; off <<= 1) {
        int v = (tid >= off) ? pscan[tid - off] : 0;
        __syncthreads();
        pscan[tid] += v;
        __syncthreads();
    }
    int excl = pscan[tid] - s;
    __syncthreads();
    int run = excl;
#pragma unroll
    for (int k = 0; k < 4; ++k) {
        if (b0 + k < NB) hist[b0 + k] = run;
        run += h[k];
    }
    __syncthreads();
    int* ot = offtab + (size_t)blockIdx.x * (NB + 1);
    for (int i = tid; i < NB; i += 256) ot[i] = hist[i];
    if (tid == 0) ot[NB] = cnt;
    __syncthreads();
    int mask = (1 << SH) - 1;
#pragma unroll
    for (int q = 0; q < 8; ++q) {
        if (myc[q] >= 0) {
            int b = myc[q] >> SH;
            int p = atomicAdd(&hist[b], 1);
            int e = base + q * 256 + tid;
            stage[p] = make_int2(myr[q], (e << SH) | (myc[q] & mask));
        }
    }
    __syncthreads();
    int2* dst = tmp + base;
    for (int i = tid; i < cnt; i += 256) dst[i] = stage[i];
}

// ---------------- build pass 2: per-bucket exact CSR scatter (f16 source rows, 32B each) ----------
__global__ __launch_bounds__(256) void k_build(const int* __restrict__ rowptr, const int2* __restrict__ tmp,
                                               const int* __restrict__ offtab, const int4* __restrict__ eah,
                                               int* __restrict__ erow, __half* __restrict__ eap,
                                               int N, int NB, int SH, int PB) {
    __shared__ int lcur[1024];
    int tid = threadIdx.x;
    int b = blockIdx.x;
    int NPB = 1 << SH;
    int nodelo = b << SH;
    for (int j = tid; j < NPB; j += 256) {
        int n = nodelo + j;
        lcur[j] = (n < N) ? rowptr[n] : 0;
    }
    __syncthreads();
    int mask = NPB - 1;
    for (int i = tid; i < PB; i += 256) {
        const int* ot = offtab + (size_t)i * (NB + 1);
        int j0 = ot[b], j1 = ot[b + 1];
        for (int j = j0; j < j1; ++j) {
            int2 v = tmp[(size_t)i * CPART + j];
            int e = (int)(((unsigned)v.y) >> SH);
            int cl = v.y & mask;
            int p = atomicAdd(&lcur[cl], 1);
            erow[p] = v.x;
            int4 a0 = eah[(size_t)e * 2 + 0];
            int4 a1 = eah[(size_t)e * 2 + 1];
            int4* d = reinterpret_cast<int4*>(eap + (size_t)p * ED);
            d[0] = a0; d[1] = a1;
        }
    }
}

// ---------------- gather (f16 input): agg[n] = T(x[n]) + sum_in T(x[row]) ----
template <int CIN, bool GN>
__global__ __launch_bounds__(256) void k_gather(const __half* __restrict__ x, const int* __restrict__ rowptr,
                         const int* __restrict__ ranges,
                         const int* __restrict__ erow, float* __restrict__ agg,
                         const float* __restrict__ s1, const float* __restrict__ s2,
                         const float* __restrict__ gng, const float* __restrict__ gnb,
                         const float* __restrict__ gna, float Ninv, int N) {
    int lane = threadIdx.x & 63;
    int w = (blockIdx.x * blockDim.x + threadIdx.x) >> 6;
    float A = 1.f, B = 0.f;
    if (GN) {
        float mu = s1[lane] * Ninv, m2 = s2[lane] * Ninv, a = gna[lane];
        float var = m2 - 2.f * a * mu * mu + a * a * mu * mu;
        A = gng[lane] * rsqrtf(var + EPSV);
        B = gnb[lane] - A * a * mu;
    }
    int n0 = ranges[w], n1 = ranges[w + 1];
    for (int n = n0; n < n1; ++n) {
        int s = rowptr[n], te = rowptr[n + 1];
        if (CIN == 64) {
            float raw = __half2float(x[(size_t)n * 64 + lane]);
            float acc = GN ? fmaxf(fmaf(A, raw, B), 0.f) : raw;
            int i = s;
            for (; i + 7 < te; i += 8) {
                int r0 = erow[i],     r1 = erow[i + 1], r2 = erow[i + 2], r3 = erow[i + 3];
                int r4 = erow[i + 4], r5 = erow[i + 5], r6 = erow[i + 6], r7 = erow[i + 7];
                float x0 = __half2float(x[(size_t)r0 * 64 + lane]);
                float x1 = __half2float(x[(size_t)r1 * 64 + lane]);
                float x2 = __half2float(x[(size_t)r2 * 64 + lane]);
                float x3 = __half2float(x[(size_t)r3 * 64 + lane]);
                float x4 = __half2float(x[(size_t)r4 * 64 + lane]);
                float x5 = __half2float(x[(size_t)r5 * 64 + lane]);
                float x6 = __half2float(x[(size_t)r6 * 64 + lane]);
                float x7 = __half2float(x[(size_t)r7 * 64 + lane]);
                if (GN) {
                    x0 = fmaxf(fmaf(A, x0, B), 0.f); x1 = fmaxf(fmaf(A, x1, B), 0.f);
                    x2 = fmaxf(fmaf(A, x2, B), 0.f); x3 = fmaxf(fmaf(A, x3, B), 0.f);
                    x4 = fmaxf(fmaf(A, x4, B), 0.f); x5 = fmaxf(fmaf(A, x5, B), 0.f);
                    x6 = fmaxf(fmaf(A, x6, B), 0.f); x7 = fmaxf(fmaf(A, x7, B), 0.f);
                }
                acc += ((x0 + x1) + (x2 + x3)) + ((x4 + x5) + (x6 + x7));
            }
            for (; i < te; ++i) {
                float xv = __half2float(x[(size_t)erow[i] * 64 + lane]);
                if (GN) xv = fmaxf(fmaf(A, xv, B), 0.f);
                acc += xv;
            }
            agg[(size_t)n * H + lane] = acc;
        } else {
            int c = lane & 31, half = lane >> 5;
            float acc = half ? 0.f : __half2float(x[(size_t)n * 32 + c]);
            int i = s + half;
            for (; i + 6 < te; i += 8) {
                int r0 = erow[i], r1 = erow[i + 2], r2 = erow[i + 4], r3 = erow[i + 6];
                float x0 = __half2float(x[(size_t)r0 * 32 + c]);
                float x1 = __half2float(x[(size_t)r1 * 32 + c]);
                float x2 = __half2float(x[(size_t)r2 * 32 + c]);
                float x3 = __half2float(x[(size_t)r3 * 32 + c]);
                acc += (x0 + x1) + (x2 + x3);
            }
            for (; i < te; i += 2) acc += __half2float(x[(size_t)erow[i] * 32 + c]);
            acc += __shfl_xor(acc, 32);
            if (half == 0) agg[(size_t)n * H + c] = acc;
        }
    }
}

// ---------------- fused GEMM: pre = (agg/deg)@Wl + T(x)@Wr + bl ; u = (pre@Wg_top + bg)*log2e ----------
#define MT4A(mq, aval) \
    acc[mq][0] = fmaf(aval, w1.x, acc[mq][0]); acc[mq][1] = fmaf(aval, w1.y, acc[mq][1]); \
    acc[mq][2] = fmaf(aval, w1.z, acc[mq][2]); acc[mq][3] = fmaf(aval, w1.w, acc[mq][3]);
#define MT4X(mq, aval) \
    acc[mq][0] = fmaf(aval, w2.x, acc[mq][0]); acc[mq][1] = fmaf(aval, w2.y, acc[mq][1]); \
    acc[mq][2] = fmaf(aval, w2.z, acc[mq][2]); acc[mq][3] = fmaf(aval, w2.w, acc[mq][3]);

template <int K, bool GN>
__global__ __launch_bounds__(256) void k_gemmfu(
        const float* __restrict__ A,               // agg, stride 64
        const __half* __restrict__ A2, int lda2,   // x-side (f16)
        const float* __restrict__ W1, const float* __restrict__ W2,
        const float* __restrict__ bias,
        const float* __restrict__ Wg, const float* __restrict__ bg,
        const float* __restrict__ s1, const float* __restrict__ s2,
        const float* __restrict__ gng, const float* __restrict__ gnb,
        const float* __restrict__ gna, float Ninv,
        const int* __restrict__ rowptr,
        __half* __restrict__ pre, __half* __restrict__ uout, int N) {
    __shared__ float WA[64 * 64];
    __shared__ float WB[K * 64];
    __shared__ float big[64][68];
    __shared__ float As[64], Bs[64], invd[64];
    int tid = threadIdx.x;
    for (int idx = tid; idx < K * 64; idx += 256) { WA[idx] = W1[idx]; WB[idx] = W2[idx]; }
    int nb = blockIdx.x * 64;
    if (tid < 64) {
        if (GN) {
            float mu = s1[tid] * Ninv, m2 = s2[tid] * Ninv, a = gna[tid];
            float var = m2 - 2.f * a * mu * mu + a * a * mu * mu;
            float Av = gng[tid] * rsqrtf(var + EPSV);
            As[tid] = Av; Bs[tid] = gnb[tid] - Av * a * mu;
        }
        int n = nb + tid;
        invd[tid] = (n < N) ? 1.f / (float)(rowptr[n + 1] - rowptr[n] + 1) : 0.f;
    }
    __syncthreads();
    int tm = tid >> 4, tn = tid & 15;
    int m0 = tm * 4, j0 = tn * 4;
    float acc[4][4];
#pragma unroll
    for (int jq = 0; jq < 4; ++jq) {
        float b = bias[j0 + jq];
#pragma unroll
        for (int mq = 0; mq < 4; ++mq) acc[mq][jq] = b;
    }
    int sn = tid >> 2, kq4 = (tid & 3) * 4;
    int sg = nb + sn;
    for (int k0 = 0; k0 < K; k0 += 16) {
        if (k0) __syncthreads();
        if (sg < N) {
            float4 av = *reinterpret_cast<const float4*>(A + (size_t)sg * 64 + k0 + kq4);
            float sc = invd[sn];
            av.x *= sc; av.y *= sc; av.z *= sc; av.w *= sc;
            big[kq4 + 0][sn] = av.x; big[kq4 + 1][sn] = av.y;
            big[kq4 + 2][sn] = av.z; big[kq4 + 3][sn] = av.w;
            uint2 hv = *reinterpret_cast<const uint2*>(A2 + (size_t)sg * lda2 + k0 + kq4);
            __half2 h01 = *reinterpret_cast<__half2*>(&hv.x);
            __half2 h23 = *reinterpret_cast<__half2*>(&hv.y);
            float2 f01 = __half22float2(h01), f23 = __half22float2(h23);
            float xv0 = f01.x, xv1 = f01.y, xv2 = f23.x, xv3 = f23.y;
            if (GN) {
                xv0 = fmaxf(fmaf(As[k0 + kq4 + 0], xv0, Bs[k0 + kq4 + 0]), 0.f);
                xv1 = fmaxf(fmaf(As[k0 + kq4 + 1], xv1, Bs[k0 + kq4 + 1]), 0.f);
                xv2 = fmaxf(fmaf(As[k0 + kq4 + 2], xv2, Bs[k0 + kq4 + 2]), 0.f);
                xv3 = fmaxf(fmaf(As[k0 + kq4 + 3], xv3, Bs[k0 + kq4 + 3]), 0.f);
            }
            big[16 + kq4 + 0][sn] = xv0; big[16 + kq4 + 1][sn] = xv1;
            big[16 + kq4 + 2][sn] = xv2; big[16 + kq4 + 3][sn] = xv3;
        } else {
#pragma unroll
            for (int q = 0; q < 4; ++q) { big[kq4 + q][sn] = 0.f; big[16 + kq4 + q][sn] = 0.f; }
        }
        __syncthreads();
#pragma unroll
        for (int k = 0; k < 16; ++k) {
            float4 am = *reinterpret_cast<const float4*>(&big[k][m0]);
            float4 w1 = *reinterpret_cast<const float4*>(&WA[(k0 + k) * 64 + j0]);
            MT4A(0, am.x) MT4A(1, am.y) MT4A(2, am.z) MT4A(3, am.w)
            float4 xm = *reinterpret_cast<const float4*>(&big[16 + k][m0]);
            float4 w2 = *reinterpret_cast<const float4*>(&WB[(k0 + k) * 64 + j0]);
            MT4X(0, xm.x) MT4X(1, xm.y) MT4X(2, xm.z) MT4X(3, xm.w)
        }
    }
    __syncthreads();
#pragma unroll
    for (int mq = 0; mq < 4; ++mq) {
        int n = nb + m0 + mq;
        if (n < N) {
            uint2 o;
            o.x = pack2(acc[mq][0], acc[mq][1]);
            o.y = pack2(acc[mq][2], acc[mq][3]);
            *reinterpret_cast<uint2*>(pre + (size_t)n * 64 + j0) = o;
        }
#pragma unroll
        for (int jq = 0; jq < 4; ++jq) big[j0 + jq][m0 + mq] = acc[mq][jq];
    }
    for (int idx = tid; idx < 4096; idx += 256) WA[idx] = Wg[idx] * LOG2E;
    __syncthreads();
    float acc2[4][4];
#pragma unroll
    for (int jq = 0; jq < 4; ++jq) {
        float b = bg[j0 + jq] * LOG2E;
#pragma unroll
        for (int mq = 0; mq < 4; ++mq) acc2[mq][jq] = b;
    }
#pragma unroll 8
    for (int k = 0; k < 64; ++k) {
        float4 pm = *reinterpret_cast<const float4*>(&big[k][m0]);
        float4 w1 = *reinterpret_cast<const float4*>(&WA[k * 64 + j0]);
        acc2[0][0] = fmaf(pm.x, w1.x, acc2[0][0]); acc2[0][1] = fmaf(pm.x, w1.y, acc2[0][1]);
        acc2[0][2] = fmaf(pm.x, w1.z, acc2[0][2]); acc2[0][3] = fmaf(pm.x, w1.w, acc2[0][3]);
        acc2[1][0] = fmaf(pm.y, w1.x, acc2[1][0]); acc2[1][1] = fmaf(pm.y, w1.y, acc2[1][1]);
        acc2[1][2] = fmaf(pm.y, w1.z, acc2[1][2]); acc2[1][3] = fmaf(pm.y, w1.w, acc2[1][3]);
        acc2[2][0] = fmaf(pm.z, w1.x, acc2[2][0]); acc2[2][1] = fmaf(pm.z, w1.y, acc2[2][1]);
        acc2[2][2] = fmaf(pm.z, w1.z, acc2[2][2]); acc2[2][3] = fmaf(pm.z, w1.w, acc2[2][3]);
        acc2[3][0] = fmaf(pm.w, w1.x, acc2[3][0]); acc2[3][1] = fmaf(pm.w, w1.y, acc2[3][1]);
        acc2[3][2] = fmaf(pm.w, w1.z, acc2[3][2]); acc2[3][3] = fmaf(pm.w, w1.w, acc2[3][3]);
    }
#pragma unroll
    for (int mq = 0; mq < 4; ++mq) {
        int n = nb + m0 + mq;
        if (n < N) {
            uint2 o;
            o.x = pack2(acc2[mq][0], acc2[mq][1]);
            o.y = pack2(acc2[mq][2], acc2[mq][3]);
            *reinterpret_cast<uint2*>(uout + (size_t)n * 64 + j0) = o;
        }
    }
}

// ---------------- gate edge term: 2 dots via v_dot2_f32_f16 (direct components, no copies) ----------
__device__ __forceinline__ float edge_term(const int4& a, const int4& b,
                                           const h2v* wt, const h2v* wg,
                                           float be_l, float dv_l, float u_l) {
    float et = be_l, v = dv_l;
    et = __builtin_amdgcn_fdot2(as_h2(a.x), wt[0], et, false);
    v  = __builtin_amdgcn_fdot2(as_h2(a.x), wg[0], v,  false);
    et = __builtin_amdgcn_fdot2(as_h2(a.y), wt[1], et, false);
    v  = __builtin_amdgcn_fdot2(as_h2(a.y), wg[1], v,  false);
    et = __builtin_amdgcn_fdot2(as_h2(a.z), wt[2], et, false);
    v  = __builtin_amdgcn_fdot2(as_h2(a.z), wg[2], v,  false);
    et = __builtin_amdgcn_fdot2(as_h2(a.w), wt[3], et, false);
    v  = __builtin_amdgcn_fdot2(as_h2(a.w), wg[3], v,  false);
    et = __builtin_amdgcn_fdot2(as_h2(b.x), wt[4], et, false);
    v  = __builtin_amdgcn_fdot2(as_h2(b.x), wg[4], v,  false);
    et = __builtin_amdgcn_fdot2(as_h2(b.y), wt[5], et, false);
    v  = __builtin_amdgcn_fdot2(as_h2(b.y), wg[5], v,  false);
    et = __builtin_amdgcn_fdot2(as_h2(b.z), wt[6], et, false);
    v  = __builtin_amdgcn_fdot2(as_h2(b.z), wg[6], v,  false);
    et = __builtin_amdgcn_fdot2(as_h2(b.w), wt[7], et, false);
    v  = __builtin_amdgcn_fdot2(as_h2(b.w), wg[7], v,  false);
    return sigm2(u_l + v) * et;
}

// ---------------- gate: LDS-staged edge stream, boundary-free inner runs, next-node prefetch --------
__global__ __launch_bounds__(256) void k_gate(
        const int* __restrict__ rowptr, const int* __restrict__ ranges,
        const __half* __restrict__ eap,
        const int* __restrict__ wth, const int* __restrict__ wgh,
        const float* __restrict__ be, const float* __restrict__ dv,
        const float* __restrict__ ets, const float* __restrict__ vs,
        const __half* __restrict__ u, __half* __restrict__ pre,
        float* __restrict__ s1, float* __restrict__ s2, int N) {
    __shared__ __align__(16) int4 estage[4][128];   // 2KB per wave (64 edges x 32B)
    __shared__ float ls[2][4][H];
    int lane = threadIdx.x & 63;
    int wv = threadIdx.x >> 6;
    int w = (blockIdx.x << 2) | wv;
    h2v wt[8], wg[8];
#pragma unroll
    for (int q = 0; q < 8; ++q) { wt[q] = as_h2(wth[lane * 8 + q]); wg[q] = as_h2(wgh[lane * 8 + q]); }
    float be_l = be[lane], dv_l = dv[lane], ets_l = ets[lane], vs_l = vs[lane];
    int n0 = ranges[w], n1 = ranges[w + 1];
    float s = 0.f, ss = 0.f;
    if (n0 < n1) {
        int4* dst = &estage[wv][0];
        const int4* gsrc = reinterpret_cast<const int4*>(eap);
        int e0 = rowptr[n0], e1 = rowptr[n1];
        int n = n0;
        int nend = rowptr[n0 + 1];
        size_t idx = (size_t)n * H + lane;
        float u_l = __half2float(u[idx]);
        float pv = __half2float(pre[idx]);
        // prefetch next node's u/pre
        int np = min(n + 1, n1 - 1);
        size_t idxn = (size_t)np * H + lane;
        float u_n = __half2float(u[idxn]);
        float pv_n = __half2float(pre[idxn]);
        float acc = sigm2(u_l + vs_l) * ets_l;   // folded self-loop contribution
        {   // stage first chunk
            int bytes = min(64, e1 - e0) * 32;
            int4 p0, p1;
            if (lane * 16 < bytes) p0 = gsrc[(size_t)e0 * 2 + lane];
            if (1024 + lane * 16 < bytes) p1 = gsrc[(size_t)e0 * 2 + 64 + lane];
            if (lane * 16 < bytes) dst[lane] = p0;
            if (1024 + lane * 16 < bytes) dst[64 + lane] = p1;
        }
        for (int c = e0; c < e1; c += 64) {
            int cnt = min(64, e1 - c);
            int nbytes = (c + 64 < e1) ? min(64, e1 - c - 64) * 32 : 0;
            int4 p0, p1;
            if (lane * 16 < nbytes) p0 = gsrc[(size_t)(c + 64) * 2 + lane];
            if (1024 + lane * 16 < nbytes) p1 = gsrc[(size_t)(c + 64) * 2 + 64 + lane];
            int k = 0;
            while (k < cnt) {
                while (c + k == nend) {       // node boundary: finish n, start next
                    float tval = pv + acc;
                    pre[idx] = __float2half(tval);
                    s += tval; ss += tval * tval;
                    ++n;
                    idx = idxn; u_l = u_n; pv = pv_n;
                    np = min(n + 1, n1 - 1);
                    idxn = (size_t)np * H + lane;
                    u_n = __half2float(u[idxn]);
                    pv_n = __half2float(pre[idxn]);
                    acc = sigm2(u_l + vs_l) * ets_l;
                    nend = rowptr[n + 1];
                }
                int safe = min(cnt, nend - c);
                for (; k + 1 < safe; k += 2) {
                    int4 d0 = dst[k * 2], d1 = dst[k * 2 + 1];
                    int4 d2 = dst[k * 2 + 2], d3 = dst[k * 2 + 3];
                    acc += edge_term(d0, d1, wt, wg, be_l, dv_l, u_l);
                    acc += edge_term(d2, d3, wt, wg, be_l, dv_l, u_l);
                }
                if (k < safe) {
                    int4 d0 = dst[k * 2], d1 = dst[k * 2 + 1];
                    acc += edge_term(d0, d1, wt, wg, be_l, dv_l, u_l);
                    ++k;
                }
            }
            if (lane * 16 < nbytes) dst[lane] = p0;
            if (1024 + lane * 16 < nbytes) dst[64 + lane] = p1;
        }
        for (;;) {   // finish current + trailing zero-edge nodes
            float tval = pv + acc;
            pre[idx] = __float2half(tval);
            s += tval; ss += tval * tval;
            ++n;
            if (n >= n1) break;
            idx = idxn; u_l = u_n; pv = pv_n;
            np = min(n + 1, n1 - 1);
            idxn = (size_t)np * H + lane;
            u_n = __half2float(u[idxn]);
            pv_n = __half2float(pre[idxn]);
            acc = sigm2(u_l + vs_l) * ets_l;
        }
    }
    ls[0][wv][lane] = s; ls[1][wv][lane] = ss;
    __syncthreads();
    if (threadIdx.x < H) {
        float a = ls[0][0][lane] + ls[0][1][lane] + ls[0][2][lane] + ls[0][3][lane];
        float b = ls[1][0][lane] + ls[1][1][lane] + ls[1][2][lane] + ls[1][3][lane];
        atomicAdd(&s1[lane], a);
        atomicAdd(&s2[lane], b);
    }
}

// ---------------- apply: h = relu(2*bn(t)) -> f16 + GraphNorm stats ----------------
__global__ void k_apply(const __half* __restrict__ in, __half* __restrict__ outb,
                        const float* __restrict__ bng, const float* __restrict__ bnb,
                        const float* __restrict__ s1b, const float* __restrict__ s2b,
                        float* __restrict__ s1g, float* __restrict__ s2g, float Ninv, int N) {
    int j = threadIdx.x, ty = threadIdx.y;
    __shared__ float As[H], Bs[H];
    if (ty == 0) {
        float mu = s1b[j] * Ninv, var = s2b[j] * Ninv - mu * mu;
        float r = rsqrtf(var + EPSV);
        float A = 2.f * bng[j] * r;
        As[j] = A; Bs[j] = 2.f * (bnb[j] - bng[j] * r * mu);
    }
    __syncthreads();
    float A = As[j], B = Bs[j];
    float s = 0.f, ss = 0.f;
    for (int n = blockIdx.x * 4 + ty; n < N; n += gridDim.x * 4) {
        size_t idx = (size_t)n * H + j;
        float v = fmaxf(fmaf(A, __half2float(in[idx]), B), 0.f);
        outb[idx] = __float2half(v);
        s += v; ss += v * v;
    }
    __shared__ float ls[2][4][H];
    ls[0][ty][j] = s; ls[1][ty][j] = ss;
    __syncthreads();
    if (ty == 0) {
        float a = ls[0][0][j] + ls[0][1][j] + ls[0][2][j] + ls[0][3][j];
        float b = ls[1][0][j] + ls[1][1][j] + ls[1][2][j] + ls[1][3][j];
        atomicAdd(&s1g[j], a);
        atomicAdd(&s2g[j], b);
    }
}

// ---------------- final: out = relu(gn2(h)) @ lin_W + lin_b ----------------
__global__ __launch_bounds__(256) void k_final(const __half* __restrict__ hraw, const float* __restrict__ W,
                        const float* __restrict__ bias,
                        const float* __restrict__ s1, const float* __restrict__ s2,
                        const float* __restrict__ gng, const float* __restrict__ gnb,
                        const float* __restrict__ gna, float Ninv,
                        float* __restrict__ outp, int N) {
    __shared__ float As[H], Bs[H];
    if (threadIdx.x < H) {
        int j = threadIdx.x;
        float mu = s1[j] * Ninv, m2 = s2[j] * Ninv, a = gna[j];
        float var = m2 - 2.f * a * mu * mu + a * a * mu * mu;
        float A = gng[j] * rsqrtf(var + EPSV);
        As[j] = A; Bs[j] = gnb[j] - A * a * mu;
    }
    __syncthreads();
    int n = blockIdx.x * blockDim.x + threadIdx.x;
    if (n >= N) return;
    float o[CO];
#pragma unroll
    for (int t = 0; t < CO; ++t) o[t] = bias[t];
    const __half* hr = hraw + (size_t)n * H;
    for (int m4 = 0; m4 < H / 4; ++m4) {
        uint2 hv = *reinterpret_cast<const uint2*>(hr + m4 * 4);
        __half2 h01 = *reinterpret_cast<__half2*>(&hv.x);
        __half2 h23 = *reinterpret_cast<__half2*>(&hv.y);
        float2 f01 = __half22float2(h01), f23 = __half22float2(h23);
        float hx = fmaxf(fmaf(As[m4*4+0], f01.x, Bs[m4*4+0]), 0.f);
        float hy = fmaxf(fmaf(As[m4*4+1], f01.y, Bs[m4*4+1]), 0.f);
        float hz = fmaxf(fmaf(As[m4*4+2], f23.x, Bs[m4*4+2]), 0.f);
        float hw = fmaxf(fmaf(As[m4*4+3], f23.y, Bs[m4*4+3]), 0.f);
#pragma unroll
        for (int t = 0; t < CO; ++t) {
            o[t] += hx * W[(m4*4+0) * CO + t];
            o[t] += hy * W[(m4*4+1) * CO + t];
            o[t] += hz * W[(m4*4+2) * CO + t];
            o[t] += hw * W[(m4*4+3) * CO + t];
        }
    }
    float* orow = outp + (size_t)n * CO;
#pragma unroll
    for (int t4 = 0; t4 < CO / 4; ++t4)
        reinterpret_cast<float4*>(orow)[t4] = make_float4(o[t4*4+0], o[t4*4+1], o[t4*4+2], o[t4*4+3]);
}

extern "C" void kernel_launch(void* const* d_in, const int* in_sizes, int n_in,
                              void* d_out, int out_size, void* d_ws, size_t ws_size,
                              hipStream_t stream) {
    const float* x     = (const float*)d_in[0];
    const int*   ei    = (const int*)d_in[1];
    const float* ea    = (const float*)d_in[2];
    const float* l1_Wl = (const float*)d_in[3];  const float* l1_bl = (const float*)d_in[4];
    const float* l1_Wr = (const float*)d_in[5];  const float* l1_We = (const float*)d_in[6];
    const float* l1_be = (const float*)d_in[7];  const float* l1_Wg = (const float*)d_in[8];
    const float* l1_bg = (const float*)d_in[9];  const float* l1_bng= (const float*)d_in[10];
    const float* l1_bnb= (const float*)d_in[11];
    const float* l2_Wl = (const float*)d_in[12]; const float* l2_bl = (const float*)d_in[13];
    const float* l2_Wr = (const float*)d_in[14]; const float* l2_We = (const float*)d_in[15];
    const float* l2_be = (const float*)d_in[16]; const float* l2_Wg = (const float*)d_in[17];
    const float* l2_bg = (const float*)d_in[18]; const float* l2_bng= (const float*)d_in[19];
    const float* l2_bnb= (const float*)d_in[20];
    const float* gn1_g = (const float*)d_in[21]; const float* gn1_b = (const float*)d_in[22];
    const float* gn1_a = (const float*)d_in[23];
    const float* gn2_g = (const float*)d_in[24]; const float* gn2_b = (const float*)d_in[25];
    const float* gn2_a = (const float*)d_in[26];
    const float* lin_W = (const float*)d_in[27]; const float* lin_b = (const float*)d_in[28];

    const int N = in_sizes[0] / 32;
    const int E = in_sizes[1] / 2;
    const int* rows = ei;
    const int* cols = ei + E;

    // bucket geometry
    int SH = 7, NPB = 128;
    while (((N + NPB - 1) >> SH) > 1024) { SH++; NPB <<= 1; }
    const int NB = (N + NPB - 1) >> SH;
    const int PB = (E + CPART - 1) / CPART;

    float* w    = (float*)d_ws;
    int* wth1   = (int*)w;
    int* wgh1   = (int*)(w + 512);
    int* wth2   = (int*)(w + 1024);
    int* wgh2   = (int*)(w + 1536);
    float* ets1 = w + 2048; float* vs1 = w + 2112; float* dv1 = w + 2176;
    float* ets2 = w + 2240; float* vs2 = w + 2304; float* dv2 = w + 2368;
    float* stats= w + 2432;

    int* ip     = (int*)(w + 8192);
    int* rowptr = ip;                 // N+1 (persistent)
    int* cnt    = ip + (N + 1);       // N
    int* bs     = cnt + N;            // 1024
    int* ranges = bs + 1024;          // NWAVES+2 (persistent)
    int* erow   = ranges + (NWAVES + 2);  // E (persistent)

    uintptr_t pa = (uintptr_t)(erow + E);
    pa = (pa + 255) & ~(uintptr_t)255;
    __half* eap = (__half*)pa;        // E*16 halves (persistent)
    uintptr_t px = (uintptr_t)(eap + (size_t)E * ED);
    px = (px + 255) & ~(uintptr_t)255;
    __half* xh = (__half*)px;         // N*32 halves (persistent)
    uintptr_t pz = (uintptr_t)(xh + (size_t)N * 32);
    pz = (pz + 255) & ~(uintptr_t)255;

    // --- overlap zone: {tmp, offtab, eah} (CSR build) then {B0, Bpre, Bu, B3h} (layers) ---
    int2* tmp   = (int2*)pz;                       // E
    int* offtab = (int*)(tmp + E);                 // PB*(NB+1)
    uintptr_t pe = (uintptr_t)(offtab + (size_t)PB * (NB + 1));
    pe = (pe + 255) & ~(uintptr_t)255;
    int4* eah = (int4*)pe;                         // E*2 int4 (32B/edge)

    size_t NB64 = (size_t)N * H;
    float* B0 = (float*)pz;                        // agg (fp32, N*64) — aliases tmp/offtab/eah
    __half* Bpre = (__half*)(B0 + NB64);           // pre/t (f16)
    __half* Bu   = Bpre + NB64;                    // u (f16)
    __half* B3h  = Bu + NB64;                      // h layer1 (f16)
    __half* B0h  = (__half*)B0;                    // h layer2 reuses B0 space

    const float Ninv = 1.0f / (float)N;
    dim3 rb(64, 4);
    int egrid = (E + 255) / 256;
    int ngrid = (N + 255) / 256;
    int g64 = (N + 63) / 64;
    const int SB = (N + 1023) >> 10;

    k_prep<<<1, 64, 0, stream>>>(l1_We, l1_be, l1_Wg, l2_We, l2_be, l2_Wg, w);
    k_xh<<<(N * 8 + 255) / 256, 256, 0, stream>>>(x, xh, N * 8);
    k_eah<<<egrid, 256, 0, stream>>>(ea, eah, E);

    // ---- CSR build: count -> scan -> partition -> per-bucket exact build ----
    hipMemsetAsync(cnt, 0, sizeof(int) * (size_t)N, stream);
    k_count<<<egrid, 256, 0, stream>>>(cols, cnt, E);
    k_scan1<<<SB, 1024, 0, stream>>>(cnt, bs, N);
    k_scan2<<<1, 1024, 0, stream>>>(bs, SB);
    k_scan3<<<SB, 1024, 0, stream>>>(cnt, bs, rowptr, N, E);
    k_ranges<<<(NWAVES + 256) / 256, 256, 0, stream>>>(rowptr, ranges, N, E, NWAVES);
    k_part<<<PB, 256, 0, stream>>>(rows, cols, tmp, offtab, E, NB, SH);
    k_build<<<NB, 256, 0, stream>>>(rowptr, tmp, offtab, eah, erow, eap, N, NB, SH, PB);

    // ---- layer 1 ----
    k_gather<32, false><<<WGRID, 256, 0, stream>>>(xh, rowptr, ranges, erow, B0,
                                                   nullptr, nullptr, nullptr, nullptr, nullptr, 0.f, N);
    k_gemmfu<32, false><<<g64, 256, 0, stream>>>(B0, xh, 32, l1_Wl, l1_Wr, l1_bl, l1_Wg, l1_bg,
                                                 nullptr, nullptr, nullptr, nullptr, nullptr, 0.f,
                                                 rowptr, Bpre, Bu, N);
    k_gate<<<WGRID, 256, 0, stream>>>(rowptr, ranges, eap, wth1, wgh1, l1_be, dv1, ets1, vs1,
                                      Bu, Bpre, stats + 0, stats + 64, N);
    k_apply<<<256, rb, 0, stream>>>(Bpre, B3h, l1_bng, l1_bnb, stats + 0, stats + 64,
                                    stats + 128, stats + 192, Ninv, N);

    // ---- layer 2 (gn1 folded into readers of B3h) ----
    k_gather<64, true><<<WGRID, 256, 0, stream>>>(B3h, rowptr, ranges, erow, B0,
                                                  stats + 128, stats + 192, gn1_g, gn1_b, gn1_a, Ninv, N);
    k_gemmfu<64, true><<<g64, 256, 0, stream>>>(B0, B3h, 64, l2_Wl, l2_Wr, l2_bl, l2_Wg, l2_bg,
                                                stats + 128, stats + 192, gn1_g, gn1_b, gn1_a, Ninv,
                                                rowptr, Bpre, Bu, N);
    k_gate<<<WGRID, 256, 0, stream>>>(rowptr, ranges, eap, wth2, wgh2, l2_be, dv2, ets2, vs2,
                                      Bu, Bpre, stats + 256, stats + 320, N);
    k_apply<<<256, rb, 0, stream>>>(Bpre, B0h, l2_bng, l2_bnb, stats + 256, stats + 320,
                                    stats + 384, stats + 448, Ninv, N);

    // ---- final ----
    k_final<<<ngrid, 256, 0, stream>>>(B0h, lin_W, lin_b, stats + 384, stats + 448,
                                       gn2_g, gn2_b, gn2_a, Ninv, (float*)d_out, N);
}

// Round 11
// 695.394 us; speedup vs baseline: 1.0932x; 1.0253x over previous
//
#include <hip/hip_runtime.h>
#include <hip/hip_fp16.h>
#include <math.h>
#include <stdint.h>

#define H 64
#define ED 16
#define CO 16
#define WGRID 2048
#define NWAVES (WGRID * 4)
#define CPART 2048
static constexpr float EPSV = 1e-5f;
static constexpr float LOG2E = 1.44269504f;

typedef _Float16 h2v __attribute__((ext_vector_type(2)));
typedef _Float16 f16x8 __attribute__((ext_vector_type(8)));
typedef float f32x4 __attribute__((ext_vector_type(4)));

__device__ __forceinline__ float sigm2(float z) {
    return __builtin_amdgcn_rcpf(1.0f + __builtin_amdgcn_exp2f(-z));
}

__device__ __forceinline__ h2v as_h2(int x) { union { int i; h2v h; } u; u.i = x; return u.h; }

__device__ __forceinline__ f16x8 as_f16x8(int4 v) { union { int4 i; f16x8 h; } u; u.i = v; return u.h; }

__device__ __forceinline__ int pack2(float a, float b) {
    __half2 h = __floats2half2_rn(a, b);
    return *reinterpret_cast<int*>(&h);
}

// ---------------- prep: packed-f16 gate weights (log2e-folded gate path), self-loop consts, zero stats --
__global__ void k_prep(const float* __restrict__ We1, const float* __restrict__ be1, const float* __restrict__ Wg1,
                       const float* __restrict__ We2, const float* __restrict__ be2, const float* __restrict__ Wg2,
                       float* __restrict__ ws) {
    int j = threadIdx.x;  // 0..63
    for (int l = 0; l < 2; ++l) {
        const float* We = l ? We2 : We1;
        const float* be = l ? be2 : be1;
        const float* Wg = l ? Wg2 : Wg1;
        int* wth = (int*)(ws + (l ? 1024 : 0));
        int* wgh = (int*)(ws + (l ? 1536 : 512));
        float* ets = ws + 2048 + l * 192;
        float* vs  = ws + 2112 + l * 192;
        float* dv  = ws + 2176 + l * 192;
        float wt[ED], wg[ED];
        float et = be[j];
        for (int k = 0; k < ED; ++k) { wt[k] = We[k * H + j]; et += wt[k]; }
        ets[j] = et;                                   // ea_t for self-loop (ea = ones)
        float d = 0.f;
        for (int m = 0; m < H; ++m) d += be[m] * Wg[(H + m) * H + j];
        float vsum = d;
        for (int k = 0; k < ED; ++k) {
            float acc = 0.f;
            for (int m = 0; m < H; ++m) acc += We[k * H + m] * Wg[(H + m) * H + j];
            wg[k] = acc;                               // (We @ Wg_bot)^T
            vsum += acc;
        }
        dv[j] = d * LOG2E;
        vs[j] = vsum * LOG2E;
        for (int q = 0; q < 8; ++q) {
            wth[j * 8 + q] = pack2(wt[2 * q], wt[2 * q + 1]);
            wgh[j * 8 + q] = pack2(wg[2 * q] * LOG2E, wg[2 * q + 1] * LOG2E);
        }
    }
    for (int s = 0; s < 8; ++s) ws[2432 + s * 64 + j] = 0.f;  // zero all stats
}

// ---------------- x -> f16 ----------------
__global__ void k_xh(const float* __restrict__ x, __half* __restrict__ xh, int total4) {
    int i = blockIdx.x * blockDim.x + threadIdx.x;
    if (i >= total4) return;
    float4 v = *reinterpret_cast<const float4*>(x + (size_t)i * 4);
    __half2 h0 = __floats2half2_rn(v.x, v.y), h1 = __floats2half2_rn(v.z, v.w);
    uint2 o;
    o.x = *reinterpret_cast<unsigned*>(&h0);
    o.y = *reinterpret_cast<unsigned*>(&h1);
    *reinterpret_cast<uint2*>(xh + (size_t)i * 4) = o;
}

// ---------------- ea -> f16 (input order, coalesced) ----------------
__global__ void k_eah(const float* __restrict__ ea, int4* __restrict__ eah, int E) {
    int e = blockIdx.x * blockDim.x + threadIdx.x;
    if (e >= E) return;
    const float4* src = reinterpret_cast<const float4*>(ea + (size_t)e * ED);
    float4 v0 = src[0], v1 = src[1], v2 = src[2], v3 = src[3];
    int hh[8];
    hh[0] = pack2(v0.x, v0.y); hh[1] = pack2(v0.z, v0.w);
    hh[2] = pack2(v1.x, v1.y); hh[3] = pack2(v1.z, v1.w);
    hh[4] = pack2(v2.x, v2.y); hh[5] = pack2(v2.z, v2.w);
    hh[6] = pack2(v3.x, v3.y); hh[7] = pack2(v3.z, v3.w);
    const int4* o = reinterpret_cast<const int4*>(hh);
    eah[(size_t)e * 2 + 0] = o[0];
    eah[(size_t)e * 2 + 1] = o[1];
}

// ---------------- CSR build: count + scan ----------------
__global__ void k_count(const int* __restrict__ cols, int* __restrict__ cnt, int E) {
    int e = blockIdx.x * blockDim.x + threadIdx.x;
    if (e < E) atomicAdd(&cnt[cols[e]], 1);
}

__global__ __launch_bounds__(1024) void k_scan1(const int* __restrict__ cnt, int* __restrict__ bs, int N) {
    __shared__ int ls[1024];
    int t = threadIdx.x;
    int i = blockIdx.x * 1024 + t;
    ls[t] = (i < N) ? cnt[i] : 0;
    __syncthreads();
    for (int off = 512; off > 0; off >>= 1) {
        if (t < off) ls[t] += ls[t + off];
        __syncthreads();
    }
    if (t == 0) bs[blockIdx.x] = ls[0];
}

__global__ __launch_bounds__(1024) void k_scan2(int* __restrict__ bs, int SB) {
    __shared__ int ls[1024];
    int t = threadIdx.x;
    int v = (t < SB) ? bs[t] : 0;
    ls[t] = v;
    __syncthreads();
    for (int off = 1; off < 1024; off <<= 1) {
        int x = (t >= off) ? ls[t - off] : 0;
        __syncthreads();
        ls[t] += x;
        __syncthreads();
    }
    if (t < SB) bs[t] = ls[t] - v;  // exclusive
}

__global__ __launch_bounds__(1024) void k_scan3(const int* __restrict__ cnt, const int* __restrict__ bs,
                                                int* __restrict__ rowptr, int N, int E) {
    __shared__ int ls[1024];
    int t = threadIdx.x;
    int i = blockIdx.x * 1024 + t;
    int v = (i < N) ? cnt[i] : 0;
    ls[t] = v;
    __syncthreads();
    for (int off = 1; off < 1024; off <<= 1) {
        int x = (t >= off) ? ls[t - off] : 0;
        __syncthreads();
        ls[t] += x;
        __syncthreads();
    }
    if (i < N) rowptr[i] = bs[blockIdx.x] + ls[t] - v;  // exclusive prefix
    if (i == 0) rowptr[N] = E;
}

// ---------------- wave ranges ----------------
__global__ void k_ranges(const int* __restrict__ rowptr, int* __restrict__ ranges, int N, int E, int nw) {
    int w = blockIdx.x * blockDim.x + threadIdx.x;
    if (w > nw) return;
    if (w == nw) { ranges[nw] = N; return; }
    int t0 = (int)((long)E * w / nw);
    int lo = 0, hi = N;
    while (lo < hi) { int mid = (lo + hi) >> 1; if (rowptr[mid] < t0) lo = mid + 1; else hi = mid; }
    ranges[w] = lo;
}

// ---------------- partition pass 1: block-local bucket sort, fully coalesced writes ----------------
__global__ __launch_bounds__(256) void k_part(const int* __restrict__ rows, const int* __restrict__ cols,
                                              int2* __restrict__ tmp, int* __restrict__ offtab,
                                              int E, int NB, int SH) {
    __shared__ int hist[1025];
    __shared__ int pscan[256];
    __shared__ int2 stage[CPART];
    int tid = threadIdx.x;
    int base = blockIdx.x * CPART;
    int cnt = min(CPART, E - base);
    for (int i = tid; i <= NB; i += 256) hist[i] = 0;
    __syncthreads();
    int myc[8], myr[8];
#pragma unroll
    for (int q = 0; q < 8; ++q) {
        int li = q * 256 + tid;
        if (li < cnt) {
            int e = base + li;
            myc[q] = cols[e];
            myr[q] = rows[e];
            atomicAdd(&hist[myc[q] >> SH], 1);
        } else myc[q] = -1;
    }
    __syncthreads();
    int h[4], s = 0;
    int b0 = tid * 4;
#pragma unroll
    for (int k = 0; k < 4; ++k) { h[k] = (b0 + k < NB) ? hist[b0 + k] : 0; s += h[k]; }
    pscan[tid] = s;
    __syncthreads();
    for (int off = 1; off < 256; off <<= 1) {
        int v = (tid >= off) ? pscan[tid - off] : 0;
        __syncthreads();
        pscan[tid] += v;
        __syncthreads();
    }
    int excl = pscan[tid] - s;
    __syncthreads();
    int run = excl;
#pragma unroll
    for (int k = 0; k < 4; ++k) {
        if (b0 + k < NB) hist[b0 + k] = run;
        run += h[k];
    }
    __syncthreads();
    int* ot = offtab + (size_t)blockIdx.x * (NB + 1);
    for (int i = tid; i < NB; i += 256) ot[i] = hist[i];
    if (tid == 0) ot[NB] = cnt;
    __syncthreads();
    int mask = (1 << SH) - 1;
#pragma unroll
    for (int q = 0; q < 8; ++q) {
        if (myc[q] >= 0) {
            int b = myc[q] >> SH;
            int p = atomicAdd(&hist[b], 1);
            int e = base + q * 256 + tid;
            stage[p] = make_int2(myr[q], (e << SH) | (myc[q] & mask));
        }
    }
    __syncthreads();
    int2* dst = tmp + base;
    for (int i = tid; i < cnt; i += 256) dst[i] = stage[i];
}

// ---------------- build pass 2: per-bucket exact CSR scatter (f16 source rows, 32B each) ----------
__global__ __launch_bounds__(256) void k_build(const int* __restrict__ rowptr, const int2* __restrict__ tmp,
                                               const int* __restrict__ offtab, const int4* __restrict__ eah,
                                               int* __restrict__ erow, __half* __restrict__ eap,
                                               int N, int NB, int SH, int PB) {
    __shared__ int lcur[1024];
    int tid = threadIdx.x;
    int b = blockIdx.x;
    int NPB = 1 << SH;
    int nodelo = b << SH;
    for (int j = tid; j < NPB; j += 256) {
        int n = nodelo + j;
        lcur[j] = (n < N) ? rowptr[n] : 0;
    }
    __syncthreads();
    int mask = NPB - 1;
    for (int i = tid; i < PB; i += 256) {
        const int* ot = offtab + (size_t)i * (NB + 1);
        int j0 = ot[b], j1 = ot[b + 1];
        for (int j = j0; j < j1; ++j) {
            int2 v = tmp[(size_t)i * CPART + j];
            int e = (int)(((unsigned)v.y) >> SH);
            int cl = v.y & mask;
            int p = atomicAdd(&lcur[cl], 1);
            erow[p] = v.x;
            int4 a0 = eah[(size_t)e * 2 + 0];
            int4 a1 = eah[(size_t)e * 2 + 1];
            int4* d = reinterpret_cast<int4*>(eap + (size_t)p * ED);
            d[0] = a0; d[1] = a1;
        }
    }
}

// ---------------- gather (f16 input): agg[n] = T(x[n]) + sum_in T(x[row]) ----
template <int CIN, bool GN>
__global__ __launch_bounds__(256) void k_gather(const __half* __restrict__ x, const int* __restrict__ rowptr,
                         const int* __restrict__ ranges,
                         const int* __restrict__ erow, float* __restrict__ agg,
                         const float* __restrict__ s1, const float* __restrict__ s2,
                         const float* __restrict__ gng, const float* __restrict__ gnb,
                         const float* __restrict__ gna, float Ninv, int N) {
    int lane = threadIdx.x & 63;
    int w = (blockIdx.x * blockDim.x + threadIdx.x) >> 6;
    float A = 1.f, B = 0.f;
    if (GN) {
        float mu = s1[lane] * Ninv, m2 = s2[lane] * Ninv, a = gna[lane];
        float var = m2 - 2.f * a * mu * mu + a * a * mu * mu;
        A = gng[lane] * rsqrtf(var + EPSV);
        B = gnb[lane] - A * a * mu;
    }
    int n0 = ranges[w], n1 = ranges[w + 1];
    for (int n = n0; n < n1; ++n) {
        int s = rowptr[n], te = rowptr[n + 1];
        if (CIN == 64) {
            float raw = __half2float(x[(size_t)n * 64 + lane]);
            float acc = GN ? fmaxf(fmaf(A, raw, B), 0.f) : raw;
            int i = s;
            for (; i + 7 < te; i += 8) {
                int r0 = erow[i],     r1 = erow[i + 1], r2 = erow[i + 2], r3 = erow[i + 3];
                int r4 = erow[i + 4], r5 = erow[i + 5], r6 = erow[i + 6], r7 = erow[i + 7];
                float x0 = __half2float(x[(size_t)r0 * 64 + lane]);
                float x1 = __half2float(x[(size_t)r1 * 64 + lane]);
                float x2 = __half2float(x[(size_t)r2 * 64 + lane]);
                float x3 = __half2float(x[(size_t)r3 * 64 + lane]);
                float x4 = __half2float(x[(size_t)r4 * 64 + lane]);
                float x5 = __half2float(x[(size_t)r5 * 64 + lane]);
                float x6 = __half2float(x[(size_t)r6 * 64 + lane]);
                float x7 = __half2float(x[(size_t)r7 * 64 + lane]);
                if (GN) {
                    x0 = fmaxf(fmaf(A, x0, B), 0.f); x1 = fmaxf(fmaf(A, x1, B), 0.f);
                    x2 = fmaxf(fmaf(A, x2, B), 0.f); x3 = fmaxf(fmaf(A, x3, B), 0.f);
                    x4 = fmaxf(fmaf(A, x4, B), 0.f); x5 = fmaxf(fmaf(A, x5, B), 0.f);
                    x6 = fmaxf(fmaf(A, x6, B), 0.f); x7 = fmaxf(fmaf(A, x7, B), 0.f);
                }
                acc += ((x0 + x1) + (x2 + x3)) + ((x4 + x5) + (x6 + x7));
            }
            for (; i < te; ++i) {
                float xv = __half2float(x[(size_t)erow[i] * 64 + lane]);
                if (GN) xv = fmaxf(fmaf(A, xv, B), 0.f);
                acc += xv;
            }
            agg[(size_t)n * H + lane] = acc;
        } else {
            int c = lane & 31, half = lane >> 5;
            float acc = half ? 0.f : __half2float(x[(size_t)n * 32 + c]);
            int i = s + half;
            for (; i + 6 < te; i += 8) {
                int r0 = erow[i], r1 = erow[i + 2], r2 = erow[i + 4], r3 = erow[i + 6];
                float x0 = __half2float(x[(size_t)r0 * 32 + c]);
                float x1 = __half2float(x[(size_t)r1 * 32 + c]);
                float x2 = __half2float(x[(size_t)r2 * 32 + c]);
                float x3 = __half2float(x[(size_t)r3 * 32 + c]);
                acc += (x0 + x1) + (x2 + x3);
            }
            for (; i < te; i += 2) acc += __half2float(x[(size_t)erow[i] * 32 + c]);
            acc += __shfl_xor(acc, 32);
            if (half == 0) agg[(size_t)n * H + c] = acc;
        }
    }
}

// ---------------- fused GEMM: pre = (agg/deg)@Wl + T(x)@Wr + bl ; u = (pre@Wg_top + bg)*log2e ----------
#define MT4A(mq, aval) \
    acc[mq][0] = fmaf(aval, w1.x, acc[mq][0]); acc[mq][1] = fmaf(aval, w1.y, acc[mq][1]); \
    acc[mq][2] = fmaf(aval, w1.z, acc[mq][2]); acc[mq][3] = fmaf(aval, w1.w, acc[mq][3]);
#define MT4X(mq, aval) \
    acc[mq][0] = fmaf(aval, w2.x, acc[mq][0]); acc[mq][1] = fmaf(aval, w2.y, acc[mq][1]); \
    acc[mq][2] = fmaf(aval, w2.z, acc[mq][2]); acc[mq][3] = fmaf(aval, w2.w, acc[mq][3]);

template <int K, bool GN>
__global__ __launch_bounds__(256) void k_gemmfu(
        const float* __restrict__ A,               // agg, stride 64
        const __half* __restrict__ A2, int lda2,   // x-side (f16)
        const float* __restrict__ W1, const float* __restrict__ W2,
        const float* __restrict__ bias,
        const float* __restrict__ Wg, const float* __restrict__ bg,
        const float* __restrict__ s1, const float* __restrict__ s2,
        const float* __restrict__ gng, const float* __restrict__ gnb,
        const float* __restrict__ gna, float Ninv,
        const int* __restrict__ rowptr,
        __half* __restrict__ pre, __half* __restrict__ uout, int N) {
    __shared__ float WA[64 * 64];
    __shared__ float WB[K * 64];
    __shared__ float big[64][68];
    __shared__ float As[64], Bs[64], invd[64];
    int tid = threadIdx.x;
    for (int idx = tid; idx < K * 64; idx += 256) { WA[idx] = W1[idx]; WB[idx] = W2[idx]; }
    int nb = blockIdx.x * 64;
    if (tid < 64) {
        if (GN) {
            float mu = s1[tid] * Ninv, m2 = s2[tid] * Ninv, a = gna[tid];
            float var = m2 - 2.f * a * mu * mu + a * a * mu * mu;
            float Av = gng[tid] * rsqrtf(var + EPSV);
            As[tid] = Av; Bs[tid] = gnb[tid] - Av * a * mu;
        }
        int n = nb + tid;
        invd[tid] = (n < N) ? 1.f / (float)(rowptr[n + 1] - rowptr[n] + 1) : 0.f;
    }
    __syncthreads();
    int tm = tid >> 4, tn = tid & 15;
    int m0 = tm * 4, j0 = tn * 4;
    float acc[4][4];
#pragma unroll
    for (int jq = 0; jq < 4; ++jq) {
        float b = bias[j0 + jq];
#pragma unroll
        for (int mq = 0; mq < 4; ++mq) acc[mq][jq] = b;
    }
    int sn = tid >> 2, kq4 = (tid & 3) * 4;
    int sg = nb + sn;
    for (int k0 = 0; k0 < K; k0 += 16) {
        if (k0) __syncthreads();
        if (sg < N) {
            float4 av = *reinterpret_cast<const float4*>(A + (size_t)sg * 64 + k0 + kq4);
            float sc = invd[sn];
            av.x *= sc; av.y *= sc; av.z *= sc; av.w *= sc;
            big[kq4 + 0][sn] = av.x; big[kq4 + 1][sn] = av.y;
            big[kq4 + 2][sn] = av.z; big[kq4 + 3][sn] = av.w;
            uint2 hv = *reinterpret_cast<const uint2*>(A2 + (size_t)sg * lda2 + k0 + kq4);
            __half2 h01 = *reinterpret_cast<__half2*>(&hv.x);
            __half2 h23 = *reinterpret_cast<__half2*>(&hv.y);
            float2 f01 = __half22float2(h01), f23 = __half22float2(h23);
            float xv0 = f01.x, xv1 = f01.y, xv2 = f23.x, xv3 = f23.y;
            if (GN) {
                xv0 = fmaxf(fmaf(As[k0 + kq4 + 0], xv0, Bs[k0 + kq4 + 0]), 0.f);
                xv1 = fmaxf(fmaf(As[k0 + kq4 + 1], xv1, Bs[k0 + kq4 + 1]), 0.f);
                xv2 = fmaxf(fmaf(As[k0 + kq4 + 2], xv2, Bs[k0 + kq4 + 2]), 0.f);
                xv3 = fmaxf(fmaf(As[k0 + kq4 + 3], xv3, Bs[k0 + kq4 + 3]), 0.f);
            }
            big[16 + kq4 + 0][sn] = xv0; big[16 + kq4 + 1][sn] = xv1;
            big[16 + kq4 + 2][sn] = xv2; big[16 + kq4 + 3][sn] = xv3;
        } else {
#pragma unroll
            for (int q = 0; q < 4; ++q) { big[kq4 + q][sn] = 0.f; big[16 + kq4 + q][sn] = 0.f; }
        }
        __syncthreads();
#pragma unroll
        for (int k = 0; k < 16; ++k) {
            float4 am = *reinterpret_cast<const float4*>(&big[k][m0]);
            float4 w1 = *reinterpret_cast<const float4*>(&WA[(k0 + k) * 64 + j0]);
            MT4A(0, am.x) MT4A(1, am.y) MT4A(2, am.z) MT4A(3, am.w)
            float4 xm = *reinterpret_cast<const float4*>(&big[16 + k][m0]);
            float4 w2 = *reinterpret_cast<const float4*>(&WB[(k0 + k) * 64 + j0]);
            MT4X(0, xm.x) MT4X(1, xm.y) MT4X(2, xm.z) MT4X(3, xm.w)
        }
    }
    __syncthreads();
#pragma unroll
    for (int mq = 0; mq < 4; ++mq) {
        int n = nb + m0 + mq;
        if (n < N) {
            uint2 o;
            o.x = pack2(acc[mq][0], acc[mq][1]);
            o.y = pack2(acc[mq][2], acc[mq][3]);
            *reinterpret_cast<uint2*>(pre + (size_t)n * 64 + j0) = o;
        }
#pragma unroll
        for (int jq = 0; jq < 4; ++jq) big[j0 + jq][m0 + mq] = acc[mq][jq];
    }
    for (int idx = tid; idx < 4096; idx += 256) WA[idx] = Wg[idx] * LOG2E;
    __syncthreads();
    float acc2[4][4];
#pragma unroll
    for (int jq = 0; jq < 4; ++jq) {
        float b = bg[j0 + jq] * LOG2E;
#pragma unroll
        for (int mq = 0; mq < 4; ++mq) acc2[mq][jq] = b;
    }
#pragma unroll 8
    for (int k = 0; k < 64; ++k) {
        float4 pm = *reinterpret_cast<const float4*>(&big[k][m0]);
        float4 w1 = *reinterpret_cast<const float4*>(&WA[k * 64 + j0]);
        acc2[0][0] = fmaf(pm.x, w1.x, acc2[0][0]); acc2[0][1] = fmaf(pm.x, w1.y, acc2[0][1]);
        acc2[0][2] = fmaf(pm.x, w1.z, acc2[0][2]); acc2[0][3] = fmaf(pm.x, w1.w, acc2[0][3]);
        acc2[1][0] = fmaf(pm.y, w1.x, acc2[1][0]); acc2[1][1] = fmaf(pm.y, w1.y, acc2[1][1]);
        acc2[1][2] = fmaf(pm.y, w1.z, acc2[1][2]); acc2[1][3] = fmaf(pm.y, w1.w, acc2[1][3]);
        acc2[2][0] = fmaf(pm.z, w1.x, acc2[2][0]); acc2[2][1] = fmaf(pm.z, w1.y, acc2[2][1]);
        acc2[2][2] = fmaf(pm.z, w1.z, acc2[2][2]); acc2[2][3] = fmaf(pm.z, w1.w, acc2[2][3]);
        acc2[3][0] = fmaf(pm.w, w1.x, acc2[3][0]); acc2[3][1] = fmaf(pm.w, w1.y, acc2[3][1]);
        acc2[3][2] = fmaf(pm.w, w1.z, acc2[3][2]); acc2[3][3] = fmaf(pm.w, w1.w, acc2[3][3]);
    }
#pragma unroll
    for (int mq = 0; mq < 4; ++mq) {
        int n = nb + m0 + mq;
        if (n < N) {
            uint2 o;
            o.x = pack2(acc2[mq][0], acc2[mq][1]);
            o.y = pack2(acc2[mq][2], acc2[mq][3]);
            *reinterpret_cast<uint2*>(uout + (size_t)n * 64 + j0) = o;
        }
    }
}

// ---------------- gate: MFMA edge matmul (ET/V per 16-edge tile) + channel-lane sigmoid/accumulate ----
// ET[16x64] = ea_tile @ We ; V[16x64] = ea_tile @ (We@Wg_bot * log2e), via mfma_f32_16x16x32_f16 (K padded).
// A-frag: lane l holds A[l&15][8*(l>>4)+i] (groups 2,3 = zero pad). B-frag: B[8*(l>>4)+i][c*16+(l&15)].
// C/D: col=lane&15, row=(lane>>4)*4+reg (verified layout).
__global__ __launch_bounds__(256) void k_gate(
        const int* __restrict__ rowptr, const int* __restrict__ ranges,
        const __half* __restrict__ eap,
        const int* __restrict__ wth, const int* __restrict__ wgh,
        const float* __restrict__ be, const float* __restrict__ dv,
        const float* __restrict__ ets, const float* __restrict__ vs,
        const __half* __restrict__ u, __half* __restrict__ pre,
        float* __restrict__ s1, float* __restrict__ s2, int N) {
    __shared__ __align__(16) int4 estage[4][128];   // 2KB per wave (64 edges x 32B)
    __shared__ float vbuf[4][16][68];
    __shared__ float ebuf[4][16][68];
    __shared__ float ls[2][4][H];
    int lane = threadIdx.x & 63;
    int wv = threadIdx.x >> 6;
    int w = (blockIdx.x << 2) | wv;
    int g = lane >> 4, li = lane & 15;
    // loop-invariant B fragments (k>=16 zero-padded)
    f16x8 Bet[4], Bv[4];
#pragma unroll
    for (int c = 0; c < 4; ++c) {
        int j = c * 16 + li;
        int4 bt = make_int4(0, 0, 0, 0), bv = make_int4(0, 0, 0, 0);
        if (g < 2) {
            bt = *reinterpret_cast<const int4*>(&wth[j * 8 + g * 4]);
            bv = *reinterpret_cast<const int4*>(&wgh[j * 8 + g * 4]);
        }
        Bet[c] = as_f16x8(bt);
        Bv[c] = as_f16x8(bv);
    }
    float be_l = be[lane], dv_l = dv[lane], ets_l = ets[lane], vs_l = vs[lane];
    int n0 = ranges[w], n1 = ranges[w + 1];
    float s = 0.f, ss = 0.f;
    if (n0 < n1) {
        int4* dst = &estage[wv][0];
        const int4* gsrc = reinterpret_cast<const int4*>(eap);
        int e0 = rowptr[n0], e1 = rowptr[n1];
        int n = n0;
        int nend = rowptr[n0 + 1];
        size_t idx = (size_t)n * H + lane;
        float u_l = __half2float(u[idx]);
        float pv = __half2float(pre[idx]);
        int np = min(n + 1, n1 - 1);
        size_t idxn = (size_t)np * H + lane;
        float u_n = __half2float(u[idxn]);
        float pv_n = __half2float(pre[idxn]);
        float acc = sigm2(u_l + vs_l) * ets_l;   // folded self-loop contribution
        float u2 = u_l + dv_l;                   // gate-dot bias folded into u
        {   // stage first chunk
            int bytes = min(64, e1 - e0) * 32;
            int4 p0, p1;
            if (lane * 16 < bytes) p0 = gsrc[(size_t)e0 * 2 + lane];
            if (1024 + lane * 16 < bytes) p1 = gsrc[(size_t)e0 * 2 + 64 + lane];
            if (lane * 16 < bytes) dst[lane] = p0;
            if (1024 + lane * 16 < bytes) dst[64 + lane] = p1;
        }
        for (int c = e0; c < e1; c += 64) {
            int cnt = min(64, e1 - c);
            int nbytes = (c + 64 < e1) ? min(64, e1 - c - 64) * 32 : 0;
            int4 p0, p1;
            if (lane * 16 < nbytes) p0 = gsrc[(size_t)(c + 64) * 2 + lane];
            if (1024 + lane * 16 < nbytes) p1 = gsrc[(size_t)(c + 64) * 2 + 64 + lane];
            for (int tb = 0; tb < cnt; tb += 16) {
                // ---- MFMA: compute ET/V for this 16-edge tile ----
                int4 af = make_int4(0, 0, 0, 0);
                if (g < 2) af = dst[(tb + li) * 2 + g];
                f16x8 Af = as_f16x8(af);
                f32x4 z = {0.f, 0.f, 0.f, 0.f};
                f32x4 et0 = __builtin_amdgcn_mfma_f32_16x16x32_f16(Af, Bet[0], z, 0, 0, 0);
                f32x4 et1 = __builtin_amdgcn_mfma_f32_16x16x32_f16(Af, Bet[1], z, 0, 0, 0);
                f32x4 et2 = __builtin_amdgcn_mfma_f32_16x16x32_f16(Af, Bet[2], z, 0, 0, 0);
                f32x4 et3 = __builtin_amdgcn_mfma_f32_16x16x32_f16(Af, Bet[3], z, 0, 0, 0);
                f32x4 vv0 = __builtin_amdgcn_mfma_f32_16x16x32_f16(Af, Bv[0], z, 0, 0, 0);
                f32x4 vv1 = __builtin_amdgcn_mfma_f32_16x16x32_f16(Af, Bv[1], z, 0, 0, 0);
                f32x4 vv2 = __builtin_amdgcn_mfma_f32_16x16x32_f16(Af, Bv[2], z, 0, 0, 0);
                f32x4 vv3 = __builtin_amdgcn_mfma_f32_16x16x32_f16(Af, Bv[3], z, 0, 0, 0);
                int r0 = g * 4;
#pragma unroll
                for (int r = 0; r < 4; ++r) {
                    ebuf[wv][r0 + r][li]      = et0[r];
                    ebuf[wv][r0 + r][16 + li] = et1[r];
                    ebuf[wv][r0 + r][32 + li] = et2[r];
                    ebuf[wv][r0 + r][48 + li] = et3[r];
                    vbuf[wv][r0 + r][li]      = vv0[r];
                    vbuf[wv][r0 + r][16 + li] = vv1[r];
                    vbuf[wv][r0 + r][32 + li] = vv2[r];
                    vbuf[wv][r0 + r][48 + li] = vv3[r];
                }
                // ---- consume tile (channel = lane) ----
                int p = tb, pend = min(cnt, tb + 16);
                while (p < pend) {
                    while (c + p == nend) {       // node boundary: finish n, start next
                        float tval = pv + acc;
                        pre[idx] = __float2half(tval);
                        s += tval; ss += tval * tval;
                        ++n;
                        idx = idxn; u_l = u_n; pv = pv_n;
                        np = min(n + 1, n1 - 1);
                        idxn = (size_t)np * H + lane;
                        u_n = __half2float(u[idxn]);
                        pv_n = __half2float(pre[idxn]);
                        acc = sigm2(u_l + vs_l) * ets_l;
                        u2 = u_l + dv_l;
                        nend = rowptr[n + 1];
                    }
                    int lim = min(pend, nend - c);
                    for (; p + 1 < lim; p += 2) {
                        float V0 = vbuf[wv][p - tb][lane];
                        float E0 = ebuf[wv][p - tb][lane];
                        float V1 = vbuf[wv][p + 1 - tb][lane];
                        float E1 = ebuf[wv][p + 1 - tb][lane];
                        acc += sigm2(u2 + V0) * (be_l + E0) + sigm2(u2 + V1) * (be_l + E1);
                    }
                    if (p < lim) {
                        float V0 = vbuf[wv][p - tb][lane];
                        float E0 = ebuf[wv][p - tb][lane];
                        acc += sigm2(u2 + V0) * (be_l + E0);
                        ++p;
                    }
                }
            }
            if (lane * 16 < nbytes) dst[lane] = p0;
            if (1024 + lane * 16 < nbytes) dst[64 + lane] = p1;
        }
        for (;;) {   // finish current + trailing zero-edge nodes
            float tval = pv + acc;
            pre[idx] = __float2half(tval);
            s += tval; ss += tval * tval;
            ++n;
            if (n >= n1) break;
            idx = idxn; u_l = u_n; pv = pv_n;
            np = min(n + 1, n1 - 1);
            idxn = (size_t)np * H + lane;
            u_n = __half2float(u[idxn]);
            pv_n = __half2float(pre[idxn]);
            acc = sigm2(u_l + vs_l) * ets_l;
            u2 = u_l + dv_l;
        }
    }
    ls[0][wv][lane] = s; ls[1][wv][lane] = ss;
    __syncthreads();
    if (threadIdx.x < H) {
        float a = ls[0][0][lane] + ls[0][1][lane] + ls[0][2][lane] + ls[0][3][lane];
        float b = ls[1][0][lane] + ls[1][1][lane] + ls[1][2][lane] + ls[1][3][lane];
        atomicAdd(&s1[lane], a);
        atomicAdd(&s2[lane], b);
    }
}

// ---------------- apply: h = relu(2*bn(t)) -> f16 + GraphNorm stats ----------------
__global__ void k_apply(const __half* __restrict__ in, __half* __restrict__ outb,
                        const float* __restrict__ bng, const float* __restrict__ bnb,
                        const float* __restrict__ s1b, const float* __restrict__ s2b,
                        float* __restrict__ s1g, float* __restrict__ s2g, float Ninv, int N) {
    int j = threadIdx.x, ty = threadIdx.y;
    __shared__ float As[H], Bs[H];
    if (ty == 0) {
        float mu = s1b[j] * Ninv, var = s2b[j] * Ninv - mu * mu;
        float r = rsqrtf(var + EPSV);
        float A = 2.f * bng[j] * r;
        As[j] = A; Bs[j] = 2.f * (bnb[j] - bng[j] * r * mu);
    }
    __syncthreads();
    float A = As[j], B = Bs[j];
    float s = 0.f, ss = 0.f;
    for (int n = blockIdx.x * 4 + ty; n < N; n += gridDim.x * 4) {
        size_t idx = (size_t)n * H + j;
        float v = fmaxf(fmaf(A, __half2float(in[idx]), B), 0.f);
        outb[idx] = __float2half(v);
        s += v; ss += v * v;
    }
    __shared__ float ls[2][4][H];
    ls[0][ty][j] = s; ls[1][ty][j] = ss;
    __syncthreads();
    if (ty == 0) {
        float a = ls[0][0][j] + ls[0][1][j] + ls[0][2][j] + ls[0][3][j];
        float b = ls[1][0][j] + ls[1][1][j] + ls[1][2][j] + ls[1][3][j];
        atomicAdd(&s1g[j], a);
        atomicAdd(&s2g[j], b);
    }
}

// ---------------- final: out = relu(gn2(h)) @ lin_W + lin_b ----------------
__global__ __launch_bounds__(256) void k_final(const __half* __restrict__ hraw, const float* __restrict__ W,
                        const float* __restrict__ bias,
                        const float* __restrict__ s1, const float* __restrict__ s2,
                        const float* __restrict__ gng, const float* __restrict__ gnb,
                        const float* __restrict__ gna, float Ninv,
                        float* __restrict__ outp, int N) {
    __shared__ float As[H], Bs[H];
    if (threadIdx.x < H) {
        int j = threadIdx.x;
        float mu = s1[j] * Ninv, m2 = s2[j] * Ninv, a = gna[j];
        float var = m2 - 2.f * a * mu * mu + a * a * mu * mu;
        float A = gng[j] * rsqrtf(var + EPSV);
        As[j] = A; Bs[j] = gnb[j] - A * a * mu;
    }
    __syncthreads();
    int n = blockIdx.x * blockDim.x + threadIdx.x;
    if (n >= N) return;
    float o[CO];
#pragma unroll
    for (int t = 0; t < CO; ++t) o[t] = bias[t];
    const __half* hr = hraw + (size_t)n * H;
    for (int m4 = 0; m4 < H / 4; ++m4) {
        uint2 hv = *reinterpret_cast<const uint2*>(hr + m4 * 4);
        __half2 h01 = *reinterpret_cast<__half2*>(&hv.x);
        __half2 h23 = *reinterpret_cast<__half2*>(&hv.y);
        float2 f01 = __half22float2(h01), f23 = __half22float2(h23);
        float hx = fmaxf(fmaf(As[m4*4+0], f01.x, Bs[m4*4+0]), 0.f);
        float hy = fmaxf(fmaf(As[m4*4+1], f01.y, Bs[m4*4+1]), 0.f);
        float hz = fmaxf(fmaf(As[m4*4+2], f23.x, Bs[m4*4+2]), 0.f);
        float hw = fmaxf(fmaf(As[m4*4+3], f23.y, Bs[m4*4+3]), 0.f);
#pragma unroll
        for (int t = 0; t < CO; ++t) {
            o[t] += hx * W[(m4*4+0) * CO + t];
            o[t] += hy * W[(m4*4+1) * CO + t];
            o[t] += hz * W[(m4*4+2) * CO + t];
            o[t] += hw * W[(m4*4+3) * CO + t];
        }
    }
    float* orow = outp + (size_t)n * CO;
#pragma unroll
    for (int t4 = 0; t4 < CO / 4; ++t4)
        reinterpret_cast<float4*>(orow)[t4] = make_float4(o[t4*4+0], o[t4*4+1], o[t4*4+2], o[t4*4+3]);
}

extern "C" void kernel_launch(void* const* d_in, const int* in_sizes, int n_in,
                              void* d_out, int out_size, void* d_ws, size_t ws_size,
                              hipStream_t stream) {
    const float* x     = (const float*)d_in[0];
    const int*   ei    = (const int*)d_in[1];
    const float* ea    = (const float*)d_in[2];
    const float* l1_Wl = (const float*)d_in[3];  const float* l1_bl = (const float*)d_in[4];
    const float* l1_Wr = (const float*)d_in[5];  const float* l1_We = (const float*)d_in[6];
    const float* l1_be = (const float*)d_in[7];  const float* l1_Wg = (const float*)d_in[8];
    const float* l1_bg = (const float*)d_in[9];  const float* l1_bng= (const float*)d_in[10];
    const float* l1_bnb= (const float*)d_in[11];
    const float* l2_Wl = (const float*)d_in[12]; const float* l2_bl = (const float*)d_in[13];
    const float* l2_Wr = (const float*)d_in[14]; const float* l2_We = (const float*)d_in[15];
    const float* l2_be = (const float*)d_in[16]; const float* l2_Wg = (const float*)d_in[17];
    const float* l2_bg = (const float*)d_in[18]; const float* l2_bng= (const float*)d_in[19];
    const float* l2_bnb= (const float*)d_in[20];
    const float* gn1_g = (const float*)d_in[21]; const float* gn1_b = (const float*)d_in[22];
    const float* gn1_a = (const float*)d_in[23];
    const float* gn2_g = (const float*)d_in[24]; const float* gn2_b = (const float*)d_in[25];
    const float* gn2_a = (const float*)d_in[26];
    const float* lin_W = (const float*)d_in[27]; const float* lin_b = (const float*)d_in[28];

    const int N = in_sizes[0] / 32;
    const int E = in_sizes[1] / 2;
    const int* rows = ei;
    const int* cols = ei + E;

    // bucket geometry
    int SH = 7, NPB = 128;
    while (((N + NPB - 1) >> SH) > 1024) { SH++; NPB <<= 1; }
    const int NB = (N + NPB - 1) >> SH;
    const int PB = (E + CPART - 1) / CPART;

    float* w    = (float*)d_ws;
    int* wth1   = (int*)w;
    int* wgh1   = (int*)(w + 512);
    int* wth2   = (int*)(w + 1024);
    int* wgh2   = (int*)(w + 1536);
    float* ets1 = w + 2048; float* vs1 = w + 2112; float* dv1 = w + 2176;
    float* ets2 = w + 2240; float* vs2 = w + 2304; float* dv2 = w + 2368;
    float* stats= w + 2432;

    int* ip     = (int*)(w + 8192);
    int* rowptr = ip;                 // N+1 (persistent)
    int* cnt    = ip + (N + 1);       // N
    int* bs     = cnt + N;            // 1024
    int* ranges = bs + 1024;          // NWAVES+2 (persistent)
    int* erow   = ranges + (NWAVES + 2);  // E (persistent)

    uintptr_t pa = (uintptr_t)(erow + E);
    pa = (pa + 255) & ~(uintptr_t)255;
    __half* eap = (__half*)pa;        // E*16 halves (persistent)
    uintptr_t px = (uintptr_t)(eap + (size_t)E * ED);
    px = (px + 255) & ~(uintptr_t)255;
    __half* xh = (__half*)px;         // N*32 halves (persistent)
    uintptr_t pz = (uintptr_t)(xh + (size_t)N * 32);
    pz = (pz + 255) & ~(uintptr_t)255;

    // --- overlap zone: {tmp, offtab, eah} (CSR build) then {B0, Bpre, Bu, B3h} (layers) ---
    int2* tmp   = (int2*)pz;                       // E
    int* offtab = (int*)(tmp + E);                 // PB*(NB+1)
    uintptr_t pe = (uintptr_t)(offtab + (size_t)PB * (NB + 1));
    pe = (pe + 255) & ~(uintptr_t)255;
    int4* eah = (int4*)pe;                         // E*2 int4 (32B/edge)

    size_t NB64 = (size_t)N * H;
    float* B0 = (float*)pz;                        // agg (fp32, N*64) — aliases tmp/offtab/eah
    __half* Bpre = (__half*)(B0 + NB64);           // pre/t (f16)
    __half* Bu   = Bpre + NB64;                    // u (f16)
    __half* B3h  = Bu + NB64;                      // h layer1 (f16)
    __half* B0h  = (__half*)B0;                    // h layer2 reuses B0 space

    const float Ninv = 1.0f / (float)N;
    dim3 rb(64, 4);
    int egrid = (E + 255) / 256;
    int ngrid = (N + 255) / 256;
    int g64 = (N + 63) / 64;
    const int SB = (N + 1023) >> 10;

    k_prep<<<1, 64, 0, stream>>>(l1_We, l1_be, l1_Wg, l2_We, l2_be, l2_Wg, w);
    k_xh<<<(N * 8 + 255) / 256, 256, 0, stream>>>(x, xh, N * 8);
    k_eah<<<egrid, 256, 0, stream>>>(ea, eah, E);

    // ---- CSR build: count -> scan -> partition -> per-bucket exact build ----
    hipMemsetAsync(cnt, 0, sizeof(int) * (size_t)N, stream);
    k_count<<<egrid, 256, 0, stream>>>(cols, cnt, E);
    k_scan1<<<SB, 1024, 0, stream>>>(cnt, bs, N);
    k_scan2<<<1, 1024, 0, stream>>>(bs, SB);
    k_scan3<<<SB, 1024, 0, stream>>>(cnt, bs, rowptr, N, E);
    k_ranges<<<(NWAVES + 256) / 256, 256, 0, stream>>>(rowptr, ranges, N, E, NWAVES);
    k_part<<<PB, 256, 0, stream>>>(rows, cols, tmp, offtab, E, NB, SH);
    k_build<<<NB, 256, 0, stream>>>(rowptr, tmp, offtab, eah, erow, eap, N, NB, SH, PB);

    // ---- layer 1 ----
    k_gather<32, false><<<WGRID, 256, 0, stream>>>(xh, rowptr, ranges, erow, B0,
                                                   nullptr, nullptr, nullptr, nullptr, nullptr, 0.f, N);
    k_gemmfu<32, false><<<g64, 256, 0, stream>>>(B0, xh, 32, l1_Wl, l1_Wr, l1_bl, l1_Wg, l1_bg,
                                                 nullptr, nullptr, nullptr, nullptr, nullptr, 0.f,
                                                 rowptr, Bpre, Bu, N);
    k_gate<<<WGRID, 256, 0, stream>>>(rowptr, ranges, eap, wth1, wgh1, l1_be, dv1, ets1, vs1,
                                      Bu, Bpre, stats + 0, stats + 64, N);
    k_apply<<<256, rb, 0, stream>>>(Bpre, B3h, l1_bng, l1_bnb, stats + 0, stats + 64,
                                    stats + 128, stats + 192, Ninv, N);

    // ---- layer 2 (gn1 folded into readers of B3h) ----
    k_gather<64, true><<<WGRID, 256, 0, stream>>>(B3h, rowptr, ranges, erow, B0,
                                                  stats + 128, stats + 192, gn1_g, gn1_b, gn1_a, Ninv, N);
    k_gemmfu<64, true><<<g64, 256, 0, stream>>>(B0, B3h, 64, l2_Wl, l2_Wr, l2_bl, l2_Wg, l2_bg,
                                                stats + 128, stats + 192, gn1_g, gn1_b, gn1_a, Ninv,
                                                rowptr, Bpre, Bu, N);
    k_gate<<<WGRID, 256, 0, stream>>>(rowptr, ranges, eap, wth2, wgh2, l2_be, dv2, ets2, vs2,
                                      Bu, Bpre, stats + 256, stats + 320, N);
    k_apply<<<256, rb, 0, stream>>>(Bpre, B0h, l2_bng, l2_bnb, stats + 256, stats + 320,
                                    stats + 384, stats + 448, Ninv, N);

    // ---- final ----
    k_final<<<ngrid, 256, 0, stream>>>(B0h, lin_W, lin_b, stats + 384, stats + 448,
                                       gn2_g, gn2_b, gn2_a, Ninv, (float*)d_out, N);
}

// Round 12
// 676.466 us; speedup vs baseline: 1.1238x; 1.0280x over previous
//
#include <hip/hip_runtime.h>
#include <hip/hip_fp16.h>
#include <math.h>
#include <stdint.h>

#define H 64
#define ED 16
#define CO 16
#define WGRID 2048
#define NWAVES (WGRID * 4)
#define CPART 2048
static constexpr float EPSV = 1e-5f;
static constexpr float LOG2E = 1.44269504f;

typedef _Float16 h2v __attribute__((ext_vector_type(2)));
typedef _Float16 f16x8 __attribute__((ext_vector_type(8)));
typedef float f32x4 __attribute__((ext_vector_type(4)));

__device__ __forceinline__ float sigm2(float z) {
    return __builtin_amdgcn_rcpf(1.0f + __builtin_amdgcn_exp2f(-z));
}

__device__ __forceinline__ h2v as_h2(int x) { union { int i; h2v h; } u; u.i = x; return u.h; }

__device__ __forceinline__ f16x8 as_f16x8(int4 v) { union { int4 i; f16x8 h; } u; u.i = v; return u.h; }

__device__ __forceinline__ int pack2(float a, float b) {
    __half2 h = __floats2half2_rn(a, b);
    return *reinterpret_cast<int*>(&h);
}

// ---------------- prep: packed-f16 gate weights (log2e-folded gate path), self-loop consts, zero stats --
__global__ void k_prep(const float* __restrict__ We1, const float* __restrict__ be1, const float* __restrict__ Wg1,
                       const float* __restrict__ We2, const float* __restrict__ be2, const float* __restrict__ Wg2,
                       float* __restrict__ ws) {
    int j = threadIdx.x;  // 0..63
    for (int l = 0; l < 2; ++l) {
        const float* We = l ? We2 : We1;
        const float* be = l ? be2 : be1;
        const float* Wg = l ? Wg2 : Wg1;
        int* wth = (int*)(ws + (l ? 1024 : 0));
        int* wgh = (int*)(ws + (l ? 1536 : 512));
        float* ets = ws + 2048 + l * 192;
        float* vs  = ws + 2112 + l * 192;
        float* dv  = ws + 2176 + l * 192;
        float wt[ED], wg[ED];
        float et = be[j];
        for (int k = 0; k < ED; ++k) { wt[k] = We[k * H + j]; et += wt[k]; }
        ets[j] = et;                                   // ea_t for self-loop (ea = ones)
        float d = 0.f;
        for (int m = 0; m < H; ++m) d += be[m] * Wg[(H + m) * H + j];
        float vsum = d;
        for (int k = 0; k < ED; ++k) {
            float acc = 0.f;
            for (int m = 0; m < H; ++m) acc += We[k * H + m] * Wg[(H + m) * H + j];
            wg[k] = acc;                               // (We @ Wg_bot)^T
            vsum += acc;
        }
        dv[j] = d * LOG2E;
        vs[j] = vsum * LOG2E;
        for (int q = 0; q < 8; ++q) {
            wth[j * 8 + q] = pack2(wt[2 * q], wt[2 * q + 1]);
            wgh[j * 8 + q] = pack2(wg[2 * q] * LOG2E, wg[2 * q + 1] * LOG2E);
        }
    }
    for (int s = 0; s < 8; ++s) ws[2432 + s * 64 + j] = 0.f;  // zero all stats
}

// ---------------- x -> f16 ----------------
__global__ void k_xh(const float* __restrict__ x, __half* __restrict__ xh, int total4) {
    int i = blockIdx.x * blockDim.x + threadIdx.x;
    if (i >= total4) return;
    float4 v = *reinterpret_cast<const float4*>(x + (size_t)i * 4);
    __half2 h0 = __floats2half2_rn(v.x, v.y), h1 = __floats2half2_rn(v.z, v.w);
    uint2 o;
    o.x = *reinterpret_cast<unsigned*>(&h0);
    o.y = *reinterpret_cast<unsigned*>(&h1);
    *reinterpret_cast<uint2*>(xh + (size_t)i * 4) = o;
}

// ---------------- ea -> f16 (input order, coalesced) ----------------
__global__ void k_eah(const float* __restrict__ ea, int4* __restrict__ eah, int E) {
    int e = blockIdx.x * blockDim.x + threadIdx.x;
    if (e >= E) return;
    const float4* src = reinterpret_cast<const float4*>(ea + (size_t)e * ED);
    float4 v0 = src[0], v1 = src[1], v2 = src[2], v3 = src[3];
    int hh[8];
    hh[0] = pack2(v0.x, v0.y); hh[1] = pack2(v0.z, v0.w);
    hh[2] = pack2(v1.x, v1.y); hh[3] = pack2(v1.z, v1.w);
    hh[4] = pack2(v2.x, v2.y); hh[5] = pack2(v2.z, v2.w);
    hh[6] = pack2(v3.x, v3.y); hh[7] = pack2(v3.z, v3.w);
    const int4* o = reinterpret_cast<const int4*>(hh);
    eah[(size_t)e * 2 + 0] = o[0];
    eah[(size_t)e * 2 + 1] = o[1];
}

// ---------------- CSR build: count + scan ----------------
__global__ void k_count(const int* __restrict__ cols, int* __restrict__ cnt, int E) {
    int e = blockIdx.x * blockDim.x + threadIdx.x;
    if (e < E) atomicAdd(&cnt[cols[e]], 1);
}

__global__ __launch_bounds__(1024) void k_scan1(const int* __restrict__ cnt, int* __restrict__ bs, int N) {
    __shared__ int ls[1024];
    int t = threadIdx.x;
    int i = blockIdx.x * 1024 + t;
    ls[t] = (i < N) ? cnt[i] : 0;
    __syncthreads();
    for (int off = 512; off > 0; off >>= 1) {
        if (t < off) ls[t] += ls[t + off];
        __syncthreads();
    }
    if (t == 0) bs[blockIdx.x] = ls[0];
}

__global__ __launch_bounds__(1024) void k_scan2(int* __restrict__ bs, int SB) {
    __shared__ int ls[1024];
    int t = threadIdx.x;
    int v = (t < SB) ? bs[t] : 0;
    ls[t] = v;
    __syncthreads();
    for (int off = 1; off < 1024; off <<= 1) {
        int x = (t >= off) ? ls[t - off] : 0;
        __syncthreads();
        ls[t] += x;
        __syncthreads();
    }
    if (t < SB) bs[t] = ls[t] - v;  // exclusive
}

__global__ __launch_bounds__(1024) void k_scan3(const int* __restrict__ cnt, const int* __restrict__ bs,
                                                int* __restrict__ rowptr, int N, int E) {
    __shared__ int ls[1024];
    int t = threadIdx.x;
    int i = blockIdx.x * 1024 + t;
    int v = (i < N) ? cnt[i] : 0;
    ls[t] = v;
    __syncthreads();
    for (int off = 1; off < 1024; off <<= 1) {
        int x = (t >= off) ? ls[t - off] : 0;
        __syncthreads();
        ls[t] += x;
        __syncthreads();
    }
    if (i < N) rowptr[i] = bs[blockIdx.x] + ls[t] - v;  // exclusive prefix
    if (i == 0) rowptr[N] = E;
}

// ---------------- wave ranges ----------------
__global__ void k_ranges(const int* __restrict__ rowptr, int* __restrict__ ranges, int N, int E, int nw) {
    int w = blockIdx.x * blockDim.x + threadIdx.x;
    if (w > nw) return;
    if (w == nw) { ranges[nw] = N; return; }
    int t0 = (int)((long)E * w / nw);
    int lo = 0, hi = N;
    while (lo < hi) { int mid = (lo + hi) >> 1; if (rowptr[mid] < t0) lo = mid + 1; else hi = mid; }
    ranges[w] = lo;
}

// ---------------- partition pass 1: block-local bucket sort, fully coalesced writes ----------------
__global__ __launch_bounds__(256) void k_part(const int* __restrict__ rows, const int* __restrict__ cols,
                                              int2* __restrict__ tmp, int* __restrict__ offtab,
                                              int E, int NB, int SH) {
    __shared__ int hist[1025];
    __shared__ int pscan[256];
    __shared__ int2 stage[CPART];
    int tid = threadIdx.x;
    int base = blockIdx.x * CPART;
    int cnt = min(CPART, E - base);
    for (int i = tid; i <= NB; i += 256) hist[i] = 0;
    __syncthreads();
    int myc[8], myr[8];
#pragma unroll
    for (int q = 0; q < 8; ++q) {
        int li = q * 256 + tid;
        if (li < cnt) {
            int e = base + li;
            myc[q] = cols[e];
            myr[q] = rows[e];
            atomicAdd(&hist[myc[q] >> SH], 1);
        } else myc[q] = -1;
    }
    __syncthreads();
    int h[4], s = 0;
    int b0 = tid * 4;
#pragma unroll
    for (int k = 0; k < 4; ++k) { h[k] = (b0 + k < NB) ? hist[b0 + k] : 0; s += h[k]; }
    pscan[tid] = s;
    __syncthreads();
    for (int off = 1; off < 256; off <<= 1) {
        int v = (tid >= off) ? pscan[tid - off] : 0;
        __syncthreads();
        pscan[tid] += v;
        __syncthreads();
    }
    int excl = pscan[tid] - s;
    __syncthreads();
    int run = excl;
#pragma unroll
    for (int k = 0; k < 4; ++k) {
        if (b0 + k < NB) hist[b0 + k] = run;
        run += h[k];
    }
    __syncthreads();
    int* ot = offtab + (size_t)blockIdx.x * (NB + 1);
    for (int i = tid; i < NB; i += 256) ot[i] = hist[i];
    if (tid == 0) ot[NB] = cnt;
    __syncthreads();
    int mask = (1 << SH) - 1;
#pragma unroll
    for (int q = 0; q < 8; ++q) {
        if (myc[q] >= 0) {
            int b = myc[q] >> SH;
            int p = atomicAdd(&hist[b], 1);
            int e = base + q * 256 + tid;
            stage[p] = make_int2(myr[q], (e << SH) | (myc[q] & mask));
        }
    }
    __syncthreads();
    int2* dst = tmp + base;
    for (int i = tid; i < cnt; i += 256) dst[i] = stage[i];
}

// ---------------- build pass 2: per-bucket exact CSR scatter, 1024 threads (1 run/thread) ----------
__global__ __launch_bounds__(1024) void k_build(const int* __restrict__ rowptr, const int2* __restrict__ tmp,
                                               const int* __restrict__ offtab, const int4* __restrict__ eah,
                                               int* __restrict__ erow, __half* __restrict__ eap,
                                               int N, int NB, int SH, int PB) {
    __shared__ int lcur[1024];
    int tid = threadIdx.x;
    int b = blockIdx.x;
    int NPB = 1 << SH;
    int nodelo = b << SH;
    for (int j = tid; j < NPB; j += 1024) {
        int n = nodelo + j;
        lcur[j] = (n < N) ? rowptr[n] : 0;
    }
    __syncthreads();
    int mask = NPB - 1;
    for (int i = tid; i < PB; i += 1024) {
        const int* ot = offtab + (size_t)i * (NB + 1);
        int j0 = ot[b], j1 = ot[b + 1];
        for (int j = j0; j < j1; ++j) {
            int2 v = tmp[(size_t)i * CPART + j];
            int e = (int)(((unsigned)v.y) >> SH);
            int cl = v.y & mask;
            int p = atomicAdd(&lcur[cl], 1);
            erow[p] = v.x;
            int4 a0 = eah[(size_t)e * 2 + 0];
            int4 a1 = eah[(size_t)e * 2 + 1];
            int4* d = reinterpret_cast<int4*>(eap + (size_t)p * ED);
            d[0] = a0; d[1] = a1;
        }
    }
}

// ---------------- gather (f16 input): agg[n] = T(x[n]) + sum_in T(x[row]) ----
template <int CIN, bool GN>
__global__ __launch_bounds__(256) void k_gather(const __half* __restrict__ x, const int* __restrict__ rowptr,
                         const int* __restrict__ ranges,
                         const int* __restrict__ erow, float* __restrict__ agg,
                         const float* __restrict__ s1, const float* __restrict__ s2,
                         const float* __restrict__ gng, const float* __restrict__ gnb,
                         const float* __restrict__ gna, float Ninv, int N) {
    int lane = threadIdx.x & 63;
    int w = (blockIdx.x * blockDim.x + threadIdx.x) >> 6;
    float A = 1.f, B = 0.f;
    if (GN) {
        float mu = s1[lane] * Ninv, m2 = s2[lane] * Ninv, a = gna[lane];
        float var = m2 - 2.f * a * mu * mu + a * a * mu * mu;
        A = gng[lane] * rsqrtf(var + EPSV);
        B = gnb[lane] - A * a * mu;
    }
    int n0 = ranges[w], n1 = ranges[w + 1];
    for (int n = n0; n < n1; ++n) {
        int s = rowptr[n], te = rowptr[n + 1];
        if (CIN == 64) {
            float raw = __half2float(x[(size_t)n * 64 + lane]);
            float acc = GN ? fmaxf(fmaf(A, raw, B), 0.f) : raw;
            int i = s;
            for (; i + 7 < te; i += 8) {
                int r0 = erow[i],     r1 = erow[i + 1], r2 = erow[i + 2], r3 = erow[i + 3];
                int r4 = erow[i + 4], r5 = erow[i + 5], r6 = erow[i + 6], r7 = erow[i + 7];
                float x0 = __half2float(x[(size_t)r0 * 64 + lane]);
                float x1 = __half2float(x[(size_t)r1 * 64 + lane]);
                float x2 = __half2float(x[(size_t)r2 * 64 + lane]);
                float x3 = __half2float(x[(size_t)r3 * 64 + lane]);
                float x4 = __half2float(x[(size_t)r4 * 64 + lane]);
                float x5 = __half2float(x[(size_t)r5 * 64 + lane]);
                float x6 = __half2float(x[(size_t)r6 * 64 + lane]);
                float x7 = __half2float(x[(size_t)r7 * 64 + lane]);
                if (GN) {
                    x0 = fmaxf(fmaf(A, x0, B), 0.f); x1 = fmaxf(fmaf(A, x1, B), 0.f);
                    x2 = fmaxf(fmaf(A, x2, B), 0.f); x3 = fmaxf(fmaf(A, x3, B), 0.f);
                    x4 = fmaxf(fmaf(A, x4, B), 0.f); x5 = fmaxf(fmaf(A, x5, B), 0.f);
                    x6 = fmaxf(fmaf(A, x6, B), 0.f); x7 = fmaxf(fmaf(A, x7, B), 0.f);
                }
                acc += ((x0 + x1) + (x2 + x3)) + ((x4 + x5) + (x6 + x7));
            }
            for (; i < te; ++i) {
                float xv = __half2float(x[(size_t)erow[i] * 64 + lane]);
                if (GN) xv = fmaxf(fmaf(A, xv, B), 0.f);
                acc += xv;
            }
            agg[(size_t)n * H + lane] = acc;
        } else {
            int c = lane & 31, half = lane >> 5;
            float acc = half ? 0.f : __half2float(x[(size_t)n * 32 + c]);
            int i = s + half;
            for (; i + 6 < te; i += 8) {
                int r0 = erow[i], r1 = erow[i + 2], r2 = erow[i + 4], r3 = erow[i + 6];
                float x0 = __half2float(x[(size_t)r0 * 32 + c]);
                float x1 = __half2float(x[(size_t)r1 * 32 + c]);
                float x2 = __half2float(x[(size_t)r2 * 32 + c]);
                float x3 = __half2float(x[(size_t)r3 * 32 + c]);
                acc += (x0 + x1) + (x2 + x3);
            }
            for (; i < te; i += 2) acc += __half2float(x[(size_t)erow[i] * 32 + c]);
            acc += __shfl_xor(acc, 32);
            if (half == 0) agg[(size_t)n * H + c] = acc;
        }
    }
}

// ---------------- fused GEMM: pre = (agg/deg)@Wl + T(x)@Wr + bl ; u = (pre@Wg_top + bg)*log2e ----------
#define MT4A(mq, aval) \
    acc[mq][0] = fmaf(aval, w1.x, acc[mq][0]); acc[mq][1] = fmaf(aval, w1.y, acc[mq][1]); \
    acc[mq][2] = fmaf(aval, w1.z, acc[mq][2]); acc[mq][3] = fmaf(aval, w1.w, acc[mq][3]);
#define MT4X(mq, aval) \
    acc[mq][0] = fmaf(aval, w2.x, acc[mq][0]); acc[mq][1] = fmaf(aval, w2.y, acc[mq][1]); \
    acc[mq][2] = fmaf(aval, w2.z, acc[mq][2]); acc[mq][3] = fmaf(aval, w2.w, acc[mq][3]);

template <int K, bool GN>
__global__ __launch_bounds__(256) void k_gemmfu(
        const float* __restrict__ A,               // agg, stride 64
        const __half* __restrict__ A2, int lda2,   // x-side (f16)
        const float* __restrict__ W1, const float* __restrict__ W2,
        const float* __restrict__ bias,
        const float* __restrict__ Wg, const float* __restrict__ bg,
        const float* __restrict__ s1, const float* __restrict__ s2,
        const float* __restrict__ gng, const float* __restrict__ gnb,
        const float* __restrict__ gna, float Ninv,
        const int* __restrict__ rowptr,
        __half* __restrict__ pre, __half* __restrict__ uout, int N) {
    __shared__ float WA[64 * 64];
    __shared__ float WB[K * 64];
    __shared__ float big[64][68];
    __shared__ float As[64], Bs[64], invd[64];
    int tid = threadIdx.x;
    for (int idx = tid; idx < K * 64; idx += 256) { WA[idx] = W1[idx]; WB[idx] = W2[idx]; }
    int nb = blockIdx.x * 64;
    if (tid < 64) {
        if (GN) {
            float mu = s1[tid] * Ninv, m2 = s2[tid] * Ninv, a = gna[tid];
            float var = m2 - 2.f * a * mu * mu + a * a * mu * mu;
            float Av = gng[tid] * rsqrtf(var + EPSV);
            As[tid] = Av; Bs[tid] = gnb[tid] - Av * a * mu;
        }
        int n = nb + tid;
        invd[tid] = (n < N) ? 1.f / (float)(rowptr[n + 1] - rowptr[n] + 1) : 0.f;
    }
    __syncthreads();
    int tm = tid >> 4, tn = tid & 15;
    int m0 = tm * 4, j0 = tn * 4;
    float acc[4][4];
#pragma unroll
    for (int jq = 0; jq < 4; ++jq) {
        float b = bias[j0 + jq];
#pragma unroll
        for (int mq = 0; mq < 4; ++mq) acc[mq][jq] = b;
    }
    int sn = tid >> 2, kq4 = (tid & 3) * 4;
    int sg = nb + sn;
    for (int k0 = 0; k0 < K; k0 += 16) {
        if (k0) __syncthreads();
        if (sg < N) {
            float4 av = *reinterpret_cast<const float4*>(A + (size_t)sg * 64 + k0 + kq4);
            float sc = invd[sn];
            av.x *= sc; av.y *= sc; av.z *= sc; av.w *= sc;
            big[kq4 + 0][sn] = av.x; big[kq4 + 1][sn] = av.y;
            big[kq4 + 2][sn] = av.z; big[kq4 + 3][sn] = av.w;
            uint2 hv = *reinterpret_cast<const uint2*>(A2 + (size_t)sg * lda2 + k0 + kq4);
            __half2 h01 = *reinterpret_cast<__half2*>(&hv.x);
            __half2 h23 = *reinterpret_cast<__half2*>(&hv.y);
            float2 f01 = __half22float2(h01), f23 = __half22float2(h23);
            float xv0 = f01.x, xv1 = f01.y, xv2 = f23.x, xv3 = f23.y;
            if (GN) {
                xv0 = fmaxf(fmaf(As[k0 + kq4 + 0], xv0, Bs[k0 + kq4 + 0]), 0.f);
                xv1 = fmaxf(fmaf(As[k0 + kq4 + 1], xv1, Bs[k0 + kq4 + 1]), 0.f);
                xv2 = fmaxf(fmaf(As[k0 + kq4 + 2], xv2, Bs[k0 + kq4 + 2]), 0.f);
                xv3 = fmaxf(fmaf(As[k0 + kq4 + 3], xv3, Bs[k0 + kq4 + 3]), 0.f);
            }
            big[16 + kq4 + 0][sn] = xv0; big[16 + kq4 + 1][sn] = xv1;
            big[16 + kq4 + 2][sn] = xv2; big[16 + kq4 + 3][sn] = xv3;
        } else {
#pragma unroll
            for (int q = 0; q < 4; ++q) { big[kq4 + q][sn] = 0.f; big[16 + kq4 + q][sn] = 0.f; }
        }
        __syncthreads();
#pragma unroll
        for (int k = 0; k < 16; ++k) {
            float4 am = *reinterpret_cast<const float4*>(&big[k][m0]);
            float4 w1 = *reinterpret_cast<const float4*>(&WA[(k0 + k) * 64 + j0]);
            MT4A(0, am.x) MT4A(1, am.y) MT4A(2, am.z) MT4A(3, am.w)
            float4 xm = *reinterpret_cast<const float4*>(&big[16 + k][m0]);
            float4 w2 = *reinterpret_cast<const float4*>(&WB[(k0 + k) * 64 + j0]);
            MT4X(0, xm.x) MT4X(1, xm.y) MT4X(2, xm.z) MT4X(3, xm.w)
        }
    }
    __syncthreads();
#pragma unroll
    for (int mq = 0; mq < 4; ++mq) {
        int n = nb + m0 + mq;
        if (n < N) {
            uint2 o;
            o.x = pack2(acc[mq][0], acc[mq][1]);
            o.y = pack2(acc[mq][2], acc[mq][3]);
            *reinterpret_cast<uint2*>(pre + (size_t)n * 64 + j0) = o;
        }
#pragma unroll
        for (int jq = 0; jq < 4; ++jq) big[j0 + jq][m0 + mq] = acc[mq][jq];
    }
    for (int idx = tid; idx < 4096; idx += 256) WA[idx] = Wg[idx] * LOG2E;
    __syncthreads();
    float acc2[4][4];
#pragma unroll
    for (int jq = 0; jq < 4; ++jq) {
        float b = bg[j0 + jq] * LOG2E;
#pragma unroll
        for (int mq = 0; mq < 4; ++mq) acc2[mq][jq] = b;
    }
#pragma unroll 8
    for (int k = 0; k < 64; ++k) {
        float4 pm = *reinterpret_cast<const float4*>(&big[k][m0]);
        float4 w1 = *reinterpret_cast<const float4*>(&WA[k * 64 + j0]);
        acc2[0][0] = fmaf(pm.x, w1.x, acc2[0][0]); acc2[0][1] = fmaf(pm.x, w1.y, acc2[0][1]);
        acc2[0][2] = fmaf(pm.x, w1.z, acc2[0][2]); acc2[0][3] = fmaf(pm.x, w1.w, acc2[0][3]);
        acc2[1][0] = fmaf(pm.y, w1.x, acc2[1][0]); acc2[1][1] = fmaf(pm.y, w1.y, acc2[1][1]);
        acc2[1][2] = fmaf(pm.y, w1.z, acc2[1][2]); acc2[1][3] = fmaf(pm.y, w1.w, acc2[1][3]);
        acc2[2][0] = fmaf(pm.z, w1.x, acc2[2][0]); acc2[2][1] = fmaf(pm.z, w1.y, acc2[2][1]);
        acc2[2][2] = fmaf(pm.z, w1.z, acc2[2][2]); acc2[2][3] = fmaf(pm.z, w1.w, acc2[2][3]);
        acc2[3][0] = fmaf(pm.w, w1.x, acc2[3][0]); acc2[3][1] = fmaf(pm.w, w1.y, acc2[3][1]);
        acc2[3][2] = fmaf(pm.w, w1.z, acc2[3][2]); acc2[3][3] = fmaf(pm.w, w1.w, acc2[3][3]);
    }
#pragma unroll
    for (int mq = 0; mq < 4; ++mq) {
        int n = nb + m0 + mq;
        if (n < N) {
            uint2 o;
            o.x = pack2(acc2[mq][0], acc2[mq][1]);
            o.y = pack2(acc2[mq][2], acc2[mq][3]);
            *reinterpret_cast<uint2*>(uout + (size_t)n * 64 + j0) = o;
        }
    }
}

// ---------------- gate: MFMA edge matmul with bias baked in at k=16; packed (V,ET) f16 LDS ----------
// ET[16x64] = ea_tile @ We + be ; V[16x64] = ea_tile @ (We@Wg_bot)*log2e + dv, via mfma_f32_16x16x32_f16.
// A-frag: lane l holds A[l&15][8*(l>>4)+i]; k=16 column = 1.0 (bias). B row 16 = be / dv.
// C/D: col=lane&15, row=(lane>>4)*4+reg (verified layout).
__global__ __launch_bounds__(256) void k_gate(
        const int* __restrict__ rowptr, const int* __restrict__ ranges,
        const __half* __restrict__ eap,
        const int* __restrict__ wth, const int* __restrict__ wgh,
        const float* __restrict__ be, const float* __restrict__ dv,
        const float* __restrict__ ets, const float* __restrict__ vs,
        const __half* __restrict__ u, __half* __restrict__ pre,
        float* __restrict__ s1, float* __restrict__ s2, int N) {
    __shared__ __align__(16) int4 estage[4][128];      // 2KB per wave (64 edges x 32B)
    __shared__ unsigned pvet[4][16][68];               // packed half2{V, ET}
    __shared__ float ls[2][4][H];
    int lane = threadIdx.x & 63;
    int wv = threadIdx.x >> 6;
    int w = (blockIdx.x << 2) | wv;
    int g = lane >> 4, li = lane & 15;
    // loop-invariant B fragments; bias row at k=16 (group 2, elem 0)
    f16x8 Bet[4], Bv[4];
#pragma unroll
    for (int c = 0; c < 4; ++c) {
        int j = c * 16 + li;
        int4 bt = make_int4(0, 0, 0, 0), bv = make_int4(0, 0, 0, 0);
        if (g < 2) {
            bt = *reinterpret_cast<const int4*>(&wth[j * 8 + g * 4]);
            bv = *reinterpret_cast<const int4*>(&wgh[j * 8 + g * 4]);
        }
        Bet[c] = as_f16x8(bt);
        Bv[c] = as_f16x8(bv);
        if (g == 2) {
            Bet[c][0] = (_Float16)be[j];
            Bv[c][0]  = (_Float16)dv[j];
        }
    }
    float ets_l = ets[lane], vs_l = vs[lane];
    int n0 = ranges[w], n1 = ranges[w + 1];
    float s = 0.f, ss = 0.f;
    if (n0 < n1) {
        int4* dst = &estage[wv][0];
        const int4* gsrc = reinterpret_cast<const int4*>(eap);
        int e0 = rowptr[n0], e1 = rowptr[n1];
        int n = n0;
        int nend = rowptr[n0 + 1];
        size_t idx = (size_t)n * H + lane;
        float u_l = __half2float(u[idx]);
        float pv = __half2float(pre[idx]);
        int np = min(n + 1, n1 - 1);
        size_t idxn = (size_t)np * H + lane;
        float u_n = __half2float(u[idxn]);
        float pv_n = __half2float(pre[idxn]);
        float acc = sigm2(u_l + vs_l) * ets_l;   // folded self-loop contribution
        {   // stage first chunk
            int bytes = min(64, e1 - e0) * 32;
            int4 p0, p1;
            if (lane * 16 < bytes) p0 = gsrc[(size_t)e0 * 2 + lane];
            if (1024 + lane * 16 < bytes) p1 = gsrc[(size_t)e0 * 2 + 64 + lane];
            if (lane * 16 < bytes) dst[lane] = p0;
            if (1024 + lane * 16 < bytes) dst[64 + lane] = p1;
        }
        for (int c = e0; c < e1; c += 64) {
            int cnt = min(64, e1 - c);
            int nbytes = (c + 64 < e1) ? min(64, e1 - c - 64) * 32 : 0;
            int4 p0, p1;
            if (lane * 16 < nbytes) p0 = gsrc[(size_t)(c + 64) * 2 + lane];
            if (1024 + lane * 16 < nbytes) p1 = gsrc[(size_t)(c + 64) * 2 + 64 + lane];
            for (int tb = 0; tb < cnt; tb += 16) {
                // ---- MFMA: ET/V (+bias) for this 16-edge tile ----
                int4 af = make_int4(0, 0, 0, 0);
                if (g < 2) af = dst[(tb + li) * 2 + g];
                f16x8 Af = as_f16x8(af);
                if (g == 2) Af[0] = (_Float16)1.0f;    // bias column
                f32x4 z = {0.f, 0.f, 0.f, 0.f};
                f32x4 et0 = __builtin_amdgcn_mfma_f32_16x16x32_f16(Af, Bet[0], z, 0, 0, 0);
                f32x4 et1 = __builtin_amdgcn_mfma_f32_16x16x32_f16(Af, Bet[1], z, 0, 0, 0);
                f32x4 et2 = __builtin_amdgcn_mfma_f32_16x16x32_f16(Af, Bet[2], z, 0, 0, 0);
                f32x4 et3 = __builtin_amdgcn_mfma_f32_16x16x32_f16(Af, Bet[3], z, 0, 0, 0);
                f32x4 vv0 = __builtin_amdgcn_mfma_f32_16x16x32_f16(Af, Bv[0], z, 0, 0, 0);
                f32x4 vv1 = __builtin_amdgcn_mfma_f32_16x16x32_f16(Af, Bv[1], z, 0, 0, 0);
                f32x4 vv2 = __builtin_amdgcn_mfma_f32_16x16x32_f16(Af, Bv[2], z, 0, 0, 0);
                f32x4 vv3 = __builtin_amdgcn_mfma_f32_16x16x32_f16(Af, Bv[3], z, 0, 0, 0);
                int r0 = g * 4;
#pragma unroll
                for (int r = 0; r < 4; ++r) {
                    pvet[wv][r0 + r][li]      = (unsigned)pack2(vv0[r], et0[r]);
                    pvet[wv][r0 + r][16 + li] = (unsigned)pack2(vv1[r], et1[r]);
                    pvet[wv][r0 + r][32 + li] = (unsigned)pack2(vv2[r], et2[r]);
                    pvet[wv][r0 + r][48 + li] = (unsigned)pack2(vv3[r], et3[r]);
                }
                // ---- consume tile (channel = lane) ----
                int p = tb, pend = min(cnt, tb + 16);
                while (p < pend) {
                    while (c + p == nend) {       // node boundary: finish n, start next
                        float tval = pv + acc;
                        pre[idx] = __float2half(tval);
                        s += tval; ss += tval * tval;
                        ++n;
                        idx = idxn; u_l = u_n; pv = pv_n;
                        np = min(n + 1, n1 - 1);
                        idxn = (size_t)np * H + lane;
                        u_n = __half2float(u[idxn]);
                        pv_n = __half2float(pre[idxn]);
                        acc = sigm2(u_l + vs_l) * ets_l;
                        nend = rowptr[n + 1];
                    }
                    int lim = min(pend, nend - c);
                    for (; p + 1 < lim; p += 2) {
                        unsigned w0 = pvet[wv][p - tb][lane];
                        unsigned w1 = pvet[wv][p + 1 - tb][lane];
                        float2 f0 = __half22float2(*reinterpret_cast<__half2*>(&w0));
                        float2 f1 = __half22float2(*reinterpret_cast<__half2*>(&w1));
                        acc += sigm2(u_l + f0.x) * f0.y + sigm2(u_l + f1.x) * f1.y;
                    }
                    if (p < lim) {
                        unsigned w0 = pvet[wv][p - tb][lane];
                        float2 f0 = __half22float2(*reinterpret_cast<__half2*>(&w0));
                        acc += sigm2(u_l + f0.x) * f0.y;
                        ++p;
                    }
                }
            }
            if (lane * 16 < nbytes) dst[lane] = p0;
            if (1024 + lane * 16 < nbytes) dst[64 + lane] = p1;
        }
        for (;;) {   // finish current + trailing zero-edge nodes
            float tval = pv + acc;
            pre[idx] = __float2half(tval);
            s += tval; ss += tval * tval;
            ++n;
            if (n >= n1) break;
            idx = idxn; u_l = u_n; pv = pv_n;
            np = min(n + 1, n1 - 1);
            idxn = (size_t)np * H + lane;
            u_n = __half2float(u[idxn]);
            pv_n = __half2float(pre[idxn]);
            acc = sigm2(u_l + vs_l) * ets_l;
        }
    }
    ls[0][wv][lane] = s; ls[1][wv][lane] = ss;
    __syncthreads();
    if (threadIdx.x < H) {
        float a = ls[0][0][lane] + ls[0][1][lane] + ls[0][2][lane] + ls[0][3][lane];
        float b = ls[1][0][lane] + ls[1][1][lane] + ls[1][2][lane] + ls[1][3][lane];
        atomicAdd(&s1[lane], a);
        atomicAdd(&s2[lane], b);
    }
}

// ---------------- apply: h = relu(2*bn(t)) -> f16 + GraphNorm stats ----------------
__global__ void k_apply(const __half* __restrict__ in, __half* __restrict__ outb,
                        const float* __restrict__ bng, const float* __restrict__ bnb,
                        const float* __restrict__ s1b, const float* __restrict__ s2b,
                        float* __restrict__ s1g, float* __restrict__ s2g, float Ninv, int N) {
    int j = threadIdx.x, ty = threadIdx.y;
    __shared__ float As[H], Bs[H];
    if (ty == 0) {
        float mu = s1b[j] * Ninv, var = s2b[j] * Ninv - mu * mu;
        float r = rsqrtf(var + EPSV);
        float A = 2.f * bng[j] * r;
        As[j] = A; Bs[j] = 2.f * (bnb[j] - bng[j] * r * mu);
    }
    __syncthreads();
    float A = As[j], B = Bs[j];
    float s = 0.f, ss = 0.f;
    for (int n = blockIdx.x * 4 + ty; n < N; n += gridDim.x * 4) {
        size_t idx = (size_t)n * H + j;
        float v = fmaxf(fmaf(A, __half2float(in[idx]), B), 0.f);
        outb[idx] = __float2half(v);
        s += v; ss += v * v;
    }
    __shared__ float ls[2][4][H];
    ls[0][ty][j] = s; ls[1][ty][j] = ss;
    __syncthreads();
    if (ty == 0) {
        float a = ls[0][0][j] + ls[0][1][j] + ls[0][2][j] + ls[0][3][j];
        float b = ls[1][0][j] + ls[1][1][j] + ls[1][2][j] + ls[1][3][j];
        atomicAdd(&s1g[j], a);
        atomicAdd(&s2g[j], b);
    }
}

// ---------------- final: out = relu(gn2(h)) @ lin_W + lin_b ----------------
__global__ __launch_bounds__(256) void k_final(const __half* __restrict__ hraw, const float* __restrict__ W,
                        const float* __restrict__ bias,
                        const float* __restrict__ s1, const float* __restrict__ s2,
                        const float* __restrict__ gng, const float* __restrict__ gnb,
                        const float* __restrict__ gna, float Ninv,
                        float* __restrict__ outp, int N) {
    __shared__ float As[H], Bs[H];
    if (threadIdx.x < H) {
        int j = threadIdx.x;
        float mu = s1[j] * Ninv, m2 = s2[j] * Ninv, a = gna[j];
        float var = m2 - 2.f * a * mu * mu + a * a * mu * mu;
        float A = gng[j] * rsqrtf(var + EPSV);
        As[j] = A; Bs[j] = gnb[j] - A * a * mu;
    }
    __syncthreads();
    int n = blockIdx.x * blockDim.x + threadIdx.x;
    if (n >= N) return;
    float o[CO];
#pragma unroll
    for (int t = 0; t < CO; ++t) o[t] = bias[t];
    const __half* hr = hraw + (size_t)n * H;
    for (int m4 = 0; m4 < H / 4; ++m4) {
        uint2 hv = *reinterpret_cast<const uint2*>(hr + m4 * 4);
        __half2 h01 = *reinterpret_cast<__half2*>(&hv.x);
        __half2 h23 = *reinterpret_cast<__half2*>(&hv.y);
        float2 f01 = __half22float2(h01), f23 = __half22float2(h23);
        float hx = fmaxf(fmaf(As[m4*4+0], f01.x, Bs[m4*4+0]), 0.f);
        float hy = fmaxf(fmaf(As[m4*4+1], f01.y, Bs[m4*4+1]), 0.f);
        float hz = fmaxf(fmaf(As[m4*4+2], f23.x, Bs[m4*4+2]), 0.f);
        float hw = fmaxf(fmaf(As[m4*4+3], f23.y, Bs[m4*4+3]), 0.f);
#pragma unroll
        for (int t = 0; t < CO; ++t) {
            o[t] += hx * W[(m4*4+0) * CO + t];
            o[t] += hy * W[(m4*4+1) * CO + t];
            o[t] += hz * W[(m4*4+2) * CO + t];
            o[t] += hw * W[(m4*4+3) * CO + t];
        }
    }
    float* orow = outp + (size_t)n * CO;
#pragma unroll
    for (int t4 = 0; t4 < CO / 4; ++t4)
        reinterpret_cast<float4*>(orow)[t4] = make_float4(o[t4*4+0], o[t4*4+1], o[t4*4+2], o[t4*4+3]);
}

extern "C" void kernel_launch(void* const* d_in, const int* in_sizes, int n_in,
                              void* d_out, int out_size, void* d_ws, size_t ws_size,
                              hipStream_t stream) {
    const float* x     = (const float*)d_in[0];
    const int*   ei    = (const int*)d_in[1];
    const float* ea    = (const float*)d_in[2];
    const float* l1_Wl = (const float*)d_in[3];  const float* l1_bl = (const float*)d_in[4];
    const float* l1_Wr = (const float*)d_in[5];  const float* l1_We = (const float*)d_in[6];
    const float* l1_be = (const float*)d_in[7];  const float* l1_Wg = (const float*)d_in[8];
    const float* l1_bg = (const float*)d_in[9];  const float* l1_bng= (const float*)d_in[10];
    const float* l1_bnb= (const float*)d_in[11];
    const float* l2_Wl = (const float*)d_in[12]; const float* l2_bl = (const float*)d_in[13];
    const float* l2_Wr = (const float*)d_in[14]; const float* l2_We = (const float*)d_in[15];
    const float* l2_be = (const float*)d_in[16]; const float* l2_Wg = (const float*)d_in[17];
    const float* l2_bg = (const float*)d_in[18]; const float* l2_bng= (const float*)d_in[19];
    const float* l2_bnb= (const float*)d_in[20];
    const float* gn1_g = (const float*)d_in[21]; const float* gn1_b = (const float*)d_in[22];
    const float* gn1_a = (const float*)d_in[23];
    const float* gn2_g = (const float*)d_in[24]; const float* gn2_b = (const float*)d_in[25];
    const float* gn2_a = (const float*)d_in[26];
    const float* lin_W = (const float*)d_in[27]; const float* lin_b = (const float*)d_in[28];

    const int N = in_sizes[0] / 32;
    const int E = in_sizes[1] / 2;
    const int* rows = ei;
    const int* cols = ei + E;

    // bucket geometry
    int SH = 7, NPB = 128;
    while (((N + NPB - 1) >> SH) > 1024) { SH++; NPB <<= 1; }
    const int NB = (N + NPB - 1) >> SH;
    const int PB = (E + CPART - 1) / CPART;

    float* w    = (float*)d_ws;
    int* wth1   = (int*)w;
    int* wgh1   = (int*)(w + 512);
    int* wth2   = (int*)(w + 1024);
    int* wgh2   = (int*)(w + 1536);
    float* ets1 = w + 2048; float* vs1 = w + 2112; float* dv1 = w + 2176;
    float* ets2 = w + 2240; float* vs2 = w + 2304; float* dv2 = w + 2368;
    float* stats= w + 2432;

    int* ip     = (int*)(w + 8192);
    int* rowptr = ip;                 // N+1 (persistent)
    int* cnt    = ip + (N + 1);       // N
    int* bs     = cnt + N;            // 1024
    int* ranges = bs + 1024;          // NWAVES+2 (persistent)
    int* erow   = ranges + (NWAVES + 2);  // E (persistent)

    uintptr_t pa = (uintptr_t)(erow + E);
    pa = (pa + 255) & ~(uintptr_t)255;
    __half* eap = (__half*)pa;        // E*16 halves (persistent)
    uintptr_t px = (uintptr_t)(eap + (size_t)E * ED);
    px = (px + 255) & ~(uintptr_t)255;
    __half* xh = (__half*)px;         // N*32 halves (persistent)
    uintptr_t pz = (uintptr_t)(xh + (size_t)N * 32);
    pz = (pz + 255) & ~(uintptr_t)255;

    // --- overlap zone: {tmp, offtab, eah} (CSR build) then {B0, Bpre, Bu, B3h} (layers) ---
    int2* tmp   = (int2*)pz;                       // E
    int* offtab = (int*)(tmp + E);                 // PB*(NB+1)
    uintptr_t pe = (uintptr_t)(offtab + (size_t)PB * (NB + 1));
    pe = (pe + 255) & ~(uintptr_t)255;
    int4* eah = (int4*)pe;                         // E*2 int4 (32B/edge)

    size_t NB64 = (size_t)N * H;
    float* B0 = (float*)pz;                        // agg (fp32, N*64) — aliases tmp/offtab/eah
    __half* Bpre = (__half*)(B0 + NB64);           // pre/t (f16)
    __half* Bu   = Bpre + NB64;                    // u (f16)
    __half* B3h  = Bu + NB64;                      // h layer1 (f16)
    __half* B0h  = (__half*)B0;                    // h layer2 reuses B0 space

    const float Ninv = 1.0f / (float)N;
    dim3 rb(64, 4);
    int egrid = (E + 255) / 256;
    int ngrid = (N + 255) / 256;
    int g64 = (N + 63) / 64;
    const int SB = (N + 1023) >> 10;

    k_prep<<<1, 64, 0, stream>>>(l1_We, l1_be, l1_Wg, l2_We, l2_be, l2_Wg, w);
    k_xh<<<(N * 8 + 255) / 256, 256, 0, stream>>>(x, xh, N * 8);
    k_eah<<<egrid, 256, 0, stream>>>(ea, eah, E);

    // ---- CSR build: count -> scan -> partition -> per-bucket exact build ----
    hipMemsetAsync(cnt, 0, sizeof(int) * (size_t)N, stream);
    k_count<<<egrid, 256, 0, stream>>>(cols, cnt, E);
    k_scan1<<<SB, 1024, 0, stream>>>(cnt, bs, N);
    k_scan2<<<1, 1024, 0, stream>>>(bs, SB);
    k_scan3<<<SB, 1024, 0, stream>>>(cnt, bs, rowptr, N, E);
    k_ranges<<<(NWAVES + 256) / 256, 256, 0, stream>>>(rowptr, ranges, N, E, NWAVES);
    k_part<<<PB, 256, 0, stream>>>(rows, cols, tmp, offtab, E, NB, SH);
    k_build<<<NB, 1024, 0, stream>>>(rowptr, tmp, offtab, eah, erow, eap, N, NB, SH, PB);

    // ---- layer 1 ----
    k_gather<32, false><<<WGRID, 256, 0, stream>>>(xh, rowptr, ranges, erow, B0,
                                                   nullptr, nullptr, nullptr, nullptr, nullptr, 0.f, N);
    k_gemmfu<32, false><<<g64, 256, 0, stream>>>(B0, xh, 32, l1_Wl, l1_Wr, l1_bl, l1_Wg, l1_bg,
                                                 nullptr, nullptr, nullptr, nullptr, nullptr, 0.f,
                                                 rowptr, Bpre, Bu, N);
    k_gate<<<WGRID, 256, 0, stream>>>(rowptr, ranges, eap, wth1, wgh1, l1_be, dv1, ets1, vs1,
                                      Bu, Bpre, stats + 0, stats + 64, N);
    k_apply<<<256, rb, 0, stream>>>(Bpre, B3h, l1_bng, l1_bnb, stats + 0, stats + 64,
                                    stats + 128, stats + 192, Ninv, N);

    // ---- layer 2 (gn1 folded into readers of B3h) ----
    k_gather<64, true><<<WGRID, 256, 0, stream>>>(B3h, rowptr, ranges, erow, B0,
                                                  stats + 128, stats + 192, gn1_g, gn1_b, gn1_a, Ninv, N);
    k_gemmfu<64, true><<<g64, 256, 0, stream>>>(B0, B3h, 64, l2_Wl, l2_Wr, l2_bl, l2_Wg, l2_bg,
                                                stats + 128, stats + 192, gn1_g, gn1_b, gn1_a, Ninv,
                                                rowptr, Bpre, Bu, N);
    k_gate<<<WGRID, 256, 0, stream>>>(rowptr, ranges, eap, wth2, wgh2, l2_be, dv2, ets2, vs2,
                                      Bu, Bpre, stats + 256, stats + 320, N);
    k_apply<<<256, rb, 0, stream>>>(Bpre, B0h, l2_bng, l2_bnb, stats + 256, stats + 320,
                                    stats + 384, stats + 448, Ninv, N);

    // ---- final ----
    k_final<<<ngrid, 256, 0, stream>>>(B0h, lin_W, lin_b, stats + 384, stats + 448,
                                       gn2_g, gn2_b, gn2_a, Ninv, (float*)d_out, N);
}

// Round 13
// 674.025 us; speedup vs baseline: 1.1278x; 1.0036x over previous
//
#include <hip/hip_runtime.h>
#include <hip/hip_fp16.h>
#include <math.h>
#include <stdint.h>

#define H 64
#define ED 16
#define CO 16
#define WGRID 2048
#define NWAVES (WGRID * 4)
#define CPART 1024
static constexpr float EPSV = 1e-5f;
static constexpr float LOG2E = 1.44269504f;

typedef _Float16 h2v __attribute__((ext_vector_type(2)));
typedef _Float16 f16x8 __attribute__((ext_vector_type(8)));
typedef float f32x4 __attribute__((ext_vector_type(4)));

__device__ __forceinline__ float sigm2(float z) {
    return __builtin_amdgcn_rcpf(1.0f + __builtin_amdgcn_exp2f(-z));
}

__device__ __forceinline__ h2v as_h2(int x) { union { int i; h2v h; } u; u.i = x; return u.h; }

__device__ __forceinline__ f16x8 as_f16x8(int4 v) { union { int4 i; f16x8 h; } u; u.i = v; return u.h; }

__device__ __forceinline__ int pack2(float a, float b) {
    __half2 h = __floats2half2_rn(a, b);
    return *reinterpret_cast<int*>(&h);
}

// ---------------- prep: packed-f16 gate weights (log2e-folded gate path), self-loop consts, zero stats --
__global__ void k_prep(const float* __restrict__ We1, const float* __restrict__ be1, const float* __restrict__ Wg1,
                       const float* __restrict__ We2, const float* __restrict__ be2, const float* __restrict__ Wg2,
                       float* __restrict__ ws) {
    int j = threadIdx.x;  // 0..63
    for (int l = 0; l < 2; ++l) {
        const float* We = l ? We2 : We1;
        const float* be = l ? be2 : be1;
        const float* Wg = l ? Wg2 : Wg1;
        int* wth = (int*)(ws + (l ? 1024 : 0));
        int* wgh = (int*)(ws + (l ? 1536 : 512));
        float* ets = ws + 2048 + l * 192;
        float* vs  = ws + 2112 + l * 192;
        float* dv  = ws + 2176 + l * 192;
        float wt[ED], wg[ED];
        float et = be[j];
        for (int k = 0; k < ED; ++k) { wt[k] = We[k * H + j]; et += wt[k]; }
        ets[j] = et;                                   // ea_t for self-loop (ea = ones)
        float d = 0.f;
        for (int m = 0; m < H; ++m) d += be[m] * Wg[(H + m) * H + j];
        float vsum = d;
        for (int k = 0; k < ED; ++k) {
            float acc = 0.f;
            for (int m = 0; m < H; ++m) acc += We[k * H + m] * Wg[(H + m) * H + j];
            wg[k] = acc;                               // (We @ Wg_bot)^T
            vsum += acc;
        }
        dv[j] = d * LOG2E;
        vs[j] = vsum * LOG2E;
        for (int q = 0; q < 8; ++q) {
            wth[j * 8 + q] = pack2(wt[2 * q], wt[2 * q + 1]);
            wgh[j * 8 + q] = pack2(wg[2 * q] * LOG2E, wg[2 * q + 1] * LOG2E);
        }
    }
    for (int s = 0; s < 8; ++s) ws[2432 + s * 64 + j] = 0.f;  // zero all stats
}

// ---------------- x -> f16 ----------------
__global__ void k_xh(const float* __restrict__ x, __half* __restrict__ xh, int total4) {
    int i = blockIdx.x * blockDim.x + threadIdx.x;
    if (i >= total4) return;
    float4 v = *reinterpret_cast<const float4*>(x + (size_t)i * 4);
    __half2 h0 = __floats2half2_rn(v.x, v.y), h1 = __floats2half2_rn(v.z, v.w);
    uint2 o;
    o.x = *reinterpret_cast<unsigned*>(&h0);
    o.y = *reinterpret_cast<unsigned*>(&h1);
    *reinterpret_cast<uint2*>(xh + (size_t)i * 4) = o;
}

// ---------------- CSR build: count + scan ----------------
__global__ void k_count(const int* __restrict__ cols, int* __restrict__ cnt, int E) {
    int e = blockIdx.x * blockDim.x + threadIdx.x;
    if (e < E) atomicAdd(&cnt[cols[e]], 1);
}

__global__ __launch_bounds__(1024) void k_scan1(const int* __restrict__ cnt, int* __restrict__ bs, int N) {
    __shared__ int ls[1024];
    int t = threadIdx.x;
    int i = blockIdx.x * 1024 + t;
    ls[t] = (i < N) ? cnt[i] : 0;
    __syncthreads();
    for (int off = 512; off > 0; off >>= 1) {
        if (t < off) ls[t] += ls[t + off];
        __syncthreads();
    }
    if (t == 0) bs[blockIdx.x] = ls[0];
}

__global__ __launch_bounds__(1024) void k_scan2(int* __restrict__ bs, int SB) {
    __shared__ int ls[1024];
    int t = threadIdx.x;
    int v = (t < SB) ? bs[t] : 0;
    ls[t] = v;
    __syncthreads();
    for (int off = 1; off < 1024; off <<= 1) {
        int x = (t >= off) ? ls[t - off] : 0;
        __syncthreads();
        ls[t] += x;
        __syncthreads();
    }
    if (t < SB) bs[t] = ls[t] - v;  // exclusive
}

__global__ __launch_bounds__(1024) void k_scan3(const int* __restrict__ cnt, const int* __restrict__ bs,
                                                int* __restrict__ rowptr, int N, int E) {
    __shared__ int ls[1024];
    int t = threadIdx.x;
    int i = blockIdx.x * 1024 + t;
    int v = (i < N) ? cnt[i] : 0;
    ls[t] = v;
    __syncthreads();
    for (int off = 1; off < 1024; off <<= 1) {
        int x = (t >= off) ? ls[t - off] : 0;
        __syncthreads();
        ls[t] += x;
        __syncthreads();
    }
    if (i < N) rowptr[i] = bs[blockIdx.x] + ls[t] - v;  // exclusive prefix
    if (i == 0) rowptr[N] = E;
}

// ---------------- wave ranges ----------------
__global__ void k_ranges(const int* __restrict__ rowptr, int* __restrict__ ranges, int N, int E, int nw) {
    int w = blockIdx.x * blockDim.x + threadIdx.x;
    if (w > nw) return;
    if (w == nw) { ranges[nw] = N; return; }
    int t0 = (int)((long)E * w / nw);
    int lo = 0, hi = N;
    while (lo < hi) { int mid = (lo + hi) >> 1; if (rowptr[mid] < t0) lo = mid + 1; else hi = mid; }
    ranges[w] = lo;
}

// ---------------- partition pass 1: bucket sort WITH payload (ea read coalesced, f16 inline) ---------
__global__ __launch_bounds__(256) void k_part(const int* __restrict__ rows, const int* __restrict__ cols,
                                              const float* __restrict__ ea,
                                              int2* __restrict__ tmpk, int4* __restrict__ tmpp,
                                              int* __restrict__ offtab,
                                              int E, int NB, int SH) {
    __shared__ int hist[1025];
    __shared__ int pscan[256];
    __shared__ int2 skey[CPART];
    __shared__ int4 spay[CPART][2];
    int tid = threadIdx.x;
    int base = blockIdx.x * CPART;
    int cnt = min(CPART, E - base);
    for (int i = tid; i <= NB; i += 256) hist[i] = 0;
    __syncthreads();
    int myc[4], myr[4];
    int4 pa0[4], pa1[4];
#pragma unroll
    for (int q = 0; q < 4; ++q) {
        int li = q * 256 + tid;
        if (li < cnt) {
            int e = base + li;
            myc[q] = cols[e];
            myr[q] = rows[e];
            const float4* src = reinterpret_cast<const float4*>(ea + (size_t)e * ED);
            float4 v0 = src[0], v1 = src[1], v2 = src[2], v3 = src[3];
            int hh[8];
            hh[0] = pack2(v0.x, v0.y); hh[1] = pack2(v0.z, v0.w);
            hh[2] = pack2(v1.x, v1.y); hh[3] = pack2(v1.z, v1.w);
            hh[4] = pack2(v2.x, v2.y); hh[5] = pack2(v2.z, v2.w);
            hh[6] = pack2(v3.x, v3.y); hh[7] = pack2(v3.z, v3.w);
            pa0[q] = reinterpret_cast<const int4*>(hh)[0];
            pa1[q] = reinterpret_cast<const int4*>(hh)[1];
            atomicAdd(&hist[myc[q] >> SH], 1);
        } else myc[q] = -1;
    }
    __syncthreads();
    int h[4], s = 0;
    int b0 = tid * 4;
#pragma unroll
    for (int k = 0; k < 4; ++k) { h[k] = (b0 + k < NB) ? hist[b0 + k] : 0; s += h[k]; }
    pscan[tid] = s;
    __syncthreads();
    for (int off = 1; off < 256; off <<= 1) {
        int v = (tid >= off) ? pscan[tid - off] : 0;
        __syncthreads();
        pscan[tid] += v;
        __syncthreads();
    }
    int excl = pscan[tid] - s;
    __syncthreads();
    int run = excl;
#pragma unroll
    for (int k = 0; k < 4; ++k) {
        if (b0 + k < NB) hist[b0 + k] = run;
        run += h[k];
    }
    __syncthreads();
    int* ot = offtab + (size_t)blockIdx.x * (NB + 1);
    for (int i = tid; i < NB; i += 256) ot[i] = hist[i];
    if (tid == 0) ot[NB] = cnt;
    __syncthreads();
    int mask = (1 << SH) - 1;
#pragma unroll
    for (int q = 0; q < 4; ++q) {
        if (myc[q] >= 0) {
            int b = myc[q] >> SH;
            int p = atomicAdd(&hist[b], 1);
            skey[p] = make_int2(myr[q], myc[q] & mask);
            spay[p][0] = pa0[q];
            spay[p][1] = pa1[q];
        }
    }
    __syncthreads();
    for (int i = tid; i < cnt; i += 256) {
        tmpk[base + i] = skey[i];
        tmpp[(size_t)(base + i) * 2 + 0] = spay[i][0];
        tmpp[(size_t)(base + i) * 2 + 1] = spay[i][1];
    }
}

// ---------------- build pass 2: streaming per-bucket CSR placement (no random global reads) --------
__global__ __launch_bounds__(1024) void k_build(const int* __restrict__ rowptr, const int2* __restrict__ tmpk,
                                               const int4* __restrict__ tmpp,
                                               const int* __restrict__ offtab,
                                               int* __restrict__ erow, __half* __restrict__ eap,
                                               int N, int NB, int SH, int PB) {
    __shared__ int lcur[1024];
    int tid = threadIdx.x;
    int b = blockIdx.x;
    int NPB = 1 << SH;
    int nodelo = b << SH;
    for (int j = tid; j < NPB; j += 1024) {
        int n = nodelo + j;
        lcur[j] = (n < N) ? rowptr[n] : 0;
    }
    __syncthreads();
    for (int i = tid; i < PB; i += 1024) {
        const int* ot = offtab + (size_t)i * (NB + 1);
        int j0 = ot[b], j1 = ot[b + 1];
        for (int j = j0; j < j1; ++j) {
            size_t src = (size_t)i * CPART + j;
            int2 k = tmpk[src];
            int4 a0 = tmpp[src * 2 + 0];
            int4 a1 = tmpp[src * 2 + 1];
            int p = atomicAdd(&lcur[k.y], 1);
            erow[p] = k.x;
            int4* d = reinterpret_cast<int4*>(eap + (size_t)p * ED);
            d[0] = a0; d[1] = a1;
        }
    }
}

// ---------------- gather (f16 input): agg[n] = T(x[n]) + sum_in T(x[row]) ----
template <int CIN, bool GN>
__global__ __launch_bounds__(256) void k_gather(const __half* __restrict__ x, const int* __restrict__ rowptr,
                         const int* __restrict__ ranges,
                         const int* __restrict__ erow, float* __restrict__ agg,
                         const float* __restrict__ s1, const float* __restrict__ s2,
                         const float* __restrict__ gng, const float* __restrict__ gnb,
                         const float* __restrict__ gna, float Ninv, int N) {
    int lane = threadIdx.x & 63;
    int w = (blockIdx.x * blockDim.x + threadIdx.x) >> 6;
    float A = 1.f, B = 0.f;
    if (GN) {
        float mu = s1[lane] * Ninv, m2 = s2[lane] * Ninv, a = gna[lane];
        float var = m2 - 2.f * a * mu * mu + a * a * mu * mu;
        A = gng[lane] * rsqrtf(var + EPSV);
        B = gnb[lane] - A * a * mu;
    }
    int n0 = ranges[w], n1 = ranges[w + 1];
    for (int n = n0; n < n1; ++n) {
        int s = rowptr[n], te = rowptr[n + 1];
        if (CIN == 64) {
            float raw = __half2float(x[(size_t)n * 64 + lane]);
            float acc = GN ? fmaxf(fmaf(A, raw, B), 0.f) : raw;
            int i = s;
            for (; i + 7 < te; i += 8) {
                int r0 = erow[i],     r1 = erow[i + 1], r2 = erow[i + 2], r3 = erow[i + 3];
                int r4 = erow[i + 4], r5 = erow[i + 5], r6 = erow[i + 6], r7 = erow[i + 7];
                float x0 = __half2float(x[(size_t)r0 * 64 + lane]);
                float x1 = __half2float(x[(size_t)r1 * 64 + lane]);
                float x2 = __half2float(x[(size_t)r2 * 64 + lane]);
                float x3 = __half2float(x[(size_t)r3 * 64 + lane]);
                float x4 = __half2float(x[(size_t)r4 * 64 + lane]);
                float x5 = __half2float(x[(size_t)r5 * 64 + lane]);
                float x6 = __half2float(x[(size_t)r6 * 64 + lane]);
                float x7 = __half2float(x[(size_t)r7 * 64 + lane]);
                if (GN) {
                    x0 = fmaxf(fmaf(A, x0, B), 0.f); x1 = fmaxf(fmaf(A, x1, B), 0.f);
                    x2 = fmaxf(fmaf(A, x2, B), 0.f); x3 = fmaxf(fmaf(A, x3, B), 0.f);
                    x4 = fmaxf(fmaf(A, x4, B), 0.f); x5 = fmaxf(fmaf(A, x5, B), 0.f);
                    x6 = fmaxf(fmaf(A, x6, B), 0.f); x7 = fmaxf(fmaf(A, x7, B), 0.f);
                }
                acc += ((x0 + x1) + (x2 + x3)) + ((x4 + x5) + (x6 + x7));
            }
            for (; i < te; ++i) {
                float xv = __half2float(x[(size_t)erow[i] * 64 + lane]);
                if (GN) xv = fmaxf(fmaf(A, xv, B), 0.f);
                acc += xv;
            }
            agg[(size_t)n * H + lane] = acc;
        } else {
            int c = lane & 31, half = lane >> 5;
            float acc = half ? 0.f : __half2float(x[(size_t)n * 32 + c]);
            int i = s + half;
            for (; i + 6 < te; i += 8) {
                int r0 = erow[i], r1 = erow[i + 2], r2 = erow[i + 4], r3 = erow[i + 6];
                float x0 = __half2float(x[(size_t)r0 * 32 + c]);
                float x1 = __half2float(x[(size_t)r1 * 32 + c]);
                float x2 = __half2float(x[(size_t)r2 * 32 + c]);
                float x3 = __half2float(x[(size_t)r3 * 32 + c]);
                acc += (x0 + x1) + (x2 + x3);
            }
            for (; i < te; i += 2) acc += __half2float(x[(size_t)erow[i] * 32 + c]);
            acc += __shfl_xor(acc, 32);
            if (half == 0) agg[(size_t)n * H + c] = acc;
        }
    }
}

// ---------------- fused GEMM: pre = (agg/deg)@Wl + T(x)@Wr + bl ; u = (pre@Wg_top + bg)*log2e ----------
#define MT4A(mq, aval) \
    acc[mq][0] = fmaf(aval, w1.x, acc[mq][0]); acc[mq][1] = fmaf(aval, w1.y, acc[mq][1]); \
    acc[mq][2] = fmaf(aval, w1.z, acc[mq][2]); acc[mq][3] = fmaf(aval, w1.w, acc[mq][3]);
#define MT4X(mq, aval) \
    acc[mq][0] = fmaf(aval, w2.x, acc[mq][0]); acc[mq][1] = fmaf(aval, w2.y, acc[mq][1]); \
    acc[mq][2] = fmaf(aval, w2.z, acc[mq][2]); acc[mq][3] = fmaf(aval, w2.w, acc[mq][3]);

template <int K, bool GN>
__global__ __launch_bounds__(256) void k_gemmfu(
        const float* __restrict__ A,               // agg, stride 64
        const __half* __restrict__ A2, int lda2,   // x-side (f16)
        const float* __restrict__ W1, const float* __restrict__ W2,
        const float* __restrict__ bias,
        const float* __restrict__ Wg, const float* __restrict__ bg,
        const float* __restrict__ s1, const float* __restrict__ s2,
        const float* __restrict__ gng, const float* __restrict__ gnb,
        const float* __restrict__ gna, float Ninv,
        const int* __restrict__ rowptr,
        __half* __restrict__ pre, __half* __restrict__ uout, int N) {
    __shared__ float WA[64 * 64];
    __shared__ float WB[K * 64];
    __shared__ float big[64][68];
    __shared__ float As[64], Bs[64], invd[64];
    int tid = threadIdx.x;
    for (int idx = tid; idx < K * 64; idx += 256) { WA[idx] = W1[idx]; WB[idx] = W2[idx]; }
    int nb = blockIdx.x * 64;
    if (tid < 64) {
        if (GN) {
            float mu = s1[tid] * Ninv, m2 = s2[tid] * Ninv, a = gna[tid];
            float var = m2 - 2.f * a * mu * mu + a * a * mu * mu;
            float Av = gng[tid] * rsqrtf(var + EPSV);
            As[tid] = Av; Bs[tid] = gnb[tid] - Av * a * mu;
        }
        int n = nb + tid;
        invd[tid] = (n < N) ? 1.f / (float)(rowptr[n + 1] - rowptr[n] + 1) : 0.f;
    }
    __syncthreads();
    int tm = tid >> 4, tn = tid & 15;
    int m0 = tm * 4, j0 = tn * 4;
    float acc[4][4];
#pragma unroll
    for (int jq = 0; jq < 4; ++jq) {
        float b = bias[j0 + jq];
#pragma unroll
        for (int mq = 0; mq < 4; ++mq) acc[mq][jq] = b;
    }
    int sn = tid >> 2, kq4 = (tid & 3) * 4;
    int sg = nb + sn;
    for (int k0 = 0; k0 < K; k0 += 16) {
        if (k0) __syncthreads();
        if (sg < N) {
            float4 av = *reinterpret_cast<const float4*>(A + (size_t)sg * 64 + k0 + kq4);
            float sc = invd[sn];
            av.x *= sc; av.y *= sc; av.z *= sc; av.w *= sc;
            big[kq4 + 0][sn] = av.x; big[kq4 + 1][sn] = av.y;
            big[kq4 + 2][sn] = av.z; big[kq4 + 3][sn] = av.w;
            uint2 hv = *reinterpret_cast<const uint2*>(A2 + (size_t)sg * lda2 + k0 + kq4);
            __half2 h01 = *reinterpret_cast<__half2*>(&hv.x);
            __half2 h23 = *reinterpret_cast<__half2*>(&hv.y);
            float2 f01 = __half22float2(h01), f23 = __half22float2(h23);
            float xv0 = f01.x, xv1 = f01.y, xv2 = f23.x, xv3 = f23.y;
            if (GN) {
                xv0 = fmaxf(fmaf(As[k0 + kq4 + 0], xv0, Bs[k0 + kq4 + 0]), 0.f);
                xv1 = fmaxf(fmaf(As[k0 + kq4 + 1], xv1, Bs[k0 + kq4 + 1]), 0.f);
                xv2 = fmaxf(fmaf(As[k0 + kq4 + 2], xv2, Bs[k0 + kq4 + 2]), 0.f);
                xv3 = fmaxf(fmaf(As[k0 + kq4 + 3], xv3, Bs[k0 + kq4 + 3]), 0.f);
            }
            big[16 + kq4 + 0][sn] = xv0; big[16 + kq4 + 1][sn] = xv1;
            big[16 + kq4 + 2][sn] = xv2; big[16 + kq4 + 3][sn] = xv3;
        } else {
#pragma unroll
            for (int q = 0; q < 4; ++q) { big[kq4 + q][sn] = 0.f; big[16 + kq4 + q][sn] = 0.f; }
        }
        __syncthreads();
#pragma unroll
        for (int k = 0; k < 16; ++k) {
            float4 am = *reinterpret_cast<const float4*>(&big[k][m0]);
            float4 w1 = *reinterpret_cast<const float4*>(&WA[(k0 + k) * 64 + j0]);
            MT4A(0, am.x) MT4A(1, am.y) MT4A(2, am.z) MT4A(3, am.w)
            float4 xm = *reinterpret_cast<const float4*>(&big[16 + k][m0]);
            float4 w2 = *reinterpret_cast<const float4*>(&WB[(k0 + k) * 64 + j0]);
            MT4X(0, xm.x) MT4X(1, xm.y) MT4X(2, xm.z) MT4X(3, xm.w)
        }
    }
    __syncthreads();
#pragma unroll
    for (int mq = 0; mq < 4; ++mq) {
        int n = nb + m0 + mq;
        if (n < N) {
            uint2 o;
            o.x = pack2(acc[mq][0], acc[mq][1]);
            o.y = pack2(acc[mq][2], acc[mq][3]);
            *reinterpret_cast<uint2*>(pre + (size_t)n * 64 + j0) = o;
        }
#pragma unroll
        for (int jq = 0; jq < 4; ++jq) big[j0 + jq][m0 + mq] = acc[mq][jq];
    }
    for (int idx = tid; idx < 4096; idx += 256) WA[idx] = Wg[idx] * LOG2E;
    __syncthreads();
    float acc2[4][4];
#pragma unroll
    for (int jq = 0; jq < 4; ++jq) {
        float b = bg[j0 + jq] * LOG2E;
#pragma unroll
        for (int mq = 0; mq < 4; ++mq) acc2[mq][jq] = b;
    }
#pragma unroll 8
    for (int k = 0; k < 64; ++k) {
        float4 pm = *reinterpret_cast<const float4*>(&big[k][m0]);
        float4 w1 = *reinterpret_cast<const float4*>(&WA[k * 64 + j0]);
        acc2[0][0] = fmaf(pm.x, w1.x, acc2[0][0]); acc2[0][1] = fmaf(pm.x, w1.y, acc2[0][1]);
        acc2[0][2] = fmaf(pm.x, w1.z, acc2[0][2]); acc2[0][3] = fmaf(pm.x, w1.w, acc2[0][3]);
        acc2[1][0] = fmaf(pm.y, w1.x, acc2[1][0]); acc2[1][1] = fmaf(pm.y, w1.y, acc2[1][1]);
        acc2[1][2] = fmaf(pm.y, w1.z, acc2[1][2]); acc2[1][3] = fmaf(pm.y, w1.w, acc2[1][3]);
        acc2[2][0] = fmaf(pm.z, w1.x, acc2[2][0]); acc2[2][1] = fmaf(pm.z, w1.y, acc2[2][1]);
        acc2[2][2] = fmaf(pm.z, w1.z, acc2[2][2]); acc2[2][3] = fmaf(pm.z, w1.w, acc2[2][3]);
        acc2[3][0] = fmaf(pm.w, w1.x, acc2[3][0]); acc2[3][1] = fmaf(pm.w, w1.y, acc2[3][1]);
        acc2[3][2] = fmaf(pm.w, w1.z, acc2[3][2]); acc2[3][3] = fmaf(pm.w, w1.w, acc2[3][3]);
    }
#pragma unroll
    for (int mq = 0; mq < 4; ++mq) {
        int n = nb + m0 + mq;
        if (n < N) {
            uint2 o;
            o.x = pack2(acc2[mq][0], acc2[mq][1]);
            o.y = pack2(acc2[mq][2], acc2[mq][3]);
            *reinterpret_cast<uint2*>(uout + (size_t)n * 64 + j0) = o;
        }
    }
}

// ---------------- gate: MFMA edge matmul with bias baked in at k=16; packed (V,ET) f16 LDS ----------
__global__ __launch_bounds__(256) void k_gate(
        const int* __restrict__ rowptr, const int* __restrict__ ranges,
        const __half* __restrict__ eap,
        const int* __restrict__ wth, const int* __restrict__ wgh,
        const float* __restrict__ be, const float* __restrict__ dv,
        const float* __restrict__ ets, const float* __restrict__ vs,
        const __half* __restrict__ u, __half* __restrict__ pre,
        float* __restrict__ s1, float* __restrict__ s2, int N) {
    __shared__ __align__(16) int4 estage[4][128];      // 2KB per wave (64 edges x 32B)
    __shared__ unsigned pvet[4][16][68];               // packed half2{V, ET}
    __shared__ float ls[2][4][H];
    int lane = threadIdx.x & 63;
    int wv = threadIdx.x >> 6;
    int w = (blockIdx.x << 2) | wv;
    int g = lane >> 4, li = lane & 15;
    // loop-invariant B fragments; bias row at k=16 (group 2, elem 0)
    f16x8 Bet[4], Bv[4];
#pragma unroll
    for (int c = 0; c < 4; ++c) {
        int j = c * 16 + li;
        int4 bt = make_int4(0, 0, 0, 0), bv = make_int4(0, 0, 0, 0);
        if (g < 2) {
            bt = *reinterpret_cast<const int4*>(&wth[j * 8 + g * 4]);
            bv = *reinterpret_cast<const int4*>(&wgh[j * 8 + g * 4]);
        }
        Bet[c] = as_f16x8(bt);
        Bv[c] = as_f16x8(bv);
        if (g == 2) {
            Bet[c][0] = (_Float16)be[j];
            Bv[c][0]  = (_Float16)dv[j];
        }
    }
    float ets_l = ets[lane], vs_l = vs[lane];
    int n0 = ranges[w], n1 = ranges[w + 1];
    float s = 0.f, ss = 0.f;
    if (n0 < n1) {
        int4* dst = &estage[wv][0];
        const int4* gsrc = reinterpret_cast<const int4*>(eap);
        int e0 = rowptr[n0], e1 = rowptr[n1];
        int n = n0;
        int nend = rowptr[n0 + 1];
        size_t idx = (size_t)n * H + lane;
        float u_l = __half2float(u[idx]);
        float pv = __half2float(pre[idx]);
        int np = min(n + 1, n1 - 1);
        size_t idxn = (size_t)np * H + lane;
        float u_n = __half2float(u[idxn]);
        float pv_n = __half2float(pre[idxn]);
        float acc = sigm2(u_l + vs_l) * ets_l;   // folded self-loop contribution
        {   // stage first chunk
            int bytes = min(64, e1 - e0) * 32;
            int4 p0, p1;
            if (lane * 16 < bytes) p0 = gsrc[(size_t)e0 * 2 + lane];
            if (1024 + lane * 16 < bytes) p1 = gsrc[(size_t)e0 * 2 + 64 + lane];
            if (lane * 16 < bytes) dst[lane] = p0;
            if (1024 + lane * 16 < bytes) dst[64 + lane] = p1;
        }
        for (int c = e0; c < e1; c += 64) {
            int cnt = min(64, e1 - c);
            int nbytes = (c + 64 < e1) ? min(64, e1 - c - 64) * 32 : 0;
            int4 p0, p1;
            if (lane * 16 < nbytes) p0 = gsrc[(size_t)(c + 64) * 2 + lane];
            if (1024 + lane * 16 < nbytes) p1 = gsrc[(size_t)(c + 64) * 2 + 64 + lane];
            for (int tb = 0; tb < cnt; tb += 16) {
                // ---- MFMA: ET/V (+bias) for this 16-edge tile ----
                int4 af = make_int4(0, 0, 0, 0);
                if (g < 2) af = dst[(tb + li) * 2 + g];
                f16x8 Af = as_f16x8(af);
                if (g == 2) Af[0] = (_Float16)1.0f;    // bias column
                f32x4 z = {0.f, 0.f, 0.f, 0.f};
                f32x4 et0 = __builtin_amdgcn_mfma_f32_16x16x32_f16(Af, Bet[0], z, 0, 0, 0);
                f32x4 et1 = __builtin_amdgcn_mfma_f32_16x16x32_f16(Af, Bet[1], z, 0, 0, 0);
                f32x4 et2 = __builtin_amdgcn_mfma_f32_16x16x32_f16(Af, Bet[2], z, 0, 0, 0);
                f32x4 et3 = __builtin_amdgcn_mfma_f32_16x16x32_f16(Af, Bet[3], z, 0, 0, 0);
                f32x4 vv0 = __builtin_amdgcn_mfma_f32_16x16x32_f16(Af, Bv[0], z, 0, 0, 0);
                f32x4 vv1 = __builtin_amdgcn_mfma_f32_16x16x32_f16(Af, Bv[1], z, 0, 0, 0);
                f32x4 vv2 = __builtin_amdgcn_mfma_f32_16x16x32_f16(Af, Bv[2], z, 0, 0, 0);
                f32x4 vv3 = __builtin_amdgcn_mfma_f32_16x16x32_f16(Af, Bv[3], z, 0, 0, 0);
                int r0 = g * 4;
#pragma unroll
                for (int r = 0; r < 4; ++r) {
                    pvet[wv][r0 + r][li]      = (unsigned)pack2(vv0[r], et0[r]);
                    pvet[wv][r0 + r][16 + li] = (unsigned)pack2(vv1[r], et1[r]);
                    pvet[wv][r0 + r][32 + li] = (unsigned)pack2(vv2[r], et2[r]);
                    pvet[wv][r0 + r][48 + li] = (unsigned)pack2(vv3[r], et3[r]);
                }
                // ---- consume tile (channel = lane) ----
                int p = tb, pend = min(cnt, tb + 16);
                while (p < pend) {
                    while (c + p == nend) {       // node boundary: finish n, start next
                        float tval = pv + acc;
                        pre[idx] = __float2half(tval);
                        s += tval; ss += tval * tval;
                        ++n;
                        idx = idxn; u_l = u_n; pv = pv_n;
                        np = min(n + 1, n1 - 1);
                        idxn = (size_t)np * H + lane;
                        u_n = __half2float(u[idxn]);
                        pv_n = __half2float(pre[idxn]);
                        acc = sigm2(u_l + vs_l) * ets_l;
                        nend = rowptr[n + 1];
                    }
                    int lim = min(pend, nend - c);
                    for (; p + 1 < lim; p += 2) {
                        unsigned w0 = pvet[wv][p - tb][lane];
                        unsigned w1 = pvet[wv][p + 1 - tb][lane];
                        float2 f0 = __half22float2(*reinterpret_cast<__half2*>(&w0));
                        float2 f1 = __half22float2(*reinterpret_cast<__half2*>(&w1));
                        acc += sigm2(u_l + f0.x) * f0.y + sigm2(u_l + f1.x) * f1.y;
                    }
                    if (p < lim) {
                        unsigned w0 = pvet[wv][p - tb][lane];
                        float2 f0 = __half22float2(*reinterpret_cast<__half2*>(&w0));
                        acc += sigm2(u_l + f0.x) * f0.y;
                        ++p;
                    }
                }
            }
            if (lane * 16 < nbytes) dst[lane] = p0;
            if (1024 + lane * 16 < nbytes) dst[64 + lane] = p1;
        }
        for (;;) {   // finish current + trailing zero-edge nodes
            float tval = pv + acc;
            pre[idx] = __float2half(tval);
            s += tval; ss += tval * tval;
            ++n;
            if (n >= n1) break;
            idx = idxn; u_l = u_n; pv = pv_n;
            np = min(n + 1, n1 - 1);
            idxn = (size_t)np * H + lane;
            u_n = __half2float(u[idxn]);
            pv_n = __half2float(pre[idxn]);
            acc = sigm2(u_l + vs_l) * ets_l;
        }
    }
    ls[0][wv][lane] = s; ls[1][wv][lane] = ss;
    __syncthreads();
    if (threadIdx.x < H) {
        float a = ls[0][0][lane] + ls[0][1][lane] + ls[0][2][lane] + ls[0][3][lane];
        float b = ls[1][0][lane] + ls[1][1][lane] + ls[1][2][lane] + ls[1][3][lane];
        atomicAdd(&s1[lane], a);
        atomicAdd(&s2[lane], b);
    }
}

// ---------------- apply: h = relu(2*bn(t)) -> f16 + GraphNorm stats ----------------
__global__ void k_apply(const __half* __restrict__ in, __half* __restrict__ outb,
                        const float* __restrict__ bng, const float* __restrict__ bnb,
                        const float* __restrict__ s1b, const float* __restrict__ s2b,
                        float* __restrict__ s1g, float* __restrict__ s2g, float Ninv, int N) {
    int j = threadIdx.x, ty = threadIdx.y;
    __shared__ float As[H], Bs[H];
    if (ty == 0) {
        float mu = s1b[j] * Ninv, var = s2b[j] * Ninv - mu * mu;
        float r = rsqrtf(var + EPSV);
        float A = 2.f * bng[j] * r;
        As[j] = A; Bs[j] = 2.f * (bnb[j] - bng[j] * r * mu);
    }
    __syncthreads();
    float A = As[j], B = Bs[j];
    float s = 0.f, ss = 0.f;
    for (int n = blockIdx.x * 4 + ty; n < N; n += gridDim.x * 4) {
        size_t idx = (size_t)n * H + j;
        float v = fmaxf(fmaf(A, __half2float(in[idx]), B), 0.f);
        outb[idx] = __float2half(v);
        s += v; ss += v * v;
    }
    __shared__ float ls[2][4][H];
    ls[0][ty][j] = s; ls[1][ty][j] = ss;
    __syncthreads();
    if (ty == 0) {
        float a = ls[0][0][j] + ls[0][1][j] + ls[0][2][j] + ls[0][3][j];
        float b = ls[1][0][j] + ls[1][1][j] + ls[1][2][j] + ls[1][3][j];
        atomicAdd(&s1g[j], a);
        atomicAdd(&s2g[j], b);
    }
}

// ---------------- final: out = relu(gn2(h)) @ lin_W + lin_b ----------------
__global__ __launch_bounds__(256) void k_final(const __half* __restrict__ hraw, const float* __restrict__ W,
                        const float* __restrict__ bias,
                        const float* __restrict__ s1, const float* __restrict__ s2,
                        const float* __restrict__ gng, const float* __restrict__ gnb,
                        const float* __restrict__ gna, float Ninv,
                        float* __restrict__ outp, int N) {
    __shared__ float As[H], Bs[H];
    if (threadIdx.x < H) {
        int j = threadIdx.x;
        float mu = s1[j] * Ninv, m2 = s2[j] * Ninv, a = gna[j];
        float var = m2 - 2.f * a * mu * mu + a * a * mu * mu;
        float A = gng[j] * rsqrtf(var + EPSV);
        As[j] = A; Bs[j] = gnb[j] - A * a * mu;
    }
    __syncthreads();
    int n = blockIdx.x * blockDim.x + threadIdx.x;
    if (n >= N) return;
    float o[CO];
#pragma unroll
    for (int t = 0; t < CO; ++t) o[t] = bias[t];
    const __half* hr = hraw + (size_t)n * H;
    for (int m4 = 0; m4 < H / 4; ++m4) {
        uint2 hv = *reinterpret_cast<const uint2*>(hr + m4 * 4);
        __half2 h01 = *reinterpret_cast<__half2*>(&hv.x);
        __half2 h23 = *reinterpret_cast<__half2*>(&hv.y);
        float2 f01 = __half22float2(h01), f23 = __half22float2(h23);
        float hx = fmaxf(fmaf(As[m4*4+0], f01.x, Bs[m4*4+0]), 0.f);
        float hy = fmaxf(fmaf(As[m4*4+1], f01.y, Bs[m4*4+1]), 0.f);
        float hz = fmaxf(fmaf(As[m4*4+2], f23.x, Bs[m4*4+2]), 0.f);
        float hw = fmaxf(fmaf(As[m4*4+3], f23.y, Bs[m4*4+3]), 0.f);
#pragma unroll
        for (int t = 0; t < CO; ++t) {
            o[t] += hx * W[(m4*4+0) * CO + t];
            o[t] += hy * W[(m4*4+1) * CO + t];
            o[t] += hz * W[(m4*4+2) * CO + t];
            o[t] += hw * W[(m4*4+3) * CO + t];
        }
    }
    float* orow = outp + (size_t)n * CO;
#pragma unroll
    for (int t4 = 0; t4 < CO / 4; ++t4)
        reinterpret_cast<float4*>(orow)[t4] = make_float4(o[t4*4+0], o[t4*4+1], o[t4*4+2], o[t4*4+3]);
}

extern "C" void kernel_launch(void* const* d_in, const int* in_sizes, int n_in,
                              void* d_out, int out_size, void* d_ws, size_t ws_size,
                              hipStream_t stream) {
    const float* x     = (const float*)d_in[0];
    const int*   ei    = (const int*)d_in[1];
    const float* ea    = (const float*)d_in[2];
    const float* l1_Wl = (const float*)d_in[3];  const float* l1_bl = (const float*)d_in[4];
    const float* l1_Wr = (const float*)d_in[5];  const float* l1_We = (const float*)d_in[6];
    const float* l1_be = (const float*)d_in[7];  const float* l1_Wg = (const float*)d_in[8];
    const float* l1_bg = (const float*)d_in[9];  const float* l1_bng= (const float*)d_in[10];
    const float* l1_bnb= (const float*)d_in[11];
    const float* l2_Wl = (const float*)d_in[12]; const float* l2_bl = (const float*)d_in[13];
    const float* l2_Wr = (const float*)d_in[14]; const float* l2_We = (const float*)d_in[15];
    const float* l2_be = (const float*)d_in[16]; const float* l2_Wg = (const float*)d_in[17];
    const float* l2_bg = (const float*)d_in[18]; const float* l2_bng= (const float*)d_in[19];
    const float* l2_bnb= (const float*)d_in[20];
    const float* gn1_g = (const float*)d_in[21]; const float* gn1_b = (const float*)d_in[22];
    const float* gn1_a = (const float*)d_in[23];
    const float* gn2_g = (const float*)d_in[24]; const float* gn2_b = (const float*)d_in[25];
    const float* gn2_a = (const float*)d_in[26];
    const float* lin_W = (const float*)d_in[27]; const float* lin_b = (const float*)d_in[28];

    const int N = in_sizes[0] / 32;
    const int E = in_sizes[1] / 2;
    const int* rows = ei;
    const int* cols = ei + E;

    // bucket geometry
    int SH = 7, NPB = 128;
    while (((N + NPB - 1) >> SH) > 1024) { SH++; NPB <<= 1; }
    const int NB = (N + NPB - 1) >> SH;
    const int PB = (E + CPART - 1) / CPART;

    float* w    = (float*)d_ws;
    int* wth1   = (int*)w;
    int* wgh1   = (int*)(w + 512);
    int* wth2   = (int*)(w + 1024);
    int* wgh2   = (int*)(w + 1536);
    float* ets1 = w + 2048; float* vs1 = w + 2112; float* dv1 = w + 2176;
    float* ets2 = w + 2240; float* vs2 = w + 2304; float* dv2 = w + 2368;
    float* stats= w + 2432;

    int* ip     = (int*)(w + 8192);
    int* rowptr = ip;                 // N+1 (persistent)
    int* cnt    = ip + (N + 1);       // N
    int* bs     = cnt + N;            // 1024
    int* ranges = bs + 1024;          // NWAVES+2 (persistent)
    int* erow   = ranges + (NWAVES + 2);  // E (persistent)

    uintptr_t pa = (uintptr_t)(erow + E);
    pa = (pa + 255) & ~(uintptr_t)255;
    __half* eap = (__half*)pa;        // E*16 halves (persistent)
    uintptr_t px = (uintptr_t)(eap + (size_t)E * ED);
    px = (px + 255) & ~(uintptr_t)255;
    __half* xh = (__half*)px;         // N*32 halves (persistent)
    uintptr_t pz = (uintptr_t)(xh + (size_t)N * 32);
    pz = (pz + 255) & ~(uintptr_t)255;

    // --- overlap zone: {tmpk, tmpp, offtab} (CSR build) then {B0, Bpre, Bu, B3h} (layers) ---
    int2* tmpk  = (int2*)pz;                       // E
    int4* tmpp  = (int4*)(tmpk + E);               // E*2 (32B/edge payload)
    int* offtab = (int*)(tmpp + (size_t)E * 2);    // PB*(NB+1)

    size_t NB64 = (size_t)N * H;
    float* B0 = (float*)pz;                        // agg (fp32, N*64) — aliases tmpk/tmpp/offtab
    __half* Bpre = (__half*)(B0 + NB64);           // pre/t (f16)
    __half* Bu   = Bpre + NB64;                    // u (f16)
    __half* B3h  = Bu + NB64;                      // h layer1 (f16)
    __half* B0h  = (__half*)B0;                    // h layer2 reuses B0 space

    const float Ninv = 1.0f / (float)N;
    dim3 rb(64, 4);
    int egrid = (E + 255) / 256;
    int ngrid = (N + 255) / 256;
    int g64 = (N + 63) / 64;
    const int SB = (N + 1023) >> 10;

    k_prep<<<1, 64, 0, stream>>>(l1_We, l1_be, l1_Wg, l2_We, l2_be, l2_Wg, w);
    k_xh<<<(N * 8 + 255) / 256, 256, 0, stream>>>(x, xh, N * 8);

    // ---- CSR build: count -> scan -> payload-carrying partition -> streaming build ----
    hipMemsetAsync(cnt, 0, sizeof(int) * (size_t)N, stream);
    k_count<<<egrid, 256, 0, stream>>>(cols, cnt, E);
    k_scan1<<<SB, 1024, 0, stream>>>(cnt, bs, N);
    k_scan2<<<1, 1024, 0, stream>>>(bs, SB);
    k_scan3<<<SB, 1024, 0, stream>>>(cnt, bs, rowptr, N, E);
    k_ranges<<<(NWAVES + 256) / 256, 256, 0, stream>>>(rowptr, ranges, N, E, NWAVES);
    k_part<<<PB, 256, 0, stream>>>(rows, cols, ea, tmpk, tmpp, offtab, E, NB, SH);
    k_build<<<NB, 1024, 0, stream>>>(rowptr, tmpk, tmpp, offtab, erow, eap, N, NB, SH, PB);

    // ---- layer 1 ----
    k_gather<32, false><<<WGRID, 256, 0, stream>>>(xh, rowptr, ranges, erow, B0,
                                                   nullptr, nullptr, nullptr, nullptr, nullptr, 0.f, N);
    k_gemmfu<32, false><<<g64, 256, 0, stream>>>(B0, xh, 32, l1_Wl, l1_Wr, l1_bl, l1_Wg, l1_bg,
                                                 nullptr, nullptr, nullptr, nullptr, nullptr, 0.f,
                                                 rowptr, Bpre, Bu, N);
    k_gate<<<WGRID, 256, 0, stream>>>(rowptr, ranges, eap, wth1, wgh1, l1_be, dv1, ets1, vs1,
                                      Bu, Bpre, stats + 0, stats + 64, N);
    k_apply<<<256, rb, 0, stream>>>(Bpre, B3h, l1_bng, l1_bnb, stats + 0, stats + 64,
                                    stats + 128, stats + 192, Ninv, N);

    // ---- layer 2 (gn1 folded into readers of B3h) ----
    k_gather<64, true><<<WGRID, 256, 0, stream>>>(B3h, rowptr, ranges, erow, B0,
                                                  stats + 128, stats + 192, gn1_g, gn1_b, gn1_a, Ninv, N);
    k_gemmfu<64, true><<<g64, 256, 0, stream>>>(B0, B3h, 64, l2_Wl, l2_Wr, l2_bl, l2_Wg, l2_bg,
                                                stats + 128, stats + 192, gn1_g, gn1_b, gn1_a, Ninv,
                                                rowptr, Bpre, Bu, N);
    k_gate<<<WGRID, 256, 0, stream>>>(rowptr, ranges, eap, wth2, wgh2, l2_be, dv2, ets2, vs2,
                                      Bu, Bpre, stats + 256, stats + 320, N);
    k_apply<<<256, rb, 0, stream>>>(Bpre, B0h, l2_bng, l2_bnb, stats + 256, stats + 320,
                                    stats + 384, stats + 448, Ninv, N);

    // ---- final ----
    k_final<<<ngrid, 256, 0, stream>>>(B0h, lin_W, lin_b, stats + 384, stats + 448,
                                       gn2_g, gn2_b, gn2_a, Ninv, (float*)d_out, N);
}

// Round 14
// 644.071 us; speedup vs baseline: 1.1803x; 1.0465x over previous
//
#include <hip/hip_runtime.h>
#include <hip/hip_fp16.h>
#include <math.h>
#include <stdint.h>

#define H 64
#define ED 16
#define CO 16
#define WGRID 2048
#define NWAVES (WGRID * 4)
#define CPART 1024
static constexpr float EPSV = 1e-5f;
static constexpr float LOG2E = 1.44269504f;

typedef _Float16 h2v __attribute__((ext_vector_type(2)));
typedef _Float16 f16x8 __attribute__((ext_vector_type(8)));
typedef float f32x4 __attribute__((ext_vector_type(4)));

__device__ __forceinline__ float sigm2(float z) {
    return __builtin_amdgcn_rcpf(1.0f + __builtin_amdgcn_exp2f(-z));
}

__device__ __forceinline__ f16x8 as_f16x8(int4 v) { union { int4 i; f16x8 h; } u; u.i = v; return u.h; }

__device__ __forceinline__ int pack2(float a, float b) {
    __half2 h = __floats2half2_rn(a, b);
    return *reinterpret_cast<int*>(&h);
}

// ---------------- prep: packed-f16 gate weights (log2e-folded gate path), self-loop consts, zero stats --
__global__ void k_prep(const float* __restrict__ We1, const float* __restrict__ be1, const float* __restrict__ Wg1,
                       const float* __restrict__ We2, const float* __restrict__ be2, const float* __restrict__ Wg2,
                       float* __restrict__ ws) {
    int j = threadIdx.x;  // 0..63
    for (int l = 0; l < 2; ++l) {
        const float* We = l ? We2 : We1;
        const float* be = l ? be2 : be1;
        const float* Wg = l ? Wg2 : Wg1;
        int* wth = (int*)(ws + (l ? 1024 : 0));
        int* wgh = (int*)(ws + (l ? 1536 : 512));
        float* ets = ws + 2048 + l * 192;
        float* vs  = ws + 2112 + l * 192;
        float* dv  = ws + 2176 + l * 192;
        float wt[ED], wg[ED];
        float et = be[j];
        for (int k = 0; k < ED; ++k) { wt[k] = We[k * H + j]; et += wt[k]; }
        ets[j] = et;                                   // ea_t for self-loop (ea = ones)
        float d = 0.f;
        for (int m = 0; m < H; ++m) d += be[m] * Wg[(H + m) * H + j];
        float vsum = d;
        for (int k = 0; k < ED; ++k) {
            float acc = 0.f;
            for (int m = 0; m < H; ++m) acc += We[k * H + m] * Wg[(H + m) * H + j];
            wg[k] = acc;                               // (We @ Wg_bot)^T
            vsum += acc;
        }
        dv[j] = d * LOG2E;
        vs[j] = vsum * LOG2E;
        for (int q = 0; q < 8; ++q) {
            wth[j * 8 + q] = pack2(wt[2 * q], wt[2 * q + 1]);
            wgh[j * 8 + q] = pack2(wg[2 * q] * LOG2E, wg[2 * q + 1] * LOG2E);
        }
    }
    for (int s = 0; s < 8; ++s) ws[2432 + s * 64 + j] = 0.f;  // zero all stats
}

// ---------------- x -> f16 ----------------
__global__ void k_xh(const float* __restrict__ x, __half* __restrict__ xh, int total4) {
    int i = blockIdx.x * blockDim.x + threadIdx.x;
    if (i >= total4) return;
    float4 v = *reinterpret_cast<const float4*>(x + (size_t)i * 4);
    __half2 h0 = __floats2half2_rn(v.x, v.y), h1 = __floats2half2_rn(v.z, v.w);
    uint2 o;
    o.x = *reinterpret_cast<unsigned*>(&h0);
    o.y = *reinterpret_cast<unsigned*>(&h1);
    *reinterpret_cast<uint2*>(xh + (size_t)i * 4) = o;
}

// ---------------- scans ----------------
__global__ __launch_bounds__(1024) void k_scan1(const int* __restrict__ cnt, int* __restrict__ bs, int N) {
    __shared__ int ls[1024];
    int t = threadIdx.x;
    int i = blockIdx.x * 1024 + t;
    ls[t] = (i < N) ? cnt[i] : 0;
    __syncthreads();
    for (int off = 512; off > 0; off >>= 1) {
        if (t < off) ls[t] += ls[t + off];
        __syncthreads();
    }
    if (t == 0) bs[blockIdx.x] = ls[0];
}

__global__ __launch_bounds__(1024) void k_scan2(int* __restrict__ bs, int SB) {
    __shared__ int ls[1024];
    int t = threadIdx.x;
    int v = (t < SB) ? bs[t] : 0;
    ls[t] = v;
    __syncthreads();
    for (int off = 1; off < 1024; off <<= 1) {
        int x = (t >= off) ? ls[t - off] : 0;
        __syncthreads();
        ls[t] += x;
        __syncthreads();
    }
    if (t < SB) bs[t] = ls[t] - v;  // exclusive
}

__global__ __launch_bounds__(1024) void k_scan3(const int* __restrict__ cnt, const int* __restrict__ bs,
                                                int* __restrict__ rowptr, int N, int E) {
    __shared__ int ls[1024];
    int t = threadIdx.x;
    int i = blockIdx.x * 1024 + t;
    int v = (i < N) ? cnt[i] : 0;
    ls[t] = v;
    __syncthreads();
    for (int off = 1; off < 1024; off <<= 1) {
        int x = (t >= off) ? ls[t - off] : 0;
        __syncthreads();
        ls[t] += x;
        __syncthreads();
    }
    if (i < N) rowptr[i] = bs[blockIdx.x] + ls[t] - v;  // exclusive prefix
    if (i == 0) rowptr[N] = E;
}

// ---------------- wave ranges ----------------
__global__ void k_ranges(const int* __restrict__ rowptr, int* __restrict__ ranges, int N, int E, int nw) {
    int w = blockIdx.x * blockDim.x + threadIdx.x;
    if (w > nw) return;
    if (w == nw) { ranges[nw] = N; return; }
    int t0 = (int)((long)E * w / nw);
    int lo = 0, hi = N;
    while (lo < hi) { int mid = (lo + hi) >> 1; if (rowptr[mid] < t0) lo = mid + 1; else hi = mid; }
    ranges[w] = lo;
}

// ---------------- partition pass 1: bucket sort WITH payload + fused per-node count ----------------
__global__ __launch_bounds__(256) void k_part(const int* __restrict__ rows, const int* __restrict__ cols,
                                              const float* __restrict__ ea,
                                              int2* __restrict__ tmpk, int4* __restrict__ tmpp,
                                              int* __restrict__ offtab, int* __restrict__ cnt,
                                              int E, int NB, int SH) {
    __shared__ int hist[1025];
    __shared__ int pscan[256];
    __shared__ int2 skey[CPART];
    __shared__ int4 spay[CPART][2];
    int tid = threadIdx.x;
    int base = blockIdx.x * CPART;
    int cntE = min(CPART, E - base);
    for (int i = tid; i <= NB; i += 256) hist[i] = 0;
    __syncthreads();
    int myc[4], myr[4];
    int4 pa0[4], pa1[4];
#pragma unroll
    for (int q = 0; q < 4; ++q) {
        int li = q * 256 + tid;
        if (li < cntE) {
            int e = base + li;
            myc[q] = cols[e];
            myr[q] = rows[e];
            const float4* src = reinterpret_cast<const float4*>(ea + (size_t)e * ED);
            float4 v0 = src[0], v1 = src[1], v2 = src[2], v3 = src[3];
            int hh[8];
            hh[0] = pack2(v0.x, v0.y); hh[1] = pack2(v0.z, v0.w);
            hh[2] = pack2(v1.x, v1.y); hh[3] = pack2(v1.z, v1.w);
            hh[4] = pack2(v2.x, v2.y); hh[5] = pack2(v2.z, v2.w);
            hh[6] = pack2(v3.x, v3.y); hh[7] = pack2(v3.z, v3.w);
            pa0[q] = reinterpret_cast<const int4*>(hh)[0];
            pa1[q] = reinterpret_cast<const int4*>(hh)[1];
            atomicAdd(&hist[myc[q] >> SH], 1);
            atomicAdd(&cnt[myc[q]], 1);                 // fused per-node degree count
        } else myc[q] = -1;
    }
    __syncthreads();
    int h[4], s = 0;
    int b0 = tid * 4;
#pragma unroll
    for (int k = 0; k < 4; ++k) { h[k] = (b0 + k < NB) ? hist[b0 + k] : 0; s += h[k]; }
    pscan[tid] = s;
    __syncthreads();
    for (int off = 1; off < 256; off <<= 1) {
        int v = (tid >= off) ? pscan[tid - off] : 0;
        __syncthreads();
        pscan[tid] += v;
        __syncthreads();
    }
    int excl = pscan[tid] - s;
    __syncthreads();
    int run = excl;
#pragma unroll
    for (int k = 0; k < 4; ++k) {
        if (b0 + k < NB) hist[b0 + k] = run;
        run += h[k];
    }
    __syncthreads();
    int* ot = offtab + (size_t)blockIdx.x * (NB + 1);
    for (int i = tid; i < NB; i += 256) ot[i] = hist[i];
    if (tid == 0) ot[NB] = cntE;
    __syncthreads();
    int mask = (1 << SH) - 1;
#pragma unroll
    for (int q = 0; q < 4; ++q) {
        if (myc[q] >= 0) {
            int b = myc[q] >> SH;
            int p = atomicAdd(&hist[b], 1);
            skey[p] = make_int2(myr[q], myc[q] & mask);
            spay[p][0] = pa0[q];
            spay[p][1] = pa1[q];
        }
    }
    __syncthreads();
    for (int i = tid; i < cntE; i += 256) {
        tmpk[base + i] = skey[i];
        tmpp[(size_t)(base + i) * 2 + 0] = spay[i][0];
        tmpp[(size_t)(base + i) * 2 + 1] = spay[i][1];
    }
}

// ---------------- build pass 2: streaming per-bucket CSR placement (no random global reads) --------
__global__ __launch_bounds__(1024) void k_build(const int* __restrict__ rowptr, const int2* __restrict__ tmpk,
                                               const int4* __restrict__ tmpp,
                                               const int* __restrict__ offtab,
                                               int* __restrict__ erow, __half* __restrict__ eap,
                                               int N, int NB, int SH, int PB) {
    __shared__ int lcur[1024];
    int tid = threadIdx.x;
    int b = blockIdx.x;
    int NPB = 1 << SH;
    int nodelo = b << SH;
    for (int j = tid; j < NPB; j += 1024) {
        int n = nodelo + j;
        lcur[j] = (n < N) ? rowptr[n] : 0;
    }
    __syncthreads();
    for (int i = tid; i < PB; i += 1024) {
        const int* ot = offtab + (size_t)i * (NB + 1);
        int j0 = ot[b], j1 = ot[b + 1];
        for (int j = j0; j < j1; ++j) {
            size_t src = (size_t)i * CPART + j;
            int2 k = tmpk[src];
            int4 a0 = tmpp[src * 2 + 0];
            int4 a1 = tmpp[src * 2 + 1];
            int p = atomicAdd(&lcur[k.y], 1);
            erow[p] = k.x;
            int4* d = reinterpret_cast<int4*>(eap + (size_t)p * ED);
            d[0] = a0; d[1] = a1;
        }
    }
}

// ---------------- gather (f16 input): agg[n] = T(x[n]) + sum_in T(x[row]) ----
template <int CIN, bool GN>
__global__ __launch_bounds__(256) void k_gather(const __half* __restrict__ x, const int* __restrict__ rowptr,
                         const int* __restrict__ ranges,
                         const int* __restrict__ erow, float* __restrict__ agg,
                         const float* __restrict__ s1, const float* __restrict__ s2,
                         const float* __restrict__ gng, const float* __restrict__ gnb,
                         const float* __restrict__ gna, float Ninv, int N) {
    int lane = threadIdx.x & 63;
    int w = (blockIdx.x * blockDim.x + threadIdx.x) >> 6;
    float A = 1.f, B = 0.f;
    if (GN) {
        float mu = s1[lane] * Ninv, m2 = s2[lane] * Ninv, a = gna[lane];
        float var = m2 - 2.f * a * mu * mu + a * a * mu * mu;
        A = gng[lane] * rsqrtf(var + EPSV);
        B = gnb[lane] - A * a * mu;
    }
    int n0 = ranges[w], n1 = ranges[w + 1];
    for (int n = n0; n < n1; ++n) {
        int s = rowptr[n], te = rowptr[n + 1];
        if (CIN == 64) {
            float raw = __half2float(x[(size_t)n * 64 + lane]);
            float acc = GN ? fmaxf(fmaf(A, raw, B), 0.f) : raw;
            int i = s;
            for (; i + 7 < te; i += 8) {
                int r0 = erow[i],     r1 = erow[i + 1], r2 = erow[i + 2], r3 = erow[i + 3];
                int r4 = erow[i + 4], r5 = erow[i + 5], r6 = erow[i + 6], r7 = erow[i + 7];
                float x0 = __half2float(x[(size_t)r0 * 64 + lane]);
                float x1 = __half2float(x[(size_t)r1 * 64 + lane]);
                float x2 = __half2float(x[(size_t)r2 * 64 + lane]);
                float x3 = __half2float(x[(size_t)r3 * 64 + lane]);
                float x4 = __half2float(x[(size_t)r4 * 64 + lane]);
                float x5 = __half2float(x[(size_t)r5 * 64 + lane]);
                float x6 = __half2float(x[(size_t)r6 * 64 + lane]);
                float x7 = __half2float(x[(size_t)r7 * 64 + lane]);
                if (GN) {
                    x0 = fmaxf(fmaf(A, x0, B), 0.f); x1 = fmaxf(fmaf(A, x1, B), 0.f);
                    x2 = fmaxf(fmaf(A, x2, B), 0.f); x3 = fmaxf(fmaf(A, x3, B), 0.f);
                    x4 = fmaxf(fmaf(A, x4, B), 0.f); x5 = fmaxf(fmaf(A, x5, B), 0.f);
                    x6 = fmaxf(fmaf(A, x6, B), 0.f); x7 = fmaxf(fmaf(A, x7, B), 0.f);
                }
                acc += ((x0 + x1) + (x2 + x3)) + ((x4 + x5) + (x6 + x7));
            }
            for (; i < te; ++i) {
                float xv = __half2float(x[(size_t)erow[i] * 64 + lane]);
                if (GN) xv = fmaxf(fmaf(A, xv, B), 0.f);
                acc += xv;
            }
            agg[(size_t)n * H + lane] = acc;
        } else {
            int c = lane & 31, half = lane >> 5;
            float acc = half ? 0.f : __half2float(x[(size_t)n * 32 + c]);
            int i = s + half;
            for (; i + 6 < te; i += 8) {
                int r0 = erow[i], r1 = erow[i + 2], r2 = erow[i + 4], r3 = erow[i + 6];
                float x0 = __half2float(x[(size_t)r0 * 32 + c]);
                float x1 = __half2float(x[(size_t)r1 * 32 + c]);
                float x2 = __half2float(x[(size_t)r2 * 32 + c]);
                float x3 = __half2float(x[(size_t)r3 * 32 + c]);
                acc += (x0 + x1) + (x2 + x3);
            }
            for (; i < te; i += 2) acc += __half2float(x[(size_t)erow[i] * 32 + c]);
            acc += __shfl_xor(acc, 32);
            if (half == 0) agg[(size_t)n * H + c] = acc;
        }
    }
}

// ---------------- fused GEMM: pre = (agg/deg)@Wl + T(x)@Wr + bl ; u = (pre@Wg_top + bg)*log2e ----------
#define MT4A(mq, aval) \
    acc[mq][0] = fmaf(aval, w1.x, acc[mq][0]); acc[mq][1] = fmaf(aval, w1.y, acc[mq][1]); \
    acc[mq][2] = fmaf(aval, w1.z, acc[mq][2]); acc[mq][3] = fmaf(aval, w1.w, acc[mq][3]);
#define MT4X(mq, aval) \
    acc[mq][0] = fmaf(aval, w2.x, acc[mq][0]); acc[mq][1] = fmaf(aval, w2.y, acc[mq][1]); \
    acc[mq][2] = fmaf(aval, w2.z, acc[mq][2]); acc[mq][3] = fmaf(aval, w2.w, acc[mq][3]);

template <int K, bool GN>
__global__ __launch_bounds__(256) void k_gemmfu(
        const float* __restrict__ A,               // agg, stride 64
        const __half* __restrict__ A2, int lda2,   // x-side (f16)
        const float* __restrict__ W1, const float* __restrict__ W2,
        const float* __restrict__ bias,
        const float* __restrict__ Wg, const float* __restrict__ bg,
        const float* __restrict__ s1, const float* __restrict__ s2,
        const float* __restrict__ gng, const float* __restrict__ gnb,
        const float* __restrict__ gna, float Ninv,
        const int* __restrict__ rowptr,
        __half* __restrict__ pre, __half* __restrict__ uout, int N) {
    __shared__ float WA[64 * 64];
    __shared__ float WB[K * 64];
    __shared__ float big[64][68];
    __shared__ float As[64], Bs[64], invd[64];
    int tid = threadIdx.x;
    for (int idx = tid; idx < K * 64; idx += 256) { WA[idx] = W1[idx]; WB[idx] = W2[idx]; }
    int nb = blockIdx.x * 64;
    if (tid < 64) {
        if (GN) {
            float mu = s1[tid] * Ninv, m2 = s2[tid] * Ninv, a = gna[tid];
            float var = m2 - 2.f * a * mu * mu + a * a * mu * mu;
            float Av = gng[tid] * rsqrtf(var + EPSV);
            As[tid] = Av; Bs[tid] = gnb[tid] - Av * a * mu;
        }
        int n = nb + tid;
        invd[tid] = (n < N) ? 1.f / (float)(rowptr[n + 1] - rowptr[n] + 1) : 0.f;
    }
    __syncthreads();
    int tm = tid >> 4, tn = tid & 15;
    int m0 = tm * 4, j0 = tn * 4;
    float acc[4][4];
#pragma unroll
    for (int jq = 0; jq < 4; ++jq) {
        float b = bias[j0 + jq];
#pragma unroll
        for (int mq = 0; mq < 4; ++mq) acc[mq][jq] = b;
    }
    int sn = tid >> 2, kq4 = (tid & 3) * 4;
    int sg = nb + sn;
    for (int k0 = 0; k0 < K; k0 += 16) {
        if (k0) __syncthreads();
        if (sg < N) {
            float4 av = *reinterpret_cast<const float4*>(A + (size_t)sg * 64 + k0 + kq4);
            float sc = invd[sn];
            av.x *= sc; av.y *= sc; av.z *= sc; av.w *= sc;
            big[kq4 + 0][sn] = av.x; big[kq4 + 1][sn] = av.y;
            big[kq4 + 2][sn] = av.z; big[kq4 + 3][sn] = av.w;
            uint2 hv = *reinterpret_cast<const uint2*>(A2 + (size_t)sg * lda2 + k0 + kq4);
            __half2 h01 = *reinterpret_cast<__half2*>(&hv.x);
            __half2 h23 = *reinterpret_cast<__half2*>(&hv.y);
            float2 f01 = __half22float2(h01), f23 = __half22float2(h23);
            float xv0 = f01.x, xv1 = f01.y, xv2 = f23.x, xv3 = f23.y;
            if (GN) {
                xv0 = fmaxf(fmaf(As[k0 + kq4 + 0], xv0, Bs[k0 + kq4 + 0]), 0.f);
                xv1 = fmaxf(fmaf(As[k0 + kq4 + 1], xv1, Bs[k0 + kq4 + 1]), 0.f);
                xv2 = fmaxf(fmaf(As[k0 + kq4 + 2], xv2, Bs[k0 + kq4 + 2]), 0.f);
                xv3 = fmaxf(fmaf(As[k0 + kq4 + 3], xv3, Bs[k0 + kq4 + 3]), 0.f);
            }
            big[16 + kq4 + 0][sn] = xv0; big[16 + kq4 + 1][sn] = xv1;
            big[16 + kq4 + 2][sn] = xv2; big[16 + kq4 + 3][sn] = xv3;
        } else {
#pragma unroll
            for (int q = 0; q < 4; ++q) { big[kq4 + q][sn] = 0.f; big[16 + kq4 + q][sn] = 0.f; }
        }
        __syncthreads();
#pragma unroll
        for (int k = 0; k < 16; ++k) {
            float4 am = *reinterpret_cast<const float4*>(&big[k][m0]);
            float4 w1 = *reinterpret_cast<const float4*>(&WA[(k0 + k) * 64 + j0]);
            MT4A(0, am.x) MT4A(1, am.y) MT4A(2, am.z) MT4A(3, am.w)
            float4 xm = *reinterpret_cast<const float4*>(&big[16 + k][m0]);
            float4 w2 = *reinterpret_cast<const float4*>(&WB[(k0 + k) * 64 + j0]);
            MT4X(0, xm.x) MT4X(1, xm.y) MT4X(2, xm.z) MT4X(3, xm.w)
        }
    }
    __syncthreads();
#pragma unroll
    for (int mq = 0; mq < 4; ++mq) {
        int n = nb + m0 + mq;
        if (n < N) {
            uint2 o;
            o.x = pack2(acc[mq][0], acc[mq][1]);
            o.y = pack2(acc[mq][2], acc[mq][3]);
            *reinterpret_cast<uint2*>(pre + (size_t)n * 64 + j0) = o;
        }
#pragma unroll
        for (int jq = 0; jq < 4; ++jq) big[j0 + jq][m0 + mq] = acc[mq][jq];
    }
    for (int idx = tid; idx < 4096; idx += 256) WA[idx] = Wg[idx] * LOG2E;
    __syncthreads();
    float acc2[4][4];
#pragma unroll
    for (int jq = 0; jq < 4; ++jq) {
        float b = bg[j0 + jq] * LOG2E;
#pragma unroll
        for (int mq = 0; mq < 4; ++mq) acc2[mq][jq] = b;
    }
#pragma unroll 8
    for (int k = 0; k < 64; ++k) {
        float4 pm = *reinterpret_cast<const float4*>(&big[k][m0]);
        float4 w1 = *reinterpret_cast<const float4*>(&WA[k * 64 + j0]);
        acc2[0][0] = fmaf(pm.x, w1.x, acc2[0][0]); acc2[0][1] = fmaf(pm.x, w1.y, acc2[0][1]);
        acc2[0][2] = fmaf(pm.x, w1.z, acc2[0][2]); acc2[0][3] = fmaf(pm.x, w1.w, acc2[0][3]);
        acc2[1][0] = fmaf(pm.y, w1.x, acc2[1][0]); acc2[1][1] = fmaf(pm.y, w1.y, acc2[1][1]);
        acc2[1][2] = fmaf(pm.y, w1.z, acc2[1][2]); acc2[1][3] = fmaf(pm.y, w1.w, acc2[1][3]);
        acc2[2][0] = fmaf(pm.z, w1.x, acc2[2][0]); acc2[2][1] = fmaf(pm.z, w1.y, acc2[2][1]);
        acc2[2][2] = fmaf(pm.z, w1.z, acc2[2][2]); acc2[2][3] = fmaf(pm.z, w1.w, acc2[2][3]);
        acc2[3][0] = fmaf(pm.w, w1.x, acc2[3][0]); acc2[3][1] = fmaf(pm.w, w1.y, acc2[3][1]);
        acc2[3][2] = fmaf(pm.w, w1.z, acc2[3][2]); acc2[3][3] = fmaf(pm.w, w1.w, acc2[3][3]);
    }
#pragma unroll
    for (int mq = 0; mq < 4; ++mq) {
        int n = nb + m0 + mq;
        if (n < N) {
            uint2 o;
            o.x = pack2(acc2[mq][0], acc2[mq][1]);
            o.y = pack2(acc2[mq][2], acc2[mq][3]);
            *reinterpret_cast<uint2*>(uout + (size_t)n * 64 + j0) = o;
        }
    }
}

// ---------------- gate: MFMA edge matmul, direct coalesced A-fragment loads (no LDS staging) ----------
// ET[16x64] = ea_tile @ We + be ; V = ea_tile @ (We@Wg_bot)*log2e + dv, via mfma_f32_16x16x32_f16.
// A-frag: lane l holds A[l&15][8*(l>>4)+i]; 16-edge tile = 512 contiguous bytes of eap -> lanes 0..31
// read it coalesced from GLOBAL (16B each). k=16 column = 1.0 (bias). Register prefetch 1 tile ahead.
__global__ __launch_bounds__(256) void k_gate(
        const int* __restrict__ rowptr, const int* __restrict__ ranges,
        const __half* __restrict__ eap,
        const int* __restrict__ wth, const int* __restrict__ wgh,
        const float* __restrict__ be, const float* __restrict__ dv,
        const float* __restrict__ ets, const float* __restrict__ vs,
        const __half* __restrict__ u, __half* __restrict__ pre,
        float* __restrict__ s1, float* __restrict__ s2, int N) {
    __shared__ unsigned pvet[4][16][68];               // packed half2{V, ET}, wave-private
    __shared__ float ls[2][4][H];
    int lane = threadIdx.x & 63;
    int wv = threadIdx.x >> 6;
    int w = (blockIdx.x << 2) | wv;
    int g = lane >> 4, li = lane & 15;
    // loop-invariant B fragments; bias row at k=16 (group 2, elem 0)
    f16x8 Bet[4], Bv[4];
#pragma unroll
    for (int c = 0; c < 4; ++c) {
        int j = c * 16 + li;
        int4 bt = make_int4(0, 0, 0, 0), bv = make_int4(0, 0, 0, 0);
        if (g < 2) {
            bt = *reinterpret_cast<const int4*>(&wth[j * 8 + g * 4]);
            bv = *reinterpret_cast<const int4*>(&wgh[j * 8 + g * 4]);
        }
        Bet[c] = as_f16x8(bt);
        Bv[c] = as_f16x8(bv);
        if (g == 2) {
            Bet[c][0] = (_Float16)be[j];
            Bv[c][0]  = (_Float16)dv[j];
        }
    }
    float ets_l = ets[lane], vs_l = vs[lane];
    int n0 = ranges[w], n1 = ranges[w + 1];
    float s = 0.f, ss = 0.f;
    if (n0 < n1) {
        const int4* gsrc = reinterpret_cast<const int4*>(eap);
        int e0 = rowptr[n0], e1 = rowptr[n1];
        int n = n0;
        int nend = rowptr[n0 + 1];
        size_t idx = (size_t)n * H + lane;
        float u_l = __half2float(u[idx]);
        float pv = __half2float(pre[idx]);
        int np = min(n + 1, n1 - 1);
        size_t idxn = (size_t)np * H + lane;
        float u_n = __half2float(u[idxn]);
        float pv_n = __half2float(pre[idxn]);
        float acc = sigm2(u_l + vs_l) * ets_l;   // folded self-loop contribution
        // prefetch first tile's A-fragment (coalesced: 512B per tile, lanes 0..31)
        int4 afr = make_int4(0, 0, 0, 0);
        {
            int ei = e0 + li;
            if (g < 2 && ei < e1) afr = gsrc[(size_t)ei * 2 + g];
        }
        for (int tb = e0; tb < e1; tb += 16) {
            int4 afc = afr;
            afr = make_int4(0, 0, 0, 0);
            {
                int ei = tb + 16 + li;
                if (g < 2 && ei < e1) afr = gsrc[(size_t)ei * 2 + g];
            }
            f16x8 Af = as_f16x8(afc);
            if (g == 2) Af[0] = (_Float16)1.0f;    // bias column
            f32x4 z = {0.f, 0.f, 0.f, 0.f};
            f32x4 et0 = __builtin_amdgcn_mfma_f32_16x16x32_f16(Af, Bet[0], z, 0, 0, 0);
            f32x4 et1 = __builtin_amdgcn_mfma_f32_16x16x32_f16(Af, Bet[1], z, 0, 0, 0);
            f32x4 et2 = __builtin_amdgcn_mfma_f32_16x16x32_f16(Af, Bet[2], z, 0, 0, 0);
            f32x4 et3 = __builtin_amdgcn_mfma_f32_16x16x32_f16(Af, Bet[3], z, 0, 0, 0);
            f32x4 vv0 = __builtin_amdgcn_mfma_f32_16x16x32_f16(Af, Bv[0], z, 0, 0, 0);
            f32x4 vv1 = __builtin_amdgcn_mfma_f32_16x16x32_f16(Af, Bv[1], z, 0, 0, 0);
            f32x4 vv2 = __builtin_amdgcn_mfma_f32_16x16x32_f16(Af, Bv[2], z, 0, 0, 0);
            f32x4 vv3 = __builtin_amdgcn_mfma_f32_16x16x32_f16(Af, Bv[3], z, 0, 0, 0);
            int r0 = g * 4;
#pragma unroll
            for (int r = 0; r < 4; ++r) {
                pvet[wv][r0 + r][li]      = (unsigned)pack2(vv0[r], et0[r]);
                pvet[wv][r0 + r][16 + li] = (unsigned)pack2(vv1[r], et1[r]);
                pvet[wv][r0 + r][32 + li] = (unsigned)pack2(vv2[r], et2[r]);
                pvet[wv][r0 + r][48 + li] = (unsigned)pack2(vv3[r], et3[r]);
            }
            // ---- consume tile (channel = lane), absolute edge indices ----
            int pend = min(e1, tb + 16);
            int p = tb;
            while (p < pend) {
                while (p == nend) {           // node boundary: finish n, start next
                    float tval = pv + acc;
                    pre[idx] = __float2half(tval);
                    s += tval; ss += tval * tval;
                    ++n;
                    idx = idxn; u_l = u_n; pv = pv_n;
                    np = min(n + 1, n1 - 1);
                    idxn = (size_t)np * H + lane;
                    u_n = __half2float(u[idxn]);
                    pv_n = __half2float(pre[idxn]);
                    acc = sigm2(u_l + vs_l) * ets_l;
                    nend = rowptr[n + 1];
                }
                int lim = min(pend, nend);
                for (; p + 1 < lim; p += 2) {
                    unsigned w0 = pvet[wv][p - tb][lane];
                    unsigned w1 = pvet[wv][p + 1 - tb][lane];
                    float2 f0 = __half22float2(*reinterpret_cast<__half2*>(&w0));
                    float2 f1 = __half22float2(*reinterpret_cast<__half2*>(&w1));
                    acc += sigm2(u_l + f0.x) * f0.y + sigm2(u_l + f1.x) * f1.y;
                }
                if (p < lim) {
                    unsigned w0 = pvet[wv][p - tb][lane];
                    float2 f0 = __half22float2(*reinterpret_cast<__half2*>(&w0));
                    acc += sigm2(u_l + f0.x) * f0.y;
                    ++p;
                }
            }
        }
        for (;;) {   // finish current + trailing zero-edge nodes
            float tval = pv + acc;
            pre[idx] = __float2half(tval);
            s += tval; ss += tval * tval;
            ++n;
            if (n >= n1) break;
            idx = idxn; u_l = u_n; pv = pv_n;
            np = min(n + 1, n1 - 1);
            idxn = (size_t)np * H + lane;
            u_n = __half2float(u[idxn]);
            pv_n = __half2float(pre[idxn]);
            acc = sigm2(u_l + vs_l) * ets_l;
        }
    }
    ls[0][wv][lane] = s; ls[1][wv][lane] = ss;
    __syncthreads();
    if (threadIdx.x < H) {
        float a = ls[0][0][lane] + ls[0][1][lane] + ls[0][2][lane] + ls[0][3][lane];
        float b = ls[1][0][lane] + ls[1][1][lane] + ls[1][2][lane] + ls[1][3][lane];
        atomicAdd(&s1[lane], a);
        atomicAdd(&s2[lane], b);
    }
}

// ---------------- apply: h = relu(2*bn(t)) -> f16 + GraphNorm stats ----------------
__global__ void k_apply(const __half* __restrict__ in, __half* __restrict__ outb,
                        const float* __restrict__ bng, const float* __restrict__ bnb,
                        const float* __restrict__ s1b, const float* __restrict__ s2b,
                        float* __restrict__ s1g, float* __restrict__ s2g, float Ninv, int N) {
    int j = threadIdx.x, ty = threadIdx.y;
    __shared__ float As[H], Bs[H];
    if (ty == 0) {
        float mu = s1b[j] * Ninv, var = s2b[j] * Ninv - mu * mu;
        float r = rsqrtf(var + EPSV);
        float A = 2.f * bng[j] * r;
        As[j] = A; Bs[j] = 2.f * (bnb[j] - bng[j] * r * mu);
    }
    __syncthreads();
    float A = As[j], B = Bs[j];
    float s = 0.f, ss = 0.f;
    for (int n = blockIdx.x * 4 + ty; n < N; n += gridDim.x * 4) {
        size_t idx = (size_t)n * H + j;
        float v = fmaxf(fmaf(A, __half2float(in[idx]), B), 0.f);
        outb[idx] = __float2half(v);
        s += v; ss += v * v;
    }
    __shared__ float ls[2][4][H];
    ls[0][ty][j] = s; ls[1][ty][j] = ss;
    __syncthreads();
    if (ty == 0) {
        float a = ls[0][0][j] + ls[0][1][j] + ls[0][2][j] + ls[0][3][j];
        float b = ls[1][0][j] + ls[1][1][j] + ls[1][2][j] + ls[1][3][j];
        atomicAdd(&s1g[j], a);
        atomicAdd(&s2g[j], b);
    }
}

// ---------------- final: out = relu(gn2(h)) @ lin_W + lin_b ----------------
__global__ __launch_bounds__(256) void k_final(const __half* __restrict__ hraw, const float* __restrict__ W,
                        const float* __restrict__ bias,
                        const float* __restrict__ s1, const float* __restrict__ s2,
                        const float* __restrict__ gng, const float* __restrict__ gnb,
                        const float* __restrict__ gna, float Ninv,
                        float* __restrict__ outp, int N) {
    __shared__ float As[H], Bs[H];
    if (threadIdx.x < H) {
        int j = threadIdx.x;
        float mu = s1[j] * Ninv, m2 = s2[j] * Ninv, a = gna[j];
        float var = m2 - 2.f * a * mu * mu + a * a * mu * mu;
        float A = gng[j] * rsqrtf(var + EPSV);
        As[j] = A; Bs[j] = gnb[j] - A * a * mu;
    }
    __syncthreads();
    int n = blockIdx.x * blockDim.x + threadIdx.x;
    if (n >= N) return;
    float o[CO];
#pragma unroll
    for (int t = 0; t < CO; ++t) o[t] = bias[t];
    const __half* hr = hraw + (size_t)n * H;
    for (int m4 = 0; m4 < H / 4; ++m4) {
        uint2 hv = *reinterpret_cast<const uint2*>(hr + m4 * 4);
        __half2 h01 = *reinterpret_cast<__half2*>(&hv.x);
        __half2 h23 = *reinterpret_cast<__half2*>(&hv.y);
        float2 f01 = __half22float2(h01), f23 = __half22float2(h23);
        float hx = fmaxf(fmaf(As[m4*4+0], f01.x, Bs[m4*4+0]), 0.f);
        float hy = fmaxf(fmaf(As[m4*4+1], f01.y, Bs[m4*4+1]), 0.f);
        float hz = fmaxf(fmaf(As[m4*4+2], f23.x, Bs[m4*4+2]), 0.f);
        float hw = fmaxf(fmaf(As[m4*4+3], f23.y, Bs[m4*4+3]), 0.f);
#pragma unroll
        for (int t = 0; t < CO; ++t) {
            o[t] += hx * W[(m4*4+0) * CO + t];
            o[t] += hy * W[(m4*4+1) * CO + t];
            o[t] += hz * W[(m4*4+2) * CO + t];
            o[t] += hw * W[(m4*4+3) * CO + t];
        }
    }
    float* orow = outp + (size_t)n * CO;
#pragma unroll
    for (int t4 = 0; t4 < CO / 4; ++t4)
        reinterpret_cast<float4*>(orow)[t4] = make_float4(o[t4*4+0], o[t4*4+1], o[t4*4+2], o[t4*4+3]);
}

extern "C" void kernel_launch(void* const* d_in, const int* in_sizes, int n_in,
                              void* d_out, int out_size, void* d_ws, size_t ws_size,
                              hipStream_t stream) {
    const float* x     = (const float*)d_in[0];
    const int*   ei    = (const int*)d_in[1];
    const float* ea    = (const float*)d_in[2];
    const float* l1_Wl = (const float*)d_in[3];  const float* l1_bl = (const float*)d_in[4];
    const float* l1_Wr = (const float*)d_in[5];  const float* l1_We = (const float*)d_in[6];
    const float* l1_be = (const float*)d_in[7];  const float* l1_Wg = (const float*)d_in[8];
    const float* l1_bg = (const float*)d_in[9];  const float* l1_bng= (const float*)d_in[10];
    const float* l1_bnb= (const float*)d_in[11];
    const float* l2_Wl = (const float*)d_in[12]; const float* l2_bl = (const float*)d_in[13];
    const float* l2_Wr = (const float*)d_in[14]; const float* l2_We = (const float*)d_in[15];
    const float* l2_be = (const float*)d_in[16]; const float* l2_Wg = (const float*)d_in[17];
    const float* l2_bg = (const float*)d_in[18]; const float* l2_bng= (const float*)d_in[19];
    const float* l2_bnb= (const float*)d_in[20];
    const float* gn1_g = (const float*)d_in[21]; const float* gn1_b = (const float*)d_in[22];
    const float* gn1_a = (const float*)d_in[23];
    const float* gn2_g = (const float*)d_in[24]; const float* gn2_b = (const float*)d_in[25];
    const float* gn2_a = (const float*)d_in[26];
    const float* lin_W = (const float*)d_in[27]; const float* lin_b = (const float*)d_in[28];

    const int N = in_sizes[0] / 32;
    const int E = in_sizes[1] / 2;
    const int* rows = ei;
    const int* cols = ei + E;

    // bucket geometry
    int SH = 7, NPB = 128;
    while (((N + NPB - 1) >> SH) > 1024) { SH++; NPB <<= 1; }
    const int NB = (N + NPB - 1) >> SH;
    const int PB = (E + CPART - 1) / CPART;

    float* w    = (float*)d_ws;
    int* wth1   = (int*)w;
    int* wgh1   = (int*)(w + 512);
    int* wth2   = (int*)(w + 1024);
    int* wgh2   = (int*)(w + 1536);
    float* ets1 = w + 2048; float* vs1 = w + 2112; float* dv1 = w + 2176;
    float* ets2 = w + 2240; float* vs2 = w + 2304; float* dv2 = w + 2368;
    float* stats= w + 2432;

    int* ip     = (int*)(w + 8192);
    int* rowptr = ip;                 // N+1 (persistent)
    int* cnt    = ip + (N + 1);       // N
    int* bs     = cnt + N;            // 1024
    int* ranges = bs + 1024;          // NWAVES+2 (persistent)
    int* erow   = ranges + (NWAVES + 2);  // E (persistent)

    uintptr_t pa = (uintptr_t)(erow + E);
    pa = (pa + 255) & ~(uintptr_t)255;
    __half* eap = (__half*)pa;        // E*16 halves (persistent)
    uintptr_t px = (uintptr_t)(eap + (size_t)E * ED);
    px = (px + 255) & ~(uintptr_t)255;
    __half* xh = (__half*)px;         // N*32 halves (persistent)
    uintptr_t pz = (uintptr_t)(xh + (size_t)N * 32);
    pz = (pz + 255) & ~(uintptr_t)255;

    // --- overlap zone: {tmpk, tmpp, offtab} (CSR build) then {B0, Bpre, Bu, B3h} (layers) ---
    int2* tmpk  = (int2*)pz;                       // E
    int4* tmpp  = (int4*)(tmpk + E);               // E*2 (32B/edge payload)
    int* offtab = (int*)(tmpp + (size_t)E * 2);    // PB*(NB+1)

    size_t NB64 = (size_t)N * H;
    float* B0 = (float*)pz;                        // agg (fp32, N*64) — aliases tmpk/tmpp/offtab
    __half* Bpre = (__half*)(B0 + NB64);           // pre/t (f16)
    __half* Bu   = Bpre + NB64;                    // u (f16)
    __half* B3h  = Bu + NB64;                      // h layer1 (f16)
    __half* B0h  = (__half*)B0;                    // h layer2 reuses B0 space

    const float Ninv = 1.0f / (float)N;
    dim3 rb(64, 4);
    int ngrid = (N + 255) / 256;
    int g64 = (N + 63) / 64;
    const int SB = (N + 1023) >> 10;

    k_prep<<<1, 64, 0, stream>>>(l1_We, l1_be, l1_Wg, l2_We, l2_be, l2_Wg, w);
    k_xh<<<(N * 8 + 255) / 256, 256, 0, stream>>>(x, xh, N * 8);

    // ---- CSR build: payload-carrying partition (count fused) -> scan -> streaming build ----
    hipMemsetAsync(cnt, 0, sizeof(int) * (size_t)N, stream);
    k_part<<<PB, 256, 0, stream>>>(rows, cols, ea, tmpk, tmpp, offtab, cnt, E, NB, SH);
    k_scan1<<<SB, 1024, 0, stream>>>(cnt, bs, N);
    k_scan2<<<1, 1024, 0, stream>>>(bs, SB);
    k_scan3<<<SB, 1024, 0, stream>>>(cnt, bs, rowptr, N, E);
    k_ranges<<<(NWAVES + 256) / 256, 256, 0, stream>>>(rowptr, ranges, N, E, NWAVES);
    k_build<<<NB, 1024, 0, stream>>>(rowptr, tmpk, tmpp, offtab, erow, eap, N, NB, SH, PB);

    // ---- layer 1 ----
    k_gather<32, false><<<WGRID, 256, 0, stream>>>(xh, rowptr, ranges, erow, B0,
                                                   nullptr, nullptr, nullptr, nullptr, nullptr, 0.f, N);
    k_gemmfu<32, false><<<g64, 256, 0, stream>>>(B0, xh, 32, l1_Wl, l1_Wr, l1_bl, l1_Wg, l1_bg,
                                                 nullptr, nullptr, nullptr, nullptr, nullptr, 0.f,
                                                 rowptr, Bpre, Bu, N);
    k_gate<<<WGRID, 256, 0, stream>>>(rowptr, ranges, eap, wth1, wgh1, l1_be, dv1, ets1, vs1,
                                      Bu, Bpre, stats + 0, stats + 64, N);
    k_apply<<<256, rb, 0, stream>>>(Bpre, B3h, l1_bng, l1_bnb, stats + 0, stats + 64,
                                    stats + 128, stats + 192, Ninv, N);

    // ---- layer 2 (gn1 folded into readers of B3h) ----
    k_gather<64, true><<<WGRID, 256, 0, stream>>>(B3h, rowptr, ranges, erow, B0,
                                                  stats + 128, stats + 192, gn1_g, gn1_b, gn1_a, Ninv, N);
    k_gemmfu<64, true><<<g64, 256, 0, stream>>>(B0, B3h, 64, l2_Wl, l2_Wr, l2_bl, l2_Wg, l2_bg,
                                                stats + 128, stats + 192, gn1_g, gn1_b, gn1_a, Ninv,
                                                rowptr, Bpre, Bu, N);
    k_gate<<<WGRID, 256, 0, stream>>>(rowptr, ranges, eap, wth2, wgh2, l2_be, dv2, ets2, vs2,
                                      Bu, Bpre, stats + 256, stats + 320, N);
    k_apply<<<256, rb, 0, stream>>>(Bpre, B0h, l2_bng, l2_bnb, stats + 256, stats + 320,
                                    stats + 384, stats + 448, Ninv, N);

    // ---- final ----
    k_final<<<ngrid, 256, 0, stream>>>(B0h, lin_W, lin_b, stats + 384, stats + 448,
                                       gn2_g, gn2_b, gn2_a, Ninv, (float*)d_out, N);
}

// Round 15
// 607.191 us; speedup vs baseline: 1.2520x; 1.0607x over previous
//
#include <hip/hip_runtime.h>
#include <hip/hip_fp16.h>
#include <math.h>
#include <stdint.h>

#define H 64
#define ED 16
#define CO 16
#define WGRID 2048
#define NWAVES (WGRID * 4)
#define CPART 1024
static constexpr float EPSV = 1e-5f;
static constexpr float LOG2E = 1.44269504f;

typedef _Float16 h2v __attribute__((ext_vector_type(2)));
typedef _Float16 f16x8 __attribute__((ext_vector_type(8)));
typedef float f32x4 __attribute__((ext_vector_type(4)));

__device__ __forceinline__ float sigm2(float z) {
    return __builtin_amdgcn_rcpf(1.0f + __builtin_amdgcn_exp2f(-z));
}

__device__ __forceinline__ f16x8 as_f16x8(int4 v) { union { int4 i; f16x8 h; } u; u.i = v; return u.h; }

__device__ __forceinline__ int pack2(float a, float b) {
    __half2 h = __floats2half2_rn(a, b);
    return *reinterpret_cast<int*>(&h);
}

// ---------------- prep: packed-f16 gate weights (log2e-folded gate path), self-loop consts, zero stats --
__global__ void k_prep(const float* __restrict__ We1, const float* __restrict__ be1, const float* __restrict__ Wg1,
                       const float* __restrict__ We2, const float* __restrict__ be2, const float* __restrict__ Wg2,
                       float* __restrict__ ws) {
    int j = threadIdx.x;  // 0..63
    for (int l = 0; l < 2; ++l) {
        const float* We = l ? We2 : We1;
        const float* be = l ? be2 : be1;
        const float* Wg = l ? Wg2 : Wg1;
        int* wth = (int*)(ws + (l ? 1024 : 0));
        int* wgh = (int*)(ws + (l ? 1536 : 512));
        float* ets = ws + 2048 + l * 192;
        float* vs  = ws + 2112 + l * 192;
        float* dv  = ws + 2176 + l * 192;
        float wt[ED], wg[ED];
        float et = be[j];
        for (int k = 0; k < ED; ++k) { wt[k] = We[k * H + j]; et += wt[k]; }
        ets[j] = et;                                   // ea_t for self-loop (ea = ones)
        float d = 0.f;
        for (int m = 0; m < H; ++m) d += be[m] * Wg[(H + m) * H + j];
        float vsum = d;
        for (int k = 0; k < ED; ++k) {
            float acc = 0.f;
            for (int m = 0; m < H; ++m) acc += We[k * H + m] * Wg[(H + m) * H + j];
            wg[k] = acc;                               // (We @ Wg_bot)^T
            vsum += acc;
        }
        dv[j] = d * LOG2E;
        vs[j] = vsum * LOG2E;
        for (int q = 0; q < 8; ++q) {
            wth[j * 8 + q] = pack2(wt[2 * q], wt[2 * q + 1]);
            wgh[j * 8 + q] = pack2(wg[2 * q] * LOG2E, wg[2 * q + 1] * LOG2E);
        }
    }
    for (int s = 0; s < 8; ++s) ws[2432 + s * 64 + j] = 0.f;  // zero all stats
}

// ---------------- x -> f16 ----------------
__global__ void k_xh(const float* __restrict__ x, __half* __restrict__ xh, int total4) {
    int i = blockIdx.x * blockDim.x + threadIdx.x;
    if (i >= total4) return;
    float4 v = *reinterpret_cast<const float4*>(x + (size_t)i * 4);
    __half2 h0 = __floats2half2_rn(v.x, v.y), h1 = __floats2half2_rn(v.z, v.w);
    uint2 o;
    o.x = *reinterpret_cast<unsigned*>(&h0);
    o.y = *reinterpret_cast<unsigned*>(&h1);
    *reinterpret_cast<uint2*>(xh + (size_t)i * 4) = o;
}

// ---------------- scans ----------------
__global__ __launch_bounds__(1024) void k_scan1(const int* __restrict__ cnt, int* __restrict__ bs, int N) {
    __shared__ int ls[1024];
    int t = threadIdx.x;
    int i = blockIdx.x * 1024 + t;
    ls[t] = (i < N) ? cnt[i] : 0;
    __syncthreads();
    for (int off = 512; off > 0; off >>= 1) {
        if (t < off) ls[t] += ls[t + off];
        __syncthreads();
    }
    if (t == 0) bs[blockIdx.x] = ls[0];
}

__global__ __launch_bounds__(1024) void k_scan2(int* __restrict__ bs, int SB) {
    __shared__ int ls[1024];
    int t = threadIdx.x;
    int v = (t < SB) ? bs[t] : 0;
    ls[t] = v;
    __syncthreads();
    for (int off = 1; off < 1024; off <<= 1) {
        int x = (t >= off) ? ls[t - off] : 0;
        __syncthreads();
        ls[t] += x;
        __syncthreads();
    }
    if (t < SB) bs[t] = ls[t] - v;  // exclusive
}

__global__ __launch_bounds__(1024) void k_scan3(const int* __restrict__ cnt, const int* __restrict__ bs,
                                                int* __restrict__ rowptr, int N, int E) {
    __shared__ int ls[1024];
    int t = threadIdx.x;
    int i = blockIdx.x * 1024 + t;
    int v = (i < N) ? cnt[i] : 0;
    ls[t] = v;
    __syncthreads();
    for (int off = 1; off < 1024; off <<= 1) {
        int x = (t >= off) ? ls[t - off] : 0;
        __syncthreads();
        ls[t] += x;
        __syncthreads();
    }
    if (i < N) rowptr[i] = bs[blockIdx.x] + ls[t] - v;  // exclusive prefix
    if (i == 0) rowptr[N] = E;
}

// ---------------- wave ranges ----------------
__global__ void k_ranges(const int* __restrict__ rowptr, int* __restrict__ ranges, int N, int E, int nw) {
    int w = blockIdx.x * blockDim.x + threadIdx.x;
    if (w > nw) return;
    if (w == nw) { ranges[nw] = N; return; }
    int t0 = (int)((long)E * w / nw);
    int lo = 0, hi = N;
    while (lo < hi) { int mid = (lo + hi) >> 1; if (rowptr[mid] < t0) lo = mid + 1; else hi = mid; }
    ranges[w] = lo;
}

// ---------------- partition pass 1: bucket sort WITH payload + fused per-node count ----------------
__global__ __launch_bounds__(256) void k_part(const int* __restrict__ rows, const int* __restrict__ cols,
                                              const float* __restrict__ ea,
                                              int2* __restrict__ tmpk, int4* __restrict__ tmpp,
                                              int* __restrict__ offtab, int* __restrict__ cnt,
                                              int E, int NB, int SH) {
    __shared__ int hist[1025];
    __shared__ int pscan[256];
    __shared__ int2 skey[CPART];
    __shared__ int4 spay[CPART][2];
    int tid = threadIdx.x;
    int base = blockIdx.x * CPART;
    int cntE = min(CPART, E - base);
    for (int i = tid; i <= NB; i += 256) hist[i] = 0;
    __syncthreads();
    int myc[4], myr[4];
    int4 pa0[4], pa1[4];
#pragma unroll
    for (int q = 0; q < 4; ++q) {
        int li = q * 256 + tid;
        if (li < cntE) {
            int e = base + li;
            myc[q] = cols[e];
            myr[q] = rows[e];
            const float4* src = reinterpret_cast<const float4*>(ea + (size_t)e * ED);
            float4 v0 = src[0], v1 = src[1], v2 = src[2], v3 = src[3];
            int hh[8];
            hh[0] = pack2(v0.x, v0.y); hh[1] = pack2(v0.z, v0.w);
            hh[2] = pack2(v1.x, v1.y); hh[3] = pack2(v1.z, v1.w);
            hh[4] = pack2(v2.x, v2.y); hh[5] = pack2(v2.z, v2.w);
            hh[6] = pack2(v3.x, v3.y); hh[7] = pack2(v3.z, v3.w);
            pa0[q] = reinterpret_cast<const int4*>(hh)[0];
            pa1[q] = reinterpret_cast<const int4*>(hh)[1];
            atomicAdd(&hist[myc[q] >> SH], 1);
            atomicAdd(&cnt[myc[q]], 1);                 // fused per-node degree count
        } else myc[q] = -1;
    }
    __syncthreads();
    int h[4], s = 0;
    int b0 = tid * 4;
#pragma unroll
    for (int k = 0; k < 4; ++k) { h[k] = (b0 + k < NB) ? hist[b0 + k] : 0; s += h[k]; }
    pscan[tid] = s;
    __syncthreads();
    for (int off = 1; off < 256; off <<= 1) {
        int v = (tid >= off) ? pscan[tid - off] : 0;
        __syncthreads();
        pscan[tid] += v;
        __syncthreads();
    }
    int excl = pscan[tid] - s;
    __syncthreads();
    int run = excl;
#pragma unroll
    for (int k = 0; k < 4; ++k) {
        if (b0 + k < NB) hist[b0 + k] = run;
        run += h[k];
    }
    __syncthreads();
    int* ot = offtab + (size_t)blockIdx.x * (NB + 1);
    for (int i = tid; i < NB; i += 256) ot[i] = hist[i];
    if (tid == 0) ot[NB] = cntE;
    __syncthreads();
    int mask = (1 << SH) - 1;
#pragma unroll
    for (int q = 0; q < 4; ++q) {
        if (myc[q] >= 0) {
            int b = myc[q] >> SH;
            int p = atomicAdd(&hist[b], 1);
            skey[p] = make_int2(myr[q], myc[q] & mask);
            spay[p][0] = pa0[q];
            spay[p][1] = pa1[q];
        }
    }
    __syncthreads();
    for (int i = tid; i < cntE; i += 256) {
        tmpk[base + i] = skey[i];
        tmpp[(size_t)(base + i) * 2 + 0] = spay[i][0];
        tmpp[(size_t)(base + i) * 2 + 1] = spay[i][1];
    }
}

// ---------------- build pass 2: streaming per-bucket CSR placement (no random global reads) --------
__global__ __launch_bounds__(1024) void k_build(const int* __restrict__ rowptr, const int2* __restrict__ tmpk,
                                               const int4* __restrict__ tmpp,
                                               const int* __restrict__ offtab,
                                               int* __restrict__ erow, __half* __restrict__ eap,
                                               int N, int NB, int SH, int PB) {
    __shared__ int lcur[1024];
    int tid = threadIdx.x;
    int b = blockIdx.x;
    int NPB = 1 << SH;
    int nodelo = b << SH;
    for (int j = tid; j < NPB; j += 1024) {
        int n = nodelo + j;
        lcur[j] = (n < N) ? rowptr[n] : 0;
    }
    __syncthreads();
    for (int i = tid; i < PB; i += 1024) {
        const int* ot = offtab + (size_t)i * (NB + 1);
        int j0 = ot[b], j1 = ot[b + 1];
        for (int j = j0; j < j1; ++j) {
            size_t src = (size_t)i * CPART + j;
            int2 k = tmpk[src];
            int4 a0 = tmpp[src * 2 + 0];
            int4 a1 = tmpp[src * 2 + 1];
            int p = atomicAdd(&lcur[k.y], 1);
            erow[p] = k.x;
            int4* d = reinterpret_cast<int4*>(eap + (size_t)p * ED);
            d[0] = a0; d[1] = a1;
        }
    }
}

// ---------------- gather (f16 in/out): agg[n] = T(x[n]) + sum_in T(x[row]) ----
template <int CIN, bool GN>
__global__ __launch_bounds__(256) void k_gather(const __half* __restrict__ x, const int* __restrict__ rowptr,
                         const int* __restrict__ ranges,
                         const int* __restrict__ erow, __half* __restrict__ agg,
                         const float* __restrict__ s1, const float* __restrict__ s2,
                         const float* __restrict__ gng, const float* __restrict__ gnb,
                         const float* __restrict__ gna, float Ninv, int N) {
    int lane = threadIdx.x & 63;
    int w = (blockIdx.x * blockDim.x + threadIdx.x) >> 6;
    float A = 1.f, B = 0.f;
    if (GN) {
        float mu = s1[lane] * Ninv, m2 = s2[lane] * Ninv, a = gna[lane];
        float var = m2 - 2.f * a * mu * mu + a * a * mu * mu;
        A = gng[lane] * rsqrtf(var + EPSV);
        B = gnb[lane] - A * a * mu;
    }
    int n0 = ranges[w], n1 = ranges[w + 1];
    for (int n = n0; n < n1; ++n) {
        int s = rowptr[n], te = rowptr[n + 1];
        if (CIN == 64) {
            float raw = __half2float(x[(size_t)n * 64 + lane]);
            float acc = GN ? fmaxf(fmaf(A, raw, B), 0.f) : raw;
            int i = s;
            for (; i + 15 < te; i += 16) {
                float xv[16];
#pragma unroll
                for (int q = 0; q < 16; ++q)
                    xv[q] = __half2float(x[(size_t)erow[i + q] * 64 + lane]);
                float t0 = 0.f, t1 = 0.f;
#pragma unroll
                for (int q = 0; q < 16; q += 2) {
                    float a0 = xv[q], a1 = xv[q + 1];
                    if (GN) {
                        a0 = fmaxf(fmaf(A, a0, B), 0.f);
                        a1 = fmaxf(fmaf(A, a1, B), 0.f);
                    }
                    t0 += a0; t1 += a1;
                }
                acc += t0 + t1;
            }
            for (; i + 7 < te; i += 8) {
                float xv[8];
#pragma unroll
                for (int q = 0; q < 8; ++q)
                    xv[q] = __half2float(x[(size_t)erow[i + q] * 64 + lane]);
                float t0 = 0.f;
#pragma unroll
                for (int q = 0; q < 8; ++q) {
                    float a0 = xv[q];
                    if (GN) a0 = fmaxf(fmaf(A, a0, B), 0.f);
                    t0 += a0;
                }
                acc += t0;
            }
            for (; i < te; ++i) {
                float xv = __half2float(x[(size_t)erow[i] * 64 + lane]);
                if (GN) xv = fmaxf(fmaf(A, xv, B), 0.f);
                acc += xv;
            }
            agg[(size_t)n * H + lane] = __float2half(acc);
        } else {
            int c = lane & 31, half = lane >> 5;
            float acc = half ? 0.f : __half2float(x[(size_t)n * 32 + c]);
            int i = s + half;
            for (; i + 6 < te; i += 8) {
                int r0 = erow[i], r1 = erow[i + 2], r2 = erow[i + 4], r3 = erow[i + 6];
                float x0 = __half2float(x[(size_t)r0 * 32 + c]);
                float x1 = __half2float(x[(size_t)r1 * 32 + c]);
                float x2 = __half2float(x[(size_t)r2 * 32 + c]);
                float x3 = __half2float(x[(size_t)r3 * 32 + c]);
                acc += (x0 + x1) + (x2 + x3);
            }
            for (; i < te; i += 2) acc += __half2float(x[(size_t)erow[i] * 32 + c]);
            acc += __shfl_xor(acc, 32);
            if (half == 0) agg[(size_t)n * H + c] = __float2half(acc);
        }
    }
}

// ---------------- fused GEMM: pre = (agg/deg)@Wl + T(x)@Wr + bl ; u = (pre@Wg_top + bg)*log2e ----------
#define MT4A(mq, aval) \
    acc[mq][0] = fmaf(aval, w1.x, acc[mq][0]); acc[mq][1] = fmaf(aval, w1.y, acc[mq][1]); \
    acc[mq][2] = fmaf(aval, w1.z, acc[mq][2]); acc[mq][3] = fmaf(aval, w1.w, acc[mq][3]);
#define MT4X(mq, aval) \
    acc[mq][0] = fmaf(aval, w2.x, acc[mq][0]); acc[mq][1] = fmaf(aval, w2.y, acc[mq][1]); \
    acc[mq][2] = fmaf(aval, w2.z, acc[mq][2]); acc[mq][3] = fmaf(aval, w2.w, acc[mq][3]);

template <int K, bool GN>
__global__ __launch_bounds__(256) void k_gemmfu(
        const __half* __restrict__ A,              // agg (f16), stride 64
        const __half* __restrict__ A2, int lda2,   // x-side (f16)
        const float* __restrict__ W1, const float* __restrict__ W2,
        const float* __restrict__ bias,
        const float* __restrict__ Wg, const float* __restrict__ bg,
        const float* __restrict__ s1, const float* __restrict__ s2,
        const float* __restrict__ gng, const float* __restrict__ gnb,
        const float* __restrict__ gna, float Ninv,
        const int* __restrict__ rowptr,
        __half* __restrict__ pre, __half* __restrict__ uout, int N) {
    __shared__ float WA[64 * 64];
    __shared__ float WB[K * 64];
    __shared__ float big[64][68];
    __shared__ float As[64], Bs[64], invd[64];
    int tid = threadIdx.x;
    for (int idx = tid; idx < K * 64; idx += 256) { WA[idx] = W1[idx]; WB[idx] = W2[idx]; }
    int nb = blockIdx.x * 64;
    if (tid < 64) {
        if (GN) {
            float mu = s1[tid] * Ninv, m2 = s2[tid] * Ninv, a = gna[tid];
            float var = m2 - 2.f * a * mu * mu + a * a * mu * mu;
            float Av = gng[tid] * rsqrtf(var + EPSV);
            As[tid] = Av; Bs[tid] = gnb[tid] - Av * a * mu;
        }
        int n = nb + tid;
        invd[tid] = (n < N) ? 1.f / (float)(rowptr[n + 1] - rowptr[n] + 1) : 0.f;
    }
    __syncthreads();
    int tm = tid >> 4, tn = tid & 15;
    int m0 = tm * 4, j0 = tn * 4;
    float acc[4][4];
#pragma unroll
    for (int jq = 0; jq < 4; ++jq) {
        float b = bias[j0 + jq];
#pragma unroll
        for (int mq = 0; mq < 4; ++mq) acc[mq][jq] = b;
    }
    int sn = tid >> 2, kq4 = (tid & 3) * 4;
    int sg = nb + sn;
    for (int k0 = 0; k0 < K; k0 += 16) {
        if (k0) __syncthreads();
        if (sg < N) {
            uint2 av2 = *reinterpret_cast<const uint2*>(A + (size_t)sg * 64 + k0 + kq4);
            __half2 a01 = *reinterpret_cast<__half2*>(&av2.x);
            __half2 a23 = *reinterpret_cast<__half2*>(&av2.y);
            float2 fa01 = __half22float2(a01), fa23 = __half22float2(a23);
            float sc = invd[sn];
            big[kq4 + 0][sn] = fa01.x * sc; big[kq4 + 1][sn] = fa01.y * sc;
            big[kq4 + 2][sn] = fa23.x * sc; big[kq4 + 3][sn] = fa23.y * sc;
            uint2 hv = *reinterpret_cast<const uint2*>(A2 + (size_t)sg * lda2 + k0 + kq4);
            __half2 h01 = *reinterpret_cast<__half2*>(&hv.x);
            __half2 h23 = *reinterpret_cast<__half2*>(&hv.y);
            float2 f01 = __half22float2(h01), f23 = __half22float2(h23);
            float xv0 = f01.x, xv1 = f01.y, xv2 = f23.x, xv3 = f23.y;
            if (GN) {
                xv0 = fmaxf(fmaf(As[k0 + kq4 + 0], xv0, Bs[k0 + kq4 + 0]), 0.f);
                xv1 = fmaxf(fmaf(As[k0 + kq4 + 1], xv1, Bs[k0 + kq4 + 1]), 0.f);
                xv2 = fmaxf(fmaf(As[k0 + kq4 + 2], xv2, Bs[k0 + kq4 + 2]), 0.f);
                xv3 = fmaxf(fmaf(As[k0 + kq4 + 3], xv3, Bs[k0 + kq4 + 3]), 0.f);
            }
            big[16 + kq4 + 0][sn] = xv0; big[16 + kq4 + 1][sn] = xv1;
            big[16 + kq4 + 2][sn] = xv2; big[16 + kq4 + 3][sn] = xv3;
        } else {
#pragma unroll
            for (int q = 0; q < 4; ++q) { big[kq4 + q][sn] = 0.f; big[16 + kq4 + q][sn] = 0.f; }
        }
        __syncthreads();
#pragma unroll
        for (int k = 0; k < 16; ++k) {
            float4 am = *reinterpret_cast<const float4*>(&big[k][m0]);
            float4 w1 = *reinterpret_cast<const float4*>(&WA[(k0 + k) * 64 + j0]);
            MT4A(0, am.x) MT4A(1, am.y) MT4A(2, am.z) MT4A(3, am.w)
            float4 xm = *reinterpret_cast<const float4*>(&big[16 + k][m0]);
            float4 w2 = *reinterpret_cast<const float4*>(&WB[(k0 + k) * 64 + j0]);
            MT4X(0, xm.x) MT4X(1, xm.y) MT4X(2, xm.z) MT4X(3, xm.w)
        }
    }
    __syncthreads();
#pragma unroll
    for (int mq = 0; mq < 4; ++mq) {
        int n = nb + m0 + mq;
        if (n < N) {
            uint2 o;
            o.x = pack2(acc[mq][0], acc[mq][1]);
            o.y = pack2(acc[mq][2], acc[mq][3]);
            *reinterpret_cast<uint2*>(pre + (size_t)n * 64 + j0) = o;
        }
#pragma unroll
        for (int jq = 0; jq < 4; ++jq) big[j0 + jq][m0 + mq] = acc[mq][jq];
    }
    for (int idx = tid; idx < 4096; idx += 256) WA[idx] = Wg[idx] * LOG2E;
    __syncthreads();
    float acc2[4][4];
#pragma unroll
    for (int jq = 0; jq < 4; ++jq) {
        float b = bg[j0 + jq] * LOG2E;
#pragma unroll
        for (int mq = 0; mq < 4; ++mq) acc2[mq][jq] = b;
    }
#pragma unroll 8
    for (int k = 0; k < 64; ++k) {
        float4 pm = *reinterpret_cast<const float4*>(&big[k][m0]);
        float4 w1 = *reinterpret_cast<const float4*>(&WA[k * 64 + j0]);
        acc2[0][0] = fmaf(pm.x, w1.x, acc2[0][0]); acc2[0][1] = fmaf(pm.x, w1.y, acc2[0][1]);
        acc2[0][2] = fmaf(pm.x, w1.z, acc2[0][2]); acc2[0][3] = fmaf(pm.x, w1.w, acc2[0][3]);
        acc2[1][0] = fmaf(pm.y, w1.x, acc2[1][0]); acc2[1][1] = fmaf(pm.y, w1.y, acc2[1][1]);
        acc2[1][2] = fmaf(pm.y, w1.z, acc2[1][2]); acc2[1][3] = fmaf(pm.y, w1.w, acc2[1][3]);
        acc2[2][0] = fmaf(pm.z, w1.x, acc2[2][0]); acc2[2][1] = fmaf(pm.z, w1.y, acc2[2][1]);
        acc2[2][2] = fmaf(pm.z, w1.z, acc2[2][2]); acc2[2][3] = fmaf(pm.z, w1.w, acc2[2][3]);
        acc2[3][0] = fmaf(pm.w, w1.x, acc2[3][0]); acc2[3][1] = fmaf(pm.w, w1.y, acc2[3][1]);
        acc2[3][2] = fmaf(pm.w, w1.z, acc2[3][2]); acc2[3][3] = fmaf(pm.w, w1.w, acc2[3][3]);
    }
#pragma unroll
    for (int mq = 0; mq < 4; ++mq) {
        int n = nb + m0 + mq;
        if (n < N) {
            uint2 o;
            o.x = pack2(acc2[mq][0], acc2[mq][1]);
            o.y = pack2(acc2[mq][2], acc2[mq][3]);
            *reinterpret_cast<uint2*>(uout + (size_t)n * 64 + j0) = o;
        }
    }
}

// ---------------- gate: MFMA edge matmul, direct coalesced A-fragment loads (no LDS staging) ----------
__global__ __launch_bounds__(256) void k_gate(
        const int* __restrict__ rowptr, const int* __restrict__ ranges,
        const __half* __restrict__ eap,
        const int* __restrict__ wth, const int* __restrict__ wgh,
        const float* __restrict__ be, const float* __restrict__ dv,
        const float* __restrict__ ets, const float* __restrict__ vs,
        const __half* __restrict__ u, __half* __restrict__ pre,
        float* __restrict__ s1, float* __restrict__ s2, int N) {
    __shared__ unsigned pvet[4][16][68];               // packed half2{V, ET}, wave-private
    __shared__ float ls[2][4][H];
    int lane = threadIdx.x & 63;
    int wv = threadIdx.x >> 6;
    int w = (blockIdx.x << 2) | wv;
    int g = lane >> 4, li = lane & 15;
    // loop-invariant B fragments; bias row at k=16 (group 2, elem 0)
    f16x8 Bet[4], Bv[4];
#pragma unroll
    for (int c = 0; c < 4; ++c) {
        int j = c * 16 + li;
        int4 bt = make_int4(0, 0, 0, 0), bv = make_int4(0, 0, 0, 0);
        if (g < 2) {
            bt = *reinterpret_cast<const int4*>(&wth[j * 8 + g * 4]);
            bv = *reinterpret_cast<const int4*>(&wgh[j * 8 + g * 4]);
        }
        Bet[c] = as_f16x8(bt);
        Bv[c] = as_f16x8(bv);
        if (g == 2) {
            Bet[c][0] = (_Float16)be[j];
            Bv[c][0]  = (_Float16)dv[j];
        }
    }
    float ets_l = ets[lane], vs_l = vs[lane];
    int n0 = ranges[w], n1 = ranges[w + 1];
    float s = 0.f, ss = 0.f;
    if (n0 < n1) {
        const int4* gsrc = reinterpret_cast<const int4*>(eap);
        int e0 = rowptr[n0], e1 = rowptr[n1];
        int n = n0;
        int nend = rowptr[n0 + 1];
        size_t idx = (size_t)n * H + lane;
        float u_l = __half2float(u[idx]);
        float pv = __half2float(pre[idx]);
        int np = min(n + 1, n1 - 1);
        size_t idxn = (size_t)np * H + lane;
        float u_n = __half2float(u[idxn]);
        float pv_n = __half2float(pre[idxn]);
        float acc = sigm2(u_l + vs_l) * ets_l;   // folded self-loop contribution
        // prefetch first tile's A-fragment (coalesced: 512B per tile, lanes 0..31)
        int4 afr = make_int4(0, 0, 0, 0);
        {
            int ei = e0 + li;
            if (g < 2 && ei < e1) afr = gsrc[(size_t)ei * 2 + g];
        }
        for (int tb = e0; tb < e1; tb += 16) {
            int4 afc = afr;
            afr = make_int4(0, 0, 0, 0);
            {
                int ei = tb + 16 + li;
                if (g < 2 && ei < e1) afr = gsrc[(size_t)ei * 2 + g];
            }
            f16x8 Af = as_f16x8(afc);
            if (g == 2) Af[0] = (_Float16)1.0f;    // bias column
            f32x4 z = {0.f, 0.f, 0.f, 0.f};
            f32x4 et0 = __builtin_amdgcn_mfma_f32_16x16x32_f16(Af, Bet[0], z, 0, 0, 0);
            f32x4 et1 = __builtin_amdgcn_mfma_f32_16x16x32_f16(Af, Bet[1], z, 0, 0, 0);
            f32x4 et2 = __builtin_amdgcn_mfma_f32_16x16x32_f16(Af, Bet[2], z, 0, 0, 0);
            f32x4 et3 = __builtin_amdgcn_mfma_f32_16x16x32_f16(Af, Bet[3], z, 0, 0, 0);
            f32x4 vv0 = __builtin_amdgcn_mfma_f32_16x16x32_f16(Af, Bv[0], z, 0, 0, 0);
            f32x4 vv1 = __builtin_amdgcn_mfma_f32_16x16x32_f16(Af, Bv[1], z, 0, 0, 0);
            f32x4 vv2 = __builtin_amdgcn_mfma_f32_16x16x32_f16(Af, Bv[2], z, 0, 0, 0);
            f32x4 vv3 = __builtin_amdgcn_mfma_f32_16x16x32_f16(Af, Bv[3], z, 0, 0, 0);
            int r0 = g * 4;
#pragma unroll
            for (int r = 0; r < 4; ++r) {
                pvet[wv][r0 + r][li]      = (unsigned)pack2(vv0[r], et0[r]);
                pvet[wv][r0 + r][16 + li] = (unsigned)pack2(vv1[r], et1[r]);
                pvet[wv][r0 + r][32 + li] = (unsigned)pack2(vv2[r], et2[r]);
                pvet[wv][r0 + r][48 + li] = (unsigned)pack2(vv3[r], et3[r]);
            }
            // ---- consume tile (channel = lane), absolute edge indices ----
            int pend = min(e1, tb + 16);
            int p = tb;
            while (p < pend) {
                while (p == nend) {           // node boundary: finish n, start next
                    float tval = pv + acc;
                    pre[idx] = __float2half(tval);
                    s += tval; ss += tval * tval;
                    ++n;
                    idx = idxn; u_l = u_n; pv = pv_n;
                    np = min(n + 1, n1 - 1);
                    idxn = (size_t)np * H + lane;
                    u_n = __half2float(u[idxn]);
                    pv_n = __half2float(pre[idxn]);
                    acc = sigm2(u_l + vs_l) * ets_l;
                    nend = rowptr[n + 1];
                }
                int lim = min(pend, nend);
                for (; p + 1 < lim; p += 2) {
                    unsigned w0 = pvet[wv][p - tb][lane];
                    unsigned w1 = pvet[wv][p + 1 - tb][lane];
                    float2 f0 = __half22float2(*reinterpret_cast<__half2*>(&w0));
                    float2 f1 = __half22float2(*reinterpret_cast<__half2*>(&w1));
                    acc += sigm2(u_l + f0.x) * f0.y + sigm2(u_l + f1.x) * f1.y;
                }
                if (p < lim) {
                    unsigned w0 = pvet[wv][p - tb][lane];
                    float2 f0 = __half22float2(*reinterpret_cast<__half2*>(&w0));
                    acc += sigm2(u_l + f0.x) * f0.y;
                    ++p;
                }
            }
        }
        for (;;) {   // finish current + trailing zero-edge nodes
            float tval = pv + acc;
            pre[idx] = __float2half(tval);
            s += tval; ss += tval * tval;
            ++n;
            if (n >= n1) break;
            idx = idxn; u_l = u_n; pv = pv_n;
            np = min(n + 1, n1 - 1);
            idxn = (size_t)np * H + lane;
            u_n = __half2float(u[idxn]);
            pv_n = __half2float(pre[idxn]);
            acc = sigm2(u_l + vs_l) * ets_l;
        }
    }
    ls[0][wv][lane] = s; ls[1][wv][lane] = ss;
    __syncthreads();
    if (threadIdx.x < H) {
        float a = ls[0][0][lane] + ls[0][1][lane] + ls[0][2][lane] + ls[0][3][lane];
        float b = ls[1][0][lane] + ls[1][1][lane] + ls[1][2][lane] + ls[1][3][lane];
        atomicAdd(&s1[lane], a);
        atomicAdd(&s2[lane], b);
    }
}

// ---------------- apply: h = relu(2*bn(t)) -> f16, vectorized (uint2 = 4ch), + GraphNorm stats ------
__global__ __launch_bounds__(256) void k_apply(const __half* __restrict__ in, __half* __restrict__ outb,
                        const float* __restrict__ bng, const float* __restrict__ bnb,
                        const float* __restrict__ s1b, const float* __restrict__ s2b,
                        float* __restrict__ s1g, float* __restrict__ s2g, float Ninv, int N) {
    int tid = threadIdx.x;
    int cg = (tid & 15) * 4;          // channel group base
    int ty = tid >> 4;                // 0..15 node row
    __shared__ float As[H], Bs[H];
    __shared__ float red[2][16][H];
    if (tid < 64) {
        float mu = s1b[tid] * Ninv, var = s2b[tid] * Ninv - mu * mu;
        float r = rsqrtf(var + EPSV);
        float A = 2.f * bng[tid] * r;
        As[tid] = A; Bs[tid] = 2.f * (bnb[tid] - bng[tid] * r * mu);
    }
    __syncthreads();
    float A0 = As[cg], A1 = As[cg + 1], A2 = As[cg + 2], A3 = As[cg + 3];
    float B0 = Bs[cg], B1 = Bs[cg + 1], B2 = Bs[cg + 2], B3 = Bs[cg + 3];
    float s0 = 0.f, s1_ = 0.f, s2_ = 0.f, s3 = 0.f;
    float q0 = 0.f, q1 = 0.f, q2 = 0.f, q3 = 0.f;
    for (int n = blockIdx.x * 16 + ty; n < N; n += gridDim.x * 16) {
        size_t idx = (size_t)n * H + cg;
        uint2 hv = *reinterpret_cast<const uint2*>(in + idx);
        __half2 h01 = *reinterpret_cast<__half2*>(&hv.x);
        __half2 h23 = *reinterpret_cast<__half2*>(&hv.y);
        float2 f01 = __half22float2(h01), f23 = __half22float2(h23);
        float v0 = fmaxf(fmaf(A0, f01.x, B0), 0.f);
        float v1 = fmaxf(fmaf(A1, f01.y, B1), 0.f);
        float v2 = fmaxf(fmaf(A2, f23.x, B2), 0.f);
        float v3 = fmaxf(fmaf(A3, f23.y, B3), 0.f);
        uint2 o;
        o.x = (unsigned)pack2(v0, v1);
        o.y = (unsigned)pack2(v2, v3);
        *reinterpret_cast<uint2*>(outb + idx) = o;
        s0 += v0; s1_ += v1; s2_ += v2; s3 += v3;
        q0 += v0 * v0; q1 += v1 * v1; q2 += v2 * v2; q3 += v3 * v3;
    }
    *reinterpret_cast<float4*>(&red[0][ty][cg]) = make_float4(s0, s1_, s2_, s3);
    *reinterpret_cast<float4*>(&red[1][ty][cg]) = make_float4(q0, q1, q2, q3);
    __syncthreads();
    if (tid < H) {
        float a = 0.f, b = 0.f;
#pragma unroll
        for (int r = 0; r < 16; ++r) { a += red[0][r][tid]; b += red[1][r][tid]; }
        atomicAdd(&s1g[tid], a);
        atomicAdd(&s2g[tid], b);
    }
}

// ---------------- final: out = relu(gn2(h)) @ lin_W + lin_b ----------------
__global__ __launch_bounds__(256) void k_final(const __half* __restrict__ hraw, const float* __restrict__ W,
                        const float* __restrict__ bias,
                        const float* __restrict__ s1, const float* __restrict__ s2,
                        const float* __restrict__ gng, const float* __restrict__ gnb,
                        const float* __restrict__ gna, float Ninv,
                        float* __restrict__ outp, int N) {
    __shared__ float As[H], Bs[H];
    if (threadIdx.x < H) {
        int j = threadIdx.x;
        float mu = s1[j] * Ninv, m2 = s2[j] * Ninv, a = gna[j];
        float var = m2 - 2.f * a * mu * mu + a * a * mu * mu;
        float A = gng[j] * rsqrtf(var + EPSV);
        As[j] = A; Bs[j] = gnb[j] - A * a * mu;
    }
    __syncthreads();
    int n = blockIdx.x * blockDim.x + threadIdx.x;
    if (n >= N) return;
    float o[CO];
#pragma unroll
    for (int t = 0; t < CO; ++t) o[t] = bias[t];
    const __half* hr = hraw + (size_t)n * H;
    for (int m4 = 0; m4 < H / 4; ++m4) {
        uint2 hv = *reinterpret_cast<const uint2*>(hr + m4 * 4);
        __half2 h01 = *reinterpret_cast<__half2*>(&hv.x);
        __half2 h23 = *reinterpret_cast<__half2*>(&hv.y);
        float2 f01 = __half22float2(h01), f23 = __half22float2(h23);
        float hx = fmaxf(fmaf(As[m4*4+0], f01.x, Bs[m4*4+0]), 0.f);
        float hy = fmaxf(fmaf(As[m4*4+1], f01.y, Bs[m4*4+1]), 0.f);
        float hz = fmaxf(fmaf(As[m4*4+2], f23.x, Bs[m4*4+2]), 0.f);
        float hw = fmaxf(fmaf(As[m4*4+3], f23.y, Bs[m4*4+3]), 0.f);
#pragma unroll
        for (int t = 0; t < CO; ++t) {
            o[t] += hx * W[(m4*4+0) * CO + t];
            o[t] += hy * W[(m4*4+1) * CO + t];
            o[t] += hz * W[(m4*4+2) * CO + t];
            o[t] += hw * W[(m4*4+3) * CO + t];
        }
    }
    float* orow = outp + (size_t)n * CO;
#pragma unroll
    for (int t4 = 0; t4 < CO / 4; ++t4)
        reinterpret_cast<float4*>(orow)[t4] = make_float4(o[t4*4+0], o[t4*4+1], o[t4*4+2], o[t4*4+3]);
}

extern "C" void kernel_launch(void* const* d_in, const int* in_sizes, int n_in,
                              void* d_out, int out_size, void* d_ws, size_t ws_size,
                              hipStream_t stream) {
    const float* x     = (const float*)d_in[0];
    const int*   ei    = (const int*)d_in[1];
    const float* ea    = (const float*)d_in[2];
    const float* l1_Wl = (const float*)d_in[3];  const float* l1_bl = (const float*)d_in[4];
    const float* l1_Wr = (const float*)d_in[5];  const float* l1_We = (const float*)d_in[6];
    const float* l1_be = (const float*)d_in[7];  const float* l1_Wg = (const float*)d_in[8];
    const float* l1_bg = (const float*)d_in[9];  const float* l1_bng= (const float*)d_in[10];
    const float* l1_bnb= (const float*)d_in[11];
    const float* l2_Wl = (const float*)d_in[12]; const float* l2_bl = (const float*)d_in[13];
    const float* l2_Wr = (const float*)d_in[14]; const float* l2_We = (const float*)d_in[15];
    const float* l2_be = (const float*)d_in[16]; const float* l2_Wg = (const float*)d_in[17];
    const float* l2_bg = (const float*)d_in[18]; const float* l2_bng= (const float*)d_in[19];
    const float* l2_bnb= (const float*)d_in[20];
    const float* gn1_g = (const float*)d_in[21]; const float* gn1_b = (const float*)d_in[22];
    const float* gn1_a = (const float*)d_in[23];
    const float* gn2_g = (const float*)d_in[24]; const float* gn2_b = (const float*)d_in[25];
    const float* gn2_a = (const float*)d_in[26];
    const float* lin_W = (const float*)d_in[27]; const float* lin_b = (const float*)d_in[28];

    const int N = in_sizes[0] / 32;
    const int E = in_sizes[1] / 2;
    const int* rows = ei;
    const int* cols = ei + E;

    // bucket geometry
    int SH = 7, NPB = 128;
    while (((N + NPB - 1) >> SH) > 1024) { SH++; NPB <<= 1; }
    const int NB = (N + NPB - 1) >> SH;
    const int PB = (E + CPART - 1) / CPART;

    float* w    = (float*)d_ws;
    int* wth1   = (int*)w;
    int* wgh1   = (int*)(w + 512);
    int* wth2   = (int*)(w + 1024);
    int* wgh2   = (int*)(w + 1536);
    float* ets1 = w + 2048; float* vs1 = w + 2112; float* dv1 = w + 2176;
    float* ets2 = w + 2240; float* vs2 = w + 2304; float* dv2 = w + 2368;
    float* stats= w + 2432;

    int* ip     = (int*)(w + 8192);
    int* rowptr = ip;                 // N+1 (persistent)
    int* cnt    = ip + (N + 1);       // N
    int* bs     = cnt + N;            // 1024
    int* ranges = bs + 1024;          // NWAVES+2 (persistent)
    int* erow   = ranges + (NWAVES + 2);  // E (persistent)

    uintptr_t pa = (uintptr_t)(erow + E);
    pa = (pa + 255) & ~(uintptr_t)255;
    __half* eap = (__half*)pa;        // E*16 halves (persistent)
    uintptr_t px = (uintptr_t)(eap + (size_t)E * ED);
    px = (px + 255) & ~(uintptr_t)255;
    __half* xh = (__half*)px;         // N*32 halves (persistent)
    uintptr_t pz = (uintptr_t)(xh + (size_t)N * 32);
    pz = (pz + 255) & ~(uintptr_t)255;

    // --- overlap zone: {tmpk, tmpp, offtab} (CSR build) then {Bagg, Bpre, Bu, B3h} (layers) ---
    int2* tmpk  = (int2*)pz;                       // E
    int4* tmpp  = (int4*)(tmpk + E);               // E*2 (32B/edge payload)
    int* offtab = (int*)(tmpp + (size_t)E * 2);    // PB*(NB+1)

    size_t NB64 = (size_t)N * H;
    __half* Bagg = (__half*)pz;                    // agg (f16) — aliases tmpk/tmpp/offtab
    __half* Bpre = Bagg + NB64;                    // pre/t (f16)
    __half* Bu   = Bpre + NB64;                    // u (f16)
    __half* B3h  = Bu + NB64;                      // h layer1 (f16)
    __half* B0h  = Bagg;                           // h layer2 reuses agg space

    const float Ninv = 1.0f / (float)N;
    int ngrid = (N + 255) / 256;
    int g64 = (N + 63) / 64;
    const int SB = (N + 1023) >> 10;

    k_prep<<<1, 64, 0, stream>>>(l1_We, l1_be, l1_Wg, l2_We, l2_be, l2_Wg, w);
    k_xh<<<(N * 8 + 255) / 256, 256, 0, stream>>>(x, xh, N * 8);

    // ---- CSR build: payload-carrying partition (count fused) -> scan -> streaming build ----
    hipMemsetAsync(cnt, 0, sizeof(int) * (size_t)N, stream);
    k_part<<<PB, 256, 0, stream>>>(rows, cols, ea, tmpk, tmpp, offtab, cnt, E, NB, SH);
    k_scan1<<<SB, 1024, 0, stream>>>(cnt, bs, N);
    k_scan2<<<1, 1024, 0, stream>>>(bs, SB);
    k_scan3<<<SB, 1024, 0, stream>>>(cnt, bs, rowptr, N, E);
    k_ranges<<<(NWAVES + 256) / 256, 256, 0, stream>>>(rowptr, ranges, N, E, NWAVES);
    k_build<<<NB, 1024, 0, stream>>>(rowptr, tmpk, tmpp, offtab, erow, eap, N, NB, SH, PB);

    // ---- layer 1 ----
    k_gather<32, false><<<WGRID, 256, 0, stream>>>(xh, rowptr, ranges, erow, Bagg,
                                                   nullptr, nullptr, nullptr, nullptr, nullptr, 0.f, N);
    k_gemmfu<32, false><<<g64, 256, 0, stream>>>(Bagg, xh, 32, l1_Wl, l1_Wr, l1_bl, l1_Wg, l1_bg,
                                                 nullptr, nullptr, nullptr, nullptr, nullptr, 0.f,
                                                 rowptr, Bpre, Bu, N);
    k_gate<<<WGRID, 256, 0, stream>>>(rowptr, ranges, eap, wth1, wgh1, l1_be, dv1, ets1, vs1,
                                      Bu, Bpre, stats + 0, stats + 64, N);
    k_apply<<<256, 256, 0, stream>>>(Bpre, B3h, l1_bng, l1_bnb, stats + 0, stats + 64,
                                     stats + 128, stats + 192, Ninv, N);

    // ---- layer 2 (gn1 folded into readers of B3h) ----
    k_gather<64, true><<<WGRID, 256, 0, stream>>>(B3h, rowptr, ranges, erow, Bagg,
                                                  stats + 128, stats + 192, gn1_g, gn1_b, gn1_a, Ninv, N);
    k_gemmfu<64, true><<<g64, 256, 0, stream>>>(Bagg, B3h, 64, l2_Wl, l2_Wr, l2_bl, l2_Wg, l2_bg,
                                                stats + 128, stats + 192, gn1_g, gn1_b, gn1_a, Ninv,
                                                rowptr, Bpre, Bu, N);
    k_gate<<<WGRID, 256, 0, stream>>>(rowptr, ranges, eap, wth2, wgh2, l2_be, dv2, ets2, vs2,
                                      Bu, Bpre, stats + 256, stats + 320, N);
    k_apply<<<256, 256, 0, stream>>>(Bpre, B0h, l2_bng, l2_bnb, stats + 256, stats + 320,
                                     stats + 384, stats + 448, Ninv, N);

    // ---- final ----
    k_final<<<ngrid, 256, 0, stream>>>(B0h, lin_W, lin_b, stats + 384, stats + 448,
                                       gn2_g, gn2_b, gn2_a, Ninv, (float*)d_out, N);
}

// Round 16
// 600.518 us; speedup vs baseline: 1.2659x; 1.0111x over previous
//
#include <hip/hip_runtime.h>
#include <hip/hip_fp16.h>
#include <math.h>
#include <stdint.h>

#define H 64
#define ED 16
#define CO 16
#define WGRID 2048
#define NWAVES (WGRID * 4)
#define CPART 1024
static constexpr float EPSV = 1e-5f;
static constexpr float LOG2E = 1.44269504f;

typedef _Float16 h2v __attribute__((ext_vector_type(2)));
typedef _Float16 f16x8 __attribute__((ext_vector_type(8)));
typedef float f32x4 __attribute__((ext_vector_type(4)));

__device__ __forceinline__ float sigm2(float z) {
    return __builtin_amdgcn_rcpf(1.0f + __builtin_amdgcn_exp2f(-z));
}

__device__ __forceinline__ f16x8 as_f16x8(int4 v) { union { int4 i; f16x8 h; } u; u.i = v; return u.h; }

__device__ __forceinline__ int pack2(float a, float b) {
    __half2 h = __floats2half2_rn(a, b);
    return *reinterpret_cast<int*>(&h);
}

__device__ __forceinline__ float2 up2(unsigned v) {
    return __half22float2(*reinterpret_cast<__half2*>(&v));
}

// ---------------- prep: packed-f16 gate weights (log2e-folded gate path), self-loop consts, zero stats --
__global__ void k_prep(const float* __restrict__ We1, const float* __restrict__ be1, const float* __restrict__ Wg1,
                       const float* __restrict__ We2, const float* __restrict__ be2, const float* __restrict__ Wg2,
                       float* __restrict__ ws) {
    int j = threadIdx.x;  // 0..63
    for (int l = 0; l < 2; ++l) {
        const float* We = l ? We2 : We1;
        const float* be = l ? be2 : be1;
        const float* Wg = l ? Wg2 : Wg1;
        int* wth = (int*)(ws + (l ? 1024 : 0));
        int* wgh = (int*)(ws + (l ? 1536 : 512));
        float* ets = ws + 2048 + l * 192;
        float* vs  = ws + 2112 + l * 192;
        float* dv  = ws + 2176 + l * 192;
        float wt[ED], wg[ED];
        float et = be[j];
        for (int k = 0; k < ED; ++k) { wt[k] = We[k * H + j]; et += wt[k]; }
        ets[j] = et;                                   // ea_t for self-loop (ea = ones)
        float d = 0.f;
        for (int m = 0; m < H; ++m) d += be[m] * Wg[(H + m) * H + j];
        float vsum = d;
        for (int k = 0; k < ED; ++k) {
            float acc = 0.f;
            for (int m = 0; m < H; ++m) acc += We[k * H + m] * Wg[(H + m) * H + j];
            wg[k] = acc;                               // (We @ Wg_bot)^T
            vsum += acc;
        }
        dv[j] = d * LOG2E;
        vs[j] = vsum * LOG2E;
        for (int q = 0; q < 8; ++q) {
            wth[j * 8 + q] = pack2(wt[2 * q], wt[2 * q + 1]);
            wgh[j * 8 + q] = pack2(wg[2 * q] * LOG2E, wg[2 * q + 1] * LOG2E);
        }
    }
    for (int s = 0; s < 8; ++s) ws[2432 + s * 64 + j] = 0.f;  // zero all stats
}

// ---------------- x -> f16 ----------------
__global__ void k_xh(const float* __restrict__ x, __half* __restrict__ xh, int total4) {
    int i = blockIdx.x * blockDim.x + threadIdx.x;
    if (i >= total4) return;
    float4 v = *reinterpret_cast<const float4*>(x + (size_t)i * 4);
    __half2 h0 = __floats2half2_rn(v.x, v.y), h1 = __floats2half2_rn(v.z, v.w);
    uint2 o;
    o.x = *reinterpret_cast<unsigned*>(&h0);
    o.y = *reinterpret_cast<unsigned*>(&h1);
    *reinterpret_cast<uint2*>(xh + (size_t)i * 4) = o;
}

// ---------------- scans ----------------
__global__ __launch_bounds__(1024) void k_scan1(const int* __restrict__ cnt, int* __restrict__ bs, int N) {
    __shared__ int ls[1024];
    int t = threadIdx.x;
    int i = blockIdx.x * 1024 + t;
    ls[t] = (i < N) ? cnt[i] : 0;
    __syncthreads();
    for (int off = 512; off > 0; off >>= 1) {
        if (t < off) ls[t] += ls[t + off];
        __syncthreads();
    }
    if (t == 0) bs[blockIdx.x] = ls[0];
}

__global__ __launch_bounds__(1024) void k_scan2(int* __restrict__ bs, int SB) {
    __shared__ int ls[1024];
    int t = threadIdx.x;
    int v = (t < SB) ? bs[t] : 0;
    ls[t] = v;
    __syncthreads();
    for (int off = 1; off < 1024; off <<= 1) {
        int x = (t >= off) ? ls[t - off] : 0;
        __syncthreads();
        ls[t] += x;
        __syncthreads();
    }
    if (t < SB) bs[t] = ls[t] - v;  // exclusive
}

__global__ __launch_bounds__(1024) void k_scan3(const int* __restrict__ cnt, const int* __restrict__ bs,
                                                int* __restrict__ rowptr, int N, int E) {
    __shared__ int ls[1024];
    int t = threadIdx.x;
    int i = blockIdx.x * 1024 + t;
    int v = (i < N) ? cnt[i] : 0;
    ls[t] = v;
    __syncthreads();
    for (int off = 1; off < 1024; off <<= 1) {
        int x = (t >= off) ? ls[t - off] : 0;
        __syncthreads();
        ls[t] += x;
        __syncthreads();
    }
    if (i < N) rowptr[i] = bs[blockIdx.x] + ls[t] - v;  // exclusive prefix
    if (i == 0) rowptr[N] = E;
}

// ---------------- wave ranges ----------------
__global__ void k_ranges(const int* __restrict__ rowptr, int* __restrict__ ranges, int N, int E, int nw) {
    int w = blockIdx.x * blockDim.x + threadIdx.x;
    if (w > nw) return;
    if (w == nw) { ranges[nw] = N; return; }
    int t0 = (int)((long)E * w / nw);
    int lo = 0, hi = N;
    while (lo < hi) { int mid = (lo + hi) >> 1; if (rowptr[mid] < t0) lo = mid + 1; else hi = mid; }
    ranges[w] = lo;
}

// ---------------- partition pass 1: bucket sort WITH payload + fused per-node count ----------------
__global__ __launch_bounds__(256) void k_part(const int* __restrict__ rows, const int* __restrict__ cols,
                                              const float* __restrict__ ea,
                                              int2* __restrict__ tmpk, int4* __restrict__ tmpp,
                                              int* __restrict__ offtab, int* __restrict__ cnt,
                                              int E, int NB, int SH) {
    __shared__ int hist[1025];
    __shared__ int pscan[256];
    __shared__ int2 skey[CPART];
    __shared__ int4 spay[CPART][2];
    int tid = threadIdx.x;
    int base = blockIdx.x * CPART;
    int cntE = min(CPART, E - base);
    for (int i = tid; i <= NB; i += 256) hist[i] = 0;
    __syncthreads();
    int myc[4], myr[4];
    int4 pa0[4], pa1[4];
#pragma unroll
    for (int q = 0; q < 4; ++q) {
        int li = q * 256 + tid;
        if (li < cntE) {
            int e = base + li;
            myc[q] = cols[e];
            myr[q] = rows[e];
            const float4* src = reinterpret_cast<const float4*>(ea + (size_t)e * ED);
            float4 v0 = src[0], v1 = src[1], v2 = src[2], v3 = src[3];
            int hh[8];
            hh[0] = pack2(v0.x, v0.y); hh[1] = pack2(v0.z, v0.w);
            hh[2] = pack2(v1.x, v1.y); hh[3] = pack2(v1.z, v1.w);
            hh[4] = pack2(v2.x, v2.y); hh[5] = pack2(v2.z, v2.w);
            hh[6] = pack2(v3.x, v3.y); hh[7] = pack2(v3.z, v3.w);
            pa0[q] = reinterpret_cast<const int4*>(hh)[0];
            pa1[q] = reinterpret_cast<const int4*>(hh)[1];
            atomicAdd(&hist[myc[q] >> SH], 1);
            atomicAdd(&cnt[myc[q]], 1);                 // fused per-node degree count
        } else myc[q] = -1;
    }
    __syncthreads();
    int h[4], s = 0;
    int b0 = tid * 4;
#pragma unroll
    for (int k = 0; k < 4; ++k) { h[k] = (b0 + k < NB) ? hist[b0 + k] : 0; s += h[k]; }
    pscan[tid] = s;
    __syncthreads();
    for (int off = 1; off < 256; off <<= 1) {
        int v = (tid >= off) ? pscan[tid - off] : 0;
        __syncthreads();
        pscan[tid] += v;
        __syncthreads();
    }
    int excl = pscan[tid] - s;
    __syncthreads();
    int run = excl;
#pragma unroll
    for (int k = 0; k < 4; ++k) {
        if (b0 + k < NB) hist[b0 + k] = run;
        run += h[k];
    }
    __syncthreads();
    int* ot = offtab + (size_t)blockIdx.x * (NB + 1);
    for (int i = tid; i < NB; i += 256) ot[i] = hist[i];
    if (tid == 0) ot[NB] = cntE;
    __syncthreads();
    int mask = (1 << SH) - 1;
#pragma unroll
    for (int q = 0; q < 4; ++q) {
        if (myc[q] >= 0) {
            int b = myc[q] >> SH;
            int p = atomicAdd(&hist[b], 1);
            skey[p] = make_int2(myr[q], myc[q] & mask);
            spay[p][0] = pa0[q];
            spay[p][1] = pa1[q];
        }
    }
    __syncthreads();
    for (int i = tid; i < cntE; i += 256) {
        tmpk[base + i] = skey[i];
        tmpp[(size_t)(base + i) * 2 + 0] = spay[i][0];
        tmpp[(size_t)(base + i) * 2 + 1] = spay[i][1];
    }
}

// ---------------- build pass 2: streaming per-bucket CSR placement (no random global reads) --------
__global__ __launch_bounds__(1024) void k_build(const int* __restrict__ rowptr, const int2* __restrict__ tmpk,
                                               const int4* __restrict__ tmpp,
                                               const int* __restrict__ offtab,
                                               int* __restrict__ erow, __half* __restrict__ eap,
                                               int N, int NB, int SH, int PB) {
    __shared__ int lcur[1024];
    int tid = threadIdx.x;
    int b = blockIdx.x;
    int NPB = 1 << SH;
    int nodelo = b << SH;
    for (int j = tid; j < NPB; j += 1024) {
        int n = nodelo + j;
        lcur[j] = (n < N) ? rowptr[n] : 0;
    }
    __syncthreads();
    for (int i = tid; i < PB; i += 1024) {
        const int* ot = offtab + (size_t)i * (NB + 1);
        int j0 = ot[b], j1 = ot[b + 1];
        for (int j = j0; j < j1; ++j) {
            size_t src = (size_t)i * CPART + j;
            int2 k = tmpk[src];
            int4 a0 = tmpp[src * 2 + 0];
            int4 a1 = tmpp[src * 2 + 1];
            int p = atomicAdd(&lcur[k.y], 1);
            erow[p] = k.x;
            int4* d = reinterpret_cast<int4*>(eap + (size_t)p * ED);
            d[0] = a0; d[1] = a1;
        }
    }
}

// ---------------- gather (f16 in/out, 2ch/lane uint loads): agg[n] = T(x[n]) + sum_in T(x[row]) ----
template <int CIN, bool GN>
__global__ __launch_bounds__(256) void k_gather(const __half* __restrict__ x, const int* __restrict__ rowptr,
                         const int* __restrict__ ranges,
                         const int* __restrict__ erow, __half* __restrict__ agg,
                         const float* __restrict__ s1, const float* __restrict__ s2,
                         const float* __restrict__ gng, const float* __restrict__ gnb,
                         const float* __restrict__ gna, float Ninv, int N) {
    int lane = threadIdx.x & 63;
    int w = (blockIdx.x * blockDim.x + threadIdx.x) >> 6;
    const unsigned* xu = reinterpret_cast<const unsigned*>(x);
    unsigned* aggu = reinterpret_cast<unsigned*>(agg);
    int n0 = ranges[w], n1 = ranges[w + 1];
    if (CIN == 64) {
        int c2 = lane & 31, half = lane >> 5;   // channel pair 2*c2, edge parity
        float A0 = 1.f, A1 = 1.f, B0 = 0.f, B1 = 0.f;
        if (GN) {
            int ch0 = c2 * 2, ch1 = ch0 + 1;
            float mu0 = s1[ch0] * Ninv, m20 = s2[ch0] * Ninv, a0 = gna[ch0];
            float var0 = m20 - 2.f * a0 * mu0 * mu0 + a0 * a0 * mu0 * mu0;
            A0 = gng[ch0] * rsqrtf(var0 + EPSV);
            B0 = gnb[ch0] - A0 * a0 * mu0;
            float mu1 = s1[ch1] * Ninv, m21 = s2[ch1] * Ninv, a1 = gna[ch1];
            float var1 = m21 - 2.f * a1 * mu1 * mu1 + a1 * a1 * mu1 * mu1;
            A1 = gng[ch1] * rsqrtf(var1 + EPSV);
            B1 = gnb[ch1] - A1 * a1 * mu1;
        }
        for (int n = n0; n < n1; ++n) {
            int s = rowptr[n], te = rowptr[n + 1];
            float2 raw = up2(xu[(size_t)n * 32 + c2]);
            float a0 = 0.f, a1 = 0.f;
            if (half == 0) {
                if (GN) {
                    a0 = fmaxf(fmaf(A0, raw.x, B0), 0.f);
                    a1 = fmaxf(fmaf(A1, raw.y, B1), 0.f);
                } else { a0 = raw.x; a1 = raw.y; }
            }
            int i = s + half;
            for (; i + 14 < te; i += 16) {
                unsigned v[8];
#pragma unroll
                for (int q = 0; q < 8; ++q)
                    v[q] = xu[(size_t)erow[i + q * 2] * 32 + c2];
#pragma unroll
                for (int q = 0; q < 8; ++q) {
                    float2 f = up2(v[q]);
                    float t0 = f.x, t1 = f.y;
                    if (GN) {
                        t0 = fmaxf(fmaf(A0, t0, B0), 0.f);
                        t1 = fmaxf(fmaf(A1, t1, B1), 0.f);
                    }
                    a0 += t0; a1 += t1;
                }
            }
            for (; i < te; i += 2) {
                float2 f = up2(xu[(size_t)erow[i] * 32 + c2]);
                float t0 = f.x, t1 = f.y;
                if (GN) {
                    t0 = fmaxf(fmaf(A0, t0, B0), 0.f);
                    t1 = fmaxf(fmaf(A1, t1, B1), 0.f);
                }
                a0 += t0; a1 += t1;
            }
            a0 += __shfl_xor(a0, 32);
            a1 += __shfl_xor(a1, 32);
            if (half == 0) aggu[(size_t)n * 32 + c2] = (unsigned)pack2(a0, a1);
        }
    } else {
        int c2 = lane & 15, qg = lane >> 4;     // channel pair (row=16 uints), edge group 0..3
        for (int n = n0; n < n1; ++n) {
            int s = rowptr[n], te = rowptr[n + 1];
            float2 raw = up2(xu[(size_t)n * 16 + c2]);
            float a0 = (qg == 0) ? raw.x : 0.f;
            float a1 = (qg == 0) ? raw.y : 0.f;
            int i = s + qg;
            for (; i + 12 < te; i += 16) {
                unsigned v[4];
#pragma unroll
                for (int q = 0; q < 4; ++q)
                    v[q] = xu[(size_t)erow[i + q * 4] * 16 + c2];
#pragma unroll
                for (int q = 0; q < 4; ++q) {
                    float2 f = up2(v[q]);
                    a0 += f.x; a1 += f.y;
                }
            }
            for (; i < te; i += 4) {
                float2 f = up2(xu[(size_t)erow[i] * 16 + c2]);
                a0 += f.x; a1 += f.y;
            }
            a0 += __shfl_xor(a0, 32); a0 += __shfl_xor(a0, 16);
            a1 += __shfl_xor(a1, 32); a1 += __shfl_xor(a1, 16);
            if (lane < 16) aggu[(size_t)n * 32 + c2] = (unsigned)pack2(a0, a1);
        }
    }
}

// ---------------- fused GEMM: pre = (agg/deg)@Wl + T(x)@Wr + bl ; u = (pre@Wg_top + bg)*log2e ----------
#define MT4A(mq, aval) \
    acc[mq][0] = fmaf(aval, w1.x, acc[mq][0]); acc[mq][1] = fmaf(aval, w1.y, acc[mq][1]); \
    acc[mq][2] = fmaf(aval, w1.z, acc[mq][2]); acc[mq][3] = fmaf(aval, w1.w, acc[mq][3]);
#define MT4X(mq, aval) \
    acc[mq][0] = fmaf(aval, w2.x, acc[mq][0]); acc[mq][1] = fmaf(aval, w2.y, acc[mq][1]); \
    acc[mq][2] = fmaf(aval, w2.z, acc[mq][2]); acc[mq][3] = fmaf(aval, w2.w, acc[mq][3]);

template <int K, bool GN>
__global__ __launch_bounds__(256) void k_gemmfu(
        const __half* __restrict__ A,              // agg (f16), stride 64
        const __half* __restrict__ A2, int lda2,   // x-side (f16)
        const float* __restrict__ W1, const float* __restrict__ W2,
        const float* __restrict__ bias,
        const float* __restrict__ Wg, const float* __restrict__ bg,
        const float* __restrict__ s1, const float* __restrict__ s2,
        const float* __restrict__ gng, const float* __restrict__ gnb,
        const float* __restrict__ gna, float Ninv,
        const int* __restrict__ rowptr,
        __half* __restrict__ pre, __half* __restrict__ uout, int N) {
    __shared__ float WA[64 * 64];
    __shared__ float WB[K * 64];
    __shared__ float big[64][68];
    __shared__ float As[64], Bs[64], invd[64];
    int tid = threadIdx.x;
    for (int idx = tid; idx < K * 64; idx += 256) { WA[idx] = W1[idx]; WB[idx] = W2[idx]; }
    int nb = blockIdx.x * 64;
    if (tid < 64) {
        if (GN) {
            float mu = s1[tid] * Ninv, m2 = s2[tid] * Ninv, a = gna[tid];
            float var = m2 - 2.f * a * mu * mu + a * a * mu * mu;
            float Av = gng[tid] * rsqrtf(var + EPSV);
            As[tid] = Av; Bs[tid] = gnb[tid] - Av * a * mu;
        }
        int n = nb + tid;
        invd[tid] = (n < N) ? 1.f / (float)(rowptr[n + 1] - rowptr[n] + 1) : 0.f;
    }
    __syncthreads();
    int tm = tid >> 4, tn = tid & 15;
    int m0 = tm * 4, j0 = tn * 4;
    float acc[4][4];
#pragma unroll
    for (int jq = 0; jq < 4; ++jq) {
        float b = bias[j0 + jq];
#pragma unroll
        for (int mq = 0; mq < 4; ++mq) acc[mq][jq] = b;
    }
    int sn = tid >> 2, kq4 = (tid & 3) * 4;
    int sg = nb + sn;
    for (int k0 = 0; k0 < K; k0 += 16) {
        if (k0) __syncthreads();
        if (sg < N) {
            uint2 av2 = *reinterpret_cast<const uint2*>(A + (size_t)sg * 64 + k0 + kq4);
            float2 fa01 = up2(av2.x), fa23 = up2(av2.y);
            float sc = invd[sn];
            big[kq4 + 0][sn] = fa01.x * sc; big[kq4 + 1][sn] = fa01.y * sc;
            big[kq4 + 2][sn] = fa23.x * sc; big[kq4 + 3][sn] = fa23.y * sc;
            uint2 hv = *reinterpret_cast<const uint2*>(A2 + (size_t)sg * lda2 + k0 + kq4);
            float2 f01 = up2(hv.x), f23 = up2(hv.y);
            float xv0 = f01.x, xv1 = f01.y, xv2 = f23.x, xv3 = f23.y;
            if (GN) {
                xv0 = fmaxf(fmaf(As[k0 + kq4 + 0], xv0, Bs[k0 + kq4 + 0]), 0.f);
                xv1 = fmaxf(fmaf(As[k0 + kq4 + 1], xv1, Bs[k0 + kq4 + 1]), 0.f);
                xv2 = fmaxf(fmaf(As[k0 + kq4 + 2], xv2, Bs[k0 + kq4 + 2]), 0.f);
                xv3 = fmaxf(fmaf(As[k0 + kq4 + 3], xv3, Bs[k0 + kq4 + 3]), 0.f);
            }
            big[16 + kq4 + 0][sn] = xv0; big[16 + kq4 + 1][sn] = xv1;
            big[16 + kq4 + 2][sn] = xv2; big[16 + kq4 + 3][sn] = xv3;
        } else {
#pragma unroll
            for (int q = 0; q < 4; ++q) { big[kq4 + q][sn] = 0.f; big[16 + kq4 + q][sn] = 0.f; }
        }
        __syncthreads();
#pragma unroll
        for (int k = 0; k < 16; ++k) {
            float4 am = *reinterpret_cast<const float4*>(&big[k][m0]);
            float4 w1 = *reinterpret_cast<const float4*>(&WA[(k0 + k) * 64 + j0]);
            MT4A(0, am.x) MT4A(1, am.y) MT4A(2, am.z) MT4A(3, am.w)
            float4 xm = *reinterpret_cast<const float4*>(&big[16 + k][m0]);
            float4 w2 = *reinterpret_cast<const float4*>(&WB[(k0 + k) * 64 + j0]);
            MT4X(0, xm.x) MT4X(1, xm.y) MT4X(2, xm.z) MT4X(3, xm.w)
        }
    }
    __syncthreads();
#pragma unroll
    for (int mq = 0; mq < 4; ++mq) {
        int n = nb + m0 + mq;
        if (n < N) {
            uint2 o;
            o.x = pack2(acc[mq][0], acc[mq][1]);
            o.y = pack2(acc[mq][2], acc[mq][3]);
            *reinterpret_cast<uint2*>(pre + (size_t)n * 64 + j0) = o;
        }
#pragma unroll
        for (int jq = 0; jq < 4; ++jq) big[j0 + jq][m0 + mq] = acc[mq][jq];
    }
    for (int idx = tid; idx < 4096; idx += 256) WA[idx] = Wg[idx] * LOG2E;
    __syncthreads();
    float acc2[4][4];
#pragma unroll
    for (int jq = 0; jq < 4; ++jq) {
        float b = bg[j0 + jq] * LOG2E;
#pragma unroll
        for (int mq = 0; mq < 4; ++mq) acc2[mq][jq] = b;
    }
#pragma unroll 8
    for (int k = 0; k < 64; ++k) {
        float4 pm = *reinterpret_cast<const float4*>(&big[k][m0]);
        float4 w1 = *reinterpret_cast<const float4*>(&WA[k * 64 + j0]);
        acc2[0][0] = fmaf(pm.x, w1.x, acc2[0][0]); acc2[0][1] = fmaf(pm.x, w1.y, acc2[0][1]);
        acc2[0][2] = fmaf(pm.x, w1.z, acc2[0][2]); acc2[0][3] = fmaf(pm.x, w1.w, acc2[0][3]);
        acc2[1][0] = fmaf(pm.y, w1.x, acc2[1][0]); acc2[1][1] = fmaf(pm.y, w1.y, acc2[1][1]);
        acc2[1][2] = fmaf(pm.y, w1.z, acc2[1][2]); acc2[1][3] = fmaf(pm.y, w1.w, acc2[1][3]);
        acc2[2][0] = fmaf(pm.z, w1.x, acc2[2][0]); acc2[2][1] = fmaf(pm.z, w1.y, acc2[2][1]);
        acc2[2][2] = fmaf(pm.z, w1.z, acc2[2][2]); acc2[2][3] = fmaf(pm.z, w1.w, acc2[2][3]);
        acc2[3][0] = fmaf(pm.w, w1.x, acc2[3][0]); acc2[3][1] = fmaf(pm.w, w1.y, acc2[3][1]);
        acc2[3][2] = fmaf(pm.w, w1.z, acc2[3][2]); acc2[3][3] = fmaf(pm.w, w1.w, acc2[3][3]);
    }
#pragma unroll
    for (int mq = 0; mq < 4; ++mq) {
        int n = nb + m0 + mq;
        if (n < N) {
            uint2 o;
            o.x = pack2(acc2[mq][0], acc2[mq][1]);
            o.y = pack2(acc2[mq][2], acc2[mq][3]);
            *reinterpret_cast<uint2*>(uout + (size_t)n * 64 + j0) = o;
        }
    }
}

// ---------------- gate: MFMA edge matmul, direct coalesced A-fragment loads (no LDS staging) ----------
__global__ __launch_bounds__(256) void k_gate(
        const int* __restrict__ rowptr, const int* __restrict__ ranges,
        const __half* __restrict__ eap,
        const int* __restrict__ wth, const int* __restrict__ wgh,
        const float* __restrict__ be, const float* __restrict__ dv,
        const float* __restrict__ ets, const float* __restrict__ vs,
        const __half* __restrict__ u, __half* __restrict__ pre,
        float* __restrict__ s1, float* __restrict__ s2, int N) {
    __shared__ unsigned pvet[4][16][68];               // packed half2{V, ET}, wave-private
    __shared__ float ls[2][4][H];
    int lane = threadIdx.x & 63;
    int wv = threadIdx.x >> 6;
    int w = (blockIdx.x << 2) | wv;
    int g = lane >> 4, li = lane & 15;
    // loop-invariant B fragments; bias row at k=16 (group 2, elem 0)
    f16x8 Bet[4], Bv[4];
#pragma unroll
    for (int c = 0; c < 4; ++c) {
        int j = c * 16 + li;
        int4 bt = make_int4(0, 0, 0, 0), bv = make_int4(0, 0, 0, 0);
        if (g < 2) {
            bt = *reinterpret_cast<const int4*>(&wth[j * 8 + g * 4]);
            bv = *reinterpret_cast<const int4*>(&wgh[j * 8 + g * 4]);
        }
        Bet[c] = as_f16x8(bt);
        Bv[c] = as_f16x8(bv);
        if (g == 2) {
            Bet[c][0] = (_Float16)be[j];
            Bv[c][0]  = (_Float16)dv[j];
        }
    }
    float ets_l = ets[lane], vs_l = vs[lane];
    int n0 = ranges[w], n1 = ranges[w + 1];
    float s = 0.f, ss = 0.f;
    if (n0 < n1) {
        const int4* gsrc = reinterpret_cast<const int4*>(eap);
        int e0 = rowptr[n0], e1 = rowptr[n1];
        int n = n0;
        int nend = rowptr[n0 + 1];
        size_t idx = (size_t)n * H + lane;
        float u_l = __half2float(u[idx]);
        float pv = __half2float(pre[idx]);
        int np = min(n + 1, n1 - 1);
        size_t idxn = (size_t)np * H + lane;
        float u_n = __half2float(u[idxn]);
        float pv_n = __half2float(pre[idxn]);
        float acc = sigm2(u_l + vs_l) * ets_l;   // folded self-loop contribution
        // prefetch first tile's A-fragment (coalesced: 512B per tile, lanes 0..31)
        int4 afr = make_int4(0, 0, 0, 0);
        {
            int ei = e0 + li;
            if (g < 2 && ei < e1) afr = gsrc[(size_t)ei * 2 + g];
        }
        for (int tb = e0; tb < e1; tb += 16) {
            int4 afc = afr;
            afr = make_int4(0, 0, 0, 0);
            {
                int ei = tb + 16 + li;
                if (g < 2 && ei < e1) afr = gsrc[(size_t)ei * 2 + g];
            }
            f16x8 Af = as_f16x8(afc);
            if (g == 2) Af[0] = (_Float16)1.0f;    // bias column
            f32x4 z = {0.f, 0.f, 0.f, 0.f};
            f32x4 et0 = __builtin_amdgcn_mfma_f32_16x16x32_f16(Af, Bet[0], z, 0, 0, 0);
            f32x4 et1 = __builtin_amdgcn_mfma_f32_16x16x32_f16(Af, Bet[1], z, 0, 0, 0);
            f32x4 et2 = __builtin_amdgcn_mfma_f32_16x16x32_f16(Af, Bet[2], z, 0, 0, 0);
            f32x4 et3 = __builtin_amdgcn_mfma_f32_16x16x32_f16(Af, Bet[3], z, 0, 0, 0);
            f32x4 vv0 = __builtin_amdgcn_mfma_f32_16x16x32_f16(Af, Bv[0], z, 0, 0, 0);
            f32x4 vv1 = __builtin_amdgcn_mfma_f32_16x16x32_f16(Af, Bv[1], z, 0, 0, 0);
            f32x4 vv2 = __builtin_amdgcn_mfma_f32_16x16x32_f16(Af, Bv[2], z, 0, 0, 0);
            f32x4 vv3 = __builtin_amdgcn_mfma_f32_16x16x32_f16(Af, Bv[3], z, 0, 0, 0);
            int r0 = g * 4;
#pragma unroll
            for (int r = 0; r < 4; ++r) {
                pvet[wv][r0 + r][li]      = (unsigned)pack2(vv0[r], et0[r]);
                pvet[wv][r0 + r][16 + li] = (unsigned)pack2(vv1[r], et1[r]);
                pvet[wv][r0 + r][32 + li] = (unsigned)pack2(vv2[r], et2[r]);
                pvet[wv][r0 + r][48 + li] = (unsigned)pack2(vv3[r], et3[r]);
            }
            // ---- consume tile (channel = lane), absolute edge indices ----
            int pend = min(e1, tb + 16);
            int p = tb;
            while (p < pend) {
                while (p == nend) {           // node boundary: finish n, start next
                    float tval = pv + acc;
                    pre[idx] = __float2half(tval);
                    s += tval; ss += tval * tval;
                    ++n;
                    idx = idxn; u_l = u_n; pv = pv_n;
                    np = min(n + 1, n1 - 1);
                    idxn = (size_t)np * H + lane;
                    u_n = __half2float(u[idxn]);
                    pv_n = __half2float(pre[idxn]);
                    acc = sigm2(u_l + vs_l) * ets_l;
                    nend = rowptr[n + 1];
                }
                int lim = min(pend, nend);
                for (; p + 1 < lim; p += 2) {
                    unsigned w0 = pvet[wv][p - tb][lane];
                    unsigned w1 = pvet[wv][p + 1 - tb][lane];
                    float2 f0 = up2(w0);
                    float2 f1 = up2(w1);
                    acc += sigm2(u_l + f0.x) * f0.y + sigm2(u_l + f1.x) * f1.y;
                }
                if (p < lim) {
                    unsigned w0 = pvet[wv][p - tb][lane];
                    float2 f0 = up2(w0);
                    acc += sigm2(u_l + f0.x) * f0.y;
                    ++p;
                }
            }
        }
        for (;;) {   // finish current + trailing zero-edge nodes
            float tval = pv + acc;
            pre[idx] = __float2half(tval);
            s += tval; ss += tval * tval;
            ++n;
            if (n >= n1) break;
            idx = idxn; u_l = u_n; pv = pv_n;
            np = min(n + 1, n1 - 1);
            idxn = (size_t)np * H + lane;
            u_n = __half2float(u[idxn]);
            pv_n = __half2float(pre[idxn]);
            acc = sigm2(u_l + vs_l) * ets_l;
        }
    }
    ls[0][wv][lane] = s; ls[1][wv][lane] = ss;
    __syncthreads();
    if (threadIdx.x < H) {
        float a = ls[0][0][lane] + ls[0][1][lane] + ls[0][2][lane] + ls[0][3][lane];
        float b = ls[1][0][lane] + ls[1][1][lane] + ls[1][2][lane] + ls[1][3][lane];
        atomicAdd(&s1[lane], a);
        atomicAdd(&s2[lane], b);
    }
}

// ---------------- apply: h = relu(2*bn(t)) -> f16, vectorized (uint2 = 4ch), + GraphNorm stats ------
__global__ __launch_bounds__(256) void k_apply(const __half* __restrict__ in, __half* __restrict__ outb,
                        const float* __restrict__ bng, const float* __restrict__ bnb,
                        const float* __restrict__ s1b, const float* __restrict__ s2b,
                        float* __restrict__ s1g, float* __restrict__ s2g, float Ninv, int N) {
    int tid = threadIdx.x;
    int cg = (tid & 15) * 4;          // channel group base
    int ty = tid >> 4;                // 0..15 node row
    __shared__ float As[H], Bs[H];
    __shared__ float red[2][16][H];
    if (tid < 64) {
        float mu = s1b[tid] * Ninv, var = s2b[tid] * Ninv - mu * mu;
        float r = rsqrtf(var + EPSV);
        float A = 2.f * bng[tid] * r;
        As[tid] = A; Bs[tid] = 2.f * (bnb[tid] - bng[tid] * r * mu);
    }
    __syncthreads();
    float A0 = As[cg], A1 = As[cg + 1], A2 = As[cg + 2], A3 = As[cg + 3];
    float B0 = Bs[cg], B1 = Bs[cg + 1], B2 = Bs[cg + 2], B3 = Bs[cg + 3];
    float s0 = 0.f, s1_ = 0.f, s2_ = 0.f, s3 = 0.f;
    float q0 = 0.f, q1 = 0.f, q2 = 0.f, q3 = 0.f;
    for (int n = blockIdx.x * 16 + ty; n < N; n += gridDim.x * 16) {
        size_t idx = (size_t)n * H + cg;
        uint2 hv = *reinterpret_cast<const uint2*>(in + idx);
        float2 f01 = up2(hv.x), f23 = up2(hv.y);
        float v0 = fmaxf(fmaf(A0, f01.x, B0), 0.f);
        float v1 = fmaxf(fmaf(A1, f01.y, B1), 0.f);
        float v2 = fmaxf(fmaf(A2, f23.x, B2), 0.f);
        float v3 = fmaxf(fmaf(A3, f23.y, B3), 0.f);
        uint2 o;
        o.x = (unsigned)pack2(v0, v1);
        o.y = (unsigned)pack2(v2, v3);
        *reinterpret_cast<uint2*>(outb + idx) = o;
        s0 += v0; s1_ += v1; s2_ += v2; s3 += v3;
        q0 += v0 * v0; q1 += v1 * v1; q2 += v2 * v2; q3 += v3 * v3;
    }
    *reinterpret_cast<float4*>(&red[0][ty][cg]) = make_float4(s0, s1_, s2_, s3);
    *reinterpret_cast<float4*>(&red[1][ty][cg]) = make_float4(q0, q1, q2, q3);
    __syncthreads();
    if (tid < H) {
        float a = 0.f, b = 0.f;
#pragma unroll
        for (int r = 0; r < 16; ++r) { a += red[0][r][tid]; b += red[1][r][tid]; }
        atomicAdd(&s1g[tid], a);
        atomicAdd(&s2g[tid], b);
    }
}

// ---------------- final: out = relu(gn2(h)) @ lin_W + lin_b ----------------
__global__ __launch_bounds__(256) void k_final(const __half* __restrict__ hraw, const float* __restrict__ W,
                        const float* __restrict__ bias,
                        const float* __restrict__ s1, const float* __restrict__ s2,
                        const float* __restrict__ gng, const float* __restrict__ gnb,
                        const float* __restrict__ gna, float Ninv,
                        float* __restrict__ outp, int N) {
    __shared__ float As[H], Bs[H];
    if (threadIdx.x < H) {
        int j = threadIdx.x;
        float mu = s1[j] * Ninv, m2 = s2[j] * Ninv, a = gna[j];
        float var = m2 - 2.f * a * mu * mu + a * a * mu * mu;
        float A = gng[j] * rsqrtf(var + EPSV);
        As[j] = A; Bs[j] = gnb[j] - A * a * mu;
    }
    __syncthreads();
    int n = blockIdx.x * blockDim.x + threadIdx.x;
    if (n >= N) return;
    float o[CO];
#pragma unroll
    for (int t = 0; t < CO; ++t) o[t] = bias[t];
    const __half* hr = hraw + (size_t)n * H;
    for (int m4 = 0; m4 < H / 4; ++m4) {
        uint2 hv = *reinterpret_cast<const uint2*>(hr + m4 * 4);
        float2 f01 = up2(hv.x), f23 = up2(hv.y);
        float hx = fmaxf(fmaf(As[m4*4+0], f01.x, Bs[m4*4+0]), 0.f);
        float hy = fmaxf(fmaf(As[m4*4+1], f01.y, Bs[m4*4+1]), 0.f);
        float hz = fmaxf(fmaf(As[m4*4+2], f23.x, Bs[m4*4+2]), 0.f);
        float hw = fmaxf(fmaf(As[m4*4+3], f23.y, Bs[m4*4+3]), 0.f);
#pragma unroll
        for (int t = 0; t < CO; ++t) {
            o[t] += hx * W[(m4*4+0) * CO + t];
            o[t] += hy * W[(m4*4+1) * CO + t];
            o[t] += hz * W[(m4*4+2) * CO + t];
            o[t] += hw * W[(m4*4+3) * CO + t];
        }
    }
    float* orow = outp + (size_t)n * CO;
#pragma unroll
    for (int t4 = 0; t4 < CO / 4; ++t4)
        reinterpret_cast<float4*>(orow)[t4] = make_float4(o[t4*4+0], o[t4*4+1], o[t4*4+2], o[t4*4+3]);
}

extern "C" void kernel_launch(void* const* d_in, const int* in_sizes, int n_in,
                              void* d_out, int out_size, void* d_ws, size_t ws_size,
                              hipStream_t stream) {
    const float* x     = (const float*)d_in[0];
    const int*   ei    = (const int*)d_in[1];
    const float* ea    = (const float*)d_in[2];
    const float* l1_Wl = (const float*)d_in[3];  const float* l1_bl = (const float*)d_in[4];
    const float* l1_Wr = (const float*)d_in[5];  const float* l1_We = (const float*)d_in[6];
    const float* l1_be = (const float*)d_in[7];  const float* l1_Wg = (const float*)d_in[8];
    const float* l1_bg = (const float*)d_in[9];  const float* l1_bng= (const float*)d_in[10];
    const float* l1_bnb= (const float*)d_in[11];
    const float* l2_Wl = (const float*)d_in[12]; const float* l2_bl = (const float*)d_in[13];
    const float* l2_Wr = (const float*)d_in[14]; const float* l2_We = (const float*)d_in[15];
    const float* l2_be = (const float*)d_in[16]; const float* l2_Wg = (const float*)d_in[17];
    const float* l2_bg = (const float*)d_in[18]; const float* l2_bng= (const float*)d_in[19];
    const float* l2_bnb= (const float*)d_in[20];
    const float* gn1_g = (const float*)d_in[21]; const float* gn1_b = (const float*)d_in[22];
    const float* gn1_a = (const float*)d_in[23];
    const float* gn2_g = (const float*)d_in[24]; const float* gn2_b = (const float*)d_in[25];
    const float* gn2_a = (const float*)d_in[26];
    const float* lin_W = (const float*)d_in[27]; const float* lin_b = (const float*)d_in[28];

    const int N = in_sizes[0] / 32;
    const int E = in_sizes[1] / 2;
    const int* rows = ei;
    const int* cols = ei + E;

    // bucket geometry
    int SH = 7, NPB = 128;
    while (((N + NPB - 1) >> SH) > 1024) { SH++; NPB <<= 1; }
    const int NB = (N + NPB - 1) >> SH;
    const int PB = (E + CPART - 1) / CPART;

    float* w    = (float*)d_ws;
    int* wth1   = (int*)w;
    int* wgh1   = (int*)(w + 512);
    int* wth2   = (int*)(w + 1024);
    int* wgh2   = (int*)(w + 1536);
    float* ets1 = w + 2048; float* vs1 = w + 2112; float* dv1 = w + 2176;
    float* ets2 = w + 2240; float* vs2 = w + 2304; float* dv2 = w + 2368;
    float* stats= w + 2432;

    int* ip     = (int*)(w + 8192);
    int* rowptr = ip;                 // N+1 (persistent)
    int* cnt    = ip + (N + 1);       // N
    int* bs     = cnt + N;            // 1024
    int* ranges = bs + 1024;          // NWAVES+2 (persistent)
    int* erow   = ranges + (NWAVES + 2);  // E (persistent)

    uintptr_t pa = (uintptr_t)(erow + E);
    pa = (pa + 255) & ~(uintptr_t)255;
    __half* eap = (__half*)pa;        // E*16 halves (persistent)
    uintptr_t px = (uintptr_t)(eap + (size_t)E * ED);
    px = (px + 255) & ~(uintptr_t)255;
    __half* xh = (__half*)px;         // N*32 halves (persistent)
    uintptr_t pz = (uintptr_t)(xh + (size_t)N * 32);
    pz = (pz + 255) & ~(uintptr_t)255;

    // --- overlap zone: {tmpk, tmpp, offtab} (CSR build) then {Bagg, Bpre, Bu, B3h} (layers) ---
    int2* tmpk  = (int2*)pz;                       // E
    int4* tmpp  = (int4*)(tmpk + E);               // E*2 (32B/edge payload)
    int* offtab = (int*)(tmpp + (size_t)E * 2);    // PB*(NB+1)

    size_t NB64 = (size_t)N * H;
    __half* Bagg = (__half*)pz;                    // agg (f16) — aliases tmpk/tmpp/offtab
    __half* Bpre = Bagg + NB64;                    // pre/t (f16)
    __half* Bu   = Bpre + NB64;                    // u (f16)
    __half* B3h  = Bu + NB64;                      // h layer1 (f16)
    __half* B0h  = Bagg;                           // h layer2 reuses agg space

    const float Ninv = 1.0f / (float)N;
    int ngrid = (N + 255) / 256;
    int g64 = (N + 63) / 64;
    const int SB = (N + 1023) >> 10;

    k_prep<<<1, 64, 0, stream>>>(l1_We, l1_be, l1_Wg, l2_We, l2_be, l2_Wg, w);
    k_xh<<<(N * 8 + 255) / 256, 256, 0, stream>>>(x, xh, N * 8);

    // ---- CSR build: payload-carrying partition (count fused) -> scan -> streaming build ----
    hipMemsetAsync(cnt, 0, sizeof(int) * (size_t)N, stream);
    k_part<<<PB, 256, 0, stream>>>(rows, cols, ea, tmpk, tmpp, offtab, cnt, E, NB, SH);
    k_scan1<<<SB, 1024, 0, stream>>>(cnt, bs, N);
    k_scan2<<<1, 1024, 0, stream>>>(bs, SB);
    k_scan3<<<SB, 1024, 0, stream>>>(cnt, bs, rowptr, N, E);
    k_ranges<<<(NWAVES + 256) / 256, 256, 0, stream>>>(rowptr, ranges, N, E, NWAVES);
    k_build<<<NB, 1024, 0, stream>>>(rowptr, tmpk, tmpp, offtab, erow, eap, N, NB, SH, PB);

    // ---- layer 1 ----
    k_gather<32, false><<<WGRID, 256, 0, stream>>>(xh, rowptr, ranges, erow, Bagg,
                                                   nullptr, nullptr, nullptr, nullptr, nullptr, 0.f, N);
    k_gemmfu<32, false><<<g64, 256, 0, stream>>>(Bagg, xh, 32, l1_Wl, l1_Wr, l1_bl, l1_Wg, l1_bg,
                                                 nullptr, nullptr, nullptr, nullptr, nullptr, 0.f,
                                                 rowptr, Bpre, Bu, N);
    k_gate<<<WGRID, 256, 0, stream>>>(rowptr, ranges, eap, wth1, wgh1, l1_be, dv1, ets1, vs1,
                                      Bu, Bpre, stats + 0, stats + 64, N);
    k_apply<<<256, 256, 0, stream>>>(Bpre, B3h, l1_bng, l1_bnb, stats + 0, stats + 64,
                                     stats + 128, stats + 192, Ninv, N);

    // ---- layer 2 (gn1 folded into readers of B3h) ----
    k_gather<64, true><<<WGRID, 256, 0, stream>>>(B3h, rowptr, ranges, erow, Bagg,
                                                  stats + 128, stats + 192, gn1_g, gn1_b, gn1_a, Ninv, N);
    k_gemmfu<64, true><<<g64, 256, 0, stream>>>(Bagg, B3h, 64, l2_Wl, l2_Wr, l2_bl, l2_Wg, l2_bg,
                                                stats + 128, stats + 192, gn1_g, gn1_b, gn1_a, Ninv,
                                                rowptr, Bpre, Bu, N);
    k_gate<<<WGRID, 256, 0, stream>>>(rowptr, ranges, eap, wth2, wgh2, l2_be, dv2, ets2, vs2,
                                      Bu, Bpre, stats + 256, stats + 320, N);
    k_apply<<<256, 256, 0, stream>>>(Bpre, B0h, l2_bng, l2_bnb, stats + 256, stats + 320,
                                     stats + 384, stats + 448, Ninv, N);

    // ---- final ----
    k_final<<<ngrid, 256, 0, stream>>>(B0h, lin_W, lin_b, stats + 384, stats + 448,
                                       gn2_g, gn2_b, gn2_a, Ninv, (float*)d_out, N);
}

// Round 17
// 595.254 us; speedup vs baseline: 1.2771x; 1.0088x over previous
//
#include <hip/hip_runtime.h>
#include <hip/hip_fp16.h>
#include <math.h>
#include <stdint.h>

#define H 64
#define ED 16
#define CO 16
#define WGRID 2048
#define NWAVES (WGRID * 4)
#define CPART 1024
static constexpr float EPSV = 1e-5f;
static constexpr float LOG2E = 1.44269504f;

typedef _Float16 h2v __attribute__((ext_vector_type(2)));
typedef _Float16 f16x8 __attribute__((ext_vector_type(8)));
typedef float f32x4 __attribute__((ext_vector_type(4)));

__device__ __forceinline__ float sigm2(float z) {
    return __builtin_amdgcn_rcpf(1.0f + __builtin_amdgcn_exp2f(-z));
}

// sigmoid from pre-negated argument: rcp(1 + 2^z) where z = -(u+V)*log2e
__device__ __forceinline__ float sigm2n(float z) {
    return __builtin_amdgcn_rcpf(1.0f + __builtin_amdgcn_exp2f(z));
}

__device__ __forceinline__ f16x8 as_f16x8(int4 v) { union { int4 i; f16x8 h; } u; u.i = v; return u.h; }

__device__ __forceinline__ int pack2(float a, float b) {
    __half2 h = __floats2half2_rn(a, b);
    return *reinterpret_cast<int*>(&h);
}

__device__ __forceinline__ float2 up2(unsigned v) {
    return __half22float2(*reinterpret_cast<__half2*>(&v));
}

// ---------------- prep: packed-f16 gate weights (log2e-folded, V-path NEGATED), self-loop consts ------
__global__ void k_prep(const float* __restrict__ We1, const float* __restrict__ be1, const float* __restrict__ Wg1,
                       const float* __restrict__ We2, const float* __restrict__ be2, const float* __restrict__ Wg2,
                       float* __restrict__ ws) {
    int j = threadIdx.x;  // 0..63
    for (int l = 0; l < 2; ++l) {
        const float* We = l ? We2 : We1;
        const float* be = l ? be2 : be1;
        const float* Wg = l ? Wg2 : Wg1;
        int* wth = (int*)(ws + (l ? 1024 : 0));
        int* wgh = (int*)(ws + (l ? 1536 : 512));
        float* ets = ws + 2048 + l * 192;
        float* vs  = ws + 2112 + l * 192;
        float* dv  = ws + 2176 + l * 192;
        float wt[ED], wg[ED];
        float et = be[j];
        for (int k = 0; k < ED; ++k) { wt[k] = We[k * H + j]; et += wt[k]; }
        ets[j] = et;                                   // ea_t for self-loop (ea = ones)
        float d = 0.f;
        for (int m = 0; m < H; ++m) d += be[m] * Wg[(H + m) * H + j];
        float vsum = d;
        for (int k = 0; k < ED; ++k) {
            float acc = 0.f;
            for (int m = 0; m < H; ++m) acc += We[k * H + m] * Wg[(H + m) * H + j];
            wg[k] = acc;                               // (We @ Wg_bot)^T
            vsum += acc;
        }
        dv[j] = d * LOG2E;                             // positive; negated at gate bias row
        vs[j] = vsum * LOG2E;
        for (int q = 0; q < 8; ++q) {
            wth[j * 8 + q] = pack2(wt[2 * q], wt[2 * q + 1]);
            wgh[j * 8 + q] = pack2(-wg[2 * q] * LOG2E, -wg[2 * q + 1] * LOG2E);  // NEGATED
        }
    }
    for (int s = 0; s < 8; ++s) ws[2432 + s * 64 + j] = 0.f;  // zero all stats
}

// ---------------- x -> f16 ----------------
__global__ void k_xh(const float* __restrict__ x, __half* __restrict__ xh, int total4) {
    int i = blockIdx.x * blockDim.x + threadIdx.x;
    if (i >= total4) return;
    float4 v = *reinterpret_cast<const float4*>(x + (size_t)i * 4);
    __half2 h0 = __floats2half2_rn(v.x, v.y), h1 = __floats2half2_rn(v.z, v.w);
    uint2 o;
    o.x = *reinterpret_cast<unsigned*>(&h0);
    o.y = *reinterpret_cast<unsigned*>(&h1);
    *reinterpret_cast<uint2*>(xh + (size_t)i * 4) = o;
}

// ---------------- scans ----------------
__global__ __launch_bounds__(1024) void k_scan1(const int* __restrict__ cnt, int* __restrict__ bs, int N) {
    __shared__ int ls[1024];
    int t = threadIdx.x;
    int i = blockIdx.x * 1024 + t;
    ls[t] = (i < N) ? cnt[i] : 0;
    __syncthreads();
    for (int off = 512; off > 0; off >>= 1) {
        if (t < off) ls[t] += ls[t + off];
        __syncthreads();
    }
    if (t == 0) bs[blockIdx.x] = ls[0];
}

__global__ __launch_bounds__(1024) void k_scan2(int* __restrict__ bs, int SB) {
    __shared__ int ls[1024];
    int t = threadIdx.x;
    int v = (t < SB) ? bs[t] : 0;
    ls[t] = v;
    __syncthreads();
    for (int off = 1; off < 1024; off <<= 1) {
        int x = (t >= off) ? ls[t - off] : 0;
        __syncthreads();
        ls[t] += x;
        __syncthreads();
    }
    if (t < SB) bs[t] = ls[t] - v;  // exclusive
}

__global__ __launch_bounds__(1024) void k_scan3(const int* __restrict__ cnt, const int* __restrict__ bs,
                                                int* __restrict__ rowptr, int N, int E) {
    __shared__ int ls[1024];
    int t = threadIdx.x;
    int i = blockIdx.x * 1024 + t;
    int v = (i < N) ? cnt[i] : 0;
    ls[t] = v;
    __syncthreads();
    for (int off = 1; off < 1024; off <<= 1) {
        int x = (t >= off) ? ls[t - off] : 0;
        __syncthreads();
        ls[t] += x;
        __syncthreads();
    }
    if (i < N) rowptr[i] = bs[blockIdx.x] + ls[t] - v;  // exclusive prefix
    if (i == 0) rowptr[N] = E;
}

// ---------------- wave ranges ----------------
__global__ void k_ranges(const int* __restrict__ rowptr, int* __restrict__ ranges, int N, int E, int nw) {
    int w = blockIdx.x * blockDim.x + threadIdx.x;
    if (w > nw) return;
    if (w == nw) { ranges[nw] = N; return; }
    int t0 = (int)((long)E * w / nw);
    int lo = 0, hi = N;
    while (lo < hi) { int mid = (lo + hi) >> 1; if (rowptr[mid] < t0) lo = mid + 1; else hi = mid; }
    ranges[w] = lo;
}

// ---------------- partition pass 1: bucket sort WITH payload + fused per-node count ----------------
__global__ __launch_bounds__(256) void k_part(const int* __restrict__ rows, const int* __restrict__ cols,
                                              const float* __restrict__ ea,
                                              int2* __restrict__ tmpk, int4* __restrict__ tmpp,
                                              int* __restrict__ offtab, int* __restrict__ cnt,
                                              int E, int NB, int SH) {
    __shared__ int hist[1025];
    __shared__ int pscan[256];
    __shared__ int2 skey[CPART];
    __shared__ int4 spay[CPART][2];
    int tid = threadIdx.x;
    int base = blockIdx.x * CPART;
    int cntE = min(CPART, E - base);
    for (int i = tid; i <= NB; i += 256) hist[i] = 0;
    __syncthreads();
    int myc[4], myr[4];
    int4 pa0[4], pa1[4];
#pragma unroll
    for (int q = 0; q < 4; ++q) {
        int li = q * 256 + tid;
        if (li < cntE) {
            int e = base + li;
            myc[q] = cols[e];
            myr[q] = rows[e];
            const float4* src = reinterpret_cast<const float4*>(ea + (size_t)e * ED);
            float4 v0 = src[0], v1 = src[1], v2 = src[2], v3 = src[3];
            int hh[8];
            hh[0] = pack2(v0.x, v0.y); hh[1] = pack2(v0.z, v0.w);
            hh[2] = pack2(v1.x, v1.y); hh[3] = pack2(v1.z, v1.w);
            hh[4] = pack2(v2.x, v2.y); hh[5] = pack2(v2.z, v2.w);
            hh[6] = pack2(v3.x, v3.y); hh[7] = pack2(v3.z, v3.w);
            pa0[q] = reinterpret_cast<const int4*>(hh)[0];
            pa1[q] = reinterpret_cast<const int4*>(hh)[1];
            atomicAdd(&hist[myc[q] >> SH], 1);
            atomicAdd(&cnt[myc[q]], 1);                 // fused per-node degree count
        } else myc[q] = -1;
    }
    __syncthreads();
    int h[4], s = 0;
    int b0 = tid * 4;
#pragma unroll
    for (int k = 0; k < 4; ++k) { h[k] = (b0 + k < NB) ? hist[b0 + k] : 0; s += h[k]; }
    pscan[tid] = s;
    __syncthreads();
    for (int off = 1; off < 256; off <<= 1) {
        int v = (tid >= off) ? pscan[tid - off] : 0;
        __syncthreads();
        pscan[tid] += v;
        __syncthreads();
    }
    int excl = pscan[tid] - s;
    __syncthreads();
    int run = excl;
#pragma unroll
    for (int k = 0; k < 4; ++k) {
        if (b0 + k < NB) hist[b0 + k] = run;
        run += h[k];
    }
    __syncthreads();
    int* ot = offtab + (size_t)blockIdx.x * (NB + 1);
    for (int i = tid; i < NB; i += 256) ot[i] = hist[i];
    if (tid == 0) ot[NB] = cntE;
    __syncthreads();
    int mask = (1 << SH) - 1;
#pragma unroll
    for (int q = 0; q < 4; ++q) {
        if (myc[q] >= 0) {
            int b = myc[q] >> SH;
            int p = atomicAdd(&hist[b], 1);
            skey[p] = make_int2(myr[q], myc[q] & mask);
            spay[p][0] = pa0[q];
            spay[p][1] = pa1[q];
        }
    }
    __syncthreads();
    for (int i = tid; i < cntE; i += 256) {
        tmpk[base + i] = skey[i];
        tmpp[(size_t)(base + i) * 2 + 0] = spay[i][0];
        tmpp[(size_t)(base + i) * 2 + 1] = spay[i][1];
    }
}

// ---------------- build pass 2: streaming per-bucket CSR placement (no random global reads) --------
__global__ __launch_bounds__(1024) void k_build(const int* __restrict__ rowptr, const int2* __restrict__ tmpk,
                                               const int4* __restrict__ tmpp,
                                               const int* __restrict__ offtab,
                                               int* __restrict__ erow, __half* __restrict__ eap,
                                               int N, int NB, int SH, int PB) {
    __shared__ int lcur[1024];
    int tid = threadIdx.x;
    int b = blockIdx.x;
    int NPB = 1 << SH;
    int nodelo = b << SH;
    for (int j = tid; j < NPB; j += 1024) {
        int n = nodelo + j;
        lcur[j] = (n < N) ? rowptr[n] : 0;
    }
    __syncthreads();
    for (int i = tid; i < PB; i += 1024) {
        const int* ot = offtab + (size_t)i * (NB + 1);
        int j0 = ot[b], j1 = ot[b + 1];
        for (int j = j0; j < j1; ++j) {
            size_t src = (size_t)i * CPART + j;
            int2 k = tmpk[src];
            int4 a0 = tmpp[src * 2 + 0];
            int4 a1 = tmpp[src * 2 + 1];
            int p = atomicAdd(&lcur[k.y], 1);
            erow[p] = k.x;
            int4* d = reinterpret_cast<int4*>(eap + (size_t)p * ED);
            d[0] = a0; d[1] = a1;
        }
    }
}

// ---------------- gather (f16 in/out, 2ch/lane uint loads): agg[n] = T(x[n]) + sum_in T(x[row]) ----
template <int CIN, bool GN>
__global__ __launch_bounds__(256) void k_gather(const __half* __restrict__ x, const int* __restrict__ rowptr,
                         const int* __restrict__ ranges,
                         const int* __restrict__ erow, __half* __restrict__ agg,
                         const float* __restrict__ s1, const float* __restrict__ s2,
                         const float* __restrict__ gng, const float* __restrict__ gnb,
                         const float* __restrict__ gna, float Ninv, int N) {
    int lane = threadIdx.x & 63;
    int w = (blockIdx.x * blockDim.x + threadIdx.x) >> 6;
    const unsigned* xu = reinterpret_cast<const unsigned*>(x);
    unsigned* aggu = reinterpret_cast<unsigned*>(agg);
    int n0 = ranges[w], n1 = ranges[w + 1];
    if (CIN == 64) {
        int c2 = lane & 31, half = lane >> 5;   // channel pair 2*c2, edge parity
        float A0 = 1.f, A1 = 1.f, B0 = 0.f, B1 = 0.f;
        if (GN) {
            int ch0 = c2 * 2, ch1 = ch0 + 1;
            float mu0 = s1[ch0] * Ninv, m20 = s2[ch0] * Ninv, a0 = gna[ch0];
            float var0 = m20 - 2.f * a0 * mu0 * mu0 + a0 * a0 * mu0 * mu0;
            A0 = gng[ch0] * rsqrtf(var0 + EPSV);
            B0 = gnb[ch0] - A0 * a0 * mu0;
            float mu1 = s1[ch1] * Ninv, m21 = s2[ch1] * Ninv, a1 = gna[ch1];
            float var1 = m21 - 2.f * a1 * mu1 * mu1 + a1 * a1 * mu1 * mu1;
            A1 = gng[ch1] * rsqrtf(var1 + EPSV);
            B1 = gnb[ch1] - A1 * a1 * mu1;
        }
        for (int n = n0; n < n1; ++n) {
            int s = rowptr[n], te = rowptr[n + 1];
            float2 raw = up2(xu[(size_t)n * 32 + c2]);
            float a0 = 0.f, a1 = 0.f;
            if (half == 0) {
                if (GN) {
                    a0 = fmaxf(fmaf(A0, raw.x, B0), 0.f);
                    a1 = fmaxf(fmaf(A1, raw.y, B1), 0.f);
                } else { a0 = raw.x; a1 = raw.y; }
            }
            int i = s + half;
            for (; i + 14 < te; i += 16) {
                unsigned v[8];
#pragma unroll
                for (int q = 0; q < 8; ++q)
                    v[q] = xu[(size_t)erow[i + q * 2] * 32 + c2];
#pragma unroll
                for (int q = 0; q < 8; ++q) {
                    float2 f = up2(v[q]);
                    float t0 = f.x, t1 = f.y;
                    if (GN) {
                        t0 = fmaxf(fmaf(A0, t0, B0), 0.f);
                        t1 = fmaxf(fmaf(A1, t1, B1), 0.f);
                    }
                    a0 += t0; a1 += t1;
                }
            }
            for (; i < te; i += 2) {
                float2 f = up2(xu[(size_t)erow[i] * 32 + c2]);
                float t0 = f.x, t1 = f.y;
                if (GN) {
                    t0 = fmaxf(fmaf(A0, t0, B0), 0.f);
                    t1 = fmaxf(fmaf(A1, t1, B1), 0.f);
                }
                a0 += t0; a1 += t1;
            }
            a0 += __shfl_xor(a0, 32);
            a1 += __shfl_xor(a1, 32);
            if (half == 0) aggu[(size_t)n * 32 + c2] = (unsigned)pack2(a0, a1);
        }
    } else {
        int c2 = lane & 15, qg = lane >> 4;     // channel pair (row=16 uints), edge group 0..3
        for (int n = n0; n < n1; ++n) {
            int s = rowptr[n], te = rowptr[n + 1];
            float2 raw = up2(xu[(size_t)n * 16 + c2]);
            float a0 = (qg == 0) ? raw.x : 0.f;
            float a1 = (qg == 0) ? raw.y : 0.f;
            int i = s + qg;
            for (; i + 12 < te; i += 16) {
                unsigned v[4];
#pragma unroll
                for (int q = 0; q < 4; ++q)
                    v[q] = xu[(size_t)erow[i + q * 4] * 16 + c2];
#pragma unroll
                for (int q = 0; q < 4; ++q) {
                    float2 f = up2(v[q]);
                    a0 += f.x; a1 += f.y;
                }
            }
            for (; i < te; i += 4) {
                float2 f = up2(xu[(size_t)erow[i] * 16 + c2]);
                a0 += f.x; a1 += f.y;
            }
            a0 += __shfl_xor(a0, 32); a0 += __shfl_xor(a0, 16);
            a1 += __shfl_xor(a1, 32); a1 += __shfl_xor(a1, 16);
            if (lane < 16) aggu[(size_t)n * 32 + c2] = (unsigned)pack2(a0, a1);
        }
    }
}

// ---------------- fused GEMM: pre = (agg/deg)@Wl + T(x)@Wr + bl ; u = (pre@Wg_top + bg)*log2e ----------
#define MT4A(mq, aval) \
    acc[mq][0] = fmaf(aval, w1.x, acc[mq][0]); acc[mq][1] = fmaf(aval, w1.y, acc[mq][1]); \
    acc[mq][2] = fmaf(aval, w1.z, acc[mq][2]); acc[mq][3] = fmaf(aval, w1.w, acc[mq][3]);
#define MT4X(mq, aval) \
    acc[mq][0] = fmaf(aval, w2.x, acc[mq][0]); acc[mq][1] = fmaf(aval, w2.y, acc[mq][1]); \
    acc[mq][2] = fmaf(aval, w2.z, acc[mq][2]); acc[mq][3] = fmaf(aval, w2.w, acc[mq][3]);

template <int K, bool GN>
__global__ __launch_bounds__(256) void k_gemmfu(
        const __half* __restrict__ A,              // agg (f16), stride 64
        const __half* __restrict__ A2, int lda2,   // x-side (f16)
        const float* __restrict__ W1, const float* __restrict__ W2,
        const float* __restrict__ bias,
        const float* __restrict__ Wg, const float* __restrict__ bg,
        const float* __restrict__ s1, const float* __restrict__ s2,
        const float* __restrict__ gng, const float* __restrict__ gnb,
        const float* __restrict__ gna, float Ninv,
        const int* __restrict__ rowptr,
        __half* __restrict__ pre, __half* __restrict__ uout, int N) {
    __shared__ float WA[64 * 64];
    __shared__ float WB[K * 64];
    __shared__ float big[64][68];
    __shared__ float As[64], Bs[64], invd[64];
    int tid = threadIdx.x;
    for (int idx = tid; idx < K * 64; idx += 256) { WA[idx] = W1[idx]; WB[idx] = W2[idx]; }
    int nb = blockIdx.x * 64;
    if (tid < 64) {
        if (GN) {
            float mu = s1[tid] * Ninv, m2 = s2[tid] * Ninv, a = gna[tid];
            float var = m2 - 2.f * a * mu * mu + a * a * mu * mu;
            float Av = gng[tid] * rsqrtf(var + EPSV);
            As[tid] = Av; Bs[tid] = gnb[tid] - Av * a * mu;
        }
        int n = nb + tid;
        invd[tid] = (n < N) ? 1.f / (float)(rowptr[n + 1] - rowptr[n] + 1) : 0.f;
    }
    __syncthreads();
    int tm = tid >> 4, tn = tid & 15;
    int m0 = tm * 4, j0 = tn * 4;
    float acc[4][4];
#pragma unroll
    for (int jq = 0; jq < 4; ++jq) {
        float b = bias[j0 + jq];
#pragma unroll
        for (int mq = 0; mq < 4; ++mq) acc[mq][jq] = b;
    }
    int sn = tid >> 2, kq4 = (tid & 3) * 4;
    int sg = nb + sn;
    for (int k0 = 0; k0 < K; k0 += 16) {
        if (k0) __syncthreads();
        if (sg < N) {
            uint2 av2 = *reinterpret_cast<const uint2*>(A + (size_t)sg * 64 + k0 + kq4);
            float2 fa01 = up2(av2.x), fa23 = up2(av2.y);
            float sc = invd[sn];
            big[kq4 + 0][sn] = fa01.x * sc; big[kq4 + 1][sn] = fa01.y * sc;
            big[kq4 + 2][sn] = fa23.x * sc; big[kq4 + 3][sn] = fa23.y * sc;
            uint2 hv = *reinterpret_cast<const uint2*>(A2 + (size_t)sg * lda2 + k0 + kq4);
            float2 f01 = up2(hv.x), f23 = up2(hv.y);
            float xv0 = f01.x, xv1 = f01.y, xv2 = f23.x, xv3 = f23.y;
            if (GN) {
                xv0 = fmaxf(fmaf(As[k0 + kq4 + 0], xv0, Bs[k0 + kq4 + 0]), 0.f);
                xv1 = fmaxf(fmaf(As[k0 + kq4 + 1], xv1, Bs[k0 + kq4 + 1]), 0.f);
                xv2 = fmaxf(fmaf(As[k0 + kq4 + 2], xv2, Bs[k0 + kq4 + 2]), 0.f);
                xv3 = fmaxf(fmaf(As[k0 + kq4 + 3], xv3, Bs[k0 + kq4 + 3]), 0.f);
            }
            big[16 + kq4 + 0][sn] = xv0; big[16 + kq4 + 1][sn] = xv1;
            big[16 + kq4 + 2][sn] = xv2; big[16 + kq4 + 3][sn] = xv3;
        } else {
#pragma unroll
            for (int q = 0; q < 4; ++q) { big[kq4 + q][sn] = 0.f; big[16 + kq4 + q][sn] = 0.f; }
        }
        __syncthreads();
#pragma unroll
        for (int k = 0; k < 16; ++k) {
            float4 am = *reinterpret_cast<const float4*>(&big[k][m0]);
            float4 w1 = *reinterpret_cast<const float4*>(&WA[(k0 + k) * 64 + j0]);
            MT4A(0, am.x) MT4A(1, am.y) MT4A(2, am.z) MT4A(3, am.w)
            float4 xm = *reinterpret_cast<const float4*>(&big[16 + k][m0]);
            float4 w2 = *reinterpret_cast<const float4*>(&WB[(k0 + k) * 64 + j0]);
            MT4X(0, xm.x) MT4X(1, xm.y) MT4X(2, xm.z) MT4X(3, xm.w)
        }
    }
    __syncthreads();
#pragma unroll
    for (int mq = 0; mq < 4; ++mq) {
        int n = nb + m0 + mq;
        if (n < N) {
            uint2 o;
            o.x = pack2(acc[mq][0], acc[mq][1]);
            o.y = pack2(acc[mq][2], acc[mq][3]);
            *reinterpret_cast<uint2*>(pre + (size_t)n * 64 + j0) = o;
        }
#pragma unroll
        for (int jq = 0; jq < 4; ++jq) big[j0 + jq][m0 + mq] = acc[mq][jq];
    }
    for (int idx = tid; idx < 4096; idx += 256) WA[idx] = Wg[idx] * LOG2E;
    __syncthreads();
    float acc2[4][4];
#pragma unroll
    for (int jq = 0; jq < 4; ++jq) {
        float b = bg[j0 + jq] * LOG2E;
#pragma unroll
        for (int mq = 0; mq < 4; ++mq) acc2[mq][jq] = b;
    }
#pragma unroll 8
    for (int k = 0; k < 64; ++k) {
        float4 pm = *reinterpret_cast<const float4*>(&big[k][m0]);
        float4 w1 = *reinterpret_cast<const float4*>(&WA[k * 64 + j0]);
        acc2[0][0] = fmaf(pm.x, w1.x, acc2[0][0]); acc2[0][1] = fmaf(pm.x, w1.y, acc2[0][1]);
        acc2[0][2] = fmaf(pm.x, w1.z, acc2[0][2]); acc2[0][3] = fmaf(pm.x, w1.w, acc2[0][3]);
        acc2[1][0] = fmaf(pm.y, w1.x, acc2[1][0]); acc2[1][1] = fmaf(pm.y, w1.y, acc2[1][1]);
        acc2[1][2] = fmaf(pm.y, w1.z, acc2[1][2]); acc2[1][3] = fmaf(pm.y, w1.w, acc2[1][3]);
        acc2[2][0] = fmaf(pm.z, w1.x, acc2[2][0]); acc2[2][1] = fmaf(pm.z, w1.y, acc2[2][1]);
        acc2[2][2] = fmaf(pm.z, w1.z, acc2[2][2]); acc2[2][3] = fmaf(pm.z, w1.w, acc2[2][3]);
        acc2[3][0] = fmaf(pm.w, w1.x, acc2[3][0]); acc2[3][1] = fmaf(pm.w, w1.y, acc2[3][1]);
        acc2[3][2] = fmaf(pm.w, w1.z, acc2[3][2]); acc2[3][3] = fmaf(pm.w, w1.w, acc2[3][3]);
    }
#pragma unroll
    for (int mq = 0; mq < 4; ++mq) {
        int n = nb + m0 + mq;
        if (n < N) {
            uint2 o;
            o.x = pack2(acc2[mq][0], acc2[mq][1]);
            o.y = pack2(acc2[mq][2], acc2[mq][3]);
            *reinterpret_cast<uint2*>(uout + (size_t)n * 64 + j0) = o;
        }
    }
}

// ---------------- gate: MFMA edge matmul; V-path negated (no per-edge negation in sigmoid) ----------
__global__ __launch_bounds__(256) void k_gate(
        const int* __restrict__ rowptr, const int* __restrict__ ranges,
        const __half* __restrict__ eap,
        const int* __restrict__ wth, const int* __restrict__ wgh,
        const float* __restrict__ be, const float* __restrict__ dv,
        const float* __restrict__ ets, const float* __restrict__ vs,
        const __half* __restrict__ u, __half* __restrict__ pre,
        float* __restrict__ s1, float* __restrict__ s2, int N) {
    __shared__ unsigned pvet[4][16][68];               // packed half2{-V, ET}, wave-private
    __shared__ float ls[2][4][H];
    int lane = threadIdx.x & 63;
    int wv = threadIdx.x >> 6;
    int w = (blockIdx.x << 2) | wv;
    int g = lane >> 4, li = lane & 15;
    // loop-invariant B fragments; bias row at k=16 (group 2, elem 0). V weights pre-negated in wgh.
    f16x8 Bet[4], Bv[4];
#pragma unroll
    for (int c = 0; c < 4; ++c) {
        int j = c * 16 + li;
        int4 bt = make_int4(0, 0, 0, 0), bv = make_int4(0, 0, 0, 0);
        if (g < 2) {
            bt = *reinterpret_cast<const int4*>(&wth[j * 8 + g * 4]);
            bv = *reinterpret_cast<const int4*>(&wgh[j * 8 + g * 4]);
        }
        Bet[c] = as_f16x8(bt);
        Bv[c] = as_f16x8(bv);
        if (g == 2) {
            Bet[c][0] = (_Float16)be[j];
            Bv[c][0]  = (_Float16)(-dv[j]);
        }
    }
    float ets_l = ets[lane], vs_l = vs[lane];
    int n0 = ranges[w], n1 = ranges[w + 1];
    float s = 0.f, ss = 0.f;
    if (n0 < n1) {
        const int4* gsrc = reinterpret_cast<const int4*>(eap);
        int e0 = rowptr[n0], e1 = rowptr[n1];
        int n = n0;
        int nend = rowptr[n0 + 1];
        size_t idx = (size_t)n * H + lane;
        float u_l = __half2float(u[idx]);
        float pv = __half2float(pre[idx]);
        int np = min(n + 1, n1 - 1);
        size_t idxn = (size_t)np * H + lane;
        float u_n = __half2float(u[idxn]);
        float pv_n = __half2float(pre[idxn]);
        float acc = sigm2(u_l + vs_l) * ets_l;   // folded self-loop contribution
        float nu = -u_l;
        // prefetch first tile's A-fragment (coalesced: 512B per tile, lanes 0..31)
        int4 afr = make_int4(0, 0, 0, 0);
        {
            int ei = e0 + li;
            if (g < 2 && ei < e1) afr = gsrc[(size_t)ei * 2 + g];
        }
        for (int tb = e0; tb < e1; tb += 16) {
            int4 afc = afr;
            afr = make_int4(0, 0, 0, 0);
            {
                int ei = tb + 16 + li;
                if (g < 2 && ei < e1) afr = gsrc[(size_t)ei * 2 + g];
            }
            f16x8 Af = as_f16x8(afc);
            if (g == 2) Af[0] = (_Float16)1.0f;    // bias column
            f32x4 z = {0.f, 0.f, 0.f, 0.f};
            f32x4 et0 = __builtin_amdgcn_mfma_f32_16x16x32_f16(Af, Bet[0], z, 0, 0, 0);
            f32x4 et1 = __builtin_amdgcn_mfma_f32_16x16x32_f16(Af, Bet[1], z, 0, 0, 0);
            f32x4 et2 = __builtin_amdgcn_mfma_f32_16x16x32_f16(Af, Bet[2], z, 0, 0, 0);
            f32x4 et3 = __builtin_amdgcn_mfma_f32_16x16x32_f16(Af, Bet[3], z, 0, 0, 0);
            f32x4 vv0 = __builtin_amdgcn_mfma_f32_16x16x32_f16(Af, Bv[0], z, 0, 0, 0);
            f32x4 vv1 = __builtin_amdgcn_mfma_f32_16x16x32_f16(Af, Bv[1], z, 0, 0, 0);
            f32x4 vv2 = __builtin_amdgcn_mfma_f32_16x16x32_f16(Af, Bv[2], z, 0, 0, 0);
            f32x4 vv3 = __builtin_amdgcn_mfma_f32_16x16x32_f16(Af, Bv[3], z, 0, 0, 0);
            int r0 = g * 4;
#pragma unroll
            for (int r = 0; r < 4; ++r) {
                pvet[wv][r0 + r][li]      = (unsigned)pack2(vv0[r], et0[r]);
                pvet[wv][r0 + r][16 + li] = (unsigned)pack2(vv1[r], et1[r]);
                pvet[wv][r0 + r][32 + li] = (unsigned)pack2(vv2[r], et2[r]);
                pvet[wv][r0 + r][48 + li] = (unsigned)pack2(vv3[r], et3[r]);
            }
            // ---- consume tile (channel = lane), absolute edge indices ----
            int pend = min(e1, tb + 16);
            int p = tb;
            while (p < pend) {
                while (p == nend) {           // node boundary: finish n, start next
                    float tval = pv + acc;
                    pre[idx] = __float2half(tval);
                    s += tval; ss += tval * tval;
                    ++n;
                    idx = idxn; u_l = u_n; pv = pv_n;
                    np = min(n + 1, n1 - 1);
                    idxn = (size_t)np * H + lane;
                    u_n = __half2float(u[idxn]);
                    pv_n = __half2float(pre[idxn]);
                    acc = sigm2(u_l + vs_l) * ets_l;
                    nu = -u_l;
                    nend = rowptr[n + 1];
                }
                int lim = min(pend, nend);
                for (; p + 3 < lim; p += 4) {
                    unsigned w0 = pvet[wv][p - tb][lane];
                    unsigned w1 = pvet[wv][p + 1 - tb][lane];
                    unsigned w2 = pvet[wv][p + 2 - tb][lane];
                    unsigned w3 = pvet[wv][p + 3 - tb][lane];
                    float2 f0 = up2(w0), f1 = up2(w1), f2 = up2(w2), f3 = up2(w3);
                    acc += sigm2n(nu + f0.x) * f0.y + sigm2n(nu + f1.x) * f1.y;
                    acc += sigm2n(nu + f2.x) * f2.y + sigm2n(nu + f3.x) * f3.y;
                }
                for (; p < lim; ++p) {
                    unsigned w0 = pvet[wv][p - tb][lane];
                    float2 f0 = up2(w0);
                    acc += sigm2n(nu + f0.x) * f0.y;
                }
            }
        }
        for (;;) {   // finish current + trailing zero-edge nodes
            float tval = pv + acc;
            pre[idx] = __float2half(tval);
            s += tval; ss += tval * tval;
            ++n;
            if (n >= n1) break;
            idx = idxn; u_l = u_n; pv = pv_n;
            np = min(n + 1, n1 - 1);
            idxn = (size_t)np * H + lane;
            u_n = __half2float(u[idxn]);
            pv_n = __half2float(pre[idxn]);
            acc = sigm2(u_l + vs_l) * ets_l;
            nu = -u_l;
        }
    }
    ls[0][wv][lane] = s; ls[1][wv][lane] = ss;
    __syncthreads();
    if (threadIdx.x < H) {
        float a = ls[0][0][lane] + ls[0][1][lane] + ls[0][2][lane] + ls[0][3][lane];
        float b = ls[1][0][lane] + ls[1][1][lane] + ls[1][2][lane] + ls[1][3][lane];
        atomicAdd(&s1[lane], a);
        atomicAdd(&s2[lane], b);
    }
}

// ---------------- apply: h = relu(2*bn(t)) -> f16, vectorized (uint2 = 4ch), + GraphNorm stats ------
__global__ __launch_bounds__(256) void k_apply(const __half* __restrict__ in, __half* __restrict__ outb,
                        const float* __restrict__ bng, const float* __restrict__ bnb,
                        const float* __restrict__ s1b, const float* __restrict__ s2b,
                        float* __restrict__ s1g, float* __restrict__ s2g, float Ninv, int N) {
    int tid = threadIdx.x;
    int cg = (tid & 15) * 4;          // channel group base
    int ty = tid >> 4;                // 0..15 node row
    __shared__ float As[H], Bs[H];
    __shared__ float red[2][16][H];
    if (tid < 64) {
        float mu = s1b[tid] * Ninv, var = s2b[tid] * Ninv - mu * mu;
        float r = rsqrtf(var + EPSV);
        float A = 2.f * bng[tid] * r;
        As[tid] = A; Bs[tid] = 2.f * (bnb[tid] - bng[tid] * r * mu);
    }
    __syncthreads();
    float A0 = As[cg], A1 = As[cg + 1], A2 = As[cg + 2], A3 = As[cg + 3];
    float B0 = Bs[cg], B1 = Bs[cg + 1], B2 = Bs[cg + 2], B3 = Bs[cg + 3];
    float s0 = 0.f, s1_ = 0.f, s2_ = 0.f, s3 = 0.f;
    float q0 = 0.f, q1 = 0.f, q2 = 0.f, q3 = 0.f;
    for (int n = blockIdx.x * 16 + ty; n < N; n += gridDim.x * 16) {
        size_t idx = (size_t)n * H + cg;
        uint2 hv = *reinterpret_cast<const uint2*>(in + idx);
        float2 f01 = up2(hv.x), f23 = up2(hv.y);
        float v0 = fmaxf(fmaf(A0, f01.x, B0), 0.f);
        float v1 = fmaxf(fmaf(A1, f01.y, B1), 0.f);
        float v2 = fmaxf(fmaf(A2, f23.x, B2), 0.f);
        float v3 = fmaxf(fmaf(A3, f23.y, B3), 0.f);
        uint2 o;
        o.x = (unsigned)pack2(v0, v1);
        o.y = (unsigned)pack2(v2, v3);
        *reinterpret_cast<uint2*>(outb + idx) = o;
        s0 += v0; s1_ += v1; s2_ += v2; s3 += v3;
        q0 += v0 * v0; q1 += v1 * v1; q2 += v2 * v2; q3 += v3 * v3;
    }
    *reinterpret_cast<float4*>(&red[0][ty][cg]) = make_float4(s0, s1_, s2_, s3);
    *reinterpret_cast<float4*>(&red[1][ty][cg]) = make_float4(q0, q1, q2, q3);
    __syncthreads();
    if (tid < H) {
        float a = 0.f, b = 0.f;
#pragma unroll
        for (int r = 0; r < 16; ++r) { a += red[0][r][tid]; b += red[1][r][tid]; }
        atomicAdd(&s1g[tid], a);
        atomicAdd(&s2g[tid], b);
    }
}

// ---------------- final: out = relu(gn2(h)) @ lin_W + lin_b ----------------
__global__ __launch_bounds__(256) void k_final(const __half* __restrict__ hraw, const float* __restrict__ W,
                        const float* __restrict__ bias,
                        const float* __restrict__ s1, const float* __restrict__ s2,
                        const float* __restrict__ gng, const float* __restrict__ gnb,
                        const float* __restrict__ gna, float Ninv,
                        float* __restrict__ outp, int N) {
    __shared__ float As[H], Bs[H];
    if (threadIdx.x < H) {
        int j = threadIdx.x;
        float mu = s1[j] * Ninv, m2 = s2[j] * Ninv, a = gna[j];
        float var = m2 - 2.f * a * mu * mu + a * a * mu * mu;
        float A = gng[j] * rsqrtf(var + EPSV);
        As[j] = A; Bs[j] = gnb[j] - A * a * mu;
    }
    __syncthreads();
    int n = blockIdx.x * blockDim.x + threadIdx.x;
    if (n >= N) return;
    float o[CO];
#pragma unroll
    for (int t = 0; t < CO; ++t) o[t] = bias[t];
    const __half* hr = hraw + (size_t)n * H;
    for (int m4 = 0; m4 < H / 4; ++m4) {
        uint2 hv = *reinterpret_cast<const uint2*>(hr + m4 * 4);
        float2 f01 = up2(hv.x), f23 = up2(hv.y);
        float hx = fmaxf(fmaf(As[m4*4+0], f01.x, Bs[m4*4+0]), 0.f);
        float hy = fmaxf(fmaf(As[m4*4+1], f01.y, Bs[m4*4+1]), 0.f);
        float hz = fmaxf(fmaf(As[m4*4+2], f23.x, Bs[m4*4+2]), 0.f);
        float hw = fmaxf(fmaf(As[m4*4+3], f23.y, Bs[m4*4+3]), 0.f);
#pragma unroll
        for (int t = 0; t < CO; ++t) {
            o[t] += hx * W[(m4*4+0) * CO + t];
            o[t] += hy * W[(m4*4+1) * CO + t];
            o[t] += hz * W[(m4*4+2) * CO + t];
            o[t] += hw * W[(m4*4+3) * CO + t];
        }
    }
    float* orow = outp + (size_t)n * CO;
#pragma unroll
    for (int t4 = 0; t4 < CO / 4; ++t4)
        reinterpret_cast<float4*>(orow)[t4] = make_float4(o[t4*4+0], o[t4*4+1], o[t4*4+2], o[t4*4+3]);
}

extern "C" void kernel_launch(void* const* d_in, const int* in_sizes, int n_in,
                              void* d_out, int out_size, void* d_ws, size_t ws_size,
                              hipStream_t stream) {
    const float* x     = (const float*)d_in[0];
    const int*   ei    = (const int*)d_in[1];
    const float* ea    = (const float*)d_in[2];
    const float* l1_Wl = (const float*)d_in[3];  const float* l1_bl = (const float*)d_in[4];
    const float* l1_Wr = (const float*)d_in[5];  const float* l1_We = (const float*)d_in[6];
    const float* l1_be = (const float*)d_in[7];  const float* l1_Wg = (const float*)d_in[8];
    const float* l1_bg = (const float*)d_in[9];  const float* l1_bng= (const float*)d_in[10];
    const float* l1_bnb= (const float*)d_in[11];
    const float* l2_Wl = (const float*)d_in[12]; const float* l2_bl = (const float*)d_in[13];
    const float* l2_Wr = (const float*)d_in[14]; const float* l2_We = (const float*)d_in[15];
    const float* l2_be = (const float*)d_in[16]; const float* l2_Wg = (const float*)d_in[17];
    const float* l2_bg = (const float*)d_in[18]; const float* l2_bng= (const float*)d_in[19];
    const float* l2_bnb= (const float*)d_in[20];
    const float* gn1_g = (const float*)d_in[21]; const float* gn1_b = (const float*)d_in[22];
    const float* gn1_a = (const float*)d_in[23];
    const float* gn2_g = (const float*)d_in[24]; const float* gn2_b = (const float*)d_in[25];
    const float* gn2_a = (const float*)d_in[26];
    const float* lin_W = (const float*)d_in[27]; const float* lin_b = (const float*)d_in[28];

    const int N = in_sizes[0] / 32;
    const int E = in_sizes[1] / 2;
    const int* rows = ei;
    const int* cols = ei + E;

    // bucket geometry
    int SH = 7, NPB = 128;
    while (((N + NPB - 1) >> SH) > 1024) { SH++; NPB <<= 1; }
    const int NB = (N + NPB - 1) >> SH;
    const int PB = (E + CPART - 1) / CPART;

    float* w    = (float*)d_ws;
    int* wth1   = (int*)w;
    int* wgh1   = (int*)(w + 512);
    int* wth2   = (int*)(w + 1024);
    int* wgh2   = (int*)(w + 1536);
    float* ets1 = w + 2048; float* vs1 = w + 2112; float* dv1 = w + 2176;
    float* ets2 = w + 2240; float* vs2 = w + 2304; float* dv2 = w + 2368;
    float* stats= w + 2432;

    int* ip     = (int*)(w + 8192);
    int* rowptr = ip;                 // N+1 (persistent)
    int* cnt    = ip + (N + 1);       // N
    int* bs     = cnt + N;            // 1024
    int* ranges = bs + 1024;          // NWAVES+2 (persistent)
    int* erow   = ranges + (NWAVES + 2);  // E (persistent)

    uintptr_t pa = (uintptr_t)(erow + E);
    pa = (pa + 255) & ~(uintptr_t)255;
    __half* eap = (__half*)pa;        // E*16 halves (persistent)
    uintptr_t px = (uintptr_t)(eap + (size_t)E * ED);
    px = (px + 255) & ~(uintptr_t)255;
    __half* xh = (__half*)px;         // N*32 halves (persistent)
    uintptr_t pz = (uintptr_t)(xh + (size_t)N * 32);
    pz = (pz + 255) & ~(uintptr_t)255;

    // --- overlap zone: {tmpk, tmpp, offtab} (CSR build) then {Bagg, Bpre, Bu, B3h} (layers) ---
    int2* tmpk  = (int2*)pz;                       // E
    int4* tmpp  = (int4*)(tmpk + E);               // E*2 (32B/edge payload)
    int* offtab = (int*)(tmpp + (size_t)E * 2);    // PB*(NB+1)

    size_t NB64 = (size_t)N * H;
    __half* Bagg = (__half*)pz;                    // agg (f16) — aliases tmpk/tmpp/offtab
    __half* Bpre = Bagg + NB64;                    // pre/t (f16)
    __half* Bu   = Bpre + NB64;                    // u (f16)
    __half* B3h  = Bu + NB64;                      // h layer1 (f16)
    __half* B0h  = Bagg;                           // h layer2 reuses agg space

    const float Ninv = 1.0f / (float)N;
    int ngrid = (N + 255) / 256;
    int g64 = (N + 63) / 64;
    const int SB = (N + 1023) >> 10;

    k_prep<<<1, 64, 0, stream>>>(l1_We, l1_be, l1_Wg, l2_We, l2_be, l2_Wg, w);
    k_xh<<<(N * 8 + 255) / 256, 256, 0, stream>>>(x, xh, N * 8);

    // ---- CSR build: payload-carrying partition (count fused) -> scan -> streaming build ----
    hipMemsetAsync(cnt, 0, sizeof(int) * (size_t)N, stream);
    k_part<<<PB, 256, 0, stream>>>(rows, cols, ea, tmpk, tmpp, offtab, cnt, E, NB, SH);
    k_scan1<<<SB, 1024, 0, stream>>>(cnt, bs, N);
    k_scan2<<<1, 1024, 0, stream>>>(bs, SB);
    k_scan3<<<SB, 1024, 0, stream>>>(cnt, bs, rowptr, N, E);
    k_ranges<<<(NWAVES + 256) / 256, 256, 0, stream>>>(rowptr, ranges, N, E, NWAVES);
    k_build<<<NB, 1024, 0, stream>>>(rowptr, tmpk, tmpp, offtab, erow, eap, N, NB, SH, PB);

    // ---- layer 1 ----
    k_gather<32, false><<<WGRID, 256, 0, stream>>>(xh, rowptr, ranges, erow, Bagg,
                                                   nullptr, nullptr, nullptr, nullptr, nullptr, 0.f, N);
    k_gemmfu<32, false><<<g64, 256, 0, stream>>>(Bagg, xh, 32, l1_Wl, l1_Wr, l1_bl, l1_Wg, l1_bg,
                                                 nullptr, nullptr, nullptr, nullptr, nullptr, 0.f,
                                                 rowptr, Bpre, Bu, N);
    k_gate<<<WGRID, 256, 0, stream>>>(rowptr, ranges, eap, wth1, wgh1, l1_be, dv1, ets1, vs1,
                                      Bu, Bpre, stats + 0, stats + 64, N);
    k_apply<<<256, 256, 0, stream>>>(Bpre, B3h, l1_bng, l1_bnb, stats + 0, stats + 64,
                                     stats + 128, stats + 192, Ninv, N);

    // ---- layer 2 (gn1 folded into readers of B3h) ----
    k_gather<64, true><<<WGRID, 256, 0, stream>>>(B3h, rowptr, ranges, erow, Bagg,
                                                  stats + 128, stats + 192, gn1_g, gn1_b, gn1_a, Ninv, N);
    k_gemmfu<64, true><<<g64, 256, 0, stream>>>(Bagg, B3h, 64, l2_Wl, l2_Wr, l2_bl, l2_Wg, l2_bg,
                                                stats + 128, stats + 192, gn1_g, gn1_b, gn1_a, Ninv,
                                                rowptr, Bpre, Bu, N);
    k_gate<<<WGRID, 256, 0, stream>>>(rowptr, ranges, eap, wth2, wgh2, l2_be, dv2, ets2, vs2,
                                      Bu, Bpre, stats + 256, stats + 320, N);
    k_apply<<<256, 256, 0, stream>>>(Bpre, B0h, l2_bng, l2_bnb, stats + 256, stats + 320,
                                     stats + 384, stats + 448, Ninv, N);

    // ---- final ----
    k_final<<<ngrid, 256, 0, stream>>>(B0h, lin_W, lin_b, stats + 384, stats + 448,
                                       gn2_g, gn2_b, gn2_a, Ninv, (float*)d_out, N);
}